// Round 1
// baseline (11540.004 us; speedup 1.0000x reference)
//
#include <hip/hip_runtime.h>

// ComTransformer on MI355X — round 1: correct fp32 implementation.
// Structure exploited:
//  - imag-branch softmax of real-input com_attn is q-independent (rank-1 output)
//  - mk/c3 cross-attentions share softmax matrices; mk values are label bcast
//  - t1i rows identical -> single vb vector per batch, score bias fused in softmax

namespace {

constexpr int kNI = 3;     // images per set
constexpr int kB  = 8;     // batch
constexpr int kD  = 512;   // feature dim
constexpr int kKD = 128;   // key dim (self/cross)
constexpr int kHW = 484;   // 22*22
constexpr int kL  = kNI * kHW;  // 1452
constexpr float kTemp = 30.0f;
constexpr float kCnt  = 247808.0f;             // d*h*w = 512*484
constexpr float kScaleN = 0.011048543456039806f; // sqrt(1/(512*16))

#define CDIV(a, b) (((a) + (b) - 1) / (b))

__device__ __forceinline__ float wsum(float v) {
#pragma unroll
  for (int o = 32; o; o >>= 1) v += __shfl_down(v, o);
  return v;
}
__device__ __forceinline__ float wmax(float v) {
#pragma unroll
  for (int o = 32; o; o >>= 1) v = fmaxf(v, __shfl_down(v, o));
  return v;
}

// ---------------- layout transform: [n,b,d,hw] -> seq [(n*hw),b,d] ----------------
__global__ void k_toseq(const float* __restrict__ in, float* __restrict__ out) {
  __shared__ float tile[32][33];
  int nb = blockIdx.z;
  int n = nb / kB, b = nb % kB;
  int p0 = blockIdx.x * 32, d0 = blockIdx.y * 32;
  int tx = threadIdx.x, ty = threadIdx.y;  // (32, 8)
  const float* ip = in + (long)nb * kD * kHW;
#pragma unroll
  for (int j = 0; j < 4; ++j) {
    int d = d0 + ty + j * 8, p = p0 + tx;
    if (d < kD && p < kHW) tile[ty + j * 8][tx] = ip[(long)d * kHW + p];
  }
  __syncthreads();
#pragma unroll
  for (int j = 0; j < 4; ++j) {
    int p = p0 + ty + j * 8, d = d0 + tx;
    if (p < kHW && d < kD)
      out[((long)(n * kHW + p) * kB + b) * kD + d] = tile[tx][ty + j * 8];
  }
}

// lab[(n*hw+p)*B + b] = train_label[n,b,p]
__global__ void k_lab(const float* __restrict__ tl, float* __restrict__ lab) {
  long i = (long)blockIdx.x * 256 + threadIdx.x;
  const long tot = (long)kNI * kB * kHW;
  if (i >= tot) return;
  int p = (int)(i % kHW);
  long t = i / kHW;
  int b = (int)(t % kB);
  int n = (int)(t / kB);
  lab[(long)(n * kHW + p) * kB + b] = tl[i];
}

// u = b / max(||b||, 1e-12)
__global__ void k_l2n_vec(const float* __restrict__ src, float* __restrict__ u, int C) {
  __shared__ float red[2];
  int tid = threadIdx.x;  // 128
  float s = 0.f;
  for (int c = tid; c < C; c += 128) { float x = src[c]; s += x * x; }
  s = wsum(s);
  if ((tid & 63) == 0) red[tid >> 6] = s;
  __syncthreads();
  float inv = 1.f / fmaxf(sqrtf(red[0] + red[1]), 1e-12f);
  for (int c = tid; c < C; c += 128) u[c] = src[c] * inv;
}

// ---------------- generic tiled GEMM: C[m,n] (+)= sum_k A[m,k] * B(n|k) -----------
// BT=true:  B element [n][k] at B[n*ldb + k]  (NT form)
// BT=false: B element [k][n] at B[k*ldb + n]  (NN form)
template <bool BT, bool ACC>
__global__ __launch_bounds__(256) void k_gemm(
    const float* __restrict__ A, const float* __restrict__ B, float* __restrict__ C,
    int M, int N, int K, int lda, int ldb, int ldc, long sAb, long sBb, long sCb) {
  A += (long)blockIdx.z * sAb;
  B += (long)blockIdx.z * sBb;
  C += (long)blockIdx.z * sCb;
  const int m0 = blockIdx.y * 64;
  const int n0 = blockIdx.x * 64;
  const int tid = threadIdx.x;
  __shared__ __align__(16) float As[16][64];
  __shared__ __align__(16) float Bs[16][64];
  float acc[4][4] = {};
  const int ty = tid / 16, tx = tid % 16;
  const int am = tid >> 2;        // 0..63
  const int ak = (tid & 3) * 4;   // 0,4,8,12

  for (int k0 = 0; k0 < K; k0 += 16) {
    {
      int gm = m0 + am;
#pragma unroll
      for (int i = 0; i < 4; ++i) {
        int gk = k0 + ak + i;
        float v = 0.f;
        if (gm < M && gk < K) v = A[(long)gm * lda + gk];
        As[ak + i][am] = v;
      }
    }
    if (BT) {
      int gn = n0 + am;
#pragma unroll
      for (int i = 0; i < 4; ++i) {
        int gk = k0 + ak + i;
        float v = 0.f;
        if (gn < N && gk < K) v = B[(long)gn * ldb + gk];
        Bs[ak + i][am] = v;
      }
    } else {
      int gn = n0 + (tid & 63);
      int kk = tid >> 6;  // 0..3
#pragma unroll
      for (int i = 0; i < 4; ++i) {
        int gk = k0 + kk + i * 4;
        float v = 0.f;
        if (gn < N && gk < K) v = B[(long)gk * ldb + gn];
        Bs[kk + i * 4][tid & 63] = v;
      }
    }
    __syncthreads();
#pragma unroll
    for (int kk = 0; kk < 16; ++kk) {
      float4 a4 = *reinterpret_cast<const float4*>(&As[kk][ty * 4]);
      float4 b4 = *reinterpret_cast<const float4*>(&Bs[kk][tx * 4]);
      float av[4] = {a4.x, a4.y, a4.z, a4.w};
      float bv[4] = {b4.x, b4.y, b4.z, b4.w};
#pragma unroll
      for (int i = 0; i < 4; ++i)
#pragma unroll
        for (int j = 0; j < 4; ++j) acc[i][j] += av[i] * bv[j];
    }
    __syncthreads();
  }
#pragma unroll
  for (int i = 0; i < 4; ++i) {
    int gm = m0 + ty * 4 + i;
    if (gm >= M) continue;
#pragma unroll
    for (int j = 0; j < 4; ++j) {
      int gn = n0 + tx * 4 + j;
      if (gn >= N) continue;
      long idx = (long)gm * ldc + gn;
      C[idx] = (ACC ? C[idx] : 0.f) + acc[i][j];
    }
  }
}

// row += bias; row /= max(||row||,1e-12).  C in {128, 512}, block 128.
__global__ void k_bias_l2n(float* __restrict__ P, const float* __restrict__ bias, int C) {
  __shared__ float red[2];
  long row = blockIdx.x;
  float* p = P + row * C;
  int tid = threadIdx.x;
  int nv = C >> 7;
  float v[4];
  float s = 0.f;
#pragma unroll
  for (int i = 0; i < 4; ++i)
    if (i < nv) {
      float x = p[tid + (i << 7)] + bias[tid + (i << 7)];
      v[i] = x;
      s += x * x;
    }
  s = wsum(s);
  if ((tid & 63) == 0) red[tid >> 6] = s;
  __syncthreads();
  float inv = 1.f / fmaxf(sqrtf(red[0] + red[1]), 1e-12f);
#pragma unroll
  for (int i = 0; i < 4; ++i)
    if (i < nv) p[tid + (i << 7)] = v[i] * inv;
}

// g[b*L + k] = u . P[k,b,:]
__global__ void k_rowdot(const float* __restrict__ P, const float* __restrict__ u,
                         float* __restrict__ g, int L, int C) {
  int idx = blockIdx.x;
  int k = idx / kB, b = idx % kB;
  const float* p = P + ((long)k * kB + b) * C;
  int lane = threadIdx.x;  // 64
  float s = 0.f;
  for (int c = lane; c < C; c += 64) s += u[c] * p[c];
  s = wsum(s);
  if (lane == 0) g[(long)b * L + k] = s;
}

// softmax rows of S [B*Lq, Lk] in place: softmax(30*(S + bsign*bias[b,k]));
// optional mk[q*B+b] = sum_k p*lab[k*B+b]
__global__ __launch_bounds__(256) void k_softmax(float* __restrict__ S, int Lq, int Lk,
                                                 const float* __restrict__ bias, float bsign,
                                                 const float* __restrict__ lab,
                                                 float* __restrict__ mk) {
  __shared__ float sm[1456];
  __shared__ float red[4];
  int row = blockIdx.x;
  int b = row / Lq, q = row - b * Lq;
  float* Sr = S + (long)row * Lk;
  int tid = threadIdx.x;
  float mx = -3.0e38f;
  for (int k = tid; k < Lk; k += 256) {
    float v = Sr[k];
    if (bias) v += bsign * bias[(long)b * Lk + k];
    v *= kTemp;
    sm[k] = v;
    mx = fmaxf(mx, v);
  }
  mx = wmax(mx);
  if ((tid & 63) == 0) red[tid >> 6] = mx;
  __syncthreads();
  mx = fmaxf(fmaxf(red[0], red[1]), fmaxf(red[2], red[3]));
  __syncthreads();
  float s = 0.f;
  for (int k = tid; k < Lk; k += 256) {
    float e = expf(sm[k] - mx);
    sm[k] = e;
    s += e;
  }
  s = wsum(s);
  if ((tid & 63) == 0) red[tid >> 6] = s;
  __syncthreads();
  float inv = 1.0f / (red[0] + red[1] + red[2] + red[3]);
  __syncthreads();
  float dot = 0.f;
  for (int k = tid; k < Lk; k += 256) {
    float p = sm[k] * inv;
    Sr[k] = p;
    if (lab) dot += p * lab[(long)k * kB + b];
  }
  if (lab) {
    dot = wsum(dot);
    if ((tid & 63) == 0) red[tid >> 6] = dot;
    __syncthreads();
    if (tid == 0) mk[(long)q * kB + b] = red[0] + red[1] + red[2] + red[3];
  }
}

// rowout[b,d] = sum_k w[b*L+k] * S[k,b,d]
__global__ void k_wrowsum(const float* __restrict__ w, const float* __restrict__ S,
                          float* __restrict__ rowout, int L) {
  int b = blockIdx.y;
  int d = blockIdx.x * 128 + threadIdx.x;
  float s = 0.f;
  for (int k = 0; k < L; ++k) s += w[(long)b * L + k] * S[((long)k * kB + b) * kD + d];
  rowout[(long)b * kD + d] = s;
}

// elementwise ops for inorm pipeline.  r = row index = l*B + b, D = 512 fixed.
// OP 0: A[r,d]+B2[r,d]   OP 1: A[b,d] (broadcast)   OP 2: A[r,d]*B2[r]
template <int OP>
__device__ __forceinline__ float opval(const float* __restrict__ A,
                                       const float* __restrict__ B2, long r, int b, int d) {
  if (OP == 0) return A[r * kD + d] + B2[r * kD + d];
  if (OP == 1) return A[(long)b * kD + d];
  return A[r * kD + d] * B2[r];
}

template <int OP>
__global__ __launch_bounds__(256) void k_ss_op(const float* __restrict__ A,
                                               const float* __restrict__ B2,
                                               float* __restrict__ ss) {
  __shared__ float red[4];
  long r = blockIdx.x;
  int l = (int)(r / kB), b = (int)(r % kB);
  int g = (l / kHW) * kB + b;
  int tid = threadIdx.x;
  float z0 = opval<OP>(A, B2, r, b, tid);
  float z1 = opval<OP>(A, B2, r, b, tid + 256);
  float s = z0 * z0 + z1 * z1;
  s = wsum(s);
  if ((tid & 63) == 0) red[tid >> 6] = s;
  __syncthreads();
  if (tid == 0) atomicAdd(&ss[g], red[0] + red[1] + red[2] + red[3]);
}

template <int OP>
__global__ __launch_bounds__(256) void k_scale_op(const float* __restrict__ A,
                                                  const float* __restrict__ B2,
                                                  const float* __restrict__ ss,
                                                  float* __restrict__ outp) {
  long r = blockIdx.x;
  int l = (int)(r / kB), b = (int)(r % kB);
  int tid = threadIdx.x;
  float fac = 1.0f;
  if (ss) {
    int g = (l / kHW) * kB + b;
    fac = kScaleN * sqrtf(kCnt / (ss[g] + 1e-5f));
  }
  outp[r * kD + tid] = opval<OP>(A, B2, r, b, tid) * fac;
  outp[r * kD + tid + 256] = opval<OP>(A, B2, r, b, tid + 256) * fac;
}

// vb[b,:] = l2n(t1i_row_b @ WkC + bkC)   (t1i rows identical; read row q=0)
__global__ void k_vb(const float* __restrict__ t1i, const float* __restrict__ Wk,
                     const float* __restrict__ bk, float* __restrict__ vb) {
  __shared__ float red[2];
  int b = blockIdx.x;
  int j = threadIdx.x;  // 128
  const float* row = t1i + (long)b * kD;
  float acc = bk[j];
  for (int d = 0; d < kD; ++d) acc += row[d] * Wk[(long)d * kKD + j];
  float s = acc * acc;
  s = wsum(s);
  if ((j & 63) == 0) red[j >> 6] = s;
  __syncthreads();
  float inv = 1.f / fmaxf(sqrtf(red[0] + red[1]), 1e-12f);
  vb[(long)b * kKD + j] = acc * inv;
}

// cR[b*L+k] = vb_b . Kr[k,b,:], cI likewise with Ki
__global__ void k_cRcI(const float* __restrict__ vb, const float* __restrict__ Kr,
                       const float* __restrict__ Ki, float* __restrict__ cR,
                       float* __restrict__ cI) {
  int idx = blockIdx.x;
  int k = idx / kB, b = idx % kB;
  int lane = threadIdx.x;  // 64
  const float* v = vb + (long)b * kKD;
  const float* pr = Kr + ((long)k * kB + b) * kKD;
  const float* pi = Ki + ((long)k * kB + b) * kKD;
  float sR = 0.f, sI = 0.f;
  for (int c = lane; c < kKD; c += 64) {
    sR += v[c] * pr[c];
    sI += v[c] * pi[c];
  }
  sR = wsum(sR);
  sI = wsum(sI);
  if (lane == 0) {
    cR[(long)b * kL + k] = sR;
    cI[(long)b * kL + k] = sI;
  }
}

void launch_gemm(bool bt, bool acc, hipStream_t s, const float* A, const float* B, float* C,
                 int M, int N, int K, int lda, int ldb, int ldc, long sAb, long sBb, long sCb,
                 int batch) {
  dim3 grd(CDIV(N, 64), CDIV(M, 64), batch), blk(256);
  if (bt && !acc)
    k_gemm<true, false><<<grd, blk, 0, s>>>(A, B, C, M, N, K, lda, ldb, ldc, sAb, sBb, sCb);
  else if (bt && acc)
    k_gemm<true, true><<<grd, blk, 0, s>>>(A, B, C, M, N, K, lda, ldb, ldc, sAb, sBb, sCb);
  else
    k_gemm<false, false><<<grd, blk, 0, s>>>(A, B, C, M, N, K, lda, ldb, ldc, sAb, sBb, sCb);
}

}  // namespace

extern "C" void kernel_launch(void* const* d_in, const int* in_sizes, int n_in, void* d_out,
                              int out_size, void* d_ws, size_t ws_size, hipStream_t stream) {
  (void)in_sizes; (void)n_in; (void)out_size;
  const float* tf  = (const float*)d_in[0];
  const float* sf  = (const float*)d_in[1];
  const float* tl  = (const float*)d_in[2];
  const float* WkE = (const float*)d_in[3];
  const float* bkE = (const float*)d_in[4];
  const float* WkS = (const float*)d_in[5];
  const float* bkS = (const float*)d_in[6];
  const float* WkC = (const float*)d_in[7];
  const float* bkC = (const float*)d_in[8];
  const float* Wc  = (const float*)d_in[9];
  float* out = (float*)d_out;
  float* ws = (float*)d_ws;

  const long LBD = (long)kL * kB * kD;    // 5,947,392
  const long LBK = (long)kL * kB * kKD;   // 1,486,848
  const long HBD = (long)kHW * kB * kD;   // 1,982,464
  const long HBK = (long)kHW * kB * kKD;  // 495,616

  long off = 0;
  auto alloc = [&](long n) {
    long o = off;
    off += (n + 255) & ~255L;
    return o;
  };
  long o_seqT = alloc(LBD);
  long o_seqS = alloc(LBD);
  long o_Kr = alloc(LBK);
  long o_Ki = alloc(LBK);
  long o_Vr = alloc(LBD);
  long o_lab = alloc((long)kL * kB);
  long o_uE = alloc(kD);
  long o_uS = alloc(kKD);
  long o_vb = alloc((long)kB * kKD);
  long o_g = alloc((long)kB * kL);
  long o_cR = alloc((long)kB * kL);
  long o_cI = alloc((long)kB * kL);
  long o_row = alloc((long)kB * kD);
  long o_mkr = alloc((long)kHW * kB);
  long o_mki = alloc((long)kHW * kB);
  long o_ss = alloc(64);
  long o_scr = off;
  // encoder overlay
  long o_Pe = o_scr;
  long o_Ae = o_Pe + LBD;
  long o_ar = o_Ae + (long)kB * kL * kL;
  long o_mr = o_ar + LBD;
  long o_mi = o_mr + LBD;
  long total = o_mi + LBD;
  // per-image overlay (same scratch region, encoder done first)
  long o_Ps = o_scr;
  long o_Pc = o_Ps + HBK;
  long o_As = o_Pc + HBK;
  long o_S1 = o_As + (long)kB * kHW * kHW;
  long o_S2 = o_S1 + (long)kB * kHW * kL;
  long o_t1r = o_S2 + (long)kB * kHW * kL;
  long o_t1i = o_t1r + HBD;
  long o_c3r = o_t1i + HBD;
  long o_c3i = o_c3r + HBD;
  long o_t2r = o_c3i + HBD;
  long o_t2i = o_t2r + HBD;

  if ((size_t)total * sizeof(float) > ws_size) return;  // insufficient workspace

  float* seqT = ws + o_seqT;
  float* seqS = ws + o_seqS;
  float* Kr = ws + o_Kr;
  float* Ki = ws + o_Ki;
  float* Vr = ws + o_Vr;
  float* lab = ws + o_lab;
  float* uE = ws + o_uE;
  float* uS = ws + o_uS;
  float* vb = ws + o_vb;
  float* g_ = ws + o_g;
  float* cR = ws + o_cR;
  float* cI = ws + o_cI;
  float* row = ws + o_row;
  float* mkr = ws + o_mkr;
  float* mki = ws + o_mki;
  float* ssp = ws + o_ss;
  float* Pe = ws + o_Pe;
  float* Ae = ws + o_Ae;
  float* ar = ws + o_ar;
  float* mr = ws + o_mr;
  float* mi = ws + o_mi;
  float* Ps = ws + o_Ps;
  float* Pc = ws + o_Pc;
  float* As_ = ws + o_As;
  float* S1 = ws + o_S1;
  float* S2 = ws + o_S2;
  float* t1r = ws + o_t1r;
  float* t1i = ws + o_t1i;
  float* c3r = ws + o_c3r;
  float* c3i = ws + o_c3i;
  float* t2r = ws + o_t2r;
  float* t2i = ws + o_t2i;

  // ---- stage 0: layout + constants ----
  {
    dim3 grd(CDIV(kHW, 32), CDIV(kD, 32), kNI * kB), blk(32, 8);
    k_toseq<<<grd, blk, 0, stream>>>(tf, seqT);
    k_toseq<<<grd, blk, 0, stream>>>(sf, seqS);
  }
  k_lab<<<CDIV(kNI * kB * kHW, 256), 256, 0, stream>>>(tl, lab);
  k_l2n_vec<<<1, 128, 0, stream>>>(bkE, uE, kD);
  k_l2n_vec<<<1, 128, 0, stream>>>(bkS, uS, kKD);

  // ---- encoder ----
  launch_gemm(false, false, stream, seqT, WkE, Pe, kL * kB, kD, kD, kD, kD, kD, 0, 0, 0, 1);
  k_bias_l2n<<<kL * kB, 128, 0, stream>>>(Pe, bkE, kD);
  k_rowdot<<<kL * kB, 64, 0, stream>>>(Pe, uE, g_, kL, kD);
  k_softmax<<<kB, 256, 0, stream>>>(g_, 1, kL, nullptr, 0.f, nullptr, nullptr);  // wi_en
  launch_gemm(true, false, stream, Pe, Pe, Ae, kL, kL, kD, kB * kD, kB * kD, kL, kD, kD,
              (long)kL * kL, kB);
  k_softmax<<<kB * kL, 256, 0, stream>>>(Ae, kL, kL, nullptr, 0.f, nullptr, nullptr);
  launch_gemm(false, false, stream, Ae, seqT, ar, kL, kD, kL, kL, kB * kD, kB * kD,
              (long)kL * kL, kD, kD, kB);
  k_wrowsum<<<dim3(kD / 128, kB), 128, 0, stream>>>(g_, seqT, row, kL);  // ai row
  // mem_r = inorm(seqT + ar)
  hipMemsetAsync(ssp, 0, 64 * sizeof(float), stream);
  k_ss_op<0><<<kL * kB, 256, 0, stream>>>(seqT, ar, ssp);
  k_scale_op<0><<<kL * kB, 256, 0, stream>>>(seqT, ar, ssp, mr);
  // mem_i = inorm(bcast ai row)
  hipMemsetAsync(ssp, 0, 64 * sizeof(float), stream);
  k_ss_op<1><<<kL * kB, 256, 0, stream>>>(row, nullptr, ssp);
  k_scale_op<1><<<kL * kB, 256, 0, stream>>>(row, nullptr, ssp, mi);
  // Kr/Ki = l2n(mem @ WkC + bkC)
  launch_gemm(false, false, stream, mr, WkC, Kr, kL * kB, kKD, kD, kD, kKD, kKD, 0, 0, 0, 1);
  k_bias_l2n<<<kL * kB, 128, 0, stream>>>(Kr, bkC, kKD);
  launch_gemm(false, false, stream, mi, WkC, Ki, kL * kB, kKD, kD, kD, kKD, kKD, 0, 0, 0, 1);
  k_bias_l2n<<<kL * kB, 128, 0, stream>>>(Ki, bkC, kKD);
  // Vr = mem_r * lab
  k_scale_op<2><<<kL * kB, 256, 0, stream>>>(mr, lab, nullptr, Vr);

  // ---- decoder: 3 train images then 3 test images ----
  for (int img = 0; img < 6; ++img) {
    const float* t = (img < 3) ? (seqT + (long)img * HBD) : (seqS + (long)(img - 3) * HBD);
    float* osl = out + (long)img * kB * kD * kHW;

    // self-attention
    launch_gemm(false, false, stream, t, WkS, Ps, kHW * kB, kKD, kD, kD, kKD, kKD, 0, 0, 0, 1);
    k_bias_l2n<<<kHW * kB, 128, 0, stream>>>(Ps, bkS, kKD);
    k_rowdot<<<kHW * kB, 64, 0, stream>>>(Ps, uS, g_, kHW, kKD);
    k_softmax<<<kB, 256, 0, stream>>>(g_, 1, kHW, nullptr, 0.f, nullptr, nullptr);  // wi_s
    launch_gemm(true, false, stream, Ps, Ps, As_, kHW, kHW, kKD, kB * kKD, kB * kKD, kHW, kKD,
                kKD, (long)kHW * kHW, kB);
    k_softmax<<<kB * kHW, 256, 0, stream>>>(As_, kHW, kHW, nullptr, 0.f, nullptr, nullptr);
    launch_gemm(false, false, stream, As_, t, c3r, kHW, kD, kHW, kHW, kB * kD, kB * kD,
                (long)kHW * kHW, kD, kD, kB);  // s2r (staged in c3r)
    k_wrowsum<<<dim3(kD / 128, kB), 128, 0, stream>>>(g_, t, row, kHW);  // s2i row
    // t1r = inorm(t + s2r); t1i = inorm(bcast s2i)
    hipMemsetAsync(ssp, 0, 64 * sizeof(float), stream);
    k_ss_op<0><<<kHW * kB, 256, 0, stream>>>(t, c3r, ssp);
    k_scale_op<0><<<kHW * kB, 256, 0, stream>>>(t, c3r, ssp, t1r);
    hipMemsetAsync(ssp, 0, 64 * sizeof(float), stream);
    k_ss_op<1><<<kHW * kB, 256, 0, stream>>>(row, nullptr, ssp);
    k_scale_op<1><<<kHW * kB, 256, 0, stream>>>(row, nullptr, ssp, t1i);
    // cross-attention (shared by mk and c3)
    k_vb<<<kB, 128, 0, stream>>>(t1i, WkC, bkC, vb);
    launch_gemm(false, false, stream, t1r, WkC, Pc, kHW * kB, kKD, kD, kD, kKD, kKD, 0, 0, 0, 1);
    k_bias_l2n<<<kHW * kB, 128, 0, stream>>>(Pc, bkC, kKD);
    k_cRcI<<<kL * kB, 64, 0, stream>>>(vb, Kr, Ki, cR, cI);
    launch_gemm(true, false, stream, Pc, Kr, S1, kHW, kL, kKD, kB * kKD, kB * kKD, kL, kKD, kKD,
                (long)kHW * kL, kB);
    launch_gemm(true, false, stream, Pc, Ki, S2, kHW, kL, kKD, kB * kKD, kB * kKD, kL, kKD, kKD,
                (long)kHW * kL, kB);
    k_softmax<<<kB * kHW, 256, 0, stream>>>(S1, kHW, kL, cI, -1.f, lab, mkr);  // Ar, mkr
    k_softmax<<<kB * kHW, 256, 0, stream>>>(S2, kHW, kL, cR, +1.f, lab, mki);  // Ai, mki
    launch_gemm(false, false, stream, S1, Vr, c3r, kHW, kD, kL, kL, kB * kD, kB * kD,
                (long)kHW * kL, kD, kD, kB);
    launch_gemm(false, false, stream, S2, Vr, c3i, kHW, kD, kL, kL, kB * kD, kB * kD,
                (long)kHW * kL, kD, kD, kB);
    // t2 = inorm(t1 * mk)
    hipMemsetAsync(ssp, 0, 64 * sizeof(float), stream);
    k_ss_op<2><<<kHW * kB, 256, 0, stream>>>(t1r, mkr, ssp);
    k_scale_op<2><<<kHW * kB, 256, 0, stream>>>(t1r, mkr, ssp, t2r);
    hipMemsetAsync(ssp, 0, 64 * sizeof(float), stream);
    k_ss_op<2><<<kHW * kB, 256, 0, stream>>>(t1i, mki, ssp);
    k_scale_op<2><<<kHW * kB, 256, 0, stream>>>(t1i, mki, ssp, t2i);
    // t4 = inorm(t1 + c3)  (in place into c3)
    hipMemsetAsync(ssp, 0, 64 * sizeof(float), stream);
    k_ss_op<0><<<kHW * kB, 256, 0, stream>>>(t1r, c3r, ssp);
    k_scale_op<0><<<kHW * kB, 256, 0, stream>>>(t1r, c3r, ssp, c3r);
    hipMemsetAsync(ssp, 0, 64 * sizeof(float), stream);
    k_ss_op<0><<<kHW * kB, 256, 0, stream>>>(t1i, c3i, ssp);
    k_scale_op<0><<<kHW * kB, 256, 0, stream>>>(t1i, c3i, ssp, c3i);
    // out = inorm(t2 + t4)  (in place into t2)
    hipMemsetAsync(ssp, 0, 64 * sizeof(float), stream);
    k_ss_op<0><<<kHW * kB, 256, 0, stream>>>(t2r, c3r, ssp);
    k_scale_op<0><<<kHW * kB, 256, 0, stream>>>(t2r, c3r, ssp, t2r);
    hipMemsetAsync(ssp, 0, 64 * sizeof(float), stream);
    k_ss_op<0><<<kHW * kB, 256, 0, stream>>>(t2i, c3i, ssp);
    k_scale_op<0><<<kHW * kB, 256, 0, stream>>>(t2i, c3i, ssp, t2i);
    // 1x1 compress conv: out[o,hw] = Wc[:,0:512]@outr^T + Wc[:,512:]@outi^T
    launch_gemm(true, false, stream, Wc, t2r, osl, kD, kHW, kD, 2 * kD, kB * kD, kHW, 0, kD,
                (long)kD * kHW, kB);
    launch_gemm(true, true, stream, Wc + kD, t2i, osl, kD, kHW, kD, 2 * kD, kB * kD, kHW, 0, kD,
                (long)kD * kHW, kB);
  }
}

// Round 2
// 6625.896 us; speedup vs baseline: 1.7417x; 1.7417x over previous
//
#include <hip/hip_runtime.h>

// ComTransformer on MI355X — round 2: bf16 MFMA GEMMs (fp32 elsewhere).
// Structure exploited (from round 1):
//  - imag-branch softmax of real-input com_attn is q-independent (rank-1 output)
//  - mk/c3 cross-attentions share softmax matrices; mk values are label bcast
//  - t1i rows identical -> single vb vector per batch, score bias fused in softmax
// New: all GEMMs via v_mfma_f32_16x16x32_bf16 (inline asm), fp32->bf16 in staging.

namespace {

constexpr int kNI = 3;     // images per set
constexpr int kB  = 8;     // batch
constexpr int kD  = 512;   // feature dim
constexpr int kKD = 128;   // key dim (self/cross)
constexpr int kHW = 484;   // 22*22
constexpr int kL  = kNI * kHW;  // 1452
constexpr float kTemp = 30.0f;
constexpr float kCnt  = 247808.0f;             // d*h*w = 512*484
constexpr float kScaleN = 0.011048543456039806f; // sqrt(1/(512*16))

#define CDIV(a, b) (((a) + (b) - 1) / (b))

typedef float f32x4 __attribute__((ext_vector_type(4)));
typedef unsigned int u32x4 __attribute__((ext_vector_type(4)));

__device__ __forceinline__ float wsum(float v) {
#pragma unroll
  for (int o = 32; o; o >>= 1) v += __shfl_down(v, o);
  return v;
}
__device__ __forceinline__ float wmax(float v) {
#pragma unroll
  for (int o = 32; o; o >>= 1) v = fmaxf(v, __shfl_down(v, o));
  return v;
}

// pack two floats -> u32 of two bf16 (RNE)
__device__ __forceinline__ unsigned pk2bf(float lo, float hi) {
  union { float f; unsigned u; } a, b;
  a.f = lo; b.f = hi;
  unsigned ra = (a.u + 0x7FFFu + ((a.u >> 16) & 1u)) >> 16;
  unsigned rb = (b.u + 0x7FFFu + ((b.u >> 16) & 1u)) >> 16;
  return (ra & 0xFFFFu) | (rb << 16);
}

__device__ __forceinline__ void mfma_bf16(f32x4& d, const u32x4& a, const u32x4& b) {
  asm("v_mfma_f32_16x16x32_bf16 %0, %1, %2, %0" : "+v"(d) : "v"(a), "v"(b));
}

// ---------------- layout transform: [n,b,d,hw] -> seq [(n*hw),b,d] ----------------
__global__ void k_toseq(const float* __restrict__ in, float* __restrict__ out) {
  __shared__ float tile[32][33];
  int nb = blockIdx.z;
  int n = nb / kB, b = nb % kB;
  int p0 = blockIdx.x * 32, d0 = blockIdx.y * 32;
  int tx = threadIdx.x, ty = threadIdx.y;  // (32, 8)
  const float* ip = in + (long)nb * kD * kHW;
#pragma unroll
  for (int j = 0; j < 4; ++j) {
    int d = d0 + ty + j * 8, p = p0 + tx;
    if (d < kD && p < kHW) tile[ty + j * 8][tx] = ip[(long)d * kHW + p];
  }
  __syncthreads();
#pragma unroll
  for (int j = 0; j < 4; ++j) {
    int p = p0 + ty + j * 8, d = d0 + tx;
    if (p < kHW && d < kD)
      out[((long)(n * kHW + p) * kB + b) * kD + d] = tile[tx][ty + j * 8];
  }
}

// lab[(n*hw+p)*B + b] = train_label[n,b,p]
__global__ void k_lab(const float* __restrict__ tl, float* __restrict__ lab) {
  long i = (long)blockIdx.x * 256 + threadIdx.x;
  const long tot = (long)kNI * kB * kHW;
  if (i >= tot) return;
  int p = (int)(i % kHW);
  long t = i / kHW;
  int b = (int)(t % kB);
  int n = (int)(t / kB);
  lab[(long)(n * kHW + p) * kB + b] = tl[i];
}

// u = b / max(||b||, 1e-12)
__global__ void k_l2n_vec(const float* __restrict__ src, float* __restrict__ u, int C) {
  __shared__ float red[2];
  int tid = threadIdx.x;  // 128
  float s = 0.f;
  for (int c = tid; c < C; c += 128) { float x = src[c]; s += x * x; }
  s = wsum(s);
  if ((tid & 63) == 0) red[tid >> 6] = s;
  __syncthreads();
  float inv = 1.f / fmaxf(sqrtf(red[0] + red[1]), 1e-12f);
  for (int c = tid; c < C; c += 128) u[c] = src[c] * inv;
}

// ---------------- bf16 MFMA GEMM: C[m,n] (+)= sum_k A[m,k] * B(n|k) ---------------
// BT=true:  B element [n][k] at B[n*ldb + k]  (NT form)
// BT=false: B element [k][n] at B[k*ldb + n]  (NN form)
// fp32 inputs converted to bf16 during LDS staging; fp32 accumulate via MFMA.
// Tile 64x64, BK=32, 4 waves (2x2), each wave 32x32 (2x2 frags of 16x16).
// LDS rows padded to 40 bf16 (80B) -> 2-way (free) bank aliasing on b128 frag reads.
template <bool BT, bool ACC>
__global__ __launch_bounds__(256) void k_gemm_mfma(
    const float* __restrict__ A, const float* __restrict__ B, float* __restrict__ C,
    int M, int N, int K, int lda, int ldb, int ldc, long sAb, long sBb, long sCb) {
  A += (long)blockIdx.z * sAb;
  B += (long)blockIdx.z * sBb;
  C += (long)blockIdx.z * sCb;
  const int m0 = blockIdx.y * 64, n0 = blockIdx.x * 64;
  const int tid = threadIdx.x;
  const int wid = tid >> 6, lane = tid & 63;
  const int wr = wid >> 1, wc = wid & 1;
  const int fr = lane & 15, fk = lane >> 4;  // frag row(col), k-block

  __shared__ unsigned AsU[64 * 20];  // [64][20] u32 = [64][40] bf16
  __shared__ unsigned BsU[64 * 20];

  f32x4 acc[2][2] = {};

  const int sRow = tid >> 2, sKb = tid & 3;   // A (and B-NT) staging slot
  const int bN = tid & 63, bKb = tid >> 6;    // B-NN staging slot

  for (int k0 = 0; k0 < K; k0 += 32) {
    // ---- stage A tile [64 rows][32 k] ----
    {
      int gm = m0 + sRow;
      const float* ap = A + (long)gm * lda + k0 + sKb * 8;
      int krem = K - (k0 + sKb * 8);
      float v[8];
      if (gm < M && krem >= 8) {
        float4 u0 = *(const float4*)ap;
        float4 u1 = *(const float4*)(ap + 4);
        v[0] = u0.x; v[1] = u0.y; v[2] = u0.z; v[3] = u0.w;
        v[4] = u1.x; v[5] = u1.y; v[6] = u1.z; v[7] = u1.w;
      } else {
#pragma unroll
        for (int j = 0; j < 8; ++j) v[j] = (gm < M && j < krem) ? ap[j] : 0.f;
      }
      u32x4 w;
      w.x = pk2bf(v[0], v[1]); w.y = pk2bf(v[2], v[3]);
      w.z = pk2bf(v[4], v[5]); w.w = pk2bf(v[6], v[7]);
      *(u32x4*)&AsU[sRow * 20 + sKb * 4] = w;
    }
    // ---- stage B tile -> Bs[n][k] ----
    if (BT) {
      int gn = n0 + sRow;
      const float* bp = B + (long)gn * ldb + k0 + sKb * 8;
      int krem = K - (k0 + sKb * 8);
      float v[8];
      if (gn < N && krem >= 8) {
        float4 u0 = *(const float4*)bp;
        float4 u1 = *(const float4*)(bp + 4);
        v[0] = u0.x; v[1] = u0.y; v[2] = u0.z; v[3] = u0.w;
        v[4] = u1.x; v[5] = u1.y; v[6] = u1.z; v[7] = u1.w;
      } else {
#pragma unroll
        for (int j = 0; j < 8; ++j) v[j] = (gn < N && j < krem) ? bp[j] : 0.f;
      }
      u32x4 w;
      w.x = pk2bf(v[0], v[1]); w.y = pk2bf(v[2], v[3]);
      w.z = pk2bf(v[4], v[5]); w.w = pk2bf(v[6], v[7]);
      *(u32x4*)&BsU[sRow * 20 + sKb * 4] = w;
    } else {
      int gn = n0 + bN;
      int kbase = k0 + bKb * 8;
      float v[8];
#pragma unroll
      for (int j = 0; j < 8; ++j) {
        int gk = kbase + j;
        v[j] = (gn < N && gk < K) ? B[(long)gk * ldb + gn] : 0.f;
      }
      u32x4 w;
      w.x = pk2bf(v[0], v[1]); w.y = pk2bf(v[2], v[3]);
      w.z = pk2bf(v[4], v[5]); w.w = pk2bf(v[6], v[7]);
      *(u32x4*)&BsU[bN * 20 + bKb * 4] = w;
    }
    __syncthreads();
    // ---- compute: 4 MFMA per wave ----
    u32x4 af0 = *(const u32x4*)&AsU[(wr * 32 + fr) * 20 + fk * 4];
    u32x4 af1 = *(const u32x4*)&AsU[(wr * 32 + 16 + fr) * 20 + fk * 4];
    u32x4 bf0 = *(const u32x4*)&BsU[(wc * 32 + fr) * 20 + fk * 4];
    u32x4 bf1 = *(const u32x4*)&BsU[(wc * 32 + 16 + fr) * 20 + fk * 4];
    mfma_bf16(acc[0][0], af0, bf0);
    mfma_bf16(acc[0][1], af0, bf1);
    mfma_bf16(acc[1][0], af1, bf0);
    mfma_bf16(acc[1][1], af1, bf1);
    __syncthreads();
  }
  // MFMA -> VALU read hazard guard (inline asm is opaque to the scheduler)
  asm volatile("s_nop 7\n\ts_nop 7" ::: );
  // ---- epilogue: C/D layout col=lane&15, row=(lane>>4)*4+reg ----
#pragma unroll
  for (int mi = 0; mi < 2; ++mi) {
#pragma unroll
    for (int r = 0; r < 4; ++r) {
      int gm = m0 + wr * 32 + mi * 16 + fk * 4 + r;
      if (gm >= M) continue;
#pragma unroll
      for (int ni = 0; ni < 2; ++ni) {
        int gn = n0 + wc * 32 + ni * 16 + fr;
        if (gn >= N) continue;
        long idx = (long)gm * ldc + gn;
        float v = acc[mi][ni][r];
        C[idx] = ACC ? (C[idx] + v) : v;
      }
    }
  }
}

// row += bias; row /= max(||row||,1e-12).  C in {128, 512}, block 128.
__global__ void k_bias_l2n(float* __restrict__ P, const float* __restrict__ bias, int C) {
  __shared__ float red[2];
  long row = blockIdx.x;
  float* p = P + row * C;
  int tid = threadIdx.x;
  int nv = C >> 7;
  float v[4];
  float s = 0.f;
#pragma unroll
  for (int i = 0; i < 4; ++i)
    if (i < nv) {
      float x = p[tid + (i << 7)] + bias[tid + (i << 7)];
      v[i] = x;
      s += x * x;
    }
  s = wsum(s);
  if ((tid & 63) == 0) red[tid >> 6] = s;
  __syncthreads();
  float inv = 1.f / fmaxf(sqrtf(red[0] + red[1]), 1e-12f);
#pragma unroll
  for (int i = 0; i < 4; ++i)
    if (i < nv) p[tid + (i << 7)] = v[i] * inv;
}

// g[b*L + k] = u . P[k,b,:]
__global__ void k_rowdot(const float* __restrict__ P, const float* __restrict__ u,
                         float* __restrict__ g, int L, int C) {
  int idx = blockIdx.x;
  int k = idx / kB, b = idx % kB;
  const float* p = P + ((long)k * kB + b) * C;
  int lane = threadIdx.x;  // 64
  float s = 0.f;
  for (int c = lane; c < C; c += 64) s += u[c] * p[c];
  s = wsum(s);
  if (lane == 0) g[(long)b * L + k] = s;
}

// softmax rows of S [B*Lq, Lk] in place: softmax(30*(S + bsign*bias[b,k]));
// optional mk[q*B+b] = sum_k p*lab[k*B+b]
__global__ __launch_bounds__(256) void k_softmax(float* __restrict__ S, int Lq, int Lk,
                                                 const float* __restrict__ bias, float bsign,
                                                 const float* __restrict__ lab,
                                                 float* __restrict__ mk) {
  __shared__ float sm[1456];
  __shared__ float red[4];
  int row = blockIdx.x;
  int b = row / Lq, q = row - b * Lq;
  float* Sr = S + (long)row * Lk;
  int tid = threadIdx.x;
  float mx = -3.0e38f;
  for (int k = tid; k < Lk; k += 256) {
    float v = Sr[k];
    if (bias) v += bsign * bias[(long)b * Lk + k];
    v *= kTemp;
    sm[k] = v;
    mx = fmaxf(mx, v);
  }
  mx = wmax(mx);
  if ((tid & 63) == 0) red[tid >> 6] = mx;
  __syncthreads();
  mx = fmaxf(fmaxf(red[0], red[1]), fmaxf(red[2], red[3]));
  __syncthreads();
  float s = 0.f;
  for (int k = tid; k < Lk; k += 256) {
    float e = expf(sm[k] - mx);
    sm[k] = e;
    s += e;
  }
  s = wsum(s);
  if ((tid & 63) == 0) red[tid >> 6] = s;
  __syncthreads();
  float inv = 1.0f / (red[0] + red[1] + red[2] + red[3]);
  __syncthreads();
  float dot = 0.f;
  for (int k = tid; k < Lk; k += 256) {
    float p = sm[k] * inv;
    Sr[k] = p;
    if (lab) dot += p * lab[(long)k * kB + b];
  }
  if (lab) {
    dot = wsum(dot);
    if ((tid & 63) == 0) red[tid >> 6] = dot;
    __syncthreads();
    if (tid == 0) mk[(long)q * kB + b] = red[0] + red[1] + red[2] + red[3];
  }
}

// rowout[b,d] = sum_k w[b*L+k] * S[k,b,d]
__global__ void k_wrowsum(const float* __restrict__ w, const float* __restrict__ S,
                          float* __restrict__ rowout, int L) {
  int b = blockIdx.y;
  int d = blockIdx.x * 128 + threadIdx.x;
  float s = 0.f;
  for (int k = 0; k < L; ++k) s += w[(long)b * L + k] * S[((long)k * kB + b) * kD + d];
  rowout[(long)b * kD + d] = s;
}

// elementwise ops for inorm pipeline.  r = row index = l*B + b, D = 512 fixed.
// OP 0: A[r,d]+B2[r,d]   OP 1: A[b,d] (broadcast)   OP 2: A[r,d]*B2[r]
template <int OP>
__device__ __forceinline__ float opval(const float* __restrict__ A,
                                       const float* __restrict__ B2, long r, int b, int d) {
  if (OP == 0) return A[r * kD + d] + B2[r * kD + d];
  if (OP == 1) return A[(long)b * kD + d];
  return A[r * kD + d] * B2[r];
}

template <int OP>
__global__ __launch_bounds__(256) void k_ss_op(const float* __restrict__ A,
                                               const float* __restrict__ B2,
                                               float* __restrict__ ss) {
  __shared__ float red[4];
  long r = blockIdx.x;
  int l = (int)(r / kB), b = (int)(r % kB);
  int g = (l / kHW) * kB + b;
  int tid = threadIdx.x;
  float z0 = opval<OP>(A, B2, r, b, tid);
  float z1 = opval<OP>(A, B2, r, b, tid + 256);
  float s = z0 * z0 + z1 * z1;
  s = wsum(s);
  if ((tid & 63) == 0) red[tid >> 6] = s;
  __syncthreads();
  if (tid == 0) atomicAdd(&ss[g], red[0] + red[1] + red[2] + red[3]);
}

template <int OP>
__global__ __launch_bounds__(256) void k_scale_op(const float* __restrict__ A,
                                                  const float* __restrict__ B2,
                                                  const float* __restrict__ ss,
                                                  float* __restrict__ outp) {
  long r = blockIdx.x;
  int l = (int)(r / kB), b = (int)(r % kB);
  int tid = threadIdx.x;
  float fac = 1.0f;
  if (ss) {
    int g = (l / kHW) * kB + b;
    fac = kScaleN * sqrtf(kCnt / (ss[g] + 1e-5f));
  }
  outp[r * kD + tid] = opval<OP>(A, B2, r, b, tid) * fac;
  outp[r * kD + tid + 256] = opval<OP>(A, B2, r, b, tid + 256) * fac;
}

// vb[b,:] = l2n(t1i_row_b @ WkC + bkC)   (t1i rows identical; read row q=0)
__global__ void k_vb(const float* __restrict__ t1i, const float* __restrict__ Wk,
                     const float* __restrict__ bk, float* __restrict__ vb) {
  __shared__ float red[2];
  int b = blockIdx.x;
  int j = threadIdx.x;  // 128
  const float* row = t1i + (long)b * kD;
  float acc = bk[j];
  for (int d = 0; d < kD; ++d) acc += row[d] * Wk[(long)d * kKD + j];
  float s = acc * acc;
  s = wsum(s);
  if ((j & 63) == 0) red[j >> 6] = s;
  __syncthreads();
  float inv = 1.f / fmaxf(sqrtf(red[0] + red[1]), 1e-12f);
  vb[(long)b * kKD + j] = acc * inv;
}

// cR[b*L+k] = vb_b . Kr[k,b,:], cI likewise with Ki
__global__ void k_cRcI(const float* __restrict__ vb, const float* __restrict__ Kr,
                       const float* __restrict__ Ki, float* __restrict__ cR,
                       float* __restrict__ cI) {
  int idx = blockIdx.x;
  int k = idx / kB, b = idx % kB;
  int lane = threadIdx.x;  // 64
  const float* v = vb + (long)b * kKD;
  const float* pr = Kr + ((long)k * kB + b) * kKD;
  const float* pi = Ki + ((long)k * kB + b) * kKD;
  float sR = 0.f, sI = 0.f;
  for (int c = lane; c < kKD; c += 64) {
    sR += v[c] * pr[c];
    sI += v[c] * pi[c];
  }
  sR = wsum(sR);
  sI = wsum(sI);
  if (lane == 0) {
    cR[(long)b * kL + k] = sR;
    cI[(long)b * kL + k] = sI;
  }
}

void launch_gemm(bool bt, bool acc, hipStream_t s, const float* A, const float* B, float* C,
                 int M, int N, int K, int lda, int ldb, int ldc, long sAb, long sBb, long sCb,
                 int batch) {
  dim3 grd(CDIV(N, 64), CDIV(M, 64), batch), blk(256);
  if (bt && !acc)
    k_gemm_mfma<true, false><<<grd, blk, 0, s>>>(A, B, C, M, N, K, lda, ldb, ldc, sAb, sBb, sCb);
  else if (bt && acc)
    k_gemm_mfma<true, true><<<grd, blk, 0, s>>>(A, B, C, M, N, K, lda, ldb, ldc, sAb, sBb, sCb);
  else
    k_gemm_mfma<false, false><<<grd, blk, 0, s>>>(A, B, C, M, N, K, lda, ldb, ldc, sAb, sBb, sCb);
}

}  // namespace

extern "C" void kernel_launch(void* const* d_in, const int* in_sizes, int n_in, void* d_out,
                              int out_size, void* d_ws, size_t ws_size, hipStream_t stream) {
  (void)in_sizes; (void)n_in; (void)out_size;
  const float* tf  = (const float*)d_in[0];
  const float* sf  = (const float*)d_in[1];
  const float* tl  = (const float*)d_in[2];
  const float* WkE = (const float*)d_in[3];
  const float* bkE = (const float*)d_in[4];
  const float* WkS = (const float*)d_in[5];
  const float* bkS = (const float*)d_in[6];
  const float* WkC = (const float*)d_in[7];
  const float* bkC = (const float*)d_in[8];
  const float* Wc  = (const float*)d_in[9];
  float* out = (float*)d_out;
  float* ws = (float*)d_ws;

  const long LBD = (long)kL * kB * kD;    // 5,947,392
  const long LBK = (long)kL * kB * kKD;   // 1,486,848
  const long HBD = (long)kHW * kB * kD;   // 1,982,464
  const long HBK = (long)kHW * kB * kKD;  // 495,616

  long off = 0;
  auto alloc = [&](long n) {
    long o = off;
    off += (n + 255) & ~255L;
    return o;
  };
  long o_seqT = alloc(LBD);
  long o_seqS = alloc(LBD);
  long o_Kr = alloc(LBK);
  long o_Ki = alloc(LBK);
  long o_Vr = alloc(LBD);
  long o_lab = alloc((long)kL * kB);
  long o_uE = alloc(kD);
  long o_uS = alloc(kKD);
  long o_vb = alloc((long)kB * kKD);
  long o_g = alloc((long)kB * kL);
  long o_cR = alloc((long)kB * kL);
  long o_cI = alloc((long)kB * kL);
  long o_row = alloc((long)kB * kD);
  long o_mkr = alloc((long)kHW * kB);
  long o_mki = alloc((long)kHW * kB);
  long o_ss = alloc(64);
  long o_scr = off;
  // encoder overlay
  long o_Pe = o_scr;
  long o_Ae = o_Pe + LBD;
  long o_ar = o_Ae + (long)kB * kL * kL;
  long o_mr = o_ar + LBD;
  long o_mi = o_mr + LBD;
  long total = o_mi + LBD;
  // per-image overlay (same scratch region, encoder done first)
  long o_Ps = o_scr;
  long o_Pc = o_Ps + HBK;
  long o_As = o_Pc + HBK;
  long o_S1 = o_As + (long)kB * kHW * kHW;
  long o_S2 = o_S1 + (long)kB * kHW * kL;
  long o_t1r = o_S2 + (long)kB * kHW * kL;
  long o_t1i = o_t1r + HBD;
  long o_c3r = o_t1i + HBD;
  long o_c3i = o_c3r + HBD;
  long o_t2r = o_c3i + HBD;
  long o_t2i = o_t2r + HBD;

  if ((size_t)total * sizeof(float) > ws_size) return;  // insufficient workspace

  float* seqT = ws + o_seqT;
  float* seqS = ws + o_seqS;
  float* Kr = ws + o_Kr;
  float* Ki = ws + o_Ki;
  float* Vr = ws + o_Vr;
  float* lab = ws + o_lab;
  float* uE = ws + o_uE;
  float* uS = ws + o_uS;
  float* vb = ws + o_vb;
  float* g_ = ws + o_g;
  float* cR = ws + o_cR;
  float* cI = ws + o_cI;
  float* row = ws + o_row;
  float* mkr = ws + o_mkr;
  float* mki = ws + o_mki;
  float* ssp = ws + o_ss;
  float* Pe = ws + o_Pe;
  float* Ae = ws + o_Ae;
  float* ar = ws + o_ar;
  float* mr = ws + o_mr;
  float* mi = ws + o_mi;
  float* Ps = ws + o_Ps;
  float* Pc = ws + o_Pc;
  float* As_ = ws + o_As;
  float* S1 = ws + o_S1;
  float* S2 = ws + o_S2;
  float* t1r = ws + o_t1r;
  float* t1i = ws + o_t1i;
  float* c3r = ws + o_c3r;
  float* c3i = ws + o_c3i;
  float* t2r = ws + o_t2r;
  float* t2i = ws + o_t2i;

  // ---- stage 0: layout + constants ----
  {
    dim3 grd(CDIV(kHW, 32), CDIV(kD, 32), kNI * kB), blk(32, 8);
    k_toseq<<<grd, blk, 0, stream>>>(tf, seqT);
    k_toseq<<<grd, blk, 0, stream>>>(sf, seqS);
  }
  k_lab<<<CDIV(kNI * kB * kHW, 256), 256, 0, stream>>>(tl, lab);
  k_l2n_vec<<<1, 128, 0, stream>>>(bkE, uE, kD);
  k_l2n_vec<<<1, 128, 0, stream>>>(bkS, uS, kKD);

  // ---- encoder ----
  launch_gemm(false, false, stream, seqT, WkE, Pe, kL * kB, kD, kD, kD, kD, kD, 0, 0, 0, 1);
  k_bias_l2n<<<kL * kB, 128, 0, stream>>>(Pe, bkE, kD);
  k_rowdot<<<kL * kB, 64, 0, stream>>>(Pe, uE, g_, kL, kD);
  k_softmax<<<kB, 256, 0, stream>>>(g_, 1, kL, nullptr, 0.f, nullptr, nullptr);  // wi_en
  launch_gemm(true, false, stream, Pe, Pe, Ae, kL, kL, kD, kB * kD, kB * kD, kL, kD, kD,
              (long)kL * kL, kB);
  k_softmax<<<kB * kL, 256, 0, stream>>>(Ae, kL, kL, nullptr, 0.f, nullptr, nullptr);
  launch_gemm(false, false, stream, Ae, seqT, ar, kL, kD, kL, kL, kB * kD, kB * kD,
              (long)kL * kL, kD, kD, kB);
  k_wrowsum<<<dim3(kD / 128, kB), 128, 0, stream>>>(g_, seqT, row, kL);  // ai row
  // mem_r = inorm(seqT + ar); mem_i = inorm(bcast ai row)  [ss arena: slots 0..23, 24..47]
  hipMemsetAsync(ssp, 0, 48 * sizeof(float), stream);
  k_ss_op<0><<<kL * kB, 256, 0, stream>>>(seqT, ar, ssp);
  k_scale_op<0><<<kL * kB, 256, 0, stream>>>(seqT, ar, ssp, mr);
  k_ss_op<1><<<kL * kB, 256, 0, stream>>>(row, nullptr, ssp + 24);
  k_scale_op<1><<<kL * kB, 256, 0, stream>>>(row, nullptr, ssp + 24, mi);
  // Kr/Ki = l2n(mem @ WkC + bkC)
  launch_gemm(false, false, stream, mr, WkC, Kr, kL * kB, kKD, kD, kD, kKD, kKD, 0, 0, 0, 1);
  k_bias_l2n<<<kL * kB, 128, 0, stream>>>(Kr, bkC, kKD);
  launch_gemm(false, false, stream, mi, WkC, Ki, kL * kB, kKD, kD, kD, kKD, kKD, 0, 0, 0, 1);
  k_bias_l2n<<<kL * kB, 128, 0, stream>>>(Ki, bkC, kKD);
  // Vr = mem_r * lab
  k_scale_op<2><<<kL * kB, 256, 0, stream>>>(mr, lab, nullptr, Vr);

  // ---- decoder: 3 train images then 3 test images ----
  for (int img = 0; img < 6; ++img) {
    const float* t = (img < 3) ? (seqT + (long)img * HBD) : (seqS + (long)(img - 3) * HBD);
    float* osl = out + (long)img * kB * kD * kHW;

    // self-attention
    launch_gemm(false, false, stream, t, WkS, Ps, kHW * kB, kKD, kD, kD, kKD, kKD, 0, 0, 0, 1);
    k_bias_l2n<<<kHW * kB, 128, 0, stream>>>(Ps, bkS, kKD);
    k_rowdot<<<kHW * kB, 64, 0, stream>>>(Ps, uS, g_, kHW, kKD);
    k_softmax<<<kB, 256, 0, stream>>>(g_, 1, kHW, nullptr, 0.f, nullptr, nullptr);  // wi_s
    launch_gemm(true, false, stream, Ps, Ps, As_, kHW, kHW, kKD, kB * kKD, kB * kKD, kHW, kKD,
                kKD, (long)kHW * kHW, kB);
    k_softmax<<<kB * kHW, 256, 0, stream>>>(As_, kHW, kHW, nullptr, 0.f, nullptr, nullptr);
    launch_gemm(false, false, stream, As_, t, c3r, kHW, kD, kHW, kHW, kB * kD, kB * kD,
                (long)kHW * kHW, kD, kD, kB);  // s2r (staged in c3r)
    k_wrowsum<<<dim3(kD / 128, kB), 128, 0, stream>>>(g_, t, row, kHW);  // s2i row
    // ss arena for this image: slots t1r:0 t1i:8 t2r:16 t2i:24 t4r:32 t4i:40 outr:48 outi:56
    hipMemsetAsync(ssp, 0, 64 * sizeof(float), stream);
    // t1r = inorm(t + s2r); t1i = inorm(bcast s2i)
    k_ss_op<0><<<kHW * kB, 256, 0, stream>>>(t, c3r, ssp);
    k_scale_op<0><<<kHW * kB, 256, 0, stream>>>(t, c3r, ssp, t1r);
    k_ss_op<1><<<kHW * kB, 256, 0, stream>>>(row, nullptr, ssp + 8);
    k_scale_op<1><<<kHW * kB, 256, 0, stream>>>(row, nullptr, ssp + 8, t1i);
    // cross-attention (shared by mk and c3)
    k_vb<<<kB, 128, 0, stream>>>(t1i, WkC, bkC, vb);
    launch_gemm(false, false, stream, t1r, WkC, Pc, kHW * kB, kKD, kD, kD, kKD, kKD, 0, 0, 0, 1);
    k_bias_l2n<<<kHW * kB, 128, 0, stream>>>(Pc, bkC, kKD);
    k_cRcI<<<kL * kB, 64, 0, stream>>>(vb, Kr, Ki, cR, cI);
    launch_gemm(true, false, stream, Pc, Kr, S1, kHW, kL, kKD, kB * kKD, kB * kKD, kL, kKD, kKD,
                (long)kHW * kL, kB);
    launch_gemm(true, false, stream, Pc, Ki, S2, kHW, kL, kKD, kB * kKD, kB * kKD, kL, kKD, kKD,
                (long)kHW * kL, kB);
    k_softmax<<<kB * kHW, 256, 0, stream>>>(S1, kHW, kL, cI, -1.f, lab, mkr);  // Ar, mkr
    k_softmax<<<kB * kHW, 256, 0, stream>>>(S2, kHW, kL, cR, +1.f, lab, mki);  // Ai, mki
    launch_gemm(false, false, stream, S1, Vr, c3r, kHW, kD, kL, kL, kB * kD, kB * kD,
                (long)kHW * kL, kD, kD, kB);
    launch_gemm(false, false, stream, S2, Vr, c3i, kHW, kD, kL, kL, kB * kD, kB * kD,
                (long)kHW * kL, kD, kD, kB);
    // t2 = inorm(t1 * mk)
    k_ss_op<2><<<kHW * kB, 256, 0, stream>>>(t1r, mkr, ssp + 16);
    k_scale_op<2><<<kHW * kB, 256, 0, stream>>>(t1r, mkr, ssp + 16, t2r);
    k_ss_op<2><<<kHW * kB, 256, 0, stream>>>(t1i, mki, ssp + 24);
    k_scale_op<2><<<kHW * kB, 256, 0, stream>>>(t1i, mki, ssp + 24, t2i);
    // t4 = inorm(t1 + c3)  (in place into c3)
    k_ss_op<0><<<kHW * kB, 256, 0, stream>>>(t1r, c3r, ssp + 32);
    k_scale_op<0><<<kHW * kB, 256, 0, stream>>>(t1r, c3r, ssp + 32, c3r);
    k_ss_op<0><<<kHW * kB, 256, 0, stream>>>(t1i, c3i, ssp + 40);
    k_scale_op<0><<<kHW * kB, 256, 0, stream>>>(t1i, c3i, ssp + 40, c3i);
    // out = inorm(t2 + t4)  (in place into t2)
    k_ss_op<0><<<kHW * kB, 256, 0, stream>>>(t2r, c3r, ssp + 48);
    k_scale_op<0><<<kHW * kB, 256, 0, stream>>>(t2r, c3r, ssp + 48, t2r);
    k_ss_op<0><<<kHW * kB, 256, 0, stream>>>(t2i, c3i, ssp + 56);
    k_scale_op<0><<<kHW * kB, 256, 0, stream>>>(t2i, c3i, ssp + 56, t2i);
    // 1x1 compress conv: out[o,hw] = Wc[:,0:512]@outr^T + Wc[:,512:]@outi^T
    launch_gemm(true, false, stream, Wc, t2r, osl, kD, kHW, kD, 2 * kD, kB * kD, kHW, 0, kD,
                (long)kD * kHW, kB);
    launch_gemm(true, true, stream, Wc + kD, t2i, osl, kD, kHW, kD, 2 * kD, kB * kD, kHW, 0, kD,
                (long)kD * kHW, kB);
  }
}

// Round 3
// 6465.788 us; speedup vs baseline: 1.7848x; 1.0248x over previous
//
#include <hip/hip_runtime.h>

// ComTransformer on MI355X — round 3:
//  - k_wrowsum parallelized over k-chunks (was 7x348us = 37% of runtime, latency-bound)
//  - GEMM tile 64x64 -> 128x128 (4 waves x 4x4 MFMA frags, BK=32)
//  - k_vb 4-way d-split
// Structure exploited (from round 1):
//  - imag-branch softmax of real-input com_attn is q-independent (rank-1 output)
//  - mk/c3 cross-attentions share softmax matrices; mk values are label bcast
//  - t1i rows identical -> single vb vector per batch, score bias fused in softmax

namespace {

constexpr int kNI = 3;     // images per set
constexpr int kB  = 8;     // batch
constexpr int kD  = 512;   // feature dim
constexpr int kKD = 128;   // key dim (self/cross)
constexpr int kHW = 484;   // 22*22
constexpr int kL  = kNI * kHW;  // 1452
constexpr float kTemp = 30.0f;
constexpr float kCnt  = 247808.0f;             // d*h*w = 512*484
constexpr float kScaleN = 0.011048543456039806f; // sqrt(1/(512*16))

#define CDIV(a, b) (((a) + (b) - 1) / (b))

typedef float f32x4 __attribute__((ext_vector_type(4)));
typedef unsigned int u32x4 __attribute__((ext_vector_type(4)));

__device__ __forceinline__ float wsum(float v) {
#pragma unroll
  for (int o = 32; o; o >>= 1) v += __shfl_down(v, o);
  return v;
}
__device__ __forceinline__ float wmax(float v) {
#pragma unroll
  for (int o = 32; o; o >>= 1) v = fmaxf(v, __shfl_down(v, o));
  return v;
}

// pack two floats -> u32 of two bf16 (RNE)
__device__ __forceinline__ unsigned pk2bf(float lo, float hi) {
  union { float f; unsigned u; } a, b;
  a.f = lo; b.f = hi;
  unsigned ra = (a.u + 0x7FFFu + ((a.u >> 16) & 1u)) >> 16;
  unsigned rb = (b.u + 0x7FFFu + ((b.u >> 16) & 1u)) >> 16;
  return (ra & 0xFFFFu) | (rb << 16);
}

__device__ __forceinline__ void mfma_bf16(f32x4& d, const u32x4& a, const u32x4& b) {
  asm("v_mfma_f32_16x16x32_bf16 %0, %1, %2, %0" : "+v"(d) : "v"(a), "v"(b));
}

// ---------------- layout transform: [n,b,d,hw] -> seq [(n*hw),b,d] ----------------
__global__ void k_toseq(const float* __restrict__ in, float* __restrict__ out) {
  __shared__ float tile[32][33];
  int nb = blockIdx.z;
  int n = nb / kB, b = nb % kB;
  int p0 = blockIdx.x * 32, d0 = blockIdx.y * 32;
  int tx = threadIdx.x, ty = threadIdx.y;  // (32, 8)
  const float* ip = in + (long)nb * kD * kHW;
#pragma unroll
  for (int j = 0; j < 4; ++j) {
    int d = d0 + ty + j * 8, p = p0 + tx;
    if (d < kD && p < kHW) tile[ty + j * 8][tx] = ip[(long)d * kHW + p];
  }
  __syncthreads();
#pragma unroll
  for (int j = 0; j < 4; ++j) {
    int p = p0 + ty + j * 8, d = d0 + tx;
    if (p < kHW && d < kD)
      out[((long)(n * kHW + p) * kB + b) * kD + d] = tile[tx][ty + j * 8];
  }
}

// lab[(n*hw+p)*B + b] = train_label[n,b,p]
__global__ void k_lab(const float* __restrict__ tl, float* __restrict__ lab) {
  long i = (long)blockIdx.x * 256 + threadIdx.x;
  const long tot = (long)kNI * kB * kHW;
  if (i >= tot) return;
  int p = (int)(i % kHW);
  long t = i / kHW;
  int b = (int)(t % kB);
  int n = (int)(t / kB);
  lab[(long)(n * kHW + p) * kB + b] = tl[i];
}

// u = b / max(||b||, 1e-12)
__global__ void k_l2n_vec(const float* __restrict__ src, float* __restrict__ u, int C) {
  __shared__ float red[2];
  int tid = threadIdx.x;  // 128
  float s = 0.f;
  for (int c = tid; c < C; c += 128) { float x = src[c]; s += x * x; }
  s = wsum(s);
  if ((tid & 63) == 0) red[tid >> 6] = s;
  __syncthreads();
  float inv = 1.f / fmaxf(sqrtf(red[0] + red[1]), 1e-12f);
  for (int c = tid; c < C; c += 128) u[c] = src[c] * inv;
}

// ---------------- bf16 MFMA GEMM: C[m,n] (+)= sum_k A[m,k] * B(n|k) ---------------
// BT=true:  B element [n][k] at B[n*ldb + k]  (NT form)
// BT=false: B element [k][n] at B[k*ldb + n]  (NN form)
// Tile 128x128, BK=32, 4 waves (2x2), each wave 64x64 (4x4 frags of 16x16).
// LDS rows padded to 40 bf16 (80B) -> 2-way (free) bank aliasing on b128 frag reads.
template <bool BT, bool ACC>
__global__ __launch_bounds__(256) void k_gemm_mfma(
    const float* __restrict__ A, const float* __restrict__ B, float* __restrict__ C,
    int M, int N, int K, int lda, int ldb, int ldc, long sAb, long sBb, long sCb) {
  A += (long)blockIdx.z * sAb;
  B += (long)blockIdx.z * sBb;
  C += (long)blockIdx.z * sCb;
  const int m0 = blockIdx.y * 128, n0 = blockIdx.x * 128;
  const int tid = threadIdx.x;
  const int wid = tid >> 6, lane = tid & 63;
  const int wr = wid >> 1, wc = wid & 1;
  const int fr = lane & 15, fk = lane >> 4;  // frag row(col), k-block

  __shared__ unsigned AsU[128 * 20];  // [128][20] u32 = [128][40] bf16
  __shared__ unsigned BsU[128 * 20];

  f32x4 acc[4][4] = {};

  const int sRow = tid >> 1;           // 0..127
  const int sH = (tid & 1) * 16;       // k elem offset: 0 or 16
  const int bN = tid & 127;            // B-NN staging col
  const int bKb = (tid >> 7) * 16;     // B-NN staging k base

  for (int k0 = 0; k0 < K; k0 += 32) {
    // ---- stage A tile [128 rows][32 k] ----
    {
      int gm = m0 + sRow;
      int kk = k0 + sH;
      float v[16];
      if (gm < M && K - kk >= 16) {
        const float* ap = A + (long)gm * lda + kk;
        float4 u0 = *(const float4*)(ap);
        float4 u1 = *(const float4*)(ap + 4);
        float4 u2 = *(const float4*)(ap + 8);
        float4 u3 = *(const float4*)(ap + 12);
        v[0]=u0.x; v[1]=u0.y; v[2]=u0.z; v[3]=u0.w;
        v[4]=u1.x; v[5]=u1.y; v[6]=u1.z; v[7]=u1.w;
        v[8]=u2.x; v[9]=u2.y; v[10]=u2.z; v[11]=u2.w;
        v[12]=u3.x; v[13]=u3.y; v[14]=u3.z; v[15]=u3.w;
      } else {
#pragma unroll
        for (int j = 0; j < 16; ++j)
          v[j] = (gm < M && kk + j < K) ? A[(long)gm * lda + kk + j] : 0.f;
      }
      unsigned* dst = &AsU[sRow * 20 + (sH >> 1)];
      u32x4 w0, w1;
      w0.x = pk2bf(v[0], v[1]);  w0.y = pk2bf(v[2], v[3]);
      w0.z = pk2bf(v[4], v[5]);  w0.w = pk2bf(v[6], v[7]);
      w1.x = pk2bf(v[8], v[9]);  w1.y = pk2bf(v[10], v[11]);
      w1.z = pk2bf(v[12], v[13]); w1.w = pk2bf(v[14], v[15]);
      *(u32x4*)dst = w0;
      *(u32x4*)(dst + 4) = w1;
    }
    // ---- stage B tile -> Bs[n][k] ----
    if (BT) {
      int gn = n0 + sRow;
      int kk = k0 + sH;
      float v[16];
      if (gn < N && K - kk >= 16) {
        const float* bp = B + (long)gn * ldb + kk;
        float4 u0 = *(const float4*)(bp);
        float4 u1 = *(const float4*)(bp + 4);
        float4 u2 = *(const float4*)(bp + 8);
        float4 u3 = *(const float4*)(bp + 12);
        v[0]=u0.x; v[1]=u0.y; v[2]=u0.z; v[3]=u0.w;
        v[4]=u1.x; v[5]=u1.y; v[6]=u1.z; v[7]=u1.w;
        v[8]=u2.x; v[9]=u2.y; v[10]=u2.z; v[11]=u2.w;
        v[12]=u3.x; v[13]=u3.y; v[14]=u3.z; v[15]=u3.w;
      } else {
#pragma unroll
        for (int j = 0; j < 16; ++j)
          v[j] = (gn < N && kk + j < K) ? B[(long)gn * ldb + kk + j] : 0.f;
      }
      unsigned* dst = &BsU[sRow * 20 + (sH >> 1)];
      u32x4 w0, w1;
      w0.x = pk2bf(v[0], v[1]);  w0.y = pk2bf(v[2], v[3]);
      w0.z = pk2bf(v[4], v[5]);  w0.w = pk2bf(v[6], v[7]);
      w1.x = pk2bf(v[8], v[9]);  w1.y = pk2bf(v[10], v[11]);
      w1.z = pk2bf(v[12], v[13]); w1.w = pk2bf(v[14], v[15]);
      *(u32x4*)dst = w0;
      *(u32x4*)(dst + 4) = w1;
    } else {
      int gn = n0 + bN;
      float v[16];
#pragma unroll
      for (int j = 0; j < 16; ++j) {
        int gk = k0 + bKb + j;
        v[j] = (gn < N && gk < K) ? B[(long)gk * ldb + gn] : 0.f;
      }
      unsigned* dst = &BsU[bN * 20 + (bKb >> 1)];
      u32x4 w0, w1;
      w0.x = pk2bf(v[0], v[1]);  w0.y = pk2bf(v[2], v[3]);
      w0.z = pk2bf(v[4], v[5]);  w0.w = pk2bf(v[6], v[7]);
      w1.x = pk2bf(v[8], v[9]);  w1.y = pk2bf(v[10], v[11]);
      w1.z = pk2bf(v[12], v[13]); w1.w = pk2bf(v[14], v[15]);
      *(u32x4*)dst = w0;
      *(u32x4*)(dst + 4) = w1;
    }
    __syncthreads();
    // ---- compute: 16 MFMA per wave ----
    u32x4 af[4], bf[4];
#pragma unroll
    for (int mi = 0; mi < 4; ++mi)
      af[mi] = *(const u32x4*)&AsU[(wr * 64 + mi * 16 + fr) * 20 + fk * 4];
#pragma unroll
    for (int ni = 0; ni < 4; ++ni)
      bf[ni] = *(const u32x4*)&BsU[(wc * 64 + ni * 16 + fr) * 20 + fk * 4];
#pragma unroll
    for (int mi = 0; mi < 4; ++mi)
#pragma unroll
      for (int ni = 0; ni < 4; ++ni) mfma_bf16(acc[mi][ni], af[mi], bf[ni]);
    __syncthreads();
  }
  // MFMA -> VALU read hazard guard (inline asm is opaque to the scheduler)
  asm volatile("s_nop 7\n\ts_nop 7" ::: );
  // ---- epilogue: C/D layout col=lane&15, row=(lane>>4)*4+reg ----
#pragma unroll
  for (int mi = 0; mi < 4; ++mi) {
#pragma unroll
    for (int r = 0; r < 4; ++r) {
      int gm = m0 + wr * 64 + mi * 16 + fk * 4 + r;
      if (gm >= M) continue;
#pragma unroll
      for (int ni = 0; ni < 4; ++ni) {
        int gn = n0 + wc * 64 + ni * 16 + fr;
        if (gn >= N) continue;
        long idx = (long)gm * ldc + gn;
        float v = acc[mi][ni][r];
        C[idx] = ACC ? (C[idx] + v) : v;
      }
    }
  }
}

// row += bias; row /= max(||row||,1e-12).  C in {128, 512}, block 128.
__global__ void k_bias_l2n(float* __restrict__ P, const float* __restrict__ bias, int C) {
  __shared__ float red[2];
  long row = blockIdx.x;
  float* p = P + row * C;
  int tid = threadIdx.x;
  int nv = C >> 7;
  float v[4];
  float s = 0.f;
#pragma unroll
  for (int i = 0; i < 4; ++i)
    if (i < nv) {
      float x = p[tid + (i << 7)] + bias[tid + (i << 7)];
      v[i] = x;
      s += x * x;
    }
  s = wsum(s);
  if ((tid & 63) == 0) red[tid >> 6] = s;
  __syncthreads();
  float inv = 1.f / fmaxf(sqrtf(red[0] + red[1]), 1e-12f);
#pragma unroll
  for (int i = 0; i < 4; ++i)
    if (i < nv) p[tid + (i << 7)] = v[i] * inv;
}

// g[b*L + k] = u . P[k,b,:]
__global__ void k_rowdot(const float* __restrict__ P, const float* __restrict__ u,
                         float* __restrict__ g, int L, int C) {
  int idx = blockIdx.x;
  int k = idx / kB, b = idx % kB;
  const float* p = P + ((long)k * kB + b) * C;
  int lane = threadIdx.x;  // 64
  float s = 0.f;
  for (int c = lane; c < C; c += 64) s += u[c] * p[c];
  s = wsum(s);
  if (lane == 0) g[(long)b * L + k] = s;
}

// softmax rows of S [B*Lq, Lk] in place: softmax(30*(S + bsign*bias[b,k]));
// optional mk[q*B+b] = sum_k p*lab[k*B+b]
__global__ __launch_bounds__(256) void k_softmax(float* __restrict__ S, int Lq, int Lk,
                                                 const float* __restrict__ bias, float bsign,
                                                 const float* __restrict__ lab,
                                                 float* __restrict__ mk) {
  __shared__ float sm[1456];
  __shared__ float red[4];
  int row = blockIdx.x;
  int b = row / Lq, q = row - b * Lq;
  float* Sr = S + (long)row * Lk;
  int tid = threadIdx.x;
  float mx = -3.0e38f;
  for (int k = tid; k < Lk; k += 256) {
    float v = Sr[k];
    if (bias) v += bsign * bias[(long)b * Lk + k];
    v *= kTemp;
    sm[k] = v;
    mx = fmaxf(mx, v);
  }
  mx = wmax(mx);
  if ((tid & 63) == 0) red[tid >> 6] = mx;
  __syncthreads();
  mx = fmaxf(fmaxf(red[0], red[1]), fmaxf(red[2], red[3]));
  __syncthreads();
  float s = 0.f;
  for (int k = tid; k < Lk; k += 256) {
    float e = expf(sm[k] - mx);
    sm[k] = e;
    s += e;
  }
  s = wsum(s);
  if ((tid & 63) == 0) red[tid >> 6] = s;
  __syncthreads();
  float inv = 1.0f / (red[0] + red[1] + red[2] + red[3]);
  __syncthreads();
  float dot = 0.f;
  for (int k = tid; k < Lk; k += 256) {
    float p = sm[k] * inv;
    Sr[k] = p;
    if (lab) dot += p * lab[(long)k * kB + b];
  }
  if (lab) {
    dot = wsum(dot);
    if ((tid & 63) == 0) red[tid >> 6] = dot;
    __syncthreads();
    if (tid == 0) mk[(long)q * kB + b] = red[0] + red[1] + red[2] + red[3];
  }
}

// rowout[b,d] += sum_{k in chunk} w[b*L+k] * S[k,b,d]   (rowout pre-zeroed)
__global__ void k_wrowsum(const float* __restrict__ w, const float* __restrict__ S,
                          float* __restrict__ rowout, int L, int kchunk) {
  int b = blockIdx.y;
  int d = blockIdx.x * 128 + threadIdx.x;
  int k0 = blockIdx.z * kchunk;
  int k1 = min(L, k0 + kchunk);
  float s = 0.f;
  for (int k = k0; k < k1; ++k) s += w[(long)b * L + k] * S[((long)k * kB + b) * kD + d];
  atomicAdd(&rowout[(long)b * kD + d], s);
}

// elementwise ops for inorm pipeline.  r = row index = l*B + b, D = 512 fixed.
// OP 0: A[r,d]+B2[r,d]   OP 1: A[b,d] (broadcast)   OP 2: A[r,d]*B2[r]
template <int OP>
__device__ __forceinline__ float opval(const float* __restrict__ A,
                                       const float* __restrict__ B2, long r, int b, int d) {
  if (OP == 0) return A[r * kD + d] + B2[r * kD + d];
  if (OP == 1) return A[(long)b * kD + d];
  return A[r * kD + d] * B2[r];
}

template <int OP>
__global__ __launch_bounds__(256) void k_ss_op(const float* __restrict__ A,
                                               const float* __restrict__ B2,
                                               float* __restrict__ ss) {
  __shared__ float red[4];
  long r = blockIdx.x;
  int l = (int)(r / kB), b = (int)(r % kB);
  int g = (l / kHW) * kB + b;
  int tid = threadIdx.x;
  float z0 = opval<OP>(A, B2, r, b, tid);
  float z1 = opval<OP>(A, B2, r, b, tid + 256);
  float s = z0 * z0 + z1 * z1;
  s = wsum(s);
  if ((tid & 63) == 0) red[tid >> 6] = s;
  __syncthreads();
  if (tid == 0) atomicAdd(&ss[g], red[0] + red[1] + red[2] + red[3]);
}

template <int OP>
__global__ __launch_bounds__(256) void k_scale_op(const float* __restrict__ A,
                                                  const float* __restrict__ B2,
                                                  const float* __restrict__ ss,
                                                  float* __restrict__ outp) {
  long r = blockIdx.x;
  int l = (int)(r / kB), b = (int)(r % kB);
  int tid = threadIdx.x;
  float fac = 1.0f;
  if (ss) {
    int g = (l / kHW) * kB + b;
    fac = kScaleN * sqrtf(kCnt / (ss[g] + 1e-5f));
  }
  outp[r * kD + tid] = opval<OP>(A, B2, r, b, tid) * fac;
  outp[r * kD + tid + 256] = opval<OP>(A, B2, r, b, tid + 256) * fac;
}

// vb[b,:] = l2n(t1i_row_b @ WkC + bkC)   (t1i rows identical; read row q=0)
__global__ void k_vb(const float* __restrict__ t1i, const float* __restrict__ Wk,
                     const float* __restrict__ bk, float* __restrict__ vb) {
  __shared__ float part[4][128];
  __shared__ float red[2];
  int b = blockIdx.x;
  int j = threadIdx.x;   // 128
  int dz = threadIdx.y;  // 4
  const float* row = t1i + (long)b * kD;
  float acc = 0.f;
  int d0 = dz * 128;
  for (int d = d0; d < d0 + 128; ++d) acc += row[d] * Wk[(long)d * kKD + j];
  part[dz][j] = acc;
  __syncthreads();
  if (dz == 0) {
    float a = part[0][j] + part[1][j] + part[2][j] + part[3][j] + bk[j];
    float s = a * a;
    s = wsum(s);
    if ((j & 63) == 0) red[j >> 6] = s;
    part[0][j] = a;
  }
  __syncthreads();
  if (dz == 0) {
    float inv = 1.f / fmaxf(sqrtf(red[0] + red[1]), 1e-12f);
    vb[(long)b * kKD + j] = part[0][j] * inv;
  }
}

// cR[b*L+k] = vb_b . Kr[k,b,:], cI likewise with Ki
__global__ void k_cRcI(const float* __restrict__ vb, const float* __restrict__ Kr,
                       const float* __restrict__ Ki, float* __restrict__ cR,
                       float* __restrict__ cI) {
  int idx = blockIdx.x;
  int k = idx / kB, b = idx % kB;
  int lane = threadIdx.x;  // 64
  const float* v = vb + (long)b * kKD;
  const float* pr = Kr + ((long)k * kB + b) * kKD;
  const float* pi = Ki + ((long)k * kB + b) * kKD;
  float sR = 0.f, sI = 0.f;
  for (int c = lane; c < kKD; c += 64) {
    sR += v[c] * pr[c];
    sI += v[c] * pi[c];
  }
  sR = wsum(sR);
  sI = wsum(sI);
  if (lane == 0) {
    cR[(long)b * kL + k] = sR;
    cI[(long)b * kL + k] = sI;
  }
}

void launch_gemm(bool bt, bool acc, hipStream_t s, const float* A, const float* B, float* C,
                 int M, int N, int K, int lda, int ldb, int ldc, long sAb, long sBb, long sCb,
                 int batch) {
  dim3 grd(CDIV(N, 128), CDIV(M, 128), batch), blk(256);
  if (bt && !acc)
    k_gemm_mfma<true, false><<<grd, blk, 0, s>>>(A, B, C, M, N, K, lda, ldb, ldc, sAb, sBb, sCb);
  else if (bt && acc)
    k_gemm_mfma<true, true><<<grd, blk, 0, s>>>(A, B, C, M, N, K, lda, ldb, ldc, sAb, sBb, sCb);
  else
    k_gemm_mfma<false, false><<<grd, blk, 0, s>>>(A, B, C, M, N, K, lda, ldb, ldc, sAb, sBb, sCb);
}

}  // namespace

extern "C" void kernel_launch(void* const* d_in, const int* in_sizes, int n_in, void* d_out,
                              int out_size, void* d_ws, size_t ws_size, hipStream_t stream) {
  (void)in_sizes; (void)n_in; (void)out_size;
  const float* tf  = (const float*)d_in[0];
  const float* sf  = (const float*)d_in[1];
  const float* tl  = (const float*)d_in[2];
  const float* WkE = (const float*)d_in[3];
  const float* bkE = (const float*)d_in[4];
  const float* WkS = (const float*)d_in[5];
  const float* bkS = (const float*)d_in[6];
  const float* WkC = (const float*)d_in[7];
  const float* bkC = (const float*)d_in[8];
  const float* Wc  = (const float*)d_in[9];
  float* out = (float*)d_out;
  float* ws = (float*)d_ws;

  const long LBD = (long)kL * kB * kD;    // 5,947,392
  const long LBK = (long)kL * kB * kKD;   // 1,486,848
  const long HBD = (long)kHW * kB * kD;   // 1,982,464
  const long HBK = (long)kHW * kB * kKD;  // 495,616

  long off = 0;
  auto alloc = [&](long n) {
    long o = off;
    off += (n + 255) & ~255L;
    return o;
  };
  long o_seqT = alloc(LBD);
  long o_seqS = alloc(LBD);
  long o_Kr = alloc(LBK);
  long o_Ki = alloc(LBK);
  long o_Vr = alloc(LBD);
  long o_lab = alloc((long)kL * kB);
  long o_uE = alloc(kD);
  long o_uS = alloc(kKD);
  long o_vb = alloc((long)kB * kKD);
  long o_g = alloc((long)kB * kL);
  long o_cR = alloc((long)kB * kL);
  long o_cI = alloc((long)kB * kL);
  long o_row = alloc((long)kB * kD);
  long o_mkr = alloc((long)kHW * kB);
  long o_mki = alloc((long)kHW * kB);
  long o_ss = alloc(64);
  long o_scr = off;
  // encoder overlay
  long o_Pe = o_scr;
  long o_Ae = o_Pe + LBD;
  long o_ar = o_Ae + (long)kB * kL * kL;
  long o_mr = o_ar + LBD;
  long o_mi = o_mr + LBD;
  long total = o_mi + LBD;
  // per-image overlay (same scratch region, encoder done first)
  long o_Ps = o_scr;
  long o_Pc = o_Ps + HBK;
  long o_As = o_Pc + HBK;
  long o_S1 = o_As + (long)kB * kHW * kHW;
  long o_S2 = o_S1 + (long)kB * kHW * kL;
  long o_t1r = o_S2 + (long)kB * kHW * kL;
  long o_t1i = o_t1r + HBD;
  long o_c3r = o_t1i + HBD;
  long o_c3i = o_c3r + HBD;
  long o_t2r = o_c3i + HBD;
  long o_t2i = o_t2r + HBD;

  if ((size_t)total * sizeof(float) > ws_size) return;  // insufficient workspace

  float* seqT = ws + o_seqT;
  float* seqS = ws + o_seqS;
  float* Kr = ws + o_Kr;
  float* Ki = ws + o_Ki;
  float* Vr = ws + o_Vr;
  float* lab = ws + o_lab;
  float* uE = ws + o_uE;
  float* uS = ws + o_uS;
  float* vb = ws + o_vb;
  float* g_ = ws + o_g;
  float* cR = ws + o_cR;
  float* cI = ws + o_cI;
  float* row = ws + o_row;
  float* mkr = ws + o_mkr;
  float* mki = ws + o_mki;
  float* ssp = ws + o_ss;
  float* Pe = ws + o_Pe;
  float* Ae = ws + o_Ae;
  float* ar = ws + o_ar;
  float* mr = ws + o_mr;
  float* mi = ws + o_mi;
  float* Ps = ws + o_Ps;
  float* Pc = ws + o_Pc;
  float* As_ = ws + o_As;
  float* S1 = ws + o_S1;
  float* S2 = ws + o_S2;
  float* t1r = ws + o_t1r;
  float* t1i = ws + o_t1i;
  float* c3r = ws + o_c3r;
  float* c3i = ws + o_c3i;
  float* t2r = ws + o_t2r;
  float* t2i = ws + o_t2i;

  // ---- stage 0: layout + constants ----
  {
    dim3 grd(CDIV(kHW, 32), CDIV(kD, 32), kNI * kB), blk(32, 8);
    k_toseq<<<grd, blk, 0, stream>>>(tf, seqT);
    k_toseq<<<grd, blk, 0, stream>>>(sf, seqS);
  }
  k_lab<<<CDIV(kNI * kB * kHW, 256), 256, 0, stream>>>(tl, lab);
  k_l2n_vec<<<1, 128, 0, stream>>>(bkE, uE, kD);
  k_l2n_vec<<<1, 128, 0, stream>>>(bkS, uS, kKD);

  // ---- encoder ----
  launch_gemm(false, false, stream, seqT, WkE, Pe, kL * kB, kD, kD, kD, kD, kD, 0, 0, 0, 1);
  k_bias_l2n<<<kL * kB, 128, 0, stream>>>(Pe, bkE, kD);
  k_rowdot<<<kL * kB, 64, 0, stream>>>(Pe, uE, g_, kL, kD);
  k_softmax<<<kB, 256, 0, stream>>>(g_, 1, kL, nullptr, 0.f, nullptr, nullptr);  // wi_en
  launch_gemm(true, false, stream, Pe, Pe, Ae, kL, kL, kD, kB * kD, kB * kD, kL, kD, kD,
              (long)kL * kL, kB);
  k_softmax<<<kB * kL, 256, 0, stream>>>(Ae, kL, kL, nullptr, 0.f, nullptr, nullptr);
  launch_gemm(false, false, stream, Ae, seqT, ar, kL, kD, kL, kL, kB * kD, kB * kD,
              (long)kL * kL, kD, kD, kB);
  hipMemsetAsync(row, 0, kB * kD * sizeof(float), stream);
  k_wrowsum<<<dim3(kD / 128, kB, CDIV(kL, 64)), 128, 0, stream>>>(g_, seqT, row, kL, 64);  // ai
  // mem_r = inorm(seqT + ar); mem_i = inorm(bcast ai row)  [ss arena: slots 0..23, 24..47]
  hipMemsetAsync(ssp, 0, 48 * sizeof(float), stream);
  k_ss_op<0><<<kL * kB, 256, 0, stream>>>(seqT, ar, ssp);
  k_scale_op<0><<<kL * kB, 256, 0, stream>>>(seqT, ar, ssp, mr);
  k_ss_op<1><<<kL * kB, 256, 0, stream>>>(row, nullptr, ssp + 24);
  k_scale_op<1><<<kL * kB, 256, 0, stream>>>(row, nullptr, ssp + 24, mi);
  // Kr/Ki = l2n(mem @ WkC + bkC)
  launch_gemm(false, false, stream, mr, WkC, Kr, kL * kB, kKD, kD, kD, kKD, kKD, 0, 0, 0, 1);
  k_bias_l2n<<<kL * kB, 128, 0, stream>>>(Kr, bkC, kKD);
  launch_gemm(false, false, stream, mi, WkC, Ki, kL * kB, kKD, kD, kD, kKD, kKD, 0, 0, 0, 1);
  k_bias_l2n<<<kL * kB, 128, 0, stream>>>(Ki, bkC, kKD);
  // Vr = mem_r * lab
  k_scale_op<2><<<kL * kB, 256, 0, stream>>>(mr, lab, nullptr, Vr);

  // ---- decoder: 3 train images then 3 test images ----
  for (int img = 0; img < 6; ++img) {
    const float* t = (img < 3) ? (seqT + (long)img * HBD) : (seqS + (long)(img - 3) * HBD);
    float* osl = out + (long)img * kB * kD * kHW;

    // self-attention
    launch_gemm(false, false, stream, t, WkS, Ps, kHW * kB, kKD, kD, kD, kKD, kKD, 0, 0, 0, 1);
    k_bias_l2n<<<kHW * kB, 128, 0, stream>>>(Ps, bkS, kKD);
    k_rowdot<<<kHW * kB, 64, 0, stream>>>(Ps, uS, g_, kHW, kKD);
    k_softmax<<<kB, 256, 0, stream>>>(g_, 1, kHW, nullptr, 0.f, nullptr, nullptr);  // wi_s
    launch_gemm(true, false, stream, Ps, Ps, As_, kHW, kHW, kKD, kB * kKD, kB * kKD, kHW, kKD,
                kKD, (long)kHW * kHW, kB);
    k_softmax<<<kB * kHW, 256, 0, stream>>>(As_, kHW, kHW, nullptr, 0.f, nullptr, nullptr);
    launch_gemm(false, false, stream, As_, t, c3r, kHW, kD, kHW, kHW, kB * kD, kB * kD,
                (long)kHW * kHW, kD, kD, kB);  // s2r (staged in c3r)
    hipMemsetAsync(row, 0, kB * kD * sizeof(float), stream);
    k_wrowsum<<<dim3(kD / 128, kB, CDIV(kHW, 64)), 128, 0, stream>>>(g_, t, row, kHW, 64);
    // ss arena: t1r:0 t1i:8 t2r:16 t2i:24 t4r:32 t4i:40 outr:48 outi:56
    hipMemsetAsync(ssp, 0, 64 * sizeof(float), stream);
    // t1r = inorm(t + s2r); t1i = inorm(bcast s2i)
    k_ss_op<0><<<kHW * kB, 256, 0, stream>>>(t, c3r, ssp);
    k_scale_op<0><<<kHW * kB, 256, 0, stream>>>(t, c3r, ssp, t1r);
    k_ss_op<1><<<kHW * kB, 256, 0, stream>>>(row, nullptr, ssp + 8);
    k_scale_op<1><<<kHW * kB, 256, 0, stream>>>(row, nullptr, ssp + 8, t1i);
    // cross-attention (shared by mk and c3)
    k_vb<<<kB, dim3(128, 4), 0, stream>>>(t1i, WkC, bkC, vb);
    launch_gemm(false, false, stream, t1r, WkC, Pc, kHW * kB, kKD, kD, kD, kKD, kKD, 0, 0, 0, 1);
    k_bias_l2n<<<kHW * kB, 128, 0, stream>>>(Pc, bkC, kKD);
    k_cRcI<<<kL * kB, 64, 0, stream>>>(vb, Kr, Ki, cR, cI);
    launch_gemm(true, false, stream, Pc, Kr, S1, kHW, kL, kKD, kB * kKD, kB * kKD, kL, kKD, kKD,
                (long)kHW * kL, kB);
    launch_gemm(true, false, stream, Pc, Ki, S2, kHW, kL, kKD, kB * kKD, kB * kKD, kL, kKD, kKD,
                (long)kHW * kL, kB);
    k_softmax<<<kB * kHW, 256, 0, stream>>>(S1, kHW, kL, cI, -1.f, lab, mkr);  // Ar, mkr
    k_softmax<<<kB * kHW, 256, 0, stream>>>(S2, kHW, kL, cR, +1.f, lab, mki);  // Ai, mki
    launch_gemm(false, false, stream, S1, Vr, c3r, kHW, kD, kL, kL, kB * kD, kB * kD,
                (long)kHW * kL, kD, kD, kB);
    launch_gemm(false, false, stream, S2, Vr, c3i, kHW, kD, kL, kL, kB * kD, kB * kD,
                (long)kHW * kL, kD, kD, kB);
    // t2 = inorm(t1 * mk)
    k_ss_op<2><<<kHW * kB, 256, 0, stream>>>(t1r, mkr, ssp + 16);
    k_scale_op<2><<<kHW * kB, 256, 0, stream>>>(t1r, mkr, ssp + 16, t2r);
    k_ss_op<2><<<kHW * kB, 256, 0, stream>>>(t1i, mki, ssp + 24);
    k_scale_op<2><<<kHW * kB, 256, 0, stream>>>(t1i, mki, ssp + 24, t2i);
    // t4 = inorm(t1 + c3)  (in place into c3)
    k_ss_op<0><<<kHW * kB, 256, 0, stream>>>(t1r, c3r, ssp + 32);
    k_scale_op<0><<<kHW * kB, 256, 0, stream>>>(t1r, c3r, ssp + 32, c3r);
    k_ss_op<0><<<kHW * kB, 256, 0, stream>>>(t1i, c3i, ssp + 40);
    k_scale_op<0><<<kHW * kB, 256, 0, stream>>>(t1i, c3i, ssp + 40, c3i);
    // out = inorm(t2 + t4)  (in place into t2)
    k_ss_op<0><<<kHW * kB, 256, 0, stream>>>(t2r, c3r, ssp + 48);
    k_scale_op<0><<<kHW * kB, 256, 0, stream>>>(t2r, c3r, ssp + 48, t2r);
    k_ss_op<0><<<kHW * kB, 256, 0, stream>>>(t2i, c3i, ssp + 56);
    k_scale_op<0><<<kHW * kB, 256, 0, stream>>>(t2i, c3i, ssp + 56, t2i);
    // 1x1 compress conv: out[o,hw] = Wc[:,0:512]@outr^T + Wc[:,512:]@outi^T
    launch_gemm(true, false, stream, Wc, t2r, osl, kD, kHW, kD, 2 * kD, kB * kD, kHW, 0, kD,
                (long)kD * kHW, kB);
    launch_gemm(true, true, stream, Wc + kD, t2i, osl, kD, kHW, kD, 2 * kD, kB * kD, kHW, 0, kD,
                (long)kD * kHW, kB);
  }
}

// Round 4
// 3873.815 us; speedup vs baseline: 2.9790x; 1.6691x over previous
//
#include <hip/hip_runtime.h>

// ComTransformer on MI355X — round 4:
//  - inorm group-sum: atomicAdd on 8-24 hot addresses (130us each, serialized RMW)
//    -> 3-phase atomic-free (per-row partials, group reduce, scale), real/imag paired
//  - everything else as round 3 (128x128 bf16 MFMA GEMM, parallel wrowsum)
// Structure exploited:
//  - imag-branch softmax of real-input com_attn is q-independent (rank-1 output)
//  - mk/c3 cross-attentions share softmax matrices; mk values are label bcast
//  - t1i rows identical -> single vb vector per batch, score bias fused in softmax

namespace {

constexpr int kNI = 3;     // images per set
constexpr int kB  = 8;     // batch
constexpr int kD  = 512;   // feature dim
constexpr int kKD = 128;   // key dim (self/cross)
constexpr int kHW = 484;   // 22*22
constexpr int kL  = kNI * kHW;  // 1452
constexpr float kTemp = 30.0f;
constexpr float kCnt  = 247808.0f;             // d*h*w = 512*484
constexpr float kScaleN = 0.011048543456039806f; // sqrt(1/(512*16))

#define CDIV(a, b) (((a) + (b) - 1) / (b))

typedef float f32x4 __attribute__((ext_vector_type(4)));
typedef unsigned int u32x4 __attribute__((ext_vector_type(4)));

__device__ __forceinline__ float wsum(float v) {
#pragma unroll
  for (int o = 32; o; o >>= 1) v += __shfl_down(v, o);
  return v;
}
__device__ __forceinline__ float wmax(float v) {
#pragma unroll
  for (int o = 32; o; o >>= 1) v = fmaxf(v, __shfl_down(v, o));
  return v;
}

// pack two floats -> u32 of two bf16 (RNE)
__device__ __forceinline__ unsigned pk2bf(float lo, float hi) {
  union { float f; unsigned u; } a, b;
  a.f = lo; b.f = hi;
  unsigned ra = (a.u + 0x7FFFu + ((a.u >> 16) & 1u)) >> 16;
  unsigned rb = (b.u + 0x7FFFu + ((b.u >> 16) & 1u)) >> 16;
  return (ra & 0xFFFFu) | (rb << 16);
}

__device__ __forceinline__ void mfma_bf16(f32x4& d, const u32x4& a, const u32x4& b) {
  asm("v_mfma_f32_16x16x32_bf16 %0, %1, %2, %0" : "+v"(d) : "v"(a), "v"(b));
}

// ---------------- layout transform: [n,b,d,hw] -> seq [(n*hw),b,d] ----------------
__global__ void k_toseq(const float* __restrict__ in, float* __restrict__ out) {
  __shared__ float tile[32][33];
  int nb = blockIdx.z;
  int n = nb / kB, b = nb % kB;
  int p0 = blockIdx.x * 32, d0 = blockIdx.y * 32;
  int tx = threadIdx.x, ty = threadIdx.y;  // (32, 8)
  const float* ip = in + (long)nb * kD * kHW;
#pragma unroll
  for (int j = 0; j < 4; ++j) {
    int d = d0 + ty + j * 8, p = p0 + tx;
    if (d < kD && p < kHW) tile[ty + j * 8][tx] = ip[(long)d * kHW + p];
  }
  __syncthreads();
#pragma unroll
  for (int j = 0; j < 4; ++j) {
    int p = p0 + ty + j * 8, d = d0 + tx;
    if (p < kHW && d < kD)
      out[((long)(n * kHW + p) * kB + b) * kD + d] = tile[tx][ty + j * 8];
  }
}

// lab[(n*hw+p)*B + b] = train_label[n,b,p]
__global__ void k_lab(const float* __restrict__ tl, float* __restrict__ lab) {
  long i = (long)blockIdx.x * 256 + threadIdx.x;
  const long tot = (long)kNI * kB * kHW;
  if (i >= tot) return;
  int p = (int)(i % kHW);
  long t = i / kHW;
  int b = (int)(t % kB);
  int n = (int)(t / kB);
  lab[(long)(n * kHW + p) * kB + b] = tl[i];
}

// u = b / max(||b||, 1e-12)
__global__ void k_l2n_vec(const float* __restrict__ src, float* __restrict__ u, int C) {
  __shared__ float red[2];
  int tid = threadIdx.x;  // 128
  float s = 0.f;
  for (int c = tid; c < C; c += 128) { float x = src[c]; s += x * x; }
  s = wsum(s);
  if ((tid & 63) == 0) red[tid >> 6] = s;
  __syncthreads();
  float inv = 1.f / fmaxf(sqrtf(red[0] + red[1]), 1e-12f);
  for (int c = tid; c < C; c += 128) u[c] = src[c] * inv;
}

// ---------------- bf16 MFMA GEMM: C[m,n] (+)= sum_k A[m,k] * B(n|k) ---------------
// BT=true:  B element [n][k] at B[n*ldb + k]  (NT form)
// BT=false: B element [k][n] at B[k*ldb + n]  (NN form)
// Tile 128x128, BK=32, 4 waves (2x2), each wave 64x64 (4x4 frags of 16x16).
template <bool BT, bool ACC>
__global__ __launch_bounds__(256) void k_gemm_mfma(
    const float* __restrict__ A, const float* __restrict__ B, float* __restrict__ C,
    int M, int N, int K, int lda, int ldb, int ldc, long sAb, long sBb, long sCb) {
  A += (long)blockIdx.z * sAb;
  B += (long)blockIdx.z * sBb;
  C += (long)blockIdx.z * sCb;
  const int m0 = blockIdx.y * 128, n0 = blockIdx.x * 128;
  const int tid = threadIdx.x;
  const int wid = tid >> 6, lane = tid & 63;
  const int wr = wid >> 1, wc = wid & 1;
  const int fr = lane & 15, fk = lane >> 4;  // frag row(col), k-block

  __shared__ unsigned AsU[128 * 20];  // [128][20] u32 = [128][40] bf16
  __shared__ unsigned BsU[128 * 20];

  f32x4 acc[4][4] = {};

  const int sRow = tid >> 1;           // 0..127
  const int sH = (tid & 1) * 16;       // k elem offset: 0 or 16
  const int bN = tid & 127;            // B-NN staging col
  const int bKb = (tid >> 7) * 16;     // B-NN staging k base

  for (int k0 = 0; k0 < K; k0 += 32) {
    // ---- stage A tile [128 rows][32 k] ----
    {
      int gm = m0 + sRow;
      int kk = k0 + sH;
      float v[16];
      if (gm < M && K - kk >= 16) {
        const float* ap = A + (long)gm * lda + kk;
        float4 u0 = *(const float4*)(ap);
        float4 u1 = *(const float4*)(ap + 4);
        float4 u2 = *(const float4*)(ap + 8);
        float4 u3 = *(const float4*)(ap + 12);
        v[0]=u0.x; v[1]=u0.y; v[2]=u0.z; v[3]=u0.w;
        v[4]=u1.x; v[5]=u1.y; v[6]=u1.z; v[7]=u1.w;
        v[8]=u2.x; v[9]=u2.y; v[10]=u2.z; v[11]=u2.w;
        v[12]=u3.x; v[13]=u3.y; v[14]=u3.z; v[15]=u3.w;
      } else {
#pragma unroll
        for (int j = 0; j < 16; ++j)
          v[j] = (gm < M && kk + j < K) ? A[(long)gm * lda + kk + j] : 0.f;
      }
      unsigned* dst = &AsU[sRow * 20 + (sH >> 1)];
      u32x4 w0, w1;
      w0.x = pk2bf(v[0], v[1]);  w0.y = pk2bf(v[2], v[3]);
      w0.z = pk2bf(v[4], v[5]);  w0.w = pk2bf(v[6], v[7]);
      w1.x = pk2bf(v[8], v[9]);  w1.y = pk2bf(v[10], v[11]);
      w1.z = pk2bf(v[12], v[13]); w1.w = pk2bf(v[14], v[15]);
      *(u32x4*)dst = w0;
      *(u32x4*)(dst + 4) = w1;
    }
    // ---- stage B tile -> Bs[n][k] ----
    if (BT) {
      int gn = n0 + sRow;
      int kk = k0 + sH;
      float v[16];
      if (gn < N && K - kk >= 16) {
        const float* bp = B + (long)gn * ldb + kk;
        float4 u0 = *(const float4*)(bp);
        float4 u1 = *(const float4*)(bp + 4);
        float4 u2 = *(const float4*)(bp + 8);
        float4 u3 = *(const float4*)(bp + 12);
        v[0]=u0.x; v[1]=u0.y; v[2]=u0.z; v[3]=u0.w;
        v[4]=u1.x; v[5]=u1.y; v[6]=u1.z; v[7]=u1.w;
        v[8]=u2.x; v[9]=u2.y; v[10]=u2.z; v[11]=u2.w;
        v[12]=u3.x; v[13]=u3.y; v[14]=u3.z; v[15]=u3.w;
      } else {
#pragma unroll
        for (int j = 0; j < 16; ++j)
          v[j] = (gn < N && kk + j < K) ? B[(long)gn * ldb + kk + j] : 0.f;
      }
      unsigned* dst = &BsU[sRow * 20 + (sH >> 1)];
      u32x4 w0, w1;
      w0.x = pk2bf(v[0], v[1]);  w0.y = pk2bf(v[2], v[3]);
      w0.z = pk2bf(v[4], v[5]);  w0.w = pk2bf(v[6], v[7]);
      w1.x = pk2bf(v[8], v[9]);  w1.y = pk2bf(v[10], v[11]);
      w1.z = pk2bf(v[12], v[13]); w1.w = pk2bf(v[14], v[15]);
      *(u32x4*)dst = w0;
      *(u32x4*)(dst + 4) = w1;
    } else {
      int gn = n0 + bN;
      float v[16];
#pragma unroll
      for (int j = 0; j < 16; ++j) {
        int gk = k0 + bKb + j;
        v[j] = (gn < N && gk < K) ? B[(long)gk * ldb + gn] : 0.f;
      }
      unsigned* dst = &BsU[bN * 20 + (bKb >> 1)];
      u32x4 w0, w1;
      w0.x = pk2bf(v[0], v[1]);  w0.y = pk2bf(v[2], v[3]);
      w0.z = pk2bf(v[4], v[5]);  w0.w = pk2bf(v[6], v[7]);
      w1.x = pk2bf(v[8], v[9]);  w1.y = pk2bf(v[10], v[11]);
      w1.z = pk2bf(v[12], v[13]); w1.w = pk2bf(v[14], v[15]);
      *(u32x4*)dst = w0;
      *(u32x4*)(dst + 4) = w1;
    }
    __syncthreads();
    // ---- compute: 16 MFMA per wave ----
    u32x4 af[4], bf[4];
#pragma unroll
    for (int mi = 0; mi < 4; ++mi)
      af[mi] = *(const u32x4*)&AsU[(wr * 64 + mi * 16 + fr) * 20 + fk * 4];
#pragma unroll
    for (int ni = 0; ni < 4; ++ni)
      bf[ni] = *(const u32x4*)&BsU[(wc * 64 + ni * 16 + fr) * 20 + fk * 4];
#pragma unroll
    for (int mi = 0; mi < 4; ++mi)
#pragma unroll
      for (int ni = 0; ni < 4; ++ni) mfma_bf16(acc[mi][ni], af[mi], bf[ni]);
    __syncthreads();
  }
  // MFMA -> VALU read hazard guard (inline asm is opaque to the scheduler)
  asm volatile("s_nop 7\n\ts_nop 7" ::: );
  // ---- epilogue: C/D layout col=lane&15, row=(lane>>4)*4+reg ----
#pragma unroll
  for (int mi = 0; mi < 4; ++mi) {
#pragma unroll
    for (int r = 0; r < 4; ++r) {
      int gm = m0 + wr * 64 + mi * 16 + fk * 4 + r;
      if (gm >= M) continue;
#pragma unroll
      for (int ni = 0; ni < 4; ++ni) {
        int gn = n0 + wc * 64 + ni * 16 + fr;
        if (gn >= N) continue;
        long idx = (long)gm * ldc + gn;
        float v = acc[mi][ni][r];
        C[idx] = ACC ? (C[idx] + v) : v;
      }
    }
  }
}

// row += bias; row /= max(||row||,1e-12).  C in {128, 512}, block 128.
__global__ void k_bias_l2n(float* __restrict__ P, const float* __restrict__ bias, int C) {
  __shared__ float red[2];
  long row = blockIdx.x;
  float* p = P + row * C;
  int tid = threadIdx.x;
  int nv = C >> 7;
  float v[4];
  float s = 0.f;
#pragma unroll
  for (int i = 0; i < 4; ++i)
    if (i < nv) {
      float x = p[tid + (i << 7)] + bias[tid + (i << 7)];
      v[i] = x;
      s += x * x;
    }
  s = wsum(s);
  if ((tid & 63) == 0) red[tid >> 6] = s;
  __syncthreads();
  float inv = 1.f / fmaxf(sqrtf(red[0] + red[1]), 1e-12f);
#pragma unroll
  for (int i = 0; i < 4; ++i)
    if (i < nv) p[tid + (i << 7)] = v[i] * inv;
}

// g[b*L + k] = u . P[k,b,:]
__global__ void k_rowdot(const float* __restrict__ P, const float* __restrict__ u,
                         float* __restrict__ g, int L, int C) {
  int idx = blockIdx.x;
  int k = idx / kB, b = idx % kB;
  const float* p = P + ((long)k * kB + b) * C;
  int lane = threadIdx.x;  // 64
  float s = 0.f;
  for (int c = lane; c < C; c += 64) s += u[c] * p[c];
  s = wsum(s);
  if (lane == 0) g[(long)b * L + k] = s;
}

// softmax rows of S [B*Lq, Lk] in place: softmax(30*(S + bsign*bias[b,k]));
// optional mk[q*B+b] = sum_k p*lab[k*B+b]
__global__ __launch_bounds__(256) void k_softmax(float* __restrict__ S, int Lq, int Lk,
                                                 const float* __restrict__ bias, float bsign,
                                                 const float* __restrict__ lab,
                                                 float* __restrict__ mk) {
  __shared__ float sm[1456];
  __shared__ float red[4];
  int row = blockIdx.x;
  int b = row / Lq, q = row - b * Lq;
  float* Sr = S + (long)row * Lk;
  int tid = threadIdx.x;
  float mx = -3.0e38f;
  for (int k = tid; k < Lk; k += 256) {
    float v = Sr[k];
    if (bias) v += bsign * bias[(long)b * Lk + k];
    v *= kTemp;
    sm[k] = v;
    mx = fmaxf(mx, v);
  }
  mx = wmax(mx);
  if ((tid & 63) == 0) red[tid >> 6] = mx;
  __syncthreads();
  mx = fmaxf(fmaxf(red[0], red[1]), fmaxf(red[2], red[3]));
  __syncthreads();
  float s = 0.f;
  for (int k = tid; k < Lk; k += 256) {
    float e = expf(sm[k] - mx);
    sm[k] = e;
    s += e;
  }
  s = wsum(s);
  if ((tid & 63) == 0) red[tid >> 6] = s;
  __syncthreads();
  float inv = 1.0f / (red[0] + red[1] + red[2] + red[3]);
  __syncthreads();
  float dot = 0.f;
  for (int k = tid; k < Lk; k += 256) {
    float p = sm[k] * inv;
    Sr[k] = p;
    if (lab) dot += p * lab[(long)k * kB + b];
  }
  if (lab) {
    dot = wsum(dot);
    if ((tid & 63) == 0) red[tid >> 6] = dot;
    __syncthreads();
    if (tid == 0) mk[(long)q * kB + b] = red[0] + red[1] + red[2] + red[3];
  }
}

// rowout[b,d] += sum_{k in chunk} w[b*L+k] * S[k,b,d]   (rowout pre-zeroed)
__global__ void k_wrowsum(const float* __restrict__ w, const float* __restrict__ S,
                          float* __restrict__ rowout, int L, int kchunk) {
  int b = blockIdx.y;
  int d = blockIdx.x * 128 + threadIdx.x;
  int k0 = blockIdx.z * kchunk;
  int k1 = min(L, k0 + kchunk);
  float s = 0.f;
  for (int k = k0; k < k1; ++k) s += w[(long)b * L + k] * S[((long)k * kB + b) * kD + d];
  atomicAdd(&rowout[(long)b * kD + d], s);
}

// elementwise value for inorm pipeline.  r = row index = l*B + b, D = 512 fixed.
// OP 0: A[r,d]+B2[r,d]   OP 1: A[b,d] (broadcast)   OP 2: A[r,d]*B2[r]
template <int OP>
__device__ __forceinline__ float opval(const float* __restrict__ A,
                                       const float* __restrict__ B2, long r, int b, int d) {
  if (OP == 0) return A[r * kD + d] + B2[r * kD + d];
  if (OP == 1) return A[(long)b * kD + d];
  return A[r * kD + d] * B2[r];
}

// ---- 3-phase atomic-free inorm, real/imag paired via blockIdx.y ----
// phase 1: part[v*R + r] = sum_d val_v(r,d)^2
template <int OPA, int OPB>
__global__ __launch_bounds__(256) void k_ss2(const float* __restrict__ Aa,
                                             const float* __restrict__ Ba,
                                             const float* __restrict__ Ab,
                                             const float* __restrict__ Bb,
                                             float* __restrict__ part, int R) {
  __shared__ float red[4];
  int r = blockIdx.x, v = blockIdx.y;
  int b = r % kB;
  int tid = threadIdx.x;
  float z0, z1;
  if (v == 0) {
    z0 = opval<OPA>(Aa, Ba, r, b, tid);
    z1 = opval<OPA>(Aa, Ba, r, b, tid + 256);
  } else {
    z0 = opval<OPB>(Ab, Bb, r, b, tid);
    z1 = opval<OPB>(Ab, Bb, r, b, tid + 256);
  }
  float s = z0 * z0 + z1 * z1;
  s = wsum(s);
  if ((tid & 63) == 0) red[tid >> 6] = s;
  __syncthreads();
  if (tid == 0) part[(long)v * R + r] = red[0] + red[1] + red[2] + red[3];
}

// phase 2: ss[v*NG + g] = sum_p part[v*R + (n*kHW+p)*kB + b],  g = n*kB + b
__global__ void k_ssred(const float* __restrict__ part, float* __restrict__ ss, int R, int NG) {
  __shared__ float red[8];
  int g = blockIdx.x, v = blockIdx.y;
  int n = g / kB, b = g % kB;
  int tid = threadIdx.x;  // 512
  float s = 0.f;
  for (int p = tid; p < kHW; p += 512) s += part[(long)v * R + ((long)(n * kHW + p) * kB + b)];
  s = wsum(s);
  if ((tid & 63) == 0) red[tid >> 6] = s;
  __syncthreads();
  if (tid == 0) {
    float t = 0.f;
#pragma unroll
    for (int i = 0; i < 8; ++i) t += red[i];
    ss[(long)v * NG + g] = t;
  }
}

// phase 3: out_v[r,d] = val_v(r,d) * scale(ss[v*NG+g])
template <int OPA, int OPB>
__global__ __launch_bounds__(256) void k_scale2(const float* __restrict__ Aa,
                                                const float* __restrict__ Ba,
                                                float* __restrict__ outA,
                                                const float* __restrict__ Ab,
                                                const float* __restrict__ Bb,
                                                float* __restrict__ outB,
                                                const float* __restrict__ ss, int NG) {
  int r = blockIdx.x, v = blockIdx.y;
  int l = r / kB, b = r % kB;
  int g = (l / kHW) * kB + b;
  int tid = threadIdx.x;
  float fac = kScaleN * sqrtf(kCnt / (ss[(long)v * NG + g] + 1e-5f));
  if (v == 0) {
    outA[(long)r * kD + tid] = opval<OPA>(Aa, Ba, r, b, tid) * fac;
    outA[(long)r * kD + tid + 256] = opval<OPA>(Aa, Ba, r, b, tid + 256) * fac;
  } else {
    outB[(long)r * kD + tid] = opval<OPB>(Ab, Bb, r, b, tid) * fac;
    outB[(long)r * kD + tid + 256] = opval<OPB>(Ab, Bb, r, b, tid + 256) * fac;
  }
}

// out[r,d] = A[r,d] * s[r]   (Vr = mem_r * lab)
__global__ __launch_bounds__(256) void k_rowmul(const float* __restrict__ A,
                                                const float* __restrict__ s,
                                                float* __restrict__ outp) {
  long r = blockIdx.x;
  int tid = threadIdx.x;
  float f = s[r];
  outp[r * kD + tid] = A[r * kD + tid] * f;
  outp[r * kD + tid + 256] = A[r * kD + tid + 256] * f;
}

// vb[b,:] = l2n(t1i_row_b @ WkC + bkC)   (t1i rows identical; read row q=0)
__global__ void k_vb(const float* __restrict__ t1i, const float* __restrict__ Wk,
                     const float* __restrict__ bk, float* __restrict__ vb) {
  __shared__ float part[4][128];
  __shared__ float red[2];
  int b = blockIdx.x;
  int j = threadIdx.x;   // 128
  int dz = threadIdx.y;  // 4
  const float* row = t1i + (long)b * kD;
  float acc = 0.f;
  int d0 = dz * 128;
  for (int d = d0; d < d0 + 128; ++d) acc += row[d] * Wk[(long)d * kKD + j];
  part[dz][j] = acc;
  __syncthreads();
  if (dz == 0) {
    float a = part[0][j] + part[1][j] + part[2][j] + part[3][j] + bk[j];
    float s = a * a;
    s = wsum(s);
    if ((j & 63) == 0) red[j >> 6] = s;
    part[0][j] = a;
  }
  __syncthreads();
  if (dz == 0) {
    float inv = 1.f / fmaxf(sqrtf(red[0] + red[1]), 1e-12f);
    vb[(long)b * kKD + j] = part[0][j] * inv;
  }
}

// cR[b*L+k] = vb_b . Kr[k,b,:], cI likewise with Ki
__global__ void k_cRcI(const float* __restrict__ vb, const float* __restrict__ Kr,
                       const float* __restrict__ Ki, float* __restrict__ cR,
                       float* __restrict__ cI) {
  int idx = blockIdx.x;
  int k = idx / kB, b = idx % kB;
  int lane = threadIdx.x;  // 64
  const float* v = vb + (long)b * kKD;
  const float* pr = Kr + ((long)k * kB + b) * kKD;
  const float* pi = Ki + ((long)k * kB + b) * kKD;
  float sR = 0.f, sI = 0.f;
  for (int c = lane; c < kKD; c += 64) {
    sR += v[c] * pr[c];
    sI += v[c] * pi[c];
  }
  sR = wsum(sR);
  sI = wsum(sI);
  if (lane == 0) {
    cR[(long)b * kL + k] = sR;
    cI[(long)b * kL + k] = sI;
  }
}

void launch_gemm(bool bt, bool acc, hipStream_t s, const float* A, const float* B, float* C,
                 int M, int N, int K, int lda, int ldb, int ldc, long sAb, long sBb, long sCb,
                 int batch) {
  dim3 grd(CDIV(N, 128), CDIV(M, 128), batch), blk(256);
  if (bt && !acc)
    k_gemm_mfma<true, false><<<grd, blk, 0, s>>>(A, B, C, M, N, K, lda, ldb, ldc, sAb, sBb, sCb);
  else if (bt && acc)
    k_gemm_mfma<true, true><<<grd, blk, 0, s>>>(A, B, C, M, N, K, lda, ldb, ldc, sAb, sBb, sCb);
  else
    k_gemm_mfma<false, false><<<grd, blk, 0, s>>>(A, B, C, M, N, K, lda, ldb, ldc, sAb, sBb, sCb);
}

}  // namespace

extern "C" void kernel_launch(void* const* d_in, const int* in_sizes, int n_in, void* d_out,
                              int out_size, void* d_ws, size_t ws_size, hipStream_t stream) {
  (void)in_sizes; (void)n_in; (void)out_size;
  const float* tf  = (const float*)d_in[0];
  const float* sf  = (const float*)d_in[1];
  const float* tl  = (const float*)d_in[2];
  const float* WkE = (const float*)d_in[3];
  const float* bkE = (const float*)d_in[4];
  const float* WkS = (const float*)d_in[5];
  const float* bkS = (const float*)d_in[6];
  const float* WkC = (const float*)d_in[7];
  const float* bkC = (const float*)d_in[8];
  const float* Wc  = (const float*)d_in[9];
  float* out = (float*)d_out;
  float* ws = (float*)d_ws;

  const long LBD = (long)kL * kB * kD;    // 5,947,392
  const long LBK = (long)kL * kB * kKD;   // 1,486,848
  const long HBD = (long)kHW * kB * kD;   // 1,982,464
  const long HBK = (long)kHW * kB * kKD;  // 495,616

  long off = 0;
  auto alloc = [&](long n) {
    long o = off;
    off += (n + 255) & ~255L;
    return o;
  };
  long o_seqT = alloc(LBD);
  long o_seqS = alloc(LBD);
  long o_Kr = alloc(LBK);
  long o_Ki = alloc(LBK);
  long o_Vr = alloc(LBD);
  long o_lab = alloc((long)kL * kB);
  long o_uE = alloc(kD);
  long o_uS = alloc(kKD);
  long o_vb = alloc((long)kB * kKD);
  long o_g = alloc((long)kB * kL);
  long o_cR = alloc((long)kB * kL);
  long o_cI = alloc((long)kB * kL);
  long o_row = alloc((long)kB * kD);
  long o_mkr = alloc((long)kHW * kB);
  long o_mki = alloc((long)kHW * kB);
  long o_ss = alloc(64);
  long o_part = alloc(2L * kL * kB);
  long o_scr = off;
  // encoder overlay
  long o_Pe = o_scr;
  long o_Ae = o_Pe + LBD;
  long o_ar = o_Ae + (long)kB * kL * kL;
  long o_mr = o_ar + LBD;
  long o_mi = o_mr + LBD;
  long total = o_mi + LBD;
  // per-image overlay (same scratch region, encoder done first)
  long o_Ps = o_scr;
  long o_Pc = o_Ps + HBK;
  long o_As = o_Pc + HBK;
  long o_S1 = o_As + (long)kB * kHW * kHW;
  long o_S2 = o_S1 + (long)kB * kHW * kL;
  long o_t1r = o_S2 + (long)kB * kHW * kL;
  long o_t1i = o_t1r + HBD;
  long o_c3r = o_t1i + HBD;
  long o_c3i = o_c3r + HBD;
  long o_t2r = o_c3i + HBD;
  long o_t2i = o_t2r + HBD;

  if ((size_t)total * sizeof(float) > ws_size) return;  // insufficient workspace

  float* seqT = ws + o_seqT;
  float* seqS = ws + o_seqS;
  float* Kr = ws + o_Kr;
  float* Ki = ws + o_Ki;
  float* Vr = ws + o_Vr;
  float* lab = ws + o_lab;
  float* uE = ws + o_uE;
  float* uS = ws + o_uS;
  float* vb = ws + o_vb;
  float* g_ = ws + o_g;
  float* cR = ws + o_cR;
  float* cI = ws + o_cI;
  float* row = ws + o_row;
  float* mkr = ws + o_mkr;
  float* mki = ws + o_mki;
  float* ssp = ws + o_ss;
  float* part = ws + o_part;
  float* Pe = ws + o_Pe;
  float* Ae = ws + o_Ae;
  float* ar = ws + o_ar;
  float* mr = ws + o_mr;
  float* mi = ws + o_mi;
  float* Ps = ws + o_Ps;
  float* Pc = ws + o_Pc;
  float* As_ = ws + o_As;
  float* S1 = ws + o_S1;
  float* S2 = ws + o_S2;
  float* t1r = ws + o_t1r;
  float* t1i = ws + o_t1i;
  float* c3r = ws + o_c3r;
  float* c3i = ws + o_c3i;
  float* t2r = ws + o_t2r;
  float* t2i = ws + o_t2i;

  // ---- stage 0: layout + constants ----
  {
    dim3 grd(CDIV(kHW, 32), CDIV(kD, 32), kNI * kB), blk(32, 8);
    k_toseq<<<grd, blk, 0, stream>>>(tf, seqT);
    k_toseq<<<grd, blk, 0, stream>>>(sf, seqS);
  }
  k_lab<<<CDIV(kNI * kB * kHW, 256), 256, 0, stream>>>(tl, lab);
  k_l2n_vec<<<1, 128, 0, stream>>>(bkE, uE, kD);
  k_l2n_vec<<<1, 128, 0, stream>>>(bkS, uS, kKD);

  // ---- encoder ----
  launch_gemm(false, false, stream, seqT, WkE, Pe, kL * kB, kD, kD, kD, kD, kD, 0, 0, 0, 1);
  k_bias_l2n<<<kL * kB, 128, 0, stream>>>(Pe, bkE, kD);
  k_rowdot<<<kL * kB, 64, 0, stream>>>(Pe, uE, g_, kL, kD);
  k_softmax<<<kB, 256, 0, stream>>>(g_, 1, kL, nullptr, 0.f, nullptr, nullptr);  // wi_en
  launch_gemm(true, false, stream, Pe, Pe, Ae, kL, kL, kD, kB * kD, kB * kD, kL, kD, kD,
              (long)kL * kL, kB);
  k_softmax<<<kB * kL, 256, 0, stream>>>(Ae, kL, kL, nullptr, 0.f, nullptr, nullptr);
  launch_gemm(false, false, stream, Ae, seqT, ar, kL, kD, kL, kL, kB * kD, kB * kD,
              (long)kL * kL, kD, kD, kB);
  hipMemsetAsync(row, 0, kB * kD * sizeof(float), stream);
  k_wrowsum<<<dim3(kD / 128, kB, CDIV(kL, 64)), 128, 0, stream>>>(g_, seqT, row, kL, 64);  // ai
  // mem_r = inorm(seqT + ar); mem_i = inorm(bcast ai row)
  k_ss2<0, 1><<<dim3(kL * kB, 2), 256, 0, stream>>>(seqT, ar, row, nullptr, part, kL * kB);
  k_ssred<<<dim3(kNI * kB, 2), 512, 0, stream>>>(part, ssp, kL * kB, kNI * kB);
  k_scale2<0, 1><<<dim3(kL * kB, 2), 256, 0, stream>>>(seqT, ar, mr, row, nullptr, mi, ssp,
                                                       kNI * kB);
  // Kr/Ki = l2n(mem @ WkC + bkC)
  launch_gemm(false, false, stream, mr, WkC, Kr, kL * kB, kKD, kD, kD, kKD, kKD, 0, 0, 0, 1);
  k_bias_l2n<<<kL * kB, 128, 0, stream>>>(Kr, bkC, kKD);
  launch_gemm(false, false, stream, mi, WkC, Ki, kL * kB, kKD, kD, kD, kKD, kKD, 0, 0, 0, 1);
  k_bias_l2n<<<kL * kB, 128, 0, stream>>>(Ki, bkC, kKD);
  // Vr = mem_r * lab
  k_rowmul<<<kL * kB, 256, 0, stream>>>(mr, lab, Vr);

  // ---- decoder: 3 train images then 3 test images ----
  const int R = kHW * kB;  // 3872 rows per image
  for (int img = 0; img < 6; ++img) {
    const float* t = (img < 3) ? (seqT + (long)img * HBD) : (seqS + (long)(img - 3) * HBD);
    float* osl = out + (long)img * kB * kD * kHW;

    // self-attention
    launch_gemm(false, false, stream, t, WkS, Ps, kHW * kB, kKD, kD, kD, kKD, kKD, 0, 0, 0, 1);
    k_bias_l2n<<<kHW * kB, 128, 0, stream>>>(Ps, bkS, kKD);
    k_rowdot<<<kHW * kB, 64, 0, stream>>>(Ps, uS, g_, kHW, kKD);
    k_softmax<<<kB, 256, 0, stream>>>(g_, 1, kHW, nullptr, 0.f, nullptr, nullptr);  // wi_s
    launch_gemm(true, false, stream, Ps, Ps, As_, kHW, kHW, kKD, kB * kKD, kB * kKD, kHW, kKD,
                kKD, (long)kHW * kHW, kB);
    k_softmax<<<kB * kHW, 256, 0, stream>>>(As_, kHW, kHW, nullptr, 0.f, nullptr, nullptr);
    launch_gemm(false, false, stream, As_, t, c3r, kHW, kD, kHW, kHW, kB * kD, kB * kD,
                (long)kHW * kHW, kD, kD, kB);  // s2r (staged in c3r)
    hipMemsetAsync(row, 0, kB * kD * sizeof(float), stream);
    k_wrowsum<<<dim3(kD / 128, kB, CDIV(kHW, 64)), 128, 0, stream>>>(g_, t, row, kHW, 64);
    // t1r = inorm(t + s2r); t1i = inorm(bcast s2i)
    k_ss2<0, 1><<<dim3(R, 2), 256, 0, stream>>>(t, c3r, row, nullptr, part, R);
    k_ssred<<<dim3(kB, 2), 512, 0, stream>>>(part, ssp, R, kB);
    k_scale2<0, 1><<<dim3(R, 2), 256, 0, stream>>>(t, c3r, t1r, row, nullptr, t1i, ssp, kB);
    // cross-attention (shared by mk and c3)
    k_vb<<<kB, dim3(128, 4), 0, stream>>>(t1i, WkC, bkC, vb);
    launch_gemm(false, false, stream, t1r, WkC, Pc, kHW * kB, kKD, kD, kD, kKD, kKD, 0, 0, 0, 1);
    k_bias_l2n<<<kHW * kB, 128, 0, stream>>>(Pc, bkC, kKD);
    k_cRcI<<<kL * kB, 64, 0, stream>>>(vb, Kr, Ki, cR, cI);
    launch_gemm(true, false, stream, Pc, Kr, S1, kHW, kL, kKD, kB * kKD, kB * kKD, kL, kKD, kKD,
                (long)kHW * kL, kB);
    launch_gemm(true, false, stream, Pc, Ki, S2, kHW, kL, kKD, kB * kKD, kB * kKD, kL, kKD, kKD,
                (long)kHW * kL, kB);
    k_softmax<<<kB * kHW, 256, 0, stream>>>(S1, kHW, kL, cI, -1.f, lab, mkr);  // Ar, mkr
    k_softmax<<<kB * kHW, 256, 0, stream>>>(S2, kHW, kL, cR, +1.f, lab, mki);  // Ai, mki
    launch_gemm(false, false, stream, S1, Vr, c3r, kHW, kD, kL, kL, kB * kD, kB * kD,
                (long)kHW * kL, kD, kD, kB);
    launch_gemm(false, false, stream, S2, Vr, c3i, kHW, kD, kL, kL, kB * kD, kB * kD,
                (long)kHW * kL, kD, kD, kB);
    // t2 = inorm(t1 * mk)
    k_ss2<2, 2><<<dim3(R, 2), 256, 0, stream>>>(t1r, mkr, t1i, mki, part, R);
    k_ssred<<<dim3(kB, 2), 512, 0, stream>>>(part, ssp, R, kB);
    k_scale2<2, 2><<<dim3(R, 2), 256, 0, stream>>>(t1r, mkr, t2r, t1i, mki, t2i, ssp, kB);
    // t4 = inorm(t1 + c3)  (in place into c3)
    k_ss2<0, 0><<<dim3(R, 2), 256, 0, stream>>>(t1r, c3r, t1i, c3i, part, R);
    k_ssred<<<dim3(kB, 2), 512, 0, stream>>>(part, ssp, R, kB);
    k_scale2<0, 0><<<dim3(R, 2), 256, 0, stream>>>(t1r, c3r, c3r, t1i, c3i, c3i, ssp, kB);
    // out = inorm(t2 + t4)  (in place into t2)
    k_ss2<0, 0><<<dim3(R, 2), 256, 0, stream>>>(t2r, c3r, t2i, c3i, part, R);
    k_ssred<<<dim3(kB, 2), 512, 0, stream>>>(part, ssp, R, kB);
    k_scale2<0, 0><<<dim3(R, 2), 256, 0, stream>>>(t2r, c3r, t2r, t2i, c3i, t2i, ssp, kB);
    // 1x1 compress conv: out[o,hw] = Wc[:,0:512]@outr^T + Wc[:,512:]@outi^T
    launch_gemm(true, false, stream, Wc, t2r, osl, kD, kHW, kD, 2 * kD, kB * kD, kHW, 0, kD,
                (long)kD * kHW, kB);
    launch_gemm(true, true, stream, Wc + kD, t2i, osl, kD, kHW, kD, 2 * kD, kB * kD, kHW, 0, kD,
                (long)kD * kHW, kB);
  }
}

// Round 5
// 2556.078 us; speedup vs baseline: 4.5147x; 1.5155x over previous
//
#include <hip/hip_runtime.h>

// ComTransformer on MI355X — round 5: all-bf16 NT-only MFMA GEMM.
//  - operands pre-converted to bf16 by producers (no per-tile fp32->bf16 VALU storm)
//  - NN path eliminated: weights pre-transposed; AV uses raw-input layout as B^T;
//    V via dedicated VrT transpose; encoder AV = 3 ACC chunks over images
//  - tiles sized for occupancy: (128,128)/(64,128)/(64,64) per shape
// Structure exploited (earlier rounds):
//  - imag-branch softmax of real-input com_attn is q-independent (rank-1 output)
//  - mk/c3 cross-attentions share softmax matrices; mk values are label bcast
//  - t1i rows identical -> single vb vector per batch, score bias fused in softmax

namespace {

constexpr int kNI = 3;
constexpr int kB  = 8;
constexpr int kD  = 512;
constexpr int kKD = 128;
constexpr int kHW = 484;
constexpr int kL  = kNI * kHW;  // 1452
constexpr int kLp = 1456;       // kL padded to %8
constexpr int kHWp = 488;       // kHW padded to %8
constexpr float kTemp = 30.0f;
constexpr float kCnt  = 247808.0f;
constexpr float kScaleN = 0.011048543456039806f;

#define CDIV(a, b) (((a) + (b) - 1) / (b))

typedef float f32x4 __attribute__((ext_vector_type(4)));
typedef unsigned int u32x4 __attribute__((ext_vector_type(4)));
typedef unsigned short u16b;

__device__ __forceinline__ float wsum(float v) {
#pragma unroll
  for (int o = 32; o; o >>= 1) v += __shfl_down(v, o);
  return v;
}
__device__ __forceinline__ float wmax(float v) {
#pragma unroll
  for (int o = 32; o; o >>= 1) v = fmaxf(v, __shfl_down(v, o));
  return v;
}

__device__ __forceinline__ unsigned pk2bf(float lo, float hi) {
  union { float f; unsigned u; } a, b;
  a.f = lo; b.f = hi;
  unsigned ra = (a.u + 0x7FFFu + ((a.u >> 16) & 1u)) >> 16;
  unsigned rb = (b.u + 0x7FFFu + ((b.u >> 16) & 1u)) >> 16;
  return (ra & 0xFFFFu) | (rb << 16);
}
__device__ __forceinline__ u16b f2bf(float x) {
  union { float f; unsigned u; } a;
  a.f = x;
  return (u16b)((a.u + 0x7FFFu + ((a.u >> 16) & 1u)) >> 16);
}

__device__ __forceinline__ void mfma_bf16(f32x4& d, const u32x4& a, const u32x4& b) {
  asm("v_mfma_f32_16x16x32_bf16 %0, %1, %2, %0" : "+v"(d) : "v"(a), "v"(b));
}

// ---------------- layout transform: [n,b,d,hw] -> seq [(n*hw),b,d] fp32 -----------
__global__ void k_toseq(const float* __restrict__ in, float* __restrict__ out) {
  __shared__ float tile[32][33];
  int nb = blockIdx.z;
  int n = nb / kB, b = nb % kB;
  int p0 = blockIdx.x * 32, d0 = blockIdx.y * 32;
  int tx = threadIdx.x, ty = threadIdx.y;
  const float* ip = in + (long)nb * kD * kHW;
#pragma unroll
  for (int j = 0; j < 4; ++j) {
    int d = d0 + ty + j * 8, p = p0 + tx;
    if (d < kD && p < kHW) tile[ty + j * 8][tx] = ip[(long)d * kHW + p];
  }
  __syncthreads();
#pragma unroll
  for (int j = 0; j < 4; ++j) {
    int p = p0 + ty + j * 8, d = d0 + tx;
    if (p < kHW && d < kD)
      out[((long)(n * kHW + p) * kB + b) * kD + d] = tile[tx][ty + j * 8];
  }
}

// flat/padded fp32 -> bf16: out[row][0..C) stride Cp
__global__ void k_cvt2d(const float* __restrict__ in, u16b* __restrict__ out, int C, int Cp) {
  long r = blockIdx.x;
  for (int c = threadIdx.x; c < C; c += 256)
    out[r * Cp + c] = f2bf(in[r * (long)C + c]);
}

// transpose + cvt: in fp32 [R][C] -> out bf16 [C][R]
__global__ void k_tcvt(const float* __restrict__ in, u16b* __restrict__ out, int R, int C) {
  __shared__ float tile[32][33];
  int c0 = blockIdx.x * 32, r0 = blockIdx.y * 32;
  int tx = threadIdx.x, ty = threadIdx.y;
#pragma unroll
  for (int j = 0; j < 4; ++j) {
    int r = r0 + ty + j * 8, c = c0 + tx;
    if (r < R && c < C) tile[ty + j * 8][tx] = in[(long)r * C + c];
  }
  __syncthreads();
#pragma unroll
  for (int j = 0; j < 4; ++j) {
    int c = c0 + ty + j * 8, r = r0 + tx;
    if (r < R && c < C) out[(long)c * R + r] = f2bf(tile[tx][ty + j * 8]);
  }
}

// VrT[b][d][l] = bf16( mr[(l,b),d] * lab[l,b] ), stride kLp
__global__ void k_vrt(const float* __restrict__ mr, const float* __restrict__ lab,
                      u16b* __restrict__ vt) {
  __shared__ float tile[32][33];
  int l0 = blockIdx.x * 32, d0 = blockIdx.y * 32, b = blockIdx.z;
  int tx = threadIdx.x, ty = threadIdx.y;
#pragma unroll
  for (int j = 0; j < 4; ++j) {
    int l = l0 + ty + j * 8;
    if (l < kL)
      tile[ty + j * 8][tx] = mr[((long)l * kB + b) * kD + d0 + tx] * lab[(long)l * kB + b];
  }
  __syncthreads();
#pragma unroll
  for (int j = 0; j < 4; ++j) {
    int d = d0 + ty + j * 8, l = l0 + tx;
    if (l < kL) vt[((long)b * kD + d) * kLp + l] = f2bf(tile[tx][ty + j * 8]);
  }
}

// lab[(n*hw+p)*B + b] = train_label[n,b,p]
__global__ void k_lab(const float* __restrict__ tl, float* __restrict__ lab) {
  long i = (long)blockIdx.x * 256 + threadIdx.x;
  const long tot = (long)kNI * kB * kHW;
  if (i >= tot) return;
  int p = (int)(i % kHW);
  long t = i / kHW;
  int b = (int)(t % kB);
  int n = (int)(t / kB);
  lab[(long)(n * kHW + p) * kB + b] = tl[i];
}

__global__ void k_l2n_vec(const float* __restrict__ src, float* __restrict__ u, int C) {
  __shared__ float red[2];
  int tid = threadIdx.x;  // 128
  float s = 0.f;
  for (int c = tid; c < C; c += 128) { float x = src[c]; s += x * x; }
  s = wsum(s);
  if ((tid & 63) == 0) red[tid >> 6] = s;
  __syncthreads();
  float inv = 1.f / fmaxf(sqrtf(red[0] + red[1]), 1e-12f);
  for (int c = tid; c < C; c += 128) u[c] = src[c] * inv;
}

// ---------------- NT bf16 MFMA GEMM -----------------------------------------------
// C[m][n] (+)= sum_k A[m][k] * B[n][k].  A bf16 (or fp32 if AF32), B bf16.
// strides in elements; batch offsets sAb/sBb/sCb in elements.
template <int BR, bool F32>
__device__ __forceinline__ void stage_tile(const char* src, unsigned* dstU, int g0, int RM,
                                           int k0, int K, int ld) {
  const int TC = BR * 4;
  for (int ci = threadIdx.x; ci < TC; ci += 256) {
    int row = ci >> 2, c = ci & 3;
    int gr = g0 + row;
    int gk = k0 + c * 8;
    u32x4 w;
    if (F32) {
      const float* A = (const float*)src;
      if (gr < RM && gk + 8 <= K) {
        const float* ap = A + (long)gr * ld + gk;
        float4 u0 = *(const float4*)ap;
        float4 u1 = *(const float4*)(ap + 4);
        w.x = pk2bf(u0.x, u0.y); w.y = pk2bf(u0.z, u0.w);
        w.z = pk2bf(u1.x, u1.y); w.w = pk2bf(u1.z, u1.w);
      } else {
        float v[8];
#pragma unroll
        for (int j = 0; j < 8; ++j)
          v[j] = (gr < RM && gk + j < K) ? A[(long)gr * ld + gk + j] : 0.f;
        w.x = pk2bf(v[0], v[1]); w.y = pk2bf(v[2], v[3]);
        w.z = pk2bf(v[4], v[5]); w.w = pk2bf(v[6], v[7]);
      }
    } else {
      const u16b* A = (const u16b*)src;
      if (gr < RM && gk + 8 <= K) {
        w = *(const u32x4*)(A + (long)gr * ld + gk);
      } else {
        unsigned v[8];
#pragma unroll
        for (int j = 0; j < 8; ++j)
          v[j] = (gr < RM && gk + j < K) ? A[(long)gr * ld + gk + j] : 0u;
        w.x = v[0] | (v[1] << 16); w.y = v[2] | (v[3] << 16);
        w.z = v[4] | (v[5] << 16); w.w = v[6] | (v[7] << 16);
      }
    }
    *(u32x4*)&dstU[row * 20 + c * 4] = w;
  }
}

template <int BM, int BN, bool AF32, bool ACC>
__global__ __launch_bounds__(256) void k_gemm(const void* Ap, const u16b* __restrict__ B,
                                              float* __restrict__ C, int M, int N, int K,
                                              int lda, int ldb, int ldc, long sAb, long sBb,
                                              long sCb) {
  const char* Ab = (const char*)Ap + (long)blockIdx.z * sAb * (AF32 ? 4 : 2);
  const char* Bb = (const char*)B + (long)blockIdx.z * sBb * 2;
  C += (long)blockIdx.z * sCb;
  constexpr int FM = BM / 32, FN = BN / 32;
  const int m0 = blockIdx.y * BM, n0 = blockIdx.x * BN;
  const int tid = threadIdx.x;
  const int wid = tid >> 6, lane = tid & 63;
  const int wr = wid >> 1, wc = wid & 1;
  const int fr = lane & 15, fk = lane >> 4;

  __shared__ unsigned AsU[BM * 20];
  __shared__ unsigned BsU[BN * 20];
  f32x4 acc[FM][FN] = {};

  for (int k0 = 0; k0 < K; k0 += 32) {
    stage_tile<BM, AF32>(Ab, AsU, m0, M, k0, K, lda);
    stage_tile<BN, false>(Bb, BsU, n0, N, k0, K, ldb);
    __syncthreads();
    u32x4 af[FM], bf[FN];
#pragma unroll
    for (int mi = 0; mi < FM; ++mi)
      af[mi] = *(const u32x4*)&AsU[(wr * (BM / 2) + mi * 16 + fr) * 20 + fk * 4];
#pragma unroll
    for (int ni = 0; ni < FN; ++ni)
      bf[ni] = *(const u32x4*)&BsU[(wc * (BN / 2) + ni * 16 + fr) * 20 + fk * 4];
#pragma unroll
    for (int mi = 0; mi < FM; ++mi)
#pragma unroll
      for (int ni = 0; ni < FN; ++ni) mfma_bf16(acc[mi][ni], af[mi], bf[ni]);
    __syncthreads();
  }
  asm volatile("s_nop 7\n\ts_nop 7" ::: );
#pragma unroll
  for (int mi = 0; mi < FM; ++mi) {
#pragma unroll
    for (int r = 0; r < 4; ++r) {
      int gm = m0 + wr * (BM / 2) + mi * 16 + fk * 4 + r;
      if (gm >= M) continue;
#pragma unroll
      for (int ni = 0; ni < FN; ++ni) {
        int gn = n0 + wc * (BN / 2) + ni * 16 + fr;
        if (gn >= N) continue;
        long idx = (long)gm * ldc + gn;
        float v = acc[mi][ni][r];
        C[idx] = ACC ? (C[idx] + v) : v;
      }
    }
  }
}

// row += bias; l2-normalize; fp32 in place + bf16 mirror (stride C)
__global__ void k_bias_l2n(float* __restrict__ P, const float* __restrict__ bias, int C,
                           u16b* __restrict__ outb) {
  __shared__ float red[2];
  long row = blockIdx.x;
  float* p = P + row * C;
  int tid = threadIdx.x;  // 128
  int nv = C >> 7;
  float v[4];
  float s = 0.f;
#pragma unroll
  for (int i = 0; i < 4; ++i)
    if (i < nv) {
      float x = p[tid + (i << 7)] + bias[tid + (i << 7)];
      v[i] = x;
      s += x * x;
    }
  s = wsum(s);
  if ((tid & 63) == 0) red[tid >> 6] = s;
  __syncthreads();
  float inv = 1.f / fmaxf(sqrtf(red[0] + red[1]), 1e-12f);
#pragma unroll
  for (int i = 0; i < 4; ++i)
    if (i < nv) {
      float x = v[i] * inv;
      p[tid + (i << 7)] = x;
      outb[row * C + tid + (i << 7)] = f2bf(x);
    }
}

__global__ void k_rowdot(const float* __restrict__ P, const float* __restrict__ u,
                         float* __restrict__ g, int L, int C) {
  int idx = blockIdx.x;
  int k = idx / kB, b = idx % kB;
  const float* p = P + ((long)k * kB + b) * C;
  int lane = threadIdx.x;  // 64
  float s = 0.f;
  for (int c = lane; c < C; c += 64) s += u[c] * p[c];
  s = wsum(s);
  if (lane == 0) g[(long)b * L + k] = s;
}

// softmax rows of S [B*Lq, Lk]: softmax(30*(S + bsign*bias[b,k]));
// if outb: write bf16 at row*ldo (fp32 S untouched) else write fp32 in place.
// optional mk[q*B+b] = sum_k p*lab[k*B+b]
__global__ __launch_bounds__(256) void k_softmax(float* __restrict__ S, int Lq, int Lk,
                                                 const float* __restrict__ bias, float bsign,
                                                 const float* __restrict__ lab,
                                                 float* __restrict__ mk,
                                                 u16b* __restrict__ outb, int ldo) {
  __shared__ float sm[1456];
  __shared__ float red[4];
  int row = blockIdx.x;
  int b = row / Lq, q = row - b * Lq;
  float* Sr = S + (long)row * Lk;
  int tid = threadIdx.x;
  float mx = -3.0e38f;
  for (int k = tid; k < Lk; k += 256) {
    float v = Sr[k];
    if (bias) v += bsign * bias[(long)b * Lk + k];
    v *= kTemp;
    sm[k] = v;
    mx = fmaxf(mx, v);
  }
  mx = wmax(mx);
  if ((tid & 63) == 0) red[tid >> 6] = mx;
  __syncthreads();
  mx = fmaxf(fmaxf(red[0], red[1]), fmaxf(red[2], red[3]));
  __syncthreads();
  float s = 0.f;
  for (int k = tid; k < Lk; k += 256) {
    float e = expf(sm[k] - mx);
    sm[k] = e;
    s += e;
  }
  s = wsum(s);
  if ((tid & 63) == 0) red[tid >> 6] = s;
  __syncthreads();
  float inv = 1.0f / (red[0] + red[1] + red[2] + red[3]);
  __syncthreads();
  float dot = 0.f;
  for (int k = tid; k < Lk; k += 256) {
    float p = sm[k] * inv;
    if (outb) outb[(long)row * ldo + k] = f2bf(p); else Sr[k] = p;
    if (lab) dot += p * lab[(long)k * kB + b];
  }
  if (lab) {
    dot = wsum(dot);
    if ((tid & 63) == 0) red[tid >> 6] = dot;
    __syncthreads();
    if (tid == 0) mk[(long)q * kB + b] = red[0] + red[1] + red[2] + red[3];
  }
}

// rowout[b,d] += sum_{k chunk} w[b*L+k] * S[k,b,d]
__global__ void k_wrowsum(const float* __restrict__ w, const float* __restrict__ S,
                          float* __restrict__ rowout, int L, int kchunk) {
  int b = blockIdx.y;
  int d = blockIdx.x * 128 + threadIdx.x;
  int k0 = blockIdx.z * kchunk;
  int k1 = min(L, k0 + kchunk);
  float s = 0.f;
  for (int k = k0; k < k1; ++k) s += w[(long)b * L + k] * S[((long)k * kB + b) * kD + d];
  atomicAdd(&rowout[(long)b * kD + d], s);
}

// OP 0: A[r,d]+B2[r,d]   OP 1: A[b,d] (broadcast)   OP 2: A[r,d]*B2[r]
template <int OP>
__device__ __forceinline__ float opval(const float* __restrict__ A,
                                       const float* __restrict__ B2, long r, int b, int d) {
  if (OP == 0) return A[r * kD + d] + B2[r * kD + d];
  if (OP == 1) return A[(long)b * kD + d];
  return A[r * kD + d] * B2[r];
}

template <int OPA, int OPB>
__global__ __launch_bounds__(256) void k_ss2(const float* __restrict__ Aa,
                                             const float* __restrict__ Ba,
                                             const float* __restrict__ Ab,
                                             const float* __restrict__ Bb,
                                             float* __restrict__ part, int R) {
  __shared__ float red[4];
  int r = blockIdx.x, v = blockIdx.y;
  int b = r % kB;
  int tid = threadIdx.x;
  float z0, z1;
  if (v == 0) {
    z0 = opval<OPA>(Aa, Ba, r, b, tid);
    z1 = opval<OPA>(Aa, Ba, r, b, tid + 256);
  } else {
    z0 = opval<OPB>(Ab, Bb, r, b, tid);
    z1 = opval<OPB>(Ab, Bb, r, b, tid + 256);
  }
  float s = z0 * z0 + z1 * z1;
  s = wsum(s);
  if ((tid & 63) == 0) red[tid >> 6] = s;
  __syncthreads();
  if (tid == 0) part[(long)v * R + r] = red[0] + red[1] + red[2] + red[3];
}

__global__ void k_ssred(const float* __restrict__ part, float* __restrict__ ss, int R, int NG) {
  __shared__ float red[8];
  int g = blockIdx.x, v = blockIdx.y;
  int n = g / kB, b = g % kB;
  int tid = threadIdx.x;  // 512
  float s = 0.f;
  for (int p = tid; p < kHW; p += 512) s += part[(long)v * R + ((long)(n * kHW + p) * kB + b)];
  s = wsum(s);
  if ((tid & 63) == 0) red[tid >> 6] = s;
  __syncthreads();
  if (tid == 0) {
    float t = 0.f;
#pragma unroll
    for (int i = 0; i < 8; ++i) t += red[i];
    ss[(long)v * NG + g] = t;
  }
}

// phase 3 + optional bf16 mirrors
template <int OPA, int OPB>
__global__ __launch_bounds__(256) void k_scale2(const float* __restrict__ Aa,
                                                const float* __restrict__ Ba,
                                                float* __restrict__ outA,
                                                const float* __restrict__ Ab,
                                                const float* __restrict__ Bb,
                                                float* __restrict__ outB,
                                                const float* __restrict__ ss, int NG,
                                                u16b* __restrict__ oAb,
                                                u16b* __restrict__ oBb) {
  int r = blockIdx.x, v = blockIdx.y;
  int l = r / kB, b = r % kB;
  int g = (l / kHW) * kB + b;
  int tid = threadIdx.x;
  float fac = kScaleN * sqrtf(kCnt / (ss[(long)v * NG + g] + 1e-5f));
  if (v == 0) {
    float x0 = opval<OPA>(Aa, Ba, r, b, tid) * fac;
    float x1 = opval<OPA>(Aa, Ba, r, b, tid + 256) * fac;
    outA[(long)r * kD + tid] = x0;
    outA[(long)r * kD + tid + 256] = x1;
    if (oAb) { oAb[(long)r * kD + tid] = f2bf(x0); oAb[(long)r * kD + tid + 256] = f2bf(x1); }
  } else {
    float x0 = opval<OPB>(Ab, Bb, r, b, tid) * fac;
    float x1 = opval<OPB>(Ab, Bb, r, b, tid + 256) * fac;
    outB[(long)r * kD + tid] = x0;
    outB[(long)r * kD + tid + 256] = x1;
    if (oBb) { oBb[(long)r * kD + tid] = f2bf(x0); oBb[(long)r * kD + tid + 256] = f2bf(x1); }
  }
}

__global__ void k_vb(const float* __restrict__ t1i, const float* __restrict__ Wk,
                     const float* __restrict__ bk, float* __restrict__ vb) {
  __shared__ float part[4][128];
  __shared__ float red[2];
  int b = blockIdx.x;
  int j = threadIdx.x;
  int dz = threadIdx.y;
  const float* row = t1i + (long)b * kD;
  float acc = 0.f;
  int d0 = dz * 128;
  for (int d = d0; d < d0 + 128; ++d) acc += row[d] * Wk[(long)d * kKD + j];
  part[dz][j] = acc;
  __syncthreads();
  if (dz == 0) {
    float a = part[0][j] + part[1][j] + part[2][j] + part[3][j] + bk[j];
    float s = a * a;
    s = wsum(s);
    if ((j & 63) == 0) red[j >> 6] = s;
    part[0][j] = a;
  }
  __syncthreads();
  if (dz == 0) {
    float inv = 1.f / fmaxf(sqrtf(red[0] + red[1]), 1e-12f);
    vb[(long)b * kKD + j] = part[0][j] * inv;
  }
}

__global__ void k_cRcI(const float* __restrict__ vb, const float* __restrict__ Kr,
                       const float* __restrict__ Ki, float* __restrict__ cR,
                       float* __restrict__ cI) {
  int idx = blockIdx.x;
  int k = idx / kB, b = idx % kB;
  int lane = threadIdx.x;
  const float* v = vb + (long)b * kKD;
  const float* pr = Kr + ((long)k * kB + b) * kKD;
  const float* pi = Ki + ((long)k * kB + b) * kKD;
  float sR = 0.f, sI = 0.f;
  for (int c = lane; c < kKD; c += 64) {
    sR += v[c] * pr[c];
    sI += v[c] * pi[c];
  }
  sR = wsum(sR);
  sI = wsum(sI);
  if (lane == 0) {
    cR[(long)b * kL + k] = sR;
    cI[(long)b * kL + k] = sI;
  }
}

template <int BM, int BN, bool AF32, bool ACC>
void gemm(hipStream_t s, const void* A, const u16b* B, float* C, int M, int N, int K, int lda,
          int ldb, int ldc, long sAb, long sBb, long sCb, int batch) {
  dim3 grd(CDIV(N, BN), CDIV(M, BM), batch), blk(256);
  k_gemm<BM, BN, AF32, ACC><<<grd, blk, 0, s>>>(A, B, C, M, N, K, lda, ldb, ldc, sAb, sBb, sCb);
}

}  // namespace

extern "C" void kernel_launch(void* const* d_in, const int* in_sizes, int n_in, void* d_out,
                              int out_size, void* d_ws, size_t ws_size, hipStream_t stream) {
  (void)in_sizes; (void)n_in; (void)out_size;
  const float* tf  = (const float*)d_in[0];
  const float* sf  = (const float*)d_in[1];
  const float* tl  = (const float*)d_in[2];
  const float* WkE = (const float*)d_in[3];
  const float* bkE = (const float*)d_in[4];
  const float* WkS = (const float*)d_in[5];
  const float* bkS = (const float*)d_in[6];
  const float* WkC = (const float*)d_in[7];
  const float* bkC = (const float*)d_in[8];
  const float* Wc  = (const float*)d_in[9];
  float* out = (float*)d_out;
  float* ws = (float*)d_ws;

  const long LBD = (long)kL * kB * kD;
  const long LBK = (long)kL * kB * kKD;
  const long HBD = (long)kHW * kB * kD;
  const long HBK = (long)kHW * kB * kKD;

  long off = 0;
  auto alloc = [&](long n) { long o = off; off += (n + 255) & ~255L; return o; };
  auto allocU = [&](long nu) { return alloc((nu + 1) / 2); };  // ushort count -> float slots

  // fixed
  long o_seqT = alloc(LBD);
  long o_seqS = alloc(LBD);
  long o_Kr   = alloc(LBK);
  long o_Ki   = alloc(LBK);
  long o_Krb  = allocU(LBK);
  long o_Kib  = allocU(LBK);
  long o_VrT  = allocU((long)kB * kD * kLp);
  long o_tfb  = allocU((long)kNI * kB * kD * kHWp);
  long o_sfb  = allocU((long)kNI * kB * kD * kHWp);
  long o_WkTE = allocU((long)kD * kD);
  long o_WkTS = allocU((long)kKD * kD);
  long o_WkTC = allocU((long)kKD * kD);
  long o_Wcb  = allocU((long)kD * 2 * kD);
  long o_lab = alloc((long)kL * kB);
  long o_uE = alloc(kD);
  long o_uS = alloc(kKD);
  long o_vb = alloc((long)kB * kKD);
  long o_g = alloc((long)kB * kL);
  long o_cR = alloc((long)kB * kL);
  long o_cI = alloc((long)kB * kL);
  long o_row = alloc((long)kB * kD);
  long o_mkr = alloc((long)kHW * kB);
  long o_mki = alloc((long)kHW * kB);
  long o_ss = alloc(64);
  long o_part = alloc(2L * kL * kB);
  long o_scr = off;

  // encoder overlay
  long o_Pe  = o_scr;                    // LBD
  long o_Peb = o_Pe + LBD;               // LBD/2
  long o_Ae  = o_Peb + LBD / 2;          // kB*kL*kL
  long enc_end = o_Ae + (long)kB * kL * kL;
  long o_ar  = o_Pe;                     // after Pe dead
  long o_mib = o_Peb;                    // after Peb dead
  long o_mr  = o_Ae;                     // after Ae dead
  long o_mi  = o_Ae + LBD;
  long o_mrb = o_Ae + 2 * LBD;

  // per-image overlay
  long o_Ps   = o_scr;
  long o_Psb  = o_Ps + ((HBK + 255) & ~255L);
  long o_Pc   = o_Psb + ((HBK / 2 + 255) & ~255L);
  long o_Pcb  = o_Pc + ((HBK + 255) & ~255L);
  long o_As   = o_Pcb + ((HBK / 2 + 255) & ~255L);
  long o_Asb  = o_As + (long)kB * kHW * kHW;
  long o_Sf   = o_Asb + ((long)kB * kHW * kHWp / 2 + 256);
  long o_S1b  = o_Sf + (long)kB * kHW * kL;
  long o_S2b  = o_S1b + ((long)kB * kHW * kLp / 2 + 256);
  long o_t1r  = o_S2b + ((long)kB * kHW * kLp / 2 + 256);
  long o_t1rb = o_t1r + HBD;
  long o_t1i  = o_t1rb + HBD / 2;
  long o_c3r  = o_t1i + HBD;
  long o_c3i  = o_c3r + HBD;
  long o_t2r  = o_c3i + HBD;
  long o_t2i  = o_t2r + HBD;
  long o_t2rb = o_t2i + HBD;
  long o_t2ib = o_t2rb + HBD / 2;
  long img_end = o_t2ib + HBD / 2;

  long total = (enc_end > img_end ? enc_end : img_end);
  if ((size_t)total * sizeof(float) > ws_size) return;

  float* seqT = ws + o_seqT;
  float* seqS = ws + o_seqS;
  float* Kr = ws + o_Kr;
  float* Ki = ws + o_Ki;
  u16b* Krb = (u16b*)(ws + o_Krb);
  u16b* Kib = (u16b*)(ws + o_Kib);
  u16b* VrT = (u16b*)(ws + o_VrT);
  u16b* tfb = (u16b*)(ws + o_tfb);
  u16b* sfb = (u16b*)(ws + o_sfb);
  u16b* WkTE = (u16b*)(ws + o_WkTE);
  u16b* WkTS = (u16b*)(ws + o_WkTS);
  u16b* WkTC = (u16b*)(ws + o_WkTC);
  u16b* Wcb = (u16b*)(ws + o_Wcb);
  float* lab = ws + o_lab;
  float* uE = ws + o_uE;
  float* uS = ws + o_uS;
  float* vb = ws + o_vb;
  float* g_ = ws + o_g;
  float* cR = ws + o_cR;
  float* cI = ws + o_cI;
  float* row = ws + o_row;
  float* mkr = ws + o_mkr;
  float* mki = ws + o_mki;
  float* ssp = ws + o_ss;
  float* part = ws + o_part;
  float* Pe = ws + o_Pe;
  u16b* Peb = (u16b*)(ws + o_Peb);
  float* Ae = ws + o_Ae;
  float* ar = ws + o_ar;
  float* mr = ws + o_mr;
  float* mi = ws + o_mi;
  u16b* mrb = (u16b*)(ws + o_mrb);
  u16b* mib = (u16b*)(ws + o_mib);
  float* Ps = ws + o_Ps;
  u16b* Psb = (u16b*)(ws + o_Psb);
  float* Pc = ws + o_Pc;
  u16b* Pcb = (u16b*)(ws + o_Pcb);
  float* As_ = ws + o_As;
  u16b* Asb = (u16b*)(ws + o_Asb);
  float* Sf = ws + o_Sf;
  u16b* S1b = (u16b*)(ws + o_S1b);
  u16b* S2b = (u16b*)(ws + o_S2b);
  float* t1r = ws + o_t1r;
  u16b* t1rb = (u16b*)(ws + o_t1rb);
  float* t1i = ws + o_t1i;
  float* c3r = ws + o_c3r;
  float* c3i = ws + o_c3i;
  float* t2r = ws + o_t2r;
  float* t2i = ws + o_t2i;
  u16b* t2rb = (u16b*)(ws + o_t2rb);
  u16b* t2ib = (u16b*)(ws + o_t2ib);

  // ---- stage 0: layouts, casts, constants ----
  {
    dim3 grd(CDIV(kHW, 32), CDIV(kD, 32), kNI * kB), blk(32, 8);
    k_toseq<<<grd, blk, 0, stream>>>(tf, seqT);
    k_toseq<<<grd, blk, 0, stream>>>(sf, seqS);
  }
  k_cvt2d<<<kNI * kB * kD, 256, 0, stream>>>(tf, tfb, kHW, kHWp);
  k_cvt2d<<<kNI * kB * kD, 256, 0, stream>>>(sf, sfb, kHW, kHWp);
  k_cvt2d<<<kD, 256, 0, stream>>>(Wc, Wcb, 2 * kD, 2 * kD);
  k_tcvt<<<dim3(kD / 32, kD / 32), dim3(32, 8), 0, stream>>>(WkE, WkTE, kD, kD);
  k_tcvt<<<dim3(kKD / 32, kD / 32), dim3(32, 8), 0, stream>>>(WkS, WkTS, kD, kKD);
  k_tcvt<<<dim3(kKD / 32, kD / 32), dim3(32, 8), 0, stream>>>(WkC, WkTC, kD, kKD);
  k_lab<<<CDIV(kNI * kB * kHW, 256), 256, 0, stream>>>(tl, lab);
  k_l2n_vec<<<1, 128, 0, stream>>>(bkE, uE, kD);
  k_l2n_vec<<<1, 128, 0, stream>>>(bkS, uS, kKD);

  // ---- encoder ----
  gemm<64, 128, true, false>(stream, seqT, WkTE, Pe, kL * kB, kD, kD, kD, kD, kD, 0, 0, 0, 1);
  k_bias_l2n<<<kL * kB, 128, 0, stream>>>(Pe, bkE, kD, Peb);
  k_rowdot<<<kL * kB, 64, 0, stream>>>(Pe, uE, g_, kL, kD);
  k_softmax<<<kB, 256, 0, stream>>>(g_, 1, kL, nullptr, 0.f, nullptr, nullptr, nullptr, 0);
  gemm<128, 128, false, false>(stream, Peb, Peb, Ae, kL, kL, kD, kB * kD, kB * kD, kL, kD, kD,
                               (long)kL * kL, 8);
  k_softmax<<<kB * kL, 256, 0, stream>>>(Ae, kL, kL, nullptr, 0.f, nullptr, nullptr, nullptr, 0);
  // ar = Ae @ seq  (3 ACC chunks over images; B^T = raw train_feat bf16)
  gemm<64, 128, true, false>(stream, Ae, tfb, ar, kL, kD, kHW, kL, kHWp, kB * kD,
                             (long)kL * kL, (long)kD * kHWp, kD, 8);
  gemm<64, 128, true, true>(stream, Ae + kHW, tfb + (long)kB * kD * kHWp, ar, kL, kD, kHW, kL,
                            kHWp, kB * kD, (long)kL * kL, (long)kD * kHWp, kD, 8);
  gemm<64, 128, true, true>(stream, Ae + 2 * kHW, tfb + 2L * kB * kD * kHWp, ar, kL, kD, kHW,
                            kL, kHWp, kB * kD, (long)kL * kL, (long)kD * kHWp, kD, 8);
  hipMemsetAsync(row, 0, kB * kD * sizeof(float), stream);
  k_wrowsum<<<dim3(kD / 128, kB, CDIV(kL, 64)), 128, 0, stream>>>(g_, seqT, row, kL, 64);
  k_ss2<0, 1><<<dim3(kL * kB, 2), 256, 0, stream>>>(seqT, ar, row, nullptr, part, kL * kB);
  k_ssred<<<dim3(kNI * kB, 2), 512, 0, stream>>>(part, ssp, kL * kB, kNI * kB);
  k_scale2<0, 1><<<dim3(kL * kB, 2), 256, 0, stream>>>(seqT, ar, mr, row, nullptr, mi, ssp,
                                                       kNI * kB, mrb, mib);
  k_vrt<<<dim3(CDIV(kL, 32), kD / 32, kB), dim3(32, 8), 0, stream>>>(mr, lab, VrT);
  gemm<64, 64, false, false>(stream, mrb, WkTC, Kr, kL * kB, kKD, kD, kD, kD, kKD, 0, 0, 0, 1);
  k_bias_l2n<<<kL * kB, 128, 0, stream>>>(Kr, bkC, kKD, Krb);
  gemm<64, 64, false, false>(stream, mib, WkTC, Ki, kL * kB, kKD, kD, kD, kD, kKD, 0, 0, 0, 1);
  k_bias_l2n<<<kL * kB, 128, 0, stream>>>(Ki, bkC, kKD, Kib);

  // ---- decoder ----
  const int R = kHW * kB;
  for (int img = 0; img < 6; ++img) {
    const float* t = (img < 3) ? (seqT + (long)img * HBD) : (seqS + (long)(img - 3) * HBD);
    const u16b* tb = (img < 3) ? (tfb + (long)img * kB * kD * kHWp)
                               : (sfb + (long)(img - 3) * kB * kD * kHWp);
    float* osl = out + (long)img * kB * kD * kHW;

    gemm<64, 64, true, false>(stream, t, WkTS, Ps, kHW * kB, kKD, kD, kD, kD, kKD, 0, 0, 0, 1);
    k_bias_l2n<<<kHW * kB, 128, 0, stream>>>(Ps, bkS, kKD, Psb);
    k_rowdot<<<kHW * kB, 64, 0, stream>>>(Ps, uS, g_, kHW, kKD);
    k_softmax<<<kB, 256, 0, stream>>>(g_, 1, kHW, nullptr, 0.f, nullptr, nullptr, nullptr, 0);
    gemm<64, 64, false, false>(stream, Psb, Psb, As_, kHW, kHW, kKD, kB * kKD, kB * kKD, kHW,
                               kKD, kKD, (long)kHW * kHW, 8);
    k_softmax<<<kB * kHW, 256, 0, stream>>>(As_, kHW, kHW, nullptr, 0.f, nullptr, nullptr, Asb,
                                            kHWp);
    gemm<64, 64, false, false>(stream, Asb, tb, c3r, kHW, kD, kHW, kHWp, kHWp, kB * kD,
                               (long)kHW * kHWp, (long)kD * kHWp, kD, 8);  // s2r
    hipMemsetAsync(row, 0, kB * kD * sizeof(float), stream);
    k_wrowsum<<<dim3(kD / 128, kB, CDIV(kHW, 64)), 128, 0, stream>>>(g_, t, row, kHW, 64);
    k_ss2<0, 1><<<dim3(R, 2), 256, 0, stream>>>(t, c3r, row, nullptr, part, R);
    k_ssred<<<dim3(kB, 2), 512, 0, stream>>>(part, ssp, R, kB);
    k_scale2<0, 1><<<dim3(R, 2), 256, 0, stream>>>(t, c3r, t1r, row, nullptr, t1i, ssp, kB,
                                                   t1rb, nullptr);
    k_vb<<<kB, dim3(128, 4), 0, stream>>>(t1i, WkC, bkC, vb);
    gemm<64, 64, false, false>(stream, t1rb, WkTC, Pc, kHW * kB, kKD, kD, kD, kD, kKD, 0, 0, 0,
                               1);
    k_bias_l2n<<<kHW * kB, 128, 0, stream>>>(Pc, bkC, kKD, Pcb);
    k_cRcI<<<kL * kB, 64, 0, stream>>>(vb, Kr, Ki, cR, cI);
    gemm<64, 128, false, false>(stream, Pcb, Krb, Sf, kHW, kL, kKD, kB * kKD, kB * kKD, kL,
                                kKD, kKD, (long)kHW * kL, 8);
    k_softmax<<<kB * kHW, 256, 0, stream>>>(Sf, kHW, kL, cI, -1.f, lab, mkr, S1b, kLp);
    gemm<64, 128, false, false>(stream, Pcb, Kib, Sf, kHW, kL, kKD, kB * kKD, kB * kKD, kL,
                                kKD, kKD, (long)kHW * kL, 8);
    k_softmax<<<kB * kHW, 256, 0, stream>>>(Sf, kHW, kL, cR, +1.f, lab, mki, S2b, kLp);
    gemm<64, 64, false, false>(stream, S1b, VrT, c3r, kHW, kD, kL, kLp, kLp, kB * kD,
                               (long)kHW * kLp, (long)kD * kLp, kD, 8);
    gemm<64, 64, false, false>(stream, S2b, VrT, c3i, kHW, kD, kL, kLp, kLp, kB * kD,
                               (long)kHW * kLp, (long)kD * kLp, kD, 8);
    // t2 = inorm(t1 * mk)
    k_ss2<2, 2><<<dim3(R, 2), 256, 0, stream>>>(t1r, mkr, t1i, mki, part, R);
    k_ssred<<<dim3(kB, 2), 512, 0, stream>>>(part, ssp, R, kB);
    k_scale2<2, 2><<<dim3(R, 2), 256, 0, stream>>>(t1r, mkr, t2r, t1i, mki, t2i, ssp, kB,
                                                   nullptr, nullptr);
    // t4 = inorm(t1 + c3) in place into c3
    k_ss2<0, 0><<<dim3(R, 2), 256, 0, stream>>>(t1r, c3r, t1i, c3i, part, R);
    k_ssred<<<dim3(kB, 2), 512, 0, stream>>>(part, ssp, R, kB);
    k_scale2<0, 0><<<dim3(R, 2), 256, 0, stream>>>(t1r, c3r, c3r, t1i, c3i, c3i, ssp, kB,
                                                   nullptr, nullptr);
    // out = inorm(t2 + t4) -> bf16 mirrors for the 1x1 conv
    k_ss2<0, 0><<<dim3(R, 2), 256, 0, stream>>>(t2r, c3r, t2i, c3i, part, R);
    k_ssred<<<dim3(kB, 2), 512, 0, stream>>>(part, ssp, R, kB);
    k_scale2<0, 0><<<dim3(R, 2), 256, 0, stream>>>(t2r, c3r, t2r, t2i, c3i, t2i, ssp, kB,
                                                   t2rb, t2ib);
    gemm<64, 64, false, false>(stream, Wcb, t2rb, osl, kD, kHW, kD, 2 * kD, kB * kD, kHW, 0,
                               kD, (long)kD * kHW, 8);
    gemm<64, 64, false, true>(stream, Wcb + kD, t2ib, osl, kD, kHW, kD, 2 * kD, kB * kD, kHW,
                              0, kD, (long)kD * kHW, 8);
  }
}

// Round 6
// 2305.992 us; speedup vs baseline: 5.0044x; 1.1085x over previous
//
#include <hip/hip_runtime.h>

// ComTransformer on MI355X — round 6: operand-sharing fusions.
//  - S1/S2 one GEMM (N=2904, Kc=[Krb;Kib]); one paired softmax -> P-hat bf16 + mkr/mki
//  - c3r/c3i one GEMM (M=968, shared VrT); C = contiguous [c3r;c3i]
//  - Wc conv single GEMM K=1024 (t2b = [t2r|t2i] bf16 per row)
//  - tail inorms fused: ss4 -> zmk (z=t2+t4 + ss) -> zscale(bf16)
//  - 64x128 tiles for AV-class GEMMs; bf16 cRcI
// Structure exploited (earlier rounds): rank-1 imag branches, shared mk/c3 softmax,
// fused score bias, label-dot mk, atomic-free 3-phase inorm.

namespace {

constexpr int kNI = 3;
constexpr int kB  = 8;
constexpr int kD  = 512;
constexpr int kKD = 128;
constexpr int kHW = 484;
constexpr int kL  = kNI * kHW;  // 1452
constexpr int kLp = 1456;
constexpr int kHWp = 488;
constexpr float kTemp = 30.0f;
constexpr float kCnt  = 247808.0f;
constexpr float kScaleN = 0.011048543456039806f;
constexpr long kHBD = (long)kHW * kB * kD;
constexpr int kR = kHW * kB;  // 3872

#define CDIV(a, b) (((a) + (b) - 1) / (b))

typedef float f32x4 __attribute__((ext_vector_type(4)));
typedef unsigned int u32x4 __attribute__((ext_vector_type(4)));
typedef unsigned short u16b;

__device__ __forceinline__ float wsum(float v) {
#pragma unroll
  for (int o = 32; o; o >>= 1) v += __shfl_down(v, o);
  return v;
}
__device__ __forceinline__ float wmax(float v) {
#pragma unroll
  for (int o = 32; o; o >>= 1) v = fmaxf(v, __shfl_down(v, o));
  return v;
}

__device__ __forceinline__ unsigned pk2bf(float lo, float hi) {
  union { float f; unsigned u; } a, b;
  a.f = lo; b.f = hi;
  unsigned ra = (a.u + 0x7FFFu + ((a.u >> 16) & 1u)) >> 16;
  unsigned rb = (b.u + 0x7FFFu + ((b.u >> 16) & 1u)) >> 16;
  return (ra & 0xFFFFu) | (rb << 16);
}
__device__ __forceinline__ u16b f2bf(float x) {
  union { float f; unsigned u; } a;
  a.f = x;
  return (u16b)((a.u + 0x7FFFu + ((a.u >> 16) & 1u)) >> 16);
}
__device__ __forceinline__ float bf2f(u16b x) {
  union { unsigned u; float f; } a;
  a.u = (unsigned)x << 16;
  return a.f;
}

__device__ __forceinline__ void mfma_bf16(f32x4& d, const u32x4& a, const u32x4& b) {
  asm("v_mfma_f32_16x16x32_bf16 %0, %1, %2, %0" : "+v"(d) : "v"(a), "v"(b));
}

// ---------------- layout transform: [n,b,d,hw] -> seq [(n*hw),b,d] fp32 -----------
__global__ void k_toseq(const float* __restrict__ in, float* __restrict__ out) {
  __shared__ float tile[32][33];
  int nb = blockIdx.z;
  int n = nb / kB, b = nb % kB;
  int p0 = blockIdx.x * 32, d0 = blockIdx.y * 32;
  int tx = threadIdx.x, ty = threadIdx.y;
#pragma unroll
  for (int j = 0; j < 4; ++j) {
    int d = d0 + ty + j * 8, p = p0 + tx;
    if (d < kD && p < kHW) tile[ty + j * 8][tx] = in[(long)nb * kD * kHW + (long)d * kHW + p];
  }
  __syncthreads();
#pragma unroll
  for (int j = 0; j < 4; ++j) {
    int p = p0 + ty + j * 8, d = d0 + tx;
    if (p < kHW && d < kD)
      out[((long)(n * kHW + p) * kB + b) * kD + d] = tile[tx][ty + j * 8];
  }
}

__global__ void k_cvt2d(const float* __restrict__ in, u16b* __restrict__ out, int C, int Cp) {
  long r = blockIdx.x;
  for (int c = threadIdx.x; c < C; c += 256)
    out[r * Cp + c] = f2bf(in[r * (long)C + c]);
}

// transpose + cvt: in fp32 [R][C] -> out bf16 [C][R]
__global__ void k_tcvt(const float* __restrict__ in, u16b* __restrict__ out, int R, int C) {
  __shared__ float tile[32][33];
  int c0 = blockIdx.x * 32, r0 = blockIdx.y * 32;
  int tx = threadIdx.x, ty = threadIdx.y;
#pragma unroll
  for (int j = 0; j < 4; ++j) {
    int r = r0 + ty + j * 8, c = c0 + tx;
    if (r < R && c < C) tile[ty + j * 8][tx] = in[(long)r * C + c];
  }
  __syncthreads();
#pragma unroll
  for (int j = 0; j < 4; ++j) {
    int c = c0 + ty + j * 8, r = r0 + tx;
    if (r < R && c < C) out[(long)c * R + r] = f2bf(tile[tx][ty + j * 8]);
  }
}

// VrT[b][d][l] = bf16( mr[(l,b),d] * lab[l,b] ), stride kLp
__global__ void k_vrt(const float* __restrict__ mr, const float* __restrict__ lab,
                      u16b* __restrict__ vt) {
  __shared__ float tile[32][33];
  int l0 = blockIdx.x * 32, d0 = blockIdx.y * 32, b = blockIdx.z;
  int tx = threadIdx.x, ty = threadIdx.y;
#pragma unroll
  for (int j = 0; j < 4; ++j) {
    int l = l0 + ty + j * 8;
    if (l < kL)
      tile[ty + j * 8][tx] = mr[((long)l * kB + b) * kD + d0 + tx] * lab[(long)l * kB + b];
  }
  __syncthreads();
#pragma unroll
  for (int j = 0; j < 4; ++j) {
    int d = d0 + ty + j * 8, l = l0 + tx;
    if (l < kL) vt[((long)b * kD + d) * kLp + l] = f2bf(tile[tx][ty + j * 8]);
  }
}

__global__ void k_lab(const float* __restrict__ tl, float* __restrict__ lab) {
  long i = (long)blockIdx.x * 256 + threadIdx.x;
  const long tot = (long)kNI * kB * kHW;
  if (i >= tot) return;
  int p = (int)(i % kHW);
  long t = i / kHW;
  int b = (int)(t % kB);
  int n = (int)(t / kB);
  lab[(long)(n * kHW + p) * kB + b] = tl[i];
}

__global__ void k_l2n_vec(const float* __restrict__ src, float* __restrict__ u, int C) {
  __shared__ float red[2];
  int tid = threadIdx.x;  // 128
  float s = 0.f;
  for (int c = tid; c < C; c += 128) { float x = src[c]; s += x * x; }
  s = wsum(s);
  if ((tid & 63) == 0) red[tid >> 6] = s;
  __syncthreads();
  float inv = 1.f / fmaxf(sqrtf(red[0] + red[1]), 1e-12f);
  for (int c = tid; c < C; c += 128) u[c] = src[c] * inv;
}

// ---------------- NT bf16 MFMA GEMM -----------------------------------------------
template <int BR, bool F32>
__device__ __forceinline__ void stage_tile(const char* src, unsigned* dstU, int g0, int RM,
                                           int k0, int K, int ld) {
  const int TC = BR * 4;
  for (int ci = threadIdx.x; ci < TC; ci += 256) {
    int row = ci >> 2, c = ci & 3;
    int gr = g0 + row;
    int gk = k0 + c * 8;
    u32x4 w;
    if (F32) {
      const float* A = (const float*)src;
      if (gr < RM && gk + 8 <= K) {
        const float* ap = A + (long)gr * ld + gk;
        float4 u0 = *(const float4*)ap;
        float4 u1 = *(const float4*)(ap + 4);
        w.x = pk2bf(u0.x, u0.y); w.y = pk2bf(u0.z, u0.w);
        w.z = pk2bf(u1.x, u1.y); w.w = pk2bf(u1.z, u1.w);
      } else {
        float v[8];
#pragma unroll
        for (int j = 0; j < 8; ++j)
          v[j] = (gr < RM && gk + j < K) ? A[(long)gr * ld + gk + j] : 0.f;
        w.x = pk2bf(v[0], v[1]); w.y = pk2bf(v[2], v[3]);
        w.z = pk2bf(v[4], v[5]); w.w = pk2bf(v[6], v[7]);
      }
    } else {
      const u16b* A = (const u16b*)src;
      if (gr < RM && gk + 8 <= K) {
        w = *(const u32x4*)(A + (long)gr * ld + gk);
      } else {
        unsigned v[8];
#pragma unroll
        for (int j = 0; j < 8; ++j)
          v[j] = (gr < RM && gk + j < K) ? A[(long)gr * ld + gk + j] : 0u;
        w.x = v[0] | (v[1] << 16); w.y = v[2] | (v[3] << 16);
        w.z = v[4] | (v[5] << 16); w.w = v[6] | (v[7] << 16);
      }
    }
    *(u32x4*)&dstU[row * 20 + c * 4] = w;
  }
}

template <int BM, int BN, bool AF32, bool ACC>
__global__ __launch_bounds__(256) void k_gemm(const void* Ap, const u16b* __restrict__ B,
                                              float* __restrict__ C, int M, int N, int K,
                                              int lda, int ldb, int ldc, long sAb, long sBb,
                                              long sCb) {
  const char* Ab = (const char*)Ap + (long)blockIdx.z * sAb * (AF32 ? 4 : 2);
  const char* Bb = (const char*)B + (long)blockIdx.z * sBb * 2;
  C += (long)blockIdx.z * sCb;
  constexpr int FM = BM / 32, FN = BN / 32;
  const int m0 = blockIdx.y * BM, n0 = blockIdx.x * BN;
  const int tid = threadIdx.x;
  const int wid = tid >> 6, lane = tid & 63;
  const int wr = wid >> 1, wc = wid & 1;
  const int fr = lane & 15, fk = lane >> 4;

  __shared__ unsigned AsU[BM * 20];
  __shared__ unsigned BsU[BN * 20];
  f32x4 acc[FM][FN] = {};

  for (int k0 = 0; k0 < K; k0 += 32) {
    stage_tile<BM, AF32>(Ab, AsU, m0, M, k0, K, lda);
    stage_tile<BN, false>(Bb, BsU, n0, N, k0, K, ldb);
    __syncthreads();
    u32x4 af[FM], bf[FN];
#pragma unroll
    for (int mi = 0; mi < FM; ++mi)
      af[mi] = *(const u32x4*)&AsU[(wr * (BM / 2) + mi * 16 + fr) * 20 + fk * 4];
#pragma unroll
    for (int ni = 0; ni < FN; ++ni)
      bf[ni] = *(const u32x4*)&BsU[(wc * (BN / 2) + ni * 16 + fr) * 20 + fk * 4];
#pragma unroll
    for (int mi = 0; mi < FM; ++mi)
#pragma unroll
      for (int ni = 0; ni < FN; ++ni) mfma_bf16(acc[mi][ni], af[mi], bf[ni]);
    __syncthreads();
  }
  asm volatile("s_nop 7\n\ts_nop 7" ::: );
#pragma unroll
  for (int mi = 0; mi < FM; ++mi) {
#pragma unroll
    for (int r = 0; r < 4; ++r) {
      int gm = m0 + wr * (BM / 2) + mi * 16 + fk * 4 + r;
      if (gm >= M) continue;
#pragma unroll
      for (int ni = 0; ni < FN; ++ni) {
        int gn = n0 + wc * (BN / 2) + ni * 16 + fr;
        if (gn >= N) continue;
        long idx = (long)gm * ldc + gn;
        float v = acc[mi][ni][r];
        C[idx] = ACC ? (C[idx] + v) : v;
      }
    }
  }
}

// row += bias; l2-normalize; fp32 in place + bf16 mirror
__global__ void k_bias_l2n(float* __restrict__ P, const float* __restrict__ bias, int C,
                           u16b* __restrict__ outb) {
  __shared__ float red[2];
  long row = blockIdx.x;
  float* p = P + row * C;
  int tid = threadIdx.x;  // 128
  int nv = C >> 7;
  float v[4];
  float s = 0.f;
#pragma unroll
  for (int i = 0; i < 4; ++i)
    if (i < nv) {
      float x = p[tid + (i << 7)] + bias[tid + (i << 7)];
      v[i] = x;
      s += x * x;
    }
  s = wsum(s);
  if ((tid & 63) == 0) red[tid >> 6] = s;
  __syncthreads();
  float inv = 1.f / fmaxf(sqrtf(red[0] + red[1]), 1e-12f);
#pragma unroll
  for (int i = 0; i < 4; ++i)
    if (i < nv) {
      float x = v[i] * inv;
      p[tid + (i << 7)] = x;
      outb[row * C + tid + (i << 7)] = f2bf(x);
    }
}

__global__ void k_rowdot(const float* __restrict__ P, const float* __restrict__ u,
                         float* __restrict__ g, int L, int C) {
  int idx = blockIdx.x;
  int k = idx / kB, b = idx % kB;
  const float* p = P + ((long)k * kB + b) * C;
  int lane = threadIdx.x;  // 64
  float s = 0.f;
  for (int c = lane; c < C; c += 64) s += u[c] * p[c];
  s = wsum(s);
  if (lane == 0) g[(long)b * L + k] = s;
}

// generic softmax (wi / As / encoder Ae)
__global__ __launch_bounds__(256) void k_softmax(float* __restrict__ S, int Lq, int Lk,
                                                 u16b* __restrict__ outb, int ldo) {
  __shared__ float sm[1456];
  __shared__ float red[4];
  int row = blockIdx.x;
  float* Sr = S + (long)row * Lk;
  int tid = threadIdx.x;
  float mx = -3.0e38f;
  for (int k = tid; k < Lk; k += 256) {
    float v = Sr[k] * kTemp;
    sm[k] = v;
    mx = fmaxf(mx, v);
  }
  mx = wmax(mx);
  if ((tid & 63) == 0) red[tid >> 6] = mx;
  __syncthreads();
  mx = fmaxf(fmaxf(red[0], red[1]), fmaxf(red[2], red[3]));
  __syncthreads();
  float s = 0.f;
  for (int k = tid; k < Lk; k += 256) {
    float e = expf(sm[k] - mx);
    sm[k] = e;
    s += e;
  }
  s = wsum(s);
  if ((tid & 63) == 0) red[tid >> 6] = s;
  __syncthreads();
  float inv = 1.0f / (red[0] + red[1] + red[2] + red[3]);
  for (int k = tid; k < Lk; k += 256) {
    float p = sm[k] * inv;
    if (outb) outb[(long)row * ldo + k] = f2bf(p); else Sr[k] = p;
  }
}

// fused S1/S2 softmax: Sf row (b*kHW+q) x [S1 | S2]; y=0 -> S1 (bias -cI, mkr),
// y=1 -> S2 (bias +cR, mki). writes P-hat row ((b*2+y)*kHW+q) bf16 + pad zeros.
__global__ __launch_bounds__(256) void k_softmax2(const float* __restrict__ Sf,
                                                  const float* __restrict__ cR,
                                                  const float* __restrict__ cI,
                                                  const float* __restrict__ lab,
                                                  u16b* __restrict__ Ph,
                                                  float* __restrict__ mkr,
                                                  float* __restrict__ mki) {
  __shared__ float sm[1456];
  __shared__ float red[4];
  int row = blockIdx.x;  // b*kHW + q
  int y = blockIdx.y;
  int b = row / kHW, q = row - b * kHW;
  const float* Sr = Sf + (long)row * (2 * kL) + y * kL;
  const float* bias = (y ? cR : cI) + (long)b * kL;
  float sign = y ? 1.f : -1.f;
  int tid = threadIdx.x;
  float mx = -3.0e38f;
  for (int k = tid; k < kL; k += 256) {
    float v = (Sr[k] + sign * bias[k]) * kTemp;
    sm[k] = v;
    mx = fmaxf(mx, v);
  }
  mx = wmax(mx);
  if ((tid & 63) == 0) red[tid >> 6] = mx;
  __syncthreads();
  mx = fmaxf(fmaxf(red[0], red[1]), fmaxf(red[2], red[3]));
  __syncthreads();
  float s = 0.f;
  for (int k = tid; k < kL; k += 256) {
    float e = expf(sm[k] - mx);
    sm[k] = e;
    s += e;
  }
  s = wsum(s);
  if ((tid & 63) == 0) red[tid >> 6] = s;
  __syncthreads();
  float inv = 1.0f / (red[0] + red[1] + red[2] + red[3]);
  __syncthreads();
  u16b* outp = Ph + ((long)(b * 2 + y) * kHW + q) * kLp;
  float dot = 0.f;
  for (int k = tid; k < kL; k += 256) {
    float p = sm[k] * inv;
    outp[k] = f2bf(p);
    dot += p * lab[(long)k * kB + b];
  }
  for (int k = kL + tid; k < kLp; k += 256) outp[k] = 0;
  dot = wsum(dot);
  if ((tid & 63) == 0) red[tid >> 6] = dot;
  __syncthreads();
  if (tid == 0) (y ? mki : mkr)[(long)q * kB + b] = red[0] + red[1] + red[2] + red[3];
}

__global__ void k_wrowsum(const float* __restrict__ w, const float* __restrict__ S,
                          float* __restrict__ rowout, int L, int kchunk) {
  int b = blockIdx.y;
  int d = blockIdx.x * 128 + threadIdx.x;
  int k0 = blockIdx.z * kchunk;
  int k1 = min(L, k0 + kchunk);
  float s = 0.f;
  for (int k = k0; k < k1; ++k) s += w[(long)b * L + k] * S[((long)k * kB + b) * kD + d];
  atomicAdd(&rowout[(long)b * kD + d], s);
}

// OP 0: A[r,d]+B2[r,d]   OP 1: A[b,d] (broadcast)   OP 2: A[r,d]*B2[r]
template <int OP>
__device__ __forceinline__ float opval(const float* __restrict__ A,
                                       const float* __restrict__ B2, long r, int b, int d) {
  if (OP == 0) return A[r * kD + d] + B2[r * kD + d];
  if (OP == 1) return A[(long)b * kD + d];
  return A[r * kD + d] * B2[r];
}

template <int OPA, int OPB>
__global__ __launch_bounds__(256) void k_ss2(const float* __restrict__ Aa,
                                             const float* __restrict__ Ba,
                                             const float* __restrict__ Ab,
                                             const float* __restrict__ Bb,
                                             float* __restrict__ part, int R) {
  __shared__ float red[4];
  int r = blockIdx.x, v = blockIdx.y;
  int b = r % kB;
  int tid = threadIdx.x;
  float z0, z1;
  if (v == 0) {
    z0 = opval<OPA>(Aa, Ba, r, b, tid);
    z1 = opval<OPA>(Aa, Ba, r, b, tid + 256);
  } else {
    z0 = opval<OPB>(Ab, Bb, r, b, tid);
    z1 = opval<OPB>(Ab, Bb, r, b, tid + 256);
  }
  float s = z0 * z0 + z1 * z1;
  s = wsum(s);
  if ((tid & 63) == 0) red[tid >> 6] = s;
  __syncthreads();
  if (tid == 0) part[(long)v * R + r] = red[0] + red[1] + red[2] + red[3];
}

__global__ void k_ssred(const float* __restrict__ part, float* __restrict__ ss, int R, int NG) {
  __shared__ float red[8];
  int g = blockIdx.x, v = blockIdx.y;
  int n = g / kB, b = g % kB;
  int tid = threadIdx.x;  // 512
  float s = 0.f;
  for (int p = tid; p < kHW; p += 512) s += part[(long)v * R + ((long)(n * kHW + p) * kB + b)];
  s = wsum(s);
  if ((tid & 63) == 0) red[tid >> 6] = s;
  __syncthreads();
  if (tid == 0) {
    float t = 0.f;
#pragma unroll
    for (int i = 0; i < 8; ++i) t += red[i];
    ss[(long)v * NG + g] = t;
  }
}

template <int OPA, int OPB>
__global__ __launch_bounds__(256) void k_scale2(const float* __restrict__ Aa,
                                                const float* __restrict__ Ba,
                                                float* __restrict__ outA,
                                                const float* __restrict__ Ab,
                                                const float* __restrict__ Bb,
                                                float* __restrict__ outB,
                                                const float* __restrict__ ss, int NG,
                                                u16b* __restrict__ oAb,
                                                u16b* __restrict__ oBb) {
  int r = blockIdx.x, v = blockIdx.y;
  int l = r / kB, b = r % kB;
  int g = (l / kHW) * kB + b;
  int tid = threadIdx.x;
  float fac = kScaleN * sqrtf(kCnt / (ss[(long)v * NG + g] + 1e-5f));
  if (v == 0) {
    float x0 = opval<OPA>(Aa, Ba, r, b, tid) * fac;
    float x1 = opval<OPA>(Aa, Ba, r, b, tid + 256) * fac;
    outA[(long)r * kD + tid] = x0;
    outA[(long)r * kD + tid + 256] = x1;
    if (oAb) { oAb[(long)r * kD + tid] = f2bf(x0); oAb[(long)r * kD + tid + 256] = f2bf(x1); }
  } else {
    float x0 = opval<OPB>(Ab, Bb, r, b, tid) * fac;
    float x1 = opval<OPB>(Ab, Bb, r, b, tid + 256) * fac;
    outB[(long)r * kD + tid] = x0;
    outB[(long)r * kD + tid + 256] = x1;
    if (oBb) { oBb[(long)r * kD + tid] = f2bf(x0); oBb[(long)r * kD + tid + 256] = f2bf(x1); }
  }
}

// tail phase a: part[v*kR + r] = ss of {t1r*mkr, t1i*mki, t1r+c3r, t1i+c3i}[v]
__global__ __launch_bounds__(256) void k_ss_tail(const float* __restrict__ t1r,
                                                 const float* __restrict__ t1i,
                                                 const float* __restrict__ mkr,
                                                 const float* __restrict__ mki,
                                                 const float* __restrict__ c3,
                                                 float* __restrict__ part) {
  __shared__ float red[4];
  int r = blockIdx.x, v = blockIdx.y;
  int tid = threadIdx.x;
  const float* t1 = (v & 1) ? t1i : t1r;
  long base = (long)r * kD;
  float a0, a1;
  if (v < 2) {
    float mk = (v ? mki : mkr)[r];
    a0 = t1[base + tid] * mk;
    a1 = t1[base + tid + 256] * mk;
  } else {
    const float* c = c3 + (long)(v - 2) * kHBD;
    a0 = t1[base + tid] + c[base + tid];
    a1 = t1[base + tid + 256] + c[base + tid + 256];
  }
  float s = a0 * a0 + a1 * a1;
  s = wsum(s);
  if ((tid & 63) == 0) red[tid >> 6] = s;
  __syncthreads();
  if (tid == 0) part[(long)v * kR + r] = red[0] + red[1] + red[2] + red[3];
}

// tail phase c: z_v = t1_v*mk_v*fac2_v + (t1_v+c3_v)*fac4_v; ss partials of z
__global__ __launch_bounds__(256) void k_zmk(const float* __restrict__ t1r,
                                             const float* __restrict__ t1i,
                                             const float* __restrict__ mkr,
                                             const float* __restrict__ mki,
                                             const float* __restrict__ c3,
                                             const float* __restrict__ ss,
                                             float* __restrict__ z,
                                             float* __restrict__ part) {
  __shared__ float red[4];
  int r = blockIdx.x, v = blockIdx.y;
  int b = r % kB;
  int tid = threadIdx.x;
  const float* t1 = v ? t1i : t1r;
  float mk = (v ? mki : mkr)[r];
  const float* c = c3 + (long)v * kHBD;
  float f2 = kScaleN * sqrtf(kCnt / (ss[v * kB + b] + 1e-5f));
  float f4 = kScaleN * sqrtf(kCnt / (ss[(2 + v) * kB + b] + 1e-5f));
  long base = (long)r * kD;
  float t0 = t1[base + tid], t1v = t1[base + tid + 256];
  float z0 = t0 * mk * f2 + (t0 + c[base + tid]) * f4;
  float z1 = t1v * mk * f2 + (t1v + c[base + tid + 256]) * f4;
  z[(long)v * kHBD + base + tid] = z0;
  z[(long)v * kHBD + base + tid + 256] = z1;
  float s = z0 * z0 + z1 * z1;
  s = wsum(s);
  if ((tid & 63) == 0) red[tid >> 6] = s;
  __syncthreads();
  if (tid == 0) part[(long)v * kR + r] = red[0] + red[1] + red[2] + red[3];
}

// tail phase e: t2b[r][v*512 + d] = bf16(z_v * fac_v)
__global__ __launch_bounds__(256) void k_zscale(const float* __restrict__ z,
                                                const float* __restrict__ ss,
                                                u16b* __restrict__ t2b) {
  int r = blockIdx.x, v = blockIdx.y;
  int b = r % kB;
  int tid = threadIdx.x;
  float fac = kScaleN * sqrtf(kCnt / (ss[v * kB + b] + 1e-5f));
  long base = (long)r * kD;
  t2b[(long)r * 1024 + v * 512 + tid] = f2bf(z[(long)v * kHBD + base + tid] * fac);
  t2b[(long)r * 1024 + v * 512 + tid + 256] = f2bf(z[(long)v * kHBD + base + tid + 256] * fac);
}

__global__ void k_vb(const float* __restrict__ t1i, const float* __restrict__ Wk,
                     const float* __restrict__ bk, float* __restrict__ vb) {
  __shared__ float part[4][128];
  __shared__ float red[2];
  int b = blockIdx.x;
  int j = threadIdx.x;
  int dz = threadIdx.y;
  const float* row = t1i + (long)b * kD;
  float acc = 0.f;
  int d0 = dz * 128;
  for (int d = d0; d < d0 + 128; ++d) acc += row[d] * Wk[(long)d * kKD + j];
  part[dz][j] = acc;
  __syncthreads();
  if (dz == 0) {
    float a = part[0][j] + part[1][j] + part[2][j] + part[3][j] + bk[j];
    float s = a * a;
    s = wsum(s);
    if ((j & 63) == 0) red[j >> 6] = s;
    part[0][j] = a;
  }
  __syncthreads();
  if (dz == 0) {
    float inv = 1.f / fmaxf(sqrtf(red[0] + red[1]), 1e-12f);
    vb[(long)b * kKD + j] = part[0][j] * inv;
  }
}

// cR/cI from bf16 Kc = [Krb; Kib]; 4 (k,b) pairs per block (one per wave)
__global__ void k_cRcI(const float* __restrict__ vb, const u16b* __restrict__ Kc,
                       float* __restrict__ cR, float* __restrict__ cI) {
  int idx = blockIdx.x * 4 + (threadIdx.x >> 6);
  if (idx >= kL * kB) return;
  int k = idx / kB, b = idx % kB;
  int lane = threadIdx.x & 63;
  const float* v = vb + (long)b * kKD;
  const u16b* pr = Kc + ((long)k * kB + b) * kKD;
  const u16b* pi = pr + (long)kL * kB * kKD;
  float sR = 0.f, sI = 0.f;
  for (int c = lane; c < kKD; c += 64) {
    sR += v[c] * bf2f(pr[c]);
    sI += v[c] * bf2f(pi[c]);
  }
  sR = wsum(sR);
  sI = wsum(sI);
  if (lane == 0) {
    cR[(long)b * kL + k] = sR;
    cI[(long)b * kL + k] = sI;
  }
}

template <int BM, int BN, bool AF32, bool ACC>
void gemm(hipStream_t s, const void* A, const u16b* B, float* C, int M, int N, int K, int lda,
          int ldb, int ldc, long sAb, long sBb, long sCb, int batch) {
  dim3 grd(CDIV(N, BN), CDIV(M, BM), batch), blk(256);
  k_gemm<BM, BN, AF32, ACC><<<grd, blk, 0, s>>>(A, B, C, M, N, K, lda, ldb, ldc, sAb, sBb, sCb);
}

}  // namespace

extern "C" void kernel_launch(void* const* d_in, const int* in_sizes, int n_in, void* d_out,
                              int out_size, void* d_ws, size_t ws_size, hipStream_t stream) {
  (void)in_sizes; (void)n_in; (void)out_size;
  const float* tf  = (const float*)d_in[0];
  const float* sf  = (const float*)d_in[1];
  const float* tl  = (const float*)d_in[2];
  const float* WkE = (const float*)d_in[3];
  const float* bkE = (const float*)d_in[4];
  const float* WkS = (const float*)d_in[5];
  const float* bkS = (const float*)d_in[6];
  const float* WkC = (const float*)d_in[7];
  const float* bkC = (const float*)d_in[8];
  const float* Wc  = (const float*)d_in[9];
  float* out = (float*)d_out;
  float* ws = (float*)d_ws;

  const long LBD = (long)kL * kB * kD;
  const long LBK = (long)kL * kB * kKD;   // u16 count of one K-branch
  const long HBD = kHBD;

  long off = 0;
  auto alloc = [&](long n) { long o = off; off += (n + 255) & ~255L; return o; };
  auto allocU = [&](long nu) { return alloc((nu + 1) / 2); };

  long o_seqT = alloc(LBD);
  long o_seqS = alloc(LBD);
  long o_Kr   = alloc(LBK);
  long o_Ki   = alloc(LBK);
  long o_Kcb  = allocU(2 * LBK);
  long o_VrT  = allocU((long)kB * kD * kLp);
  long o_tfb  = allocU((long)kNI * kB * kD * kHWp);
  long o_sfb  = allocU((long)kNI * kB * kD * kHWp);
  long o_WkTE = allocU((long)kD * kD);
  long o_WkTS = allocU((long)kKD * kD);
  long o_WkTC = allocU((long)kKD * kD);
  long o_Wcb  = allocU((long)kD * 2 * kD);
  long o_lab = alloc((long)kL * kB);
  long o_uE = alloc(kD);
  long o_uS = alloc(kKD);
  long o_vb = alloc((long)kB * kKD);
  long o_g = alloc((long)kB * kL);
  long o_cR = alloc((long)kB * kL);
  long o_cI = alloc((long)kB * kL);
  long o_row = alloc((long)kB * kD);
  long o_mkr = alloc((long)kHW * kB);
  long o_mki = alloc((long)kHW * kB);
  long o_ss = alloc(128);
  long o_part = alloc(4L * kL * kB);
  long o_scr = off;

  // encoder overlay
  long o_Pe  = o_scr;
  long o_Peb = o_Pe + LBD;
  long o_Ae  = o_Peb + LBD / 2;
  long enc_end = o_Ae + (long)kB * kL * kL;
  long o_ar  = o_Pe;
  long o_mib = o_Peb;
  long o_mr  = o_Ae;
  long o_mi  = o_Ae + LBD;
  long o_mrb = o_Ae + 2 * LBD;

  // decoder overlay
  long p = o_scr;
  auto nxt = [&](long n) { long o = p; p += (n + 255) & ~255L; return o; };
  long o_Sf   = nxt((long)kR * 2 * kL);        // also Ps/As/Pc fp32 staging
  long o_Psb  = nxt(((long)kR * kKD + 1) / 2);
  long o_Pcb  = nxt(((long)kR * kKD + 1) / 2);
  long o_Asb  = nxt(((long)kR * kHWp + 1) / 2);
  long o_Ph   = nxt((2L * kR * kLp + 1) / 2);
  long o_t1r  = nxt(HBD);
  long o_t1rb = nxt((HBD + 1) / 2);
  long o_t1i  = nxt(HBD);
  long o_c3   = nxt(2 * HBD);
  long o_z    = nxt(2 * HBD);
  long o_t2b  = nxt(((long)kR * 1024 + 1) / 2);
  long img_end = p;

  long total = (enc_end > img_end ? enc_end : img_end);
  if ((size_t)total * sizeof(float) > ws_size) return;

  float* seqT = ws + o_seqT;
  float* seqS = ws + o_seqS;
  float* Kr = ws + o_Kr;
  float* Ki = ws + o_Ki;
  u16b* Kcb = (u16b*)(ws + o_Kcb);
  u16b* VrT = (u16b*)(ws + o_VrT);
  u16b* tfb = (u16b*)(ws + o_tfb);
  u16b* sfb = (u16b*)(ws + o_sfb);
  u16b* WkTE = (u16b*)(ws + o_WkTE);
  u16b* WkTS = (u16b*)(ws + o_WkTS);
  u16b* WkTC = (u16b*)(ws + o_WkTC);
  u16b* Wcb = (u16b*)(ws + o_Wcb);
  float* lab = ws + o_lab;
  float* uE = ws + o_uE;
  float* uS = ws + o_uS;
  float* vb = ws + o_vb;
  float* g_ = ws + o_g;
  float* cR = ws + o_cR;
  float* cI = ws + o_cI;
  float* row = ws + o_row;
  float* mkr = ws + o_mkr;
  float* mki = ws + o_mki;
  float* ssp = ws + o_ss;
  float* part = ws + o_part;
  float* Pe = ws + o_Pe;
  u16b* Peb = (u16b*)(ws + o_Peb);
  float* Ae = ws + o_Ae;
  float* ar = ws + o_ar;
  float* mr = ws + o_mr;
  float* mi = ws + o_mi;
  u16b* mrb = (u16b*)(ws + o_mrb);
  u16b* mib = (u16b*)(ws + o_mib);
  float* Sf = ws + o_Sf;
  float* Ps = ws + o_Sf;    // staging overlay (disjoint lifetimes)
  float* As_ = ws + o_Sf;
  float* Pc = ws + o_Sf;
  u16b* Psb = (u16b*)(ws + o_Psb);
  u16b* Pcb = (u16b*)(ws + o_Pcb);
  u16b* Asb = (u16b*)(ws + o_Asb);
  u16b* Ph = (u16b*)(ws + o_Ph);
  float* t1r = ws + o_t1r;
  u16b* t1rb = (u16b*)(ws + o_t1rb);
  float* t1i = ws + o_t1i;
  float* c3 = ws + o_c3;
  float* z = ws + o_z;
  u16b* t2b = (u16b*)(ws + o_t2b);

  // ---- stage 0 ----
  {
    dim3 grd(CDIV(kHW, 32), CDIV(kD, 32), kNI * kB), blk(32, 8);
    k_toseq<<<grd, blk, 0, stream>>>(tf, seqT);
    k_toseq<<<grd, blk, 0, stream>>>(sf, seqS);
  }
  k_cvt2d<<<kNI * kB * kD, 256, 0, stream>>>(tf, tfb, kHW, kHWp);
  k_cvt2d<<<kNI * kB * kD, 256, 0, stream>>>(sf, sfb, kHW, kHWp);
  k_cvt2d<<<kD, 256, 0, stream>>>(Wc, Wcb, 2 * kD, 2 * kD);
  k_tcvt<<<dim3(kD / 32, kD / 32), dim3(32, 8), 0, stream>>>(WkE, WkTE, kD, kD);
  k_tcvt<<<dim3(kKD / 32, kD / 32), dim3(32, 8), 0, stream>>>(WkS, WkTS, kD, kKD);
  k_tcvt<<<dim3(kKD / 32, kD / 32), dim3(32, 8), 0, stream>>>(WkC, WkTC, kD, kKD);
  k_lab<<<CDIV(kNI * kB * kHW, 256), 256, 0, stream>>>(tl, lab);
  k_l2n_vec<<<1, 128, 0, stream>>>(bkE, uE, kD);
  k_l2n_vec<<<1, 128, 0, stream>>>(bkS, uS, kKD);

  // ---- encoder ----
  gemm<64, 128, true, false>(stream, seqT, WkTE, Pe, kL * kB, kD, kD, kD, kD, kD, 0, 0, 0, 1);
  k_bias_l2n<<<kL * kB, 128, 0, stream>>>(Pe, bkE, kD, Peb);
  k_rowdot<<<kL * kB, 64, 0, stream>>>(Pe, uE, g_, kL, kD);
  k_softmax<<<kB, 256, 0, stream>>>(g_, 1, kL, nullptr, 0);
  gemm<128, 128, false, false>(stream, Peb, Peb, Ae, kL, kL, kD, kB * kD, kB * kD, kL, kD, kD,
                               (long)kL * kL, 8);
  k_softmax<<<kB * kL, 256, 0, stream>>>(Ae, kL, kL, nullptr, 0);
  gemm<64, 128, true, false>(stream, Ae, tfb, ar, kL, kD, kHW, kL, kHWp, kB * kD,
                             (long)kL * kL, (long)kD * kHWp, kD, 8);
  gemm<64, 128, true, true>(stream, Ae + kHW, tfb + (long)kB * kD * kHWp, ar, kL, kD, kHW, kL,
                            kHWp, kB * kD, (long)kL * kL, (long)kD * kHWp, kD, 8);
  gemm<64, 128, true, true>(stream, Ae + 2 * kHW, tfb + 2L * kB * kD * kHWp, ar, kL, kD, kHW,
                            kL, kHWp, kB * kD, (long)kL * kL, (long)kD * kHWp, kD, 8);
  hipMemsetAsync(row, 0, kB * kD * sizeof(float), stream);
  k_wrowsum<<<dim3(kD / 128, kB, CDIV(kL, 64)), 128, 0, stream>>>(g_, seqT, row, kL, 64);
  k_ss2<0, 1><<<dim3(kL * kB, 2), 256, 0, stream>>>(seqT, ar, row, nullptr, part, kL * kB);
  k_ssred<<<dim3(kNI * kB, 2), 512, 0, stream>>>(part, ssp, kL * kB, kNI * kB);
  k_scale2<0, 1><<<dim3(kL * kB, 2), 256, 0, stream>>>(seqT, ar, mr, row, nullptr, mi, ssp,
                                                       kNI * kB, mrb, mib);
  k_vrt<<<dim3(CDIV(kL, 32), kD / 32, kB), dim3(32, 8), 0, stream>>>(mr, lab, VrT);
  gemm<64, 64, false, false>(stream, mrb, WkTC, Kr, kL * kB, kKD, kD, kD, kD, kKD, 0, 0, 0, 1);
  k_bias_l2n<<<kL * kB, 128, 0, stream>>>(Kr, bkC, kKD, Kcb);
  gemm<64, 64, false, false>(stream, mib, WkTC, Ki, kL * kB, kKD, kD, kD, kD, kKD, 0, 0, 0, 1);
  k_bias_l2n<<<kL * kB, 128, 0, stream>>>(Ki, bkC, kKD, Kcb + LBK);

  // ---- decoder ----
  for (int img = 0; img < 6; ++img) {
    const float* t = (img < 3) ? (seqT + (long)img * HBD) : (seqS + (long)(img - 3) * HBD);
    const u16b* tb = (img < 3) ? (tfb + (long)img * kB * kD * kHWp)
                               : (sfb + (long)(img - 3) * kB * kD * kHWp);
    float* osl = out + (long)img * kB * kD * kHW;

    // self-attention
    gemm<64, 64, true, false>(stream, t, WkTS, Ps, kHW * kB, kKD, kD, kD, kD, kKD, 0, 0, 0, 1);
    k_bias_l2n<<<kHW * kB, 128, 0, stream>>>(Ps, bkS, kKD, Psb);
    k_rowdot<<<kHW * kB, 64, 0, stream>>>(Ps, uS, g_, kHW, kKD);
    k_softmax<<<kB, 256, 0, stream>>>(g_, 1, kHW, nullptr, 0);
    gemm<64, 128, false, false>(stream, Psb, Psb, As_, kHW, kHW, kKD, kB * kKD, kB * kKD, kHW,
                                kKD, kKD, (long)kHW * kHW, 8);
    k_softmax<<<kB * kHW, 256, 0, stream>>>(As_, kHW, kHW, Asb, kHWp);
    gemm<64, 128, false, false>(stream, Asb, tb, c3, kHW, kD, kHW, kHWp, kHWp, kB * kD,
                                (long)kHW * kHWp, (long)kD * kHWp, kD, 8);  // s2r in c3[0:HBD]
    hipMemsetAsync(row, 0, kB * kD * sizeof(float), stream);
    k_wrowsum<<<dim3(kD / 128, kB, CDIV(kHW, 64)), 128, 0, stream>>>(g_, t, row, kHW, 64);
    // t1r = inorm(t + s2r); t1i = inorm(bcast s2i)
    k_ss2<0, 1><<<dim3(kR, 2), 256, 0, stream>>>(t, c3, row, nullptr, part, kR);
    k_ssred<<<dim3(kB, 2), 512, 0, stream>>>(part, ssp, kR, kB);
    k_scale2<0, 1><<<dim3(kR, 2), 256, 0, stream>>>(t, c3, t1r, row, nullptr, t1i, ssp, kB,
                                                    t1rb, nullptr);
    // cross-attention (fused S1/S2 and c3r/c3i)
    k_vb<<<kB, dim3(128, 4), 0, stream>>>(t1i, WkC, bkC, vb);
    gemm<64, 64, false, false>(stream, t1rb, WkTC, Pc, kHW * kB, kKD, kD, kD, kD, kKD, 0, 0, 0,
                               1);
    k_bias_l2n<<<kHW * kB, 128, 0, stream>>>(Pc, bkC, kKD, Pcb);
    k_cRcI<<<CDIV(kL * kB, 4), 256, 0, stream>>>(vb, Kcb, cR, cI);
    gemm<64, 128, false, false>(stream, Pcb, Kcb, Sf, kHW, 2 * kL, kKD, kB * kKD, kB * kKD,
                                2 * kL, kKD, kKD, (long)kHW * 2 * kL, 8);
    k_softmax2<<<dim3(kB * kHW, 2), 256, 0, stream>>>(Sf, cR, cI, lab, Ph, mkr, mki);
    gemm<64, 128, false, false>(stream, Ph, VrT, c3, 2 * kHW, kD, kL, kLp, kLp, kB * kD,
                                2L * kHW * kLp, (long)kD * kLp, kD, 8);
    // fused tail: t2 = inorm(t1*mk), t4 = inorm(t1+c3), out = inorm(t2+t4) -> t2b bf16
    k_ss_tail<<<dim3(kR, 4), 256, 0, stream>>>(t1r, t1i, mkr, mki, c3, part);
    k_ssred<<<dim3(kB, 4), 512, 0, stream>>>(part, ssp, kR, kB);
    k_zmk<<<dim3(kR, 2), 256, 0, stream>>>(t1r, t1i, mkr, mki, c3, ssp, z, part);
    k_ssred<<<dim3(kB, 2), 512, 0, stream>>>(part, ssp, kR, kB);
    k_zscale<<<dim3(kR, 2), 256, 0, stream>>>(z, ssp, t2b);
    // 1x1 conv: single GEMM, K = 1024 (Wc rows already [real|imag])
    gemm<64, 128, false, false>(stream, Wcb, t2b, osl, kD, kHW, 2 * kD, 2 * kD, kB * 2 * kD,
                                kHW, 0, 2 * kD, (long)kD * kHW, 8);
  }
}

// Round 7
// 1816.727 us; speedup vs baseline: 6.3521x; 1.2693x over previous
//
#include <hip/hip_runtime.h>

// ComTransformer on MI355X — round 7: software-pipelined GEMM.
//  - k_gemm: register-prefetch pipeline (issue next tile's global loads before MFMA),
//    BK=64, padded LDS (row stride 36 u32 -> 2-way-free frag reads, balanced writes)
//  - encoder Ae softmax -> bf16 Aeb; AV GEMM reads bf16 A
//  - tiles resized for >=360-block grids
// Prior structure: rank-1 imag branches, shared mk/c3 softmax, fused score bias,
// label-dot mk, atomic-free 3-phase inorm, S1/S2+c3+Wc operand fusions.

namespace {

constexpr int kNI = 3;
constexpr int kB  = 8;
constexpr int kD  = 512;
constexpr int kKD = 128;
constexpr int kHW = 484;
constexpr int kL  = kNI * kHW;  // 1452
constexpr int kLp = 1456;
constexpr int kHWp = 488;
constexpr float kTemp = 30.0f;
constexpr float kCnt  = 247808.0f;
constexpr float kScaleN = 0.011048543456039806f;
constexpr long kHBD = (long)kHW * kB * kD;
constexpr int kR = kHW * kB;  // 3872

#define CDIV(a, b) (((a) + (b) - 1) / (b))

typedef float f32x4 __attribute__((ext_vector_type(4)));
typedef unsigned int u32x4 __attribute__((ext_vector_type(4)));
typedef unsigned short u16b;

__device__ __forceinline__ float wsum(float v) {
#pragma unroll
  for (int o = 32; o; o >>= 1) v += __shfl_down(v, o);
  return v;
}
__device__ __forceinline__ float wmax(float v) {
#pragma unroll
  for (int o = 32; o; o >>= 1) v = fmaxf(v, __shfl_down(v, o));
  return v;
}

__device__ __forceinline__ unsigned pk2bf(float lo, float hi) {
  union { float f; unsigned u; } a, b;
  a.f = lo; b.f = hi;
  unsigned ra = (a.u + 0x7FFFu + ((a.u >> 16) & 1u)) >> 16;
  unsigned rb = (b.u + 0x7FFFu + ((b.u >> 16) & 1u)) >> 16;
  return (ra & 0xFFFFu) | (rb << 16);
}
__device__ __forceinline__ u16b f2bf(float x) {
  union { float f; unsigned u; } a;
  a.f = x;
  return (u16b)((a.u + 0x7FFFu + ((a.u >> 16) & 1u)) >> 16);
}
__device__ __forceinline__ float bf2f(u16b x) {
  union { unsigned u; float f; } a;
  a.u = (unsigned)x << 16;
  return a.f;
}

__device__ __forceinline__ void mfma_bf16(f32x4& d, const u32x4& a, const u32x4& b) {
  asm("v_mfma_f32_16x16x32_bf16 %0, %1, %2, %0" : "+v"(d) : "v"(a), "v"(b));
}

// ---------------- layout transform: [n,b,d,hw] -> seq [(n*hw),b,d] fp32 -----------
__global__ void k_toseq(const float* __restrict__ in, float* __restrict__ out) {
  __shared__ float tile[32][33];
  int nb = blockIdx.z;
  int n = nb / kB, b = nb % kB;
  int p0 = blockIdx.x * 32, d0 = blockIdx.y * 32;
  int tx = threadIdx.x, ty = threadIdx.y;
#pragma unroll
  for (int j = 0; j < 4; ++j) {
    int d = d0 + ty + j * 8, p = p0 + tx;
    if (d < kD && p < kHW) tile[ty + j * 8][tx] = in[(long)nb * kD * kHW + (long)d * kHW + p];
  }
  __syncthreads();
#pragma unroll
  for (int j = 0; j < 4; ++j) {
    int p = p0 + ty + j * 8, d = d0 + tx;
    if (p < kHW && d < kD)
      out[((long)(n * kHW + p) * kB + b) * kD + d] = tile[tx][ty + j * 8];
  }
}

__global__ void k_cvt2d(const float* __restrict__ in, u16b* __restrict__ out, int C, int Cp) {
  long r = blockIdx.x;
  for (int c = threadIdx.x; c < C; c += 256)
    out[r * Cp + c] = f2bf(in[r * (long)C + c]);
}

__global__ void k_tcvt(const float* __restrict__ in, u16b* __restrict__ out, int R, int C) {
  __shared__ float tile[32][33];
  int c0 = blockIdx.x * 32, r0 = blockIdx.y * 32;
  int tx = threadIdx.x, ty = threadIdx.y;
#pragma unroll
  for (int j = 0; j < 4; ++j) {
    int r = r0 + ty + j * 8, c = c0 + tx;
    if (r < R && c < C) tile[ty + j * 8][tx] = in[(long)r * C + c];
  }
  __syncthreads();
#pragma unroll
  for (int j = 0; j < 4; ++j) {
    int c = c0 + ty + j * 8, r = r0 + tx;
    if (r < R && c < C) out[(long)c * R + r] = f2bf(tile[tx][ty + j * 8]);
  }
}

// VrT[b][d][l] = bf16( mr[(l,b),d] * lab[l,b] ), stride kLp
__global__ void k_vrt(const float* __restrict__ mr, const float* __restrict__ lab,
                      u16b* __restrict__ vt) {
  __shared__ float tile[32][33];
  int l0 = blockIdx.x * 32, d0 = blockIdx.y * 32, b = blockIdx.z;
  int tx = threadIdx.x, ty = threadIdx.y;
#pragma unroll
  for (int j = 0; j < 4; ++j) {
    int l = l0 + ty + j * 8;
    if (l < kL)
      tile[ty + j * 8][tx] = mr[((long)l * kB + b) * kD + d0 + tx] * lab[(long)l * kB + b];
  }
  __syncthreads();
#pragma unroll
  for (int j = 0; j < 4; ++j) {
    int d = d0 + ty + j * 8, l = l0 + tx;
    if (l < kL) vt[((long)b * kD + d) * kLp + l] = f2bf(tile[tx][ty + j * 8]);
  }
}

__global__ void k_lab(const float* __restrict__ tl, float* __restrict__ lab) {
  long i = (long)blockIdx.x * 256 + threadIdx.x;
  const long tot = (long)kNI * kB * kHW;
  if (i >= tot) return;
  int p = (int)(i % kHW);
  long t = i / kHW;
  int b = (int)(t % kB);
  int n = (int)(t / kB);
  lab[(long)(n * kHW + p) * kB + b] = tl[i];
}

__global__ void k_l2n_vec(const float* __restrict__ src, float* __restrict__ u, int C) {
  __shared__ float red[2];
  int tid = threadIdx.x;  // 128
  float s = 0.f;
  for (int c = tid; c < C; c += 128) { float x = src[c]; s += x * x; }
  s = wsum(s);
  if ((tid & 63) == 0) red[tid >> 6] = s;
  __syncthreads();
  float inv = 1.f / fmaxf(sqrtf(red[0] + red[1]), 1e-12f);
  for (int c = tid; c < C; c += 128) u[c] = src[c] * inv;
}

// ---------------- pipelined NT bf16 MFMA GEMM -------------------------------------
// C[m][n] (+)= sum_k A[m][k] * B[n][k].  BK=64, register-prefetch pipeline.
// LDS row stride 36 u32 (64 bf16 payload + pad): balanced writes, 2-way frag reads.
template <int BM, int BN, bool AF32, bool ACC>
__global__ __launch_bounds__(256) void k_gemm(const void* Ap, const u16b* __restrict__ B,
                                              float* __restrict__ C, int M, int N, int K,
                                              int lda, int ldb, int ldc, long sAb, long sBb,
                                              long sCb) {
  const char* Ab = (const char*)Ap + (long)blockIdx.z * sAb * (AF32 ? 4 : 2);
  const u16b* Bb = B + (long)blockIdx.z * sBb;
  C += (long)blockIdx.z * sCb;
  constexpr int FM = BM / 32, FN = BN / 32;
  constexpr int NSA = BM * 8 / 256;  // 16B segs per thread for A
  constexpr int NSB = BN * 8 / 256;
  const int m0 = blockIdx.y * BM, n0 = blockIdx.x * BN;
  const int tid = threadIdx.x;
  const int wid = tid >> 6, lane = tid & 63;
  const int wr = wid >> 1, wc = wid & 1;
  const int fr = lane & 15, fk = lane >> 4;

  __shared__ unsigned AsU[BM * 36];
  __shared__ unsigned BsU[BN * 36];
  f32x4 acc[FM][FN] = {};

  u32x4 pa[NSA];
  float4 paf[AF32 ? 2 * NSA : 1];
  u32x4 pb[NSB];

  auto loadA = [&](int k0) {
#pragma unroll
    for (int i = 0; i < NSA; ++i) {
      int si = tid + i * 256;
      int row = si >> 3, c = si & 7;
      int gr = m0 + row, gk = k0 + c * 8;
      if constexpr (AF32) {
        const float* A = (const float*)Ab;
        if (gr < M && gk + 8 <= K) {
          const float* ap = A + (long)gr * lda + gk;
          paf[2 * i] = *(const float4*)ap;
          paf[2 * i + 1] = *(const float4*)(ap + 4);
        } else {
          float v[8];
#pragma unroll
          for (int j = 0; j < 8; ++j)
            v[j] = (gr < M && gk + j < K) ? A[(long)gr * lda + gk + j] : 0.f;
          paf[2 * i] = make_float4(v[0], v[1], v[2], v[3]);
          paf[2 * i + 1] = make_float4(v[4], v[5], v[6], v[7]);
        }
      } else {
        const u16b* A = (const u16b*)Ab;
        if (gr < M && gk + 8 <= K) {
          pa[i] = *(const u32x4*)(A + (long)gr * lda + gk);
        } else {
          unsigned v[8];
#pragma unroll
          for (int j = 0; j < 8; ++j)
            v[j] = (gr < M && gk + j < K) ? A[(long)gr * lda + gk + j] : 0u;
          pa[i].x = v[0] | (v[1] << 16); pa[i].y = v[2] | (v[3] << 16);
          pa[i].z = v[4] | (v[5] << 16); pa[i].w = v[6] | (v[7] << 16);
        }
      }
    }
  };
  auto loadB = [&](int k0) {
#pragma unroll
    for (int i = 0; i < NSB; ++i) {
      int si = tid + i * 256;
      int row = si >> 3, c = si & 7;
      int gr = n0 + row, gk = k0 + c * 8;
      if (gr < N && gk + 8 <= K) {
        pb[i] = *(const u32x4*)(Bb + (long)gr * ldb + gk);
      } else {
        unsigned v[8];
#pragma unroll
        for (int j = 0; j < 8; ++j)
          v[j] = (gr < N && gk + j < K) ? Bb[(long)gr * ldb + gk + j] : 0u;
        pb[i].x = v[0] | (v[1] << 16); pb[i].y = v[2] | (v[3] << 16);
        pb[i].z = v[4] | (v[5] << 16); pb[i].w = v[6] | (v[7] << 16);
      }
    }
  };
  auto storeAB = [&]() {
#pragma unroll
    for (int i = 0; i < NSA; ++i) {
      int si = tid + i * 256;
      int row = si >> 3, c = si & 7;
      u32x4 w;
      if constexpr (AF32) {
        float4 u0 = paf[2 * i], u1 = paf[2 * i + 1];
        w.x = pk2bf(u0.x, u0.y); w.y = pk2bf(u0.z, u0.w);
        w.z = pk2bf(u1.x, u1.y); w.w = pk2bf(u1.z, u1.w);
      } else {
        w = pa[i];
      }
      *(u32x4*)&AsU[row * 36 + c * 4] = w;
    }
#pragma unroll
    for (int i = 0; i < NSB; ++i) {
      int si = tid + i * 256;
      int row = si >> 3, c = si & 7;
      *(u32x4*)&BsU[row * 36 + c * 4] = pb[i];
    }
  };

  loadA(0);
  loadB(0);
  storeAB();
  __syncthreads();
  const int nk = CDIV(K, 64);
  for (int t = 0; t < nk; ++t) {
    const bool more = (t + 1 < nk);
    if (more) { loadA((t + 1) * 64); loadB((t + 1) * 64); }
#pragma unroll
    for (int kk = 0; kk < 2; ++kk) {
      u32x4 af[FM], bf[FN];
#pragma unroll
      for (int mi = 0; mi < FM; ++mi)
        af[mi] = *(const u32x4*)&AsU[(wr * (BM / 2) + mi * 16 + fr) * 36 + kk * 16 + fk * 4];
#pragma unroll
      for (int ni = 0; ni < FN; ++ni)
        bf[ni] = *(const u32x4*)&BsU[(wc * (BN / 2) + ni * 16 + fr) * 36 + kk * 16 + fk * 4];
#pragma unroll
      for (int mi = 0; mi < FM; ++mi)
#pragma unroll
        for (int ni = 0; ni < FN; ++ni) mfma_bf16(acc[mi][ni], af[mi], bf[ni]);
    }
    if (more) {
      __syncthreads();
      storeAB();
      __syncthreads();
    }
  }
  asm volatile("s_nop 7\n\ts_nop 7" ::: );
#pragma unroll
  for (int mi = 0; mi < FM; ++mi) {
#pragma unroll
    for (int r = 0; r < 4; ++r) {
      int gm = m0 + wr * (BM / 2) + mi * 16 + fk * 4 + r;
      if (gm >= M) continue;
#pragma unroll
      for (int ni = 0; ni < FN; ++ni) {
        int gn = n0 + wc * (BN / 2) + ni * 16 + fr;
        if (gn >= N) continue;
        long idx = (long)gm * ldc + gn;
        float v = acc[mi][ni][r];
        C[idx] = ACC ? (C[idx] + v) : v;
      }
    }
  }
}

// row += bias; l2-normalize; fp32 in place + bf16 mirror
__global__ void k_bias_l2n(float* __restrict__ P, const float* __restrict__ bias, int C,
                           u16b* __restrict__ outb) {
  __shared__ float red[2];
  long row = blockIdx.x;
  float* p = P + row * C;
  int tid = threadIdx.x;  // 128
  int nv = C >> 7;
  float v[4];
  float s = 0.f;
#pragma unroll
  for (int i = 0; i < 4; ++i)
    if (i < nv) {
      float x = p[tid + (i << 7)] + bias[tid + (i << 7)];
      v[i] = x;
      s += x * x;
    }
  s = wsum(s);
  if ((tid & 63) == 0) red[tid >> 6] = s;
  __syncthreads();
  float inv = 1.f / fmaxf(sqrtf(red[0] + red[1]), 1e-12f);
#pragma unroll
  for (int i = 0; i < 4; ++i)
    if (i < nv) {
      float x = v[i] * inv;
      p[tid + (i << 7)] = x;
      outb[row * C + tid + (i << 7)] = f2bf(x);
    }
}

__global__ void k_rowdot(const float* __restrict__ P, const float* __restrict__ u,
                         float* __restrict__ g, int L, int C) {
  int idx = blockIdx.x;
  int k = idx / kB, b = idx % kB;
  const float* p = P + ((long)k * kB + b) * C;
  int lane = threadIdx.x;  // 64
  float s = 0.f;
  for (int c = lane; c < C; c += 64) s += u[c] * p[c];
  s = wsum(s);
  if (lane == 0) g[(long)b * L + k] = s;
}

// generic softmax; optional bf16 out at row*ldo
__global__ __launch_bounds__(256) void k_softmax(float* __restrict__ S, int Lq, int Lk,
                                                 u16b* __restrict__ outb, int ldo) {
  __shared__ float sm[1456];
  __shared__ float red[4];
  int row = blockIdx.x;
  float* Sr = S + (long)row * Lk;
  int tid = threadIdx.x;
  float mx = -3.0e38f;
  for (int k = tid; k < Lk; k += 256) {
    float v = Sr[k] * kTemp;
    sm[k] = v;
    mx = fmaxf(mx, v);
  }
  mx = wmax(mx);
  if ((tid & 63) == 0) red[tid >> 6] = mx;
  __syncthreads();
  mx = fmaxf(fmaxf(red[0], red[1]), fmaxf(red[2], red[3]));
  __syncthreads();
  float s = 0.f;
  for (int k = tid; k < Lk; k += 256) {
    float e = expf(sm[k] - mx);
    sm[k] = e;
    s += e;
  }
  s = wsum(s);
  if ((tid & 63) == 0) red[tid >> 6] = s;
  __syncthreads();
  float inv = 1.0f / (red[0] + red[1] + red[2] + red[3]);
  for (int k = tid; k < Lk; k += 256) {
    float p = sm[k] * inv;
    if (outb) outb[(long)row * ldo + k] = f2bf(p); else Sr[k] = p;
  }
}

// fused S1/S2 softmax -> P-hat bf16 + mkr/mki
__global__ __launch_bounds__(256) void k_softmax2(const float* __restrict__ Sf,
                                                  const float* __restrict__ cR,
                                                  const float* __restrict__ cI,
                                                  const float* __restrict__ lab,
                                                  u16b* __restrict__ Ph,
                                                  float* __restrict__ mkr,
                                                  float* __restrict__ mki) {
  __shared__ float sm[1456];
  __shared__ float red[4];
  int row = blockIdx.x;  // b*kHW + q
  int y = blockIdx.y;
  int b = row / kHW, q = row - b * kHW;
  const float* Sr = Sf + (long)row * (2 * kL) + y * kL;
  const float* bias = (y ? cR : cI) + (long)b * kL;
  float sign = y ? 1.f : -1.f;
  int tid = threadIdx.x;
  float mx = -3.0e38f;
  for (int k = tid; k < kL; k += 256) {
    float v = (Sr[k] + sign * bias[k]) * kTemp;
    sm[k] = v;
    mx = fmaxf(mx, v);
  }
  mx = wmax(mx);
  if ((tid & 63) == 0) red[tid >> 6] = mx;
  __syncthreads();
  mx = fmaxf(fmaxf(red[0], red[1]), fmaxf(red[2], red[3]));
  __syncthreads();
  float s = 0.f;
  for (int k = tid; k < kL; k += 256) {
    float e = expf(sm[k] - mx);
    sm[k] = e;
    s += e;
  }
  s = wsum(s);
  if ((tid & 63) == 0) red[tid >> 6] = s;
  __syncthreads();
  float inv = 1.0f / (red[0] + red[1] + red[2] + red[3]);
  __syncthreads();
  u16b* outp = Ph + ((long)(b * 2 + y) * kHW + q) * kLp;
  float dot = 0.f;
  for (int k = tid; k < kL; k += 256) {
    float p = sm[k] * inv;
    outp[k] = f2bf(p);
    dot += p * lab[(long)k * kB + b];
  }
  for (int k = kL + tid; k < kLp; k += 256) outp[k] = 0;
  dot = wsum(dot);
  if ((tid & 63) == 0) red[tid >> 6] = dot;
  __syncthreads();
  if (tid == 0) (y ? mki : mkr)[(long)q * kB + b] = red[0] + red[1] + red[2] + red[3];
}

__global__ void k_wrowsum(const float* __restrict__ w, const float* __restrict__ S,
                          float* __restrict__ rowout, int L, int kchunk) {
  int b = blockIdx.y;
  int d = blockIdx.x * 128 + threadIdx.x;
  int k0 = blockIdx.z * kchunk;
  int k1 = min(L, k0 + kchunk);
  float s = 0.f;
  for (int k = k0; k < k1; ++k) s += w[(long)b * L + k] * S[((long)k * kB + b) * kD + d];
  atomicAdd(&rowout[(long)b * kD + d], s);
}

// OP 0: A[r,d]+B2[r,d]   OP 1: A[b,d] (broadcast)   OP 2: A[r,d]*B2[r]
template <int OP>
__device__ __forceinline__ float opval(const float* __restrict__ A,
                                       const float* __restrict__ B2, long r, int b, int d) {
  if (OP == 0) return A[r * kD + d] + B2[r * kD + d];
  if (OP == 1) return A[(long)b * kD + d];
  return A[r * kD + d] * B2[r];
}

template <int OPA, int OPB>
__global__ __launch_bounds__(256) void k_ss2(const float* __restrict__ Aa,
                                             const float* __restrict__ Ba,
                                             const float* __restrict__ Ab,
                                             const float* __restrict__ Bb,
                                             float* __restrict__ part, int R) {
  __shared__ float red[4];
  int r = blockIdx.x, v = blockIdx.y;
  int b = r % kB;
  int tid = threadIdx.x;
  float z0, z1;
  if (v == 0) {
    z0 = opval<OPA>(Aa, Ba, r, b, tid);
    z1 = opval<OPA>(Aa, Ba, r, b, tid + 256);
  } else {
    z0 = opval<OPB>(Ab, Bb, r, b, tid);
    z1 = opval<OPB>(Ab, Bb, r, b, tid + 256);
  }
  float s = z0 * z0 + z1 * z1;
  s = wsum(s);
  if ((tid & 63) == 0) red[tid >> 6] = s;
  __syncthreads();
  if (tid == 0) part[(long)v * R + r] = red[0] + red[1] + red[2] + red[3];
}

__global__ void k_ssred(const float* __restrict__ part, float* __restrict__ ss, int R, int NG) {
  __shared__ float red[8];
  int g = blockIdx.x, v = blockIdx.y;
  int n = g / kB, b = g % kB;
  int tid = threadIdx.x;  // 512
  float s = 0.f;
  for (int p = tid; p < kHW; p += 512) s += part[(long)v * R + ((long)(n * kHW + p) * kB + b)];
  s = wsum(s);
  if ((tid & 63) == 0) red[tid >> 6] = s;
  __syncthreads();
  if (tid == 0) {
    float t = 0.f;
#pragma unroll
    for (int i = 0; i < 8; ++i) t += red[i];
    ss[(long)v * NG + g] = t;
  }
}

template <int OPA, int OPB>
__global__ __launch_bounds__(256) void k_scale2(const float* __restrict__ Aa,
                                                const float* __restrict__ Ba,
                                                float* __restrict__ outA,
                                                const float* __restrict__ Ab,
                                                const float* __restrict__ Bb,
                                                float* __restrict__ outB,
                                                const float* __restrict__ ss, int NG,
                                                u16b* __restrict__ oAb,
                                                u16b* __restrict__ oBb) {
  int r = blockIdx.x, v = blockIdx.y;
  int l = r / kB, b = r % kB;
  int g = (l / kHW) * kB + b;
  int tid = threadIdx.x;
  float fac = kScaleN * sqrtf(kCnt / (ss[(long)v * NG + g] + 1e-5f));
  if (v == 0) {
    float x0 = opval<OPA>(Aa, Ba, r, b, tid) * fac;
    float x1 = opval<OPA>(Aa, Ba, r, b, tid + 256) * fac;
    outA[(long)r * kD + tid] = x0;
    outA[(long)r * kD + tid + 256] = x1;
    if (oAb) { oAb[(long)r * kD + tid] = f2bf(x0); oAb[(long)r * kD + tid + 256] = f2bf(x1); }
  } else {
    float x0 = opval<OPB>(Ab, Bb, r, b, tid) * fac;
    float x1 = opval<OPB>(Ab, Bb, r, b, tid + 256) * fac;
    outB[(long)r * kD + tid] = x0;
    outB[(long)r * kD + tid + 256] = x1;
    if (oBb) { oBb[(long)r * kD + tid] = f2bf(x0); oBb[(long)r * kD + tid + 256] = f2bf(x1); }
  }
}

// tail phase a: part[v*kR + r] = ss of {t1r*mkr, t1i*mki, t1r+c3r, t1i+c3i}[v]
__global__ __launch_bounds__(256) void k_ss_tail(const float* __restrict__ t1r,
                                                 const float* __restrict__ t1i,
                                                 const float* __restrict__ mkr,
                                                 const float* __restrict__ mki,
                                                 const float* __restrict__ c3,
                                                 float* __restrict__ part) {
  __shared__ float red[4];
  int r = blockIdx.x, v = blockIdx.y;
  int tid = threadIdx.x;
  const float* t1 = (v & 1) ? t1i : t1r;
  long base = (long)r * kD;
  float a0, a1;
  if (v < 2) {
    float mk = (v ? mki : mkr)[r];
    a0 = t1[base + tid] * mk;
    a1 = t1[base + tid + 256] * mk;
  } else {
    const float* c = c3 + (long)(v - 2) * kHBD;
    a0 = t1[base + tid] + c[base + tid];
    a1 = t1[base + tid + 256] + c[base + tid + 256];
  }
  float s = a0 * a0 + a1 * a1;
  s = wsum(s);
  if ((tid & 63) == 0) red[tid >> 6] = s;
  __syncthreads();
  if (tid == 0) part[(long)v * kR + r] = red[0] + red[1] + red[2] + red[3];
}

// tail phase c: z_v = t1_v*mk_v*fac2_v + (t1_v+c3_v)*fac4_v; ss partials of z
__global__ __launch_bounds__(256) void k_zmk(const float* __restrict__ t1r,
                                             const float* __restrict__ t1i,
                                             const float* __restrict__ mkr,
                                             const float* __restrict__ mki,
                                             const float* __restrict__ c3,
                                             const float* __restrict__ ss,
                                             float* __restrict__ z,
                                             float* __restrict__ part) {
  __shared__ float red[4];
  int r = blockIdx.x, v = blockIdx.y;
  int b = r % kB;
  int tid = threadIdx.x;
  const float* t1 = v ? t1i : t1r;
  float mk = (v ? mki : mkr)[r];
  const float* c = c3 + (long)v * kHBD;
  float f2 = kScaleN * sqrtf(kCnt / (ss[v * kB + b] + 1e-5f));
  float f4 = kScaleN * sqrtf(kCnt / (ss[(2 + v) * kB + b] + 1e-5f));
  long base = (long)r * kD;
  float t0 = t1[base + tid], t1v = t1[base + tid + 256];
  float z0 = t0 * mk * f2 + (t0 + c[base + tid]) * f4;
  float z1 = t1v * mk * f2 + (t1v + c[base + tid + 256]) * f4;
  z[(long)v * kHBD + base + tid] = z0;
  z[(long)v * kHBD + base + tid + 256] = z1;
  float s = z0 * z0 + z1 * z1;
  s = wsum(s);
  if ((tid & 63) == 0) red[tid >> 6] = s;
  __syncthreads();
  if (tid == 0) part[(long)v * kR + r] = red[0] + red[1] + red[2] + red[3];
}

// tail phase e: t2b[r][v*512 + d] = bf16(z_v * fac_v)
__global__ __launch_bounds__(256) void k_zscale(const float* __restrict__ z,
                                                const float* __restrict__ ss,
                                                u16b* __restrict__ t2b) {
  int r = blockIdx.x, v = blockIdx.y;
  int b = r % kB;
  int tid = threadIdx.x;
  float fac = kScaleN * sqrtf(kCnt / (ss[v * kB + b] + 1e-5f));
  long base = (long)r * kD;
  t2b[(long)r * 1024 + v * 512 + tid] = f2bf(z[(long)v * kHBD + base + tid] * fac);
  t2b[(long)r * 1024 + v * 512 + tid + 256] = f2bf(z[(long)v * kHBD + base + tid + 256] * fac);
}

__global__ void k_vb(const float* __restrict__ t1i, const float* __restrict__ Wk,
                     const float* __restrict__ bk, float* __restrict__ vb) {
  __shared__ float part[4][128];
  __shared__ float red[2];
  int b = blockIdx.x;
  int j = threadIdx.x;
  int dz = threadIdx.y;
  const float* row = t1i + (long)b * kD;
  float acc = 0.f;
  int d0 = dz * 128;
  for (int d = d0; d < d0 + 128; ++d) acc += row[d] * Wk[(long)d * kKD + j];
  part[dz][j] = acc;
  __syncthreads();
  if (dz == 0) {
    float a = part[0][j] + part[1][j] + part[2][j] + part[3][j] + bk[j];
    float s = a * a;
    s = wsum(s);
    if ((j & 63) == 0) red[j >> 6] = s;
    part[0][j] = a;
  }
  __syncthreads();
  if (dz == 0) {
    float inv = 1.f / fmaxf(sqrtf(red[0] + red[1]), 1e-12f);
    vb[(long)b * kKD + j] = part[0][j] * inv;
  }
}

__global__ void k_cRcI(const float* __restrict__ vb, const u16b* __restrict__ Kc,
                       float* __restrict__ cR, float* __restrict__ cI) {
  int idx = blockIdx.x * 4 + (threadIdx.x >> 6);
  if (idx >= kL * kB) return;
  int k = idx / kB, b = idx % kB;
  int lane = threadIdx.x & 63;
  const float* v = vb + (long)b * kKD;
  const u16b* pr = Kc + ((long)k * kB + b) * kKD;
  const u16b* pi = pr + (long)kL * kB * kKD;
  float sR = 0.f, sI = 0.f;
  for (int c = lane; c < kKD; c += 64) {
    sR += v[c] * bf2f(pr[c]);
    sI += v[c] * bf2f(pi[c]);
  }
  sR = wsum(sR);
  sI = wsum(sI);
  if (lane == 0) {
    cR[(long)b * kL + k] = sR;
    cI[(long)b * kL + k] = sI;
  }
}

template <int BM, int BN, bool AF32, bool ACC>
void gemm(hipStream_t s, const void* A, const u16b* B, float* C, int M, int N, int K, int lda,
          int ldb, int ldc, long sAb, long sBb, long sCb, int batch) {
  dim3 grd(CDIV(N, BN), CDIV(M, BM), batch), blk(256);
  k_gemm<BM, BN, AF32, ACC><<<grd, blk, 0, s>>>(A, B, C, M, N, K, lda, ldb, ldc, sAb, sBb, sCb);
}

}  // namespace

extern "C" void kernel_launch(void* const* d_in, const int* in_sizes, int n_in, void* d_out,
                              int out_size, void* d_ws, size_t ws_size, hipStream_t stream) {
  (void)in_sizes; (void)n_in; (void)out_size;
  const float* tf  = (const float*)d_in[0];
  const float* sf  = (const float*)d_in[1];
  const float* tl  = (const float*)d_in[2];
  const float* WkE = (const float*)d_in[3];
  const float* bkE = (const float*)d_in[4];
  const float* WkS = (const float*)d_in[5];
  const float* bkS = (const float*)d_in[6];
  const float* WkC = (const float*)d_in[7];
  const float* bkC = (const float*)d_in[8];
  const float* Wc  = (const float*)d_in[9];
  float* out = (float*)d_out;
  float* ws = (float*)d_ws;

  const long LBD = (long)kL * kB * kD;
  const long LBK = (long)kL * kB * kKD;
  const long HBD = kHBD;

  long off = 0;
  auto alloc = [&](long n) { long o = off; off += (n + 255) & ~255L; return o; };
  auto allocU = [&](long nu) { return alloc((nu + 1) / 2); };

  long o_seqT = alloc(LBD);
  long o_seqS = alloc(LBD);
  long o_Kr   = alloc(LBK);
  long o_Ki   = alloc(LBK);
  long o_Kcb  = allocU(2 * LBK);
  long o_VrT  = allocU((long)kB * kD * kLp);
  long o_tfb  = allocU((long)kNI * kB * kD * kHWp);
  long o_sfb  = allocU((long)kNI * kB * kD * kHWp);
  long o_WkTE = allocU((long)kD * kD);
  long o_WkTS = allocU((long)kKD * kD);
  long o_WkTC = allocU((long)kKD * kD);
  long o_Wcb  = allocU((long)kD * 2 * kD);
  long o_lab = alloc((long)kL * kB);
  long o_uE = alloc(kD);
  long o_uS = alloc(kKD);
  long o_vb = alloc((long)kB * kKD);
  long o_g = alloc((long)kB * kL);
  long o_cR = alloc((long)kB * kL);
  long o_cI = alloc((long)kB * kL);
  long o_row = alloc((long)kB * kD);
  long o_mkr = alloc((long)kHW * kB);
  long o_mki = alloc((long)kHW * kB);
  long o_ss = alloc(128);
  long o_part = alloc(4L * kL * kB);
  long o_scr = off;

  // encoder overlay
  long o_Pe  = o_scr;
  long o_Peb = o_Pe + LBD;
  long o_Ae  = o_Peb + LBD / 2;
  long o_Aeb = o_Ae + (long)kB * kL * kL;   // bf16 [8][kL][kLp]
  long enc_end = o_Aeb + (8L * kL * kLp + 1) / 2;
  long o_ar  = o_Pe;
  long o_mib = o_Peb;
  long o_mr  = o_Ae;
  long o_mi  = o_Ae + LBD;
  long o_mrb = o_Ae + 2 * LBD;

  // decoder overlay
  long p = o_scr;
  auto nxt = [&](long n) { long o = p; p += (n + 255) & ~255L; return o; };
  long o_Sf   = nxt((long)kR * 2 * kL);        // also Ps/As/Pc fp32 staging
  long o_Psb  = nxt(((long)kR * kKD + 1) / 2);
  long o_Pcb  = nxt(((long)kR * kKD + 1) / 2);
  long o_Asb  = nxt(((long)kR * kHWp + 1) / 2);
  long o_Ph   = nxt((2L * kR * kLp + 1) / 2);
  long o_t1r  = nxt(HBD);
  long o_t1rb = nxt((HBD + 1) / 2);
  long o_t1i  = nxt(HBD);
  long o_c3   = nxt(2 * HBD);
  long o_z    = nxt(2 * HBD);
  long o_t2b  = nxt(((long)kR * 1024 + 1) / 2);
  long img_end = p;

  long total = (enc_end > img_end ? enc_end : img_end);
  if ((size_t)total * sizeof(float) > ws_size) return;

  float* seqT = ws + o_seqT;
  float* seqS = ws + o_seqS;
  float* Kr = ws + o_Kr;
  float* Ki = ws + o_Ki;
  u16b* Kcb = (u16b*)(ws + o_Kcb);
  u16b* VrT = (u16b*)(ws + o_VrT);
  u16b* tfb = (u16b*)(ws + o_tfb);
  u16b* sfb = (u16b*)(ws + o_sfb);
  u16b* WkTE = (u16b*)(ws + o_WkTE);
  u16b* WkTS = (u16b*)(ws + o_WkTS);
  u16b* WkTC = (u16b*)(ws + o_WkTC);
  u16b* Wcb = (u16b*)(ws + o_Wcb);
  float* lab = ws + o_lab;
  float* uE = ws + o_uE;
  float* uS = ws + o_uS;
  float* vb = ws + o_vb;
  float* g_ = ws + o_g;
  float* cR = ws + o_cR;
  float* cI = ws + o_cI;
  float* row = ws + o_row;
  float* mkr = ws + o_mkr;
  float* mki = ws + o_mki;
  float* ssp = ws + o_ss;
  float* part = ws + o_part;
  float* Pe = ws + o_Pe;
  u16b* Peb = (u16b*)(ws + o_Peb);
  float* Ae = ws + o_Ae;
  u16b* Aeb = (u16b*)(ws + o_Aeb);
  float* ar = ws + o_ar;
  float* mr = ws + o_mr;
  float* mi = ws + o_mi;
  u16b* mrb = (u16b*)(ws + o_mrb);
  u16b* mib = (u16b*)(ws + o_mib);
  float* Sf = ws + o_Sf;
  float* Ps = ws + o_Sf;
  float* As_ = ws + o_Sf;
  float* Pc = ws + o_Sf;
  u16b* Psb = (u16b*)(ws + o_Psb);
  u16b* Pcb = (u16b*)(ws + o_Pcb);
  u16b* Asb = (u16b*)(ws + o_Asb);
  u16b* Ph = (u16b*)(ws + o_Ph);
  float* t1r = ws + o_t1r;
  u16b* t1rb = (u16b*)(ws + o_t1rb);
  float* t1i = ws + o_t1i;
  float* c3 = ws + o_c3;
  float* z = ws + o_z;
  u16b* t2b = (u16b*)(ws + o_t2b);

  // ---- stage 0 ----
  {
    dim3 grd(CDIV(kHW, 32), CDIV(kD, 32), kNI * kB), blk(32, 8);
    k_toseq<<<grd, blk, 0, stream>>>(tf, seqT);
    k_toseq<<<grd, blk, 0, stream>>>(sf, seqS);
  }
  k_cvt2d<<<kNI * kB * kD, 256, 0, stream>>>(tf, tfb, kHW, kHWp);
  k_cvt2d<<<kNI * kB * kD, 256, 0, stream>>>(sf, sfb, kHW, kHWp);
  k_cvt2d<<<kD, 256, 0, stream>>>(Wc, Wcb, 2 * kD, 2 * kD);
  k_tcvt<<<dim3(kD / 32, kD / 32), dim3(32, 8), 0, stream>>>(WkE, WkTE, kD, kD);
  k_tcvt<<<dim3(kKD / 32, kD / 32), dim3(32, 8), 0, stream>>>(WkS, WkTS, kD, kKD);
  k_tcvt<<<dim3(kKD / 32, kD / 32), dim3(32, 8), 0, stream>>>(WkC, WkTC, kD, kKD);
  k_lab<<<CDIV(kNI * kB * kHW, 256), 256, 0, stream>>>(tl, lab);
  k_l2n_vec<<<1, 128, 0, stream>>>(bkE, uE, kD);
  k_l2n_vec<<<1, 128, 0, stream>>>(bkS, uS, kKD);

  // ---- encoder ----
  gemm<64, 128, true, false>(stream, seqT, WkTE, Pe, kL * kB, kD, kD, kD, kD, kD, 0, 0, 0, 1);
  k_bias_l2n<<<kL * kB, 128, 0, stream>>>(Pe, bkE, kD, Peb);
  k_rowdot<<<kL * kB, 64, 0, stream>>>(Pe, uE, g_, kL, kD);
  k_softmax<<<kB, 256, 0, stream>>>(g_, 1, kL, nullptr, 0);
  gemm<128, 128, false, false>(stream, Peb, Peb, Ae, kL, kL, kD, kB * kD, kB * kD, kL, kD, kD,
                               (long)kL * kL, 8);
  k_softmax<<<kB * kL, 256, 0, stream>>>(Ae, kL, kL, Aeb, kLp);
  gemm<64, 128, false, false>(stream, Aeb, tfb, ar, kL, kD, kHW, kLp, kHWp, kB * kD,
                              (long)kL * kLp, (long)kD * kHWp, kD, 8);
  gemm<64, 128, false, true>(stream, Aeb + kHW, tfb + (long)kB * kD * kHWp, ar, kL, kD, kHW,
                             kLp, kHWp, kB * kD, (long)kL * kLp, (long)kD * kHWp, kD, 8);
  gemm<64, 128, false, true>(stream, Aeb + 2 * kHW, tfb + 2L * kB * kD * kHWp, ar, kL, kD, kHW,
                             kLp, kHWp, kB * kD, (long)kL * kLp, (long)kD * kHWp, kD, 8);
  hipMemsetAsync(row, 0, kB * kD * sizeof(float), stream);
  k_wrowsum<<<dim3(kD / 128, kB, CDIV(kL, 64)), 128, 0, stream>>>(g_, seqT, row, kL, 64);
  k_ss2<0, 1><<<dim3(kL * kB, 2), 256, 0, stream>>>(seqT, ar, row, nullptr, part, kL * kB);
  k_ssred<<<dim3(kNI * kB, 2), 512, 0, stream>>>(part, ssp, kL * kB, kNI * kB);
  k_scale2<0, 1><<<dim3(kL * kB, 2), 256, 0, stream>>>(seqT, ar, mr, row, nullptr, mi, ssp,
                                                       kNI * kB, mrb, mib);
  k_vrt<<<dim3(CDIV(kL, 32), kD / 32, kB), dim3(32, 8), 0, stream>>>(mr, lab, VrT);
  gemm<64, 64, false, false>(stream, mrb, WkTC, Kr, kL * kB, kKD, kD, kD, kD, kKD, 0, 0, 0, 1);
  k_bias_l2n<<<kL * kB, 128, 0, stream>>>(Kr, bkC, kKD, Kcb);
  gemm<64, 64, false, false>(stream, mib, WkTC, Ki, kL * kB, kKD, kD, kD, kD, kKD, 0, 0, 0, 1);
  k_bias_l2n<<<kL * kB, 128, 0, stream>>>(Ki, bkC, kKD, Kcb + LBK);

  // ---- decoder ----
  for (int img = 0; img < 6; ++img) {
    const float* t = (img < 3) ? (seqT + (long)img * HBD) : (seqS + (long)(img - 3) * HBD);
    const u16b* tb = (img < 3) ? (tfb + (long)img * kB * kD * kHWp)
                               : (sfb + (long)(img - 3) * kB * kD * kHWp);
    float* osl = out + (long)img * kB * kD * kHW;

    // self-attention
    gemm<64, 64, true, false>(stream, t, WkTS, Ps, kHW * kB, kKD, kD, kD, kD, kKD, 0, 0, 0, 1);
    k_bias_l2n<<<kHW * kB, 128, 0, stream>>>(Ps, bkS, kKD, Psb);
    k_rowdot<<<kHW * kB, 64, 0, stream>>>(Ps, uS, g_, kHW, kKD);
    k_softmax<<<kB, 256, 0, stream>>>(g_, 1, kHW, nullptr, 0);
    gemm<64, 64, false, false>(stream, Psb, Psb, As_, kHW, kHW, kKD, kB * kKD, kB * kKD, kHW,
                               kKD, kKD, (long)kHW * kHW, 8);
    k_softmax<<<kB * kHW, 256, 0, stream>>>(As_, kHW, kHW, Asb, kHWp);
    gemm<64, 64, false, false>(stream, Asb, tb, c3, kHW, kD, kHW, kHWp, kHWp, kB * kD,
                               (long)kHW * kHWp, (long)kD * kHWp, kD, 8);  // s2r in c3[0:HBD]
    hipMemsetAsync(row, 0, kB * kD * sizeof(float), stream);
    k_wrowsum<<<dim3(kD / 128, kB, CDIV(kHW, 64)), 128, 0, stream>>>(g_, t, row, kHW, 64);
    // t1r = inorm(t + s2r); t1i = inorm(bcast s2i)
    k_ss2<0, 1><<<dim3(kR, 2), 256, 0, stream>>>(t, c3, row, nullptr, part, kR);
    k_ssred<<<dim3(kB, 2), 512, 0, stream>>>(part, ssp, kR, kB);
    k_scale2<0, 1><<<dim3(kR, 2), 256, 0, stream>>>(t, c3, t1r, row, nullptr, t1i, ssp, kB,
                                                    t1rb, nullptr);
    // cross-attention (fused S1/S2 and c3r/c3i)
    k_vb<<<kB, dim3(128, 4), 0, stream>>>(t1i, WkC, bkC, vb);
    gemm<64, 64, false, false>(stream, t1rb, WkTC, Pc, kHW * kB, kKD, kD, kD, kD, kKD, 0, 0, 0,
                               1);
    k_bias_l2n<<<kHW * kB, 128, 0, stream>>>(Pc, bkC, kKD, Pcb);
    k_cRcI<<<CDIV(kL * kB, 4), 256, 0, stream>>>(vb, Kcb, cR, cI);
    gemm<64, 128, false, false>(stream, Pcb, Kcb, Sf, kHW, 2 * kL, kKD, kB * kKD, kB * kKD,
                                2 * kL, kKD, kKD, (long)kHW * 2 * kL, 8);
    k_softmax2<<<dim3(kB * kHW, 2), 256, 0, stream>>>(Sf, cR, cI, lab, Ph, mkr, mki);
    gemm<64, 128, false, false>(stream, Ph, VrT, c3, 2 * kHW, kD, kL, kLp, kLp, kB * kD,
                                2L * kHW * kLp, (long)kD * kLp, kD, 8);
    // fused tail
    k_ss_tail<<<dim3(kR, 4), 256, 0, stream>>>(t1r, t1i, mkr, mki, c3, part);
    k_ssred<<<dim3(kB, 4), 512, 0, stream>>>(part, ssp, kR, kB);
    k_zmk<<<dim3(kR, 2), 256, 0, stream>>>(t1r, t1i, mkr, mki, c3, ssp, z, part);
    k_ssred<<<dim3(kB, 2), 512, 0, stream>>>(part, ssp, kR, kB);
    k_zscale<<<dim3(kR, 2), 256, 0, stream>>>(z, ssp, t2b);
    // 1x1 conv: single GEMM, K = 1024
    gemm<64, 64, false, false>(stream, Wcb, t2b, osl, kD, kHW, 2 * kD, 2 * kD, kB * 2 * kD,
                               kHW, 0, 2 * kD, (long)kD * kHW, 8);
  }
}

// Round 8
// 1720.656 us; speedup vs baseline: 6.7067x; 1.0558x over previous
//
#include <hip/hip_runtime.h>

// ComTransformer on MI355X — round 8:
//  - tail inorm chain via group-sum identity: ss(z)=f2^2 SSa + f4^2 SSb + 2 f2 f4 SSab
//    -> one-pass 6-partial kernel + coef kernel + direct bf16 write (z buffer gone)
//  - k_rowdot fused into k_bias_l2n (dot while row in registers)
//  - bijective XCD swizzle in k_gemm for L2 locality
// Prior structure: pipelined BK=64 bf16 NT GEMM, rank-1 imag branches, shared
// mk/c3 softmax, fused score bias, label-dot mk, operand-sharing fusions.

namespace {

constexpr int kNI = 3;
constexpr int kB  = 8;
constexpr int kD  = 512;
constexpr int kKD = 128;
constexpr int kHW = 484;
constexpr int kL  = kNI * kHW;  // 1452
constexpr int kLp = 1456;
constexpr int kHWp = 488;
constexpr float kTemp = 30.0f;
constexpr float kCnt  = 247808.0f;
constexpr float kScaleN = 0.011048543456039806f;
constexpr long kHBD = (long)kHW * kB * kD;
constexpr int kR = kHW * kB;  // 3872

#define CDIV(a, b) (((a) + (b) - 1) / (b))

typedef float f32x4 __attribute__((ext_vector_type(4)));
typedef unsigned int u32x4 __attribute__((ext_vector_type(4)));
typedef unsigned short u16b;

__device__ __forceinline__ float wsum(float v) {
#pragma unroll
  for (int o = 32; o; o >>= 1) v += __shfl_down(v, o);
  return v;
}
__device__ __forceinline__ float wmax(float v) {
#pragma unroll
  for (int o = 32; o; o >>= 1) v = fmaxf(v, __shfl_down(v, o));
  return v;
}

__device__ __forceinline__ unsigned pk2bf(float lo, float hi) {
  union { float f; unsigned u; } a, b;
  a.f = lo; b.f = hi;
  unsigned ra = (a.u + 0x7FFFu + ((a.u >> 16) & 1u)) >> 16;
  unsigned rb = (b.u + 0x7FFFu + ((b.u >> 16) & 1u)) >> 16;
  return (ra & 0xFFFFu) | (rb << 16);
}
__device__ __forceinline__ u16b f2bf(float x) {
  union { float f; unsigned u; } a;
  a.f = x;
  return (u16b)((a.u + 0x7FFFu + ((a.u >> 16) & 1u)) >> 16);
}
__device__ __forceinline__ float bf2f(u16b x) {
  union { unsigned u; float f; } a;
  a.u = (unsigned)x << 16;
  return a.f;
}

__device__ __forceinline__ void mfma_bf16(f32x4& d, const u32x4& a, const u32x4& b) {
  asm("v_mfma_f32_16x16x32_bf16 %0, %1, %2, %0" : "+v"(d) : "v"(a), "v"(b));
}

// ---------------- layout transform: [n,b,d,hw] -> seq [(n*hw),b,d] fp32 -----------
__global__ void k_toseq(const float* __restrict__ in, float* __restrict__ out) {
  __shared__ float tile[32][33];
  int nb = blockIdx.z;
  int n = nb / kB, b = nb % kB;
  int p0 = blockIdx.x * 32, d0 = blockIdx.y * 32;
  int tx = threadIdx.x, ty = threadIdx.y;
#pragma unroll
  for (int j = 0; j < 4; ++j) {
    int d = d0 + ty + j * 8, p = p0 + tx;
    if (d < kD && p < kHW) tile[ty + j * 8][tx] = in[(long)nb * kD * kHW + (long)d * kHW + p];
  }
  __syncthreads();
#pragma unroll
  for (int j = 0; j < 4; ++j) {
    int p = p0 + ty + j * 8, d = d0 + tx;
    if (p < kHW && d < kD)
      out[((long)(n * kHW + p) * kB + b) * kD + d] = tile[tx][ty + j * 8];
  }
}

__global__ void k_cvt2d(const float* __restrict__ in, u16b* __restrict__ out, int C, int Cp) {
  long r = blockIdx.x;
  for (int c = threadIdx.x; c < C; c += 256)
    out[r * Cp + c] = f2bf(in[r * (long)C + c]);
}

__global__ void k_tcvt(const float* __restrict__ in, u16b* __restrict__ out, int R, int C) {
  __shared__ float tile[32][33];
  int c0 = blockIdx.x * 32, r0 = blockIdx.y * 32;
  int tx = threadIdx.x, ty = threadIdx.y;
#pragma unroll
  for (int j = 0; j < 4; ++j) {
    int r = r0 + ty + j * 8, c = c0 + tx;
    if (r < R && c < C) tile[ty + j * 8][tx] = in[(long)r * C + c];
  }
  __syncthreads();
#pragma unroll
  for (int j = 0; j < 4; ++j) {
    int c = c0 + ty + j * 8, r = r0 + tx;
    if (r < R && c < C) out[(long)c * R + r] = f2bf(tile[tx][ty + j * 8]);
  }
}

// VrT[b][d][l] = bf16( mr[(l,b),d] * lab[l,b] ), stride kLp
__global__ void k_vrt(const float* __restrict__ mr, const float* __restrict__ lab,
                      u16b* __restrict__ vt) {
  __shared__ float tile[32][33];
  int l0 = blockIdx.x * 32, d0 = blockIdx.y * 32, b = blockIdx.z;
  int tx = threadIdx.x, ty = threadIdx.y;
#pragma unroll
  for (int j = 0; j < 4; ++j) {
    int l = l0 + ty + j * 8;
    if (l < kL)
      tile[ty + j * 8][tx] = mr[((long)l * kB + b) * kD + d0 + tx] * lab[(long)l * kB + b];
  }
  __syncthreads();
#pragma unroll
  for (int j = 0; j < 4; ++j) {
    int d = d0 + ty + j * 8, l = l0 + tx;
    if (l < kL) vt[((long)b * kD + d) * kLp + l] = f2bf(tile[tx][ty + j * 8]);
  }
}

__global__ void k_lab(const float* __restrict__ tl, float* __restrict__ lab) {
  long i = (long)blockIdx.x * 256 + threadIdx.x;
  const long tot = (long)kNI * kB * kHW;
  if (i >= tot) return;
  int p = (int)(i % kHW);
  long t = i / kHW;
  int b = (int)(t % kB);
  int n = (int)(t / kB);
  lab[(long)(n * kHW + p) * kB + b] = tl[i];
}

__global__ void k_l2n_vec(const float* __restrict__ src, float* __restrict__ u, int C) {
  __shared__ float red[2];
  int tid = threadIdx.x;  // 128
  float s = 0.f;
  for (int c = tid; c < C; c += 128) { float x = src[c]; s += x * x; }
  s = wsum(s);
  if ((tid & 63) == 0) red[tid >> 6] = s;
  __syncthreads();
  float inv = 1.f / fmaxf(sqrtf(red[0] + red[1]), 1e-12f);
  for (int c = tid; c < C; c += 128) u[c] = src[c] * inv;
}

// ---------------- pipelined NT bf16 MFMA GEMM (XCD-swizzled) ----------------------
template <int BM, int BN, bool AF32, bool ACC>
__global__ __launch_bounds__(256) void k_gemm(const void* Ap, const u16b* __restrict__ B,
                                              float* __restrict__ C, int M, int N, int K,
                                              int lda, int ldb, int ldc, long sAb, long sBb,
                                              long sCb) {
  // bijective XCD swizzle (m204): contiguous tile chunks per XCD for L2 reuse
  const int gx = gridDim.x, gy = gridDim.y;
  const int nwg = gx * gy * gridDim.z;
  const int orig = (blockIdx.z * gy + blockIdx.y) * gx + blockIdx.x;
  const int q = nwg >> 3, rr = nwg & 7, xcd = orig & 7, idx = orig >> 3;
  const int swz = (xcd < rr ? xcd * (q + 1) : rr * (q + 1) + (xcd - rr) * q) + idx;
  const int bx = swz % gx;
  const int tmp = swz / gx;
  const int by = tmp % gy, bz = tmp / gy;

  const char* Ab = (const char*)Ap + (long)bz * sAb * (AF32 ? 4 : 2);
  const u16b* Bb = B + (long)bz * sBb;
  C += (long)bz * sCb;
  constexpr int FM = BM / 32, FN = BN / 32;
  constexpr int NSA = BM * 8 / 256;
  constexpr int NSB = BN * 8 / 256;
  const int m0 = by * BM, n0 = bx * BN;
  const int tid = threadIdx.x;
  const int wid = tid >> 6, lane = tid & 63;
  const int wr = wid >> 1, wc = wid & 1;
  const int fr = lane & 15, fk = lane >> 4;

  __shared__ unsigned AsU[BM * 36];
  __shared__ unsigned BsU[BN * 36];
  f32x4 acc[FM][FN] = {};

  u32x4 pa[NSA];
  float4 paf[AF32 ? 2 * NSA : 1];
  u32x4 pb[NSB];

  auto loadA = [&](int k0) {
#pragma unroll
    for (int i = 0; i < NSA; ++i) {
      int si = tid + i * 256;
      int row = si >> 3, c = si & 7;
      int gr = m0 + row, gk = k0 + c * 8;
      if constexpr (AF32) {
        const float* A = (const float*)Ab;
        if (gr < M && gk + 8 <= K) {
          const float* ap = A + (long)gr * lda + gk;
          paf[2 * i] = *(const float4*)ap;
          paf[2 * i + 1] = *(const float4*)(ap + 4);
        } else {
          float v[8];
#pragma unroll
          for (int j = 0; j < 8; ++j)
            v[j] = (gr < M && gk + j < K) ? A[(long)gr * lda + gk + j] : 0.f;
          paf[2 * i] = make_float4(v[0], v[1], v[2], v[3]);
          paf[2 * i + 1] = make_float4(v[4], v[5], v[6], v[7]);
        }
      } else {
        const u16b* A = (const u16b*)Ab;
        if (gr < M && gk + 8 <= K) {
          pa[i] = *(const u32x4*)(A + (long)gr * lda + gk);
        } else {
          unsigned v[8];
#pragma unroll
          for (int j = 0; j < 8; ++j)
            v[j] = (gr < M && gk + j < K) ? A[(long)gr * lda + gk + j] : 0u;
          pa[i].x = v[0] | (v[1] << 16); pa[i].y = v[2] | (v[3] << 16);
          pa[i].z = v[4] | (v[5] << 16); pa[i].w = v[6] | (v[7] << 16);
        }
      }
    }
  };
  auto loadB = [&](int k0) {
#pragma unroll
    for (int i = 0; i < NSB; ++i) {
      int si = tid + i * 256;
      int row = si >> 3, c = si & 7;
      int gr = n0 + row, gk = k0 + c * 8;
      if (gr < N && gk + 8 <= K) {
        pb[i] = *(const u32x4*)(Bb + (long)gr * ldb + gk);
      } else {
        unsigned v[8];
#pragma unroll
        for (int j = 0; j < 8; ++j)
          v[j] = (gr < N && gk + j < K) ? Bb[(long)gr * ldb + gk + j] : 0u;
        pb[i].x = v[0] | (v[1] << 16); pb[i].y = v[2] | (v[3] << 16);
        pb[i].z = v[4] | (v[5] << 16); pb[i].w = v[6] | (v[7] << 16);
      }
    }
  };
  auto storeAB = [&]() {
#pragma unroll
    for (int i = 0; i < NSA; ++i) {
      int si = tid + i * 256;
      int row = si >> 3, c = si & 7;
      u32x4 w;
      if constexpr (AF32) {
        float4 u0 = paf[2 * i], u1 = paf[2 * i + 1];
        w.x = pk2bf(u0.x, u0.y); w.y = pk2bf(u0.z, u0.w);
        w.z = pk2bf(u1.x, u1.y); w.w = pk2bf(u1.z, u1.w);
      } else {
        w = pa[i];
      }
      *(u32x4*)&AsU[row * 36 + c * 4] = w;
    }
#pragma unroll
    for (int i = 0; i < NSB; ++i) {
      int si = tid + i * 256;
      int row = si >> 3, c = si & 7;
      *(u32x4*)&BsU[row * 36 + c * 4] = pb[i];
    }
  };

  loadA(0);
  loadB(0);
  storeAB();
  __syncthreads();
  const int nk = CDIV(K, 64);
  for (int t = 0; t < nk; ++t) {
    const bool more = (t + 1 < nk);
    if (more) { loadA((t + 1) * 64); loadB((t + 1) * 64); }
#pragma unroll
    for (int kk = 0; kk < 2; ++kk) {
      u32x4 af[FM], bf[FN];
#pragma unroll
      for (int mi = 0; mi < FM; ++mi)
        af[mi] = *(const u32x4*)&AsU[(wr * (BM / 2) + mi * 16 + fr) * 36 + kk * 16 + fk * 4];
#pragma unroll
      for (int ni = 0; ni < FN; ++ni)
        bf[ni] = *(const u32x4*)&BsU[(wc * (BN / 2) + ni * 16 + fr) * 36 + kk * 16 + fk * 4];
#pragma unroll
      for (int mi = 0; mi < FM; ++mi)
#pragma unroll
        for (int ni = 0; ni < FN; ++ni) mfma_bf16(acc[mi][ni], af[mi], bf[ni]);
    }
    if (more) {
      __syncthreads();
      storeAB();
      __syncthreads();
    }
  }
  asm volatile("s_nop 7\n\ts_nop 7" ::: );
#pragma unroll
  for (int mi = 0; mi < FM; ++mi) {
#pragma unroll
    for (int r = 0; r < 4; ++r) {
      int gm = m0 + wr * (BM / 2) + mi * 16 + fk * 4 + r;
      if (gm >= M) continue;
#pragma unroll
      for (int ni = 0; ni < FN; ++ni) {
        int gn = n0 + wc * (BN / 2) + ni * 16 + fr;
        if (gn >= N) continue;
        long idx2 = (long)gm * ldc + gn;
        float v = acc[mi][ni][r];
        C[idx2] = ACC ? (C[idx2] + v) : v;
      }
    }
  }
}

// row += bias; l2-normalize; fp32 in place + bf16 mirror; optional g[b*L+k] = u.row
__global__ void k_bias_l2n(float* __restrict__ P, const float* __restrict__ bias, int C,
                           u16b* __restrict__ outb, const float* __restrict__ u,
                           float* __restrict__ g, int L) {
  __shared__ float red[2];
  long row = blockIdx.x;
  float* p = P + row * C;
  int tid = threadIdx.x;  // 128
  int nv = C >> 7;
  float v[4];
  float s = 0.f;
#pragma unroll
  for (int i = 0; i < 4; ++i)
    if (i < nv) {
      float x = p[tid + (i << 7)] + bias[tid + (i << 7)];
      v[i] = x;
      s += x * x;
    }
  s = wsum(s);
  if ((tid & 63) == 0) red[tid >> 6] = s;
  __syncthreads();
  float inv = 1.f / fmaxf(sqrtf(red[0] + red[1]), 1e-12f);
  float dot = 0.f;
#pragma unroll
  for (int i = 0; i < 4; ++i)
    if (i < nv) {
      float x = v[i] * inv;
      p[tid + (i << 7)] = x;
      outb[row * C + tid + (i << 7)] = f2bf(x);
      if (u) dot += x * u[tid + (i << 7)];
    }
  if (u) {
    __syncthreads();
    dot = wsum(dot);
    if ((tid & 63) == 0) red[tid >> 6] = dot;
    __syncthreads();
    if (tid == 0) {
      int k = (int)(row / kB), b = (int)(row % kB);
      g[(long)b * L + k] = red[0] + red[1];
    }
  }
}

// generic softmax; optional bf16 out at row*ldo
__global__ __launch_bounds__(256) void k_softmax(float* __restrict__ S, int Lq, int Lk,
                                                 u16b* __restrict__ outb, int ldo) {
  __shared__ float sm[1456];
  __shared__ float red[4];
  int row = blockIdx.x;
  float* Sr = S + (long)row * Lk;
  int tid = threadIdx.x;
  float mx = -3.0e38f;
  for (int k = tid; k < Lk; k += 256) {
    float v = Sr[k] * kTemp;
    sm[k] = v;
    mx = fmaxf(mx, v);
  }
  mx = wmax(mx);
  if ((tid & 63) == 0) red[tid >> 6] = mx;
  __syncthreads();
  mx = fmaxf(fmaxf(red[0], red[1]), fmaxf(red[2], red[3]));
  __syncthreads();
  float s = 0.f;
  for (int k = tid; k < Lk; k += 256) {
    float e = expf(sm[k] - mx);
    sm[k] = e;
    s += e;
  }
  s = wsum(s);
  if ((tid & 63) == 0) red[tid >> 6] = s;
  __syncthreads();
  float inv = 1.0f / (red[0] + red[1] + red[2] + red[3]);
  for (int k = tid; k < Lk; k += 256) {
    float p = sm[k] * inv;
    if (outb) outb[(long)row * ldo + k] = f2bf(p); else Sr[k] = p;
  }
}

// fused S1/S2 softmax -> P-hat bf16 + mkr/mki
__global__ __launch_bounds__(256) void k_softmax2(const float* __restrict__ Sf,
                                                  const float* __restrict__ cR,
                                                  const float* __restrict__ cI,
                                                  const float* __restrict__ lab,
                                                  u16b* __restrict__ Ph,
                                                  float* __restrict__ mkr,
                                                  float* __restrict__ mki) {
  __shared__ float sm[1456];
  __shared__ float red[4];
  int row = blockIdx.x;  // b*kHW + q
  int y = blockIdx.y;
  int b = row / kHW, q = row - b * kHW;
  const float* Sr = Sf + (long)row * (2 * kL) + y * kL;
  const float* bias = (y ? cR : cI) + (long)b * kL;
  float sign = y ? 1.f : -1.f;
  int tid = threadIdx.x;
  float mx = -3.0e38f;
  for (int k = tid; k < kL; k += 256) {
    float v = (Sr[k] + sign * bias[k]) * kTemp;
    sm[k] = v;
    mx = fmaxf(mx, v);
  }
  mx = wmax(mx);
  if ((tid & 63) == 0) red[tid >> 6] = mx;
  __syncthreads();
  mx = fmaxf(fmaxf(red[0], red[1]), fmaxf(red[2], red[3]));
  __syncthreads();
  float s = 0.f;
  for (int k = tid; k < kL; k += 256) {
    float e = expf(sm[k] - mx);
    sm[k] = e;
    s += e;
  }
  s = wsum(s);
  if ((tid & 63) == 0) red[tid >> 6] = s;
  __syncthreads();
  float inv = 1.0f / (red[0] + red[1] + red[2] + red[3]);
  __syncthreads();
  u16b* outp = Ph + ((long)(b * 2 + y) * kHW + q) * kLp;
  float dot = 0.f;
  for (int k = tid; k < kL; k += 256) {
    float p = sm[k] * inv;
    outp[k] = f2bf(p);
    dot += p * lab[(long)k * kB + b];
  }
  for (int k = kL + tid; k < kLp; k += 256) outp[k] = 0;
  dot = wsum(dot);
  if ((tid & 63) == 0) red[tid >> 6] = dot;
  __syncthreads();
  if (tid == 0) (y ? mki : mkr)[(long)q * kB + b] = red[0] + red[1] + red[2] + red[3];
}

__global__ void k_wrowsum(const float* __restrict__ w, const float* __restrict__ S,
                          float* __restrict__ rowout, int L, int kchunk) {
  int b = blockIdx.y;
  int d = blockIdx.x * 128 + threadIdx.x;
  int k0 = blockIdx.z * kchunk;
  int k1 = min(L, k0 + kchunk);
  float s = 0.f;
  for (int k = k0; k < k1; ++k) s += w[(long)b * L + k] * S[((long)k * kB + b) * kD + d];
  atomicAdd(&rowout[(long)b * kD + d], s);
}

// OP 0: A[r,d]+B2[r,d]   OP 1: A[b,d] (broadcast)   OP 2: A[r,d]*B2[r]
template <int OP>
__device__ __forceinline__ float opval(const float* __restrict__ A,
                                       const float* __restrict__ B2, long r, int b, int d) {
  if (OP == 0) return A[r * kD + d] + B2[r * kD + d];
  if (OP == 1) return A[(long)b * kD + d];
  return A[r * kD + d] * B2[r];
}

template <int OPA, int OPB>
__global__ __launch_bounds__(256) void k_ss2(const float* __restrict__ Aa,
                                             const float* __restrict__ Ba,
                                             const float* __restrict__ Ab,
                                             const float* __restrict__ Bb,
                                             float* __restrict__ part, int R) {
  __shared__ float red[4];
  int r = blockIdx.x, v = blockIdx.y;
  int b = r % kB;
  int tid = threadIdx.x;
  float z0, z1;
  if (v == 0) {
    z0 = opval<OPA>(Aa, Ba, r, b, tid);
    z1 = opval<OPA>(Aa, Ba, r, b, tid + 256);
  } else {
    z0 = opval<OPB>(Ab, Bb, r, b, tid);
    z1 = opval<OPB>(Ab, Bb, r, b, tid + 256);
  }
  float s = z0 * z0 + z1 * z1;
  s = wsum(s);
  if ((tid & 63) == 0) red[tid >> 6] = s;
  __syncthreads();
  if (tid == 0) part[(long)v * R + r] = red[0] + red[1] + red[2] + red[3];
}

__global__ void k_ssred(const float* __restrict__ part, float* __restrict__ ss, int R, int NG) {
  __shared__ float red[8];
  int g = blockIdx.x, v = blockIdx.y;
  int n = g / kB, b = g % kB;
  int tid = threadIdx.x;  // 512
  float s = 0.f;
  for (int p = tid; p < kHW; p += 512) s += part[(long)v * R + ((long)(n * kHW + p) * kB + b)];
  s = wsum(s);
  if ((tid & 63) == 0) red[tid >> 6] = s;
  __syncthreads();
  if (tid == 0) {
    float t = 0.f;
#pragma unroll
    for (int i = 0; i < 8; ++i) t += red[i];
    ss[(long)v * NG + g] = t;
  }
}

template <int OPA, int OPB>
__global__ __launch_bounds__(256) void k_scale2(const float* __restrict__ Aa,
                                                const float* __restrict__ Ba,
                                                float* __restrict__ outA,
                                                const float* __restrict__ Ab,
                                                const float* __restrict__ Bb,
                                                float* __restrict__ outB,
                                                const float* __restrict__ ss, int NG,
                                                u16b* __restrict__ oAb,
                                                u16b* __restrict__ oBb) {
  int r = blockIdx.x, v = blockIdx.y;
  int l = r / kB, b = r % kB;
  int g = (l / kHW) * kB + b;
  int tid = threadIdx.x;
  float fac = kScaleN * sqrtf(kCnt / (ss[(long)v * NG + g] + 1e-5f));
  if (v == 0) {
    float x0 = opval<OPA>(Aa, Ba, r, b, tid) * fac;
    float x1 = opval<OPA>(Aa, Ba, r, b, tid + 256) * fac;
    outA[(long)r * kD + tid] = x0;
    outA[(long)r * kD + tid + 256] = x1;
    if (oAb) { oAb[(long)r * kD + tid] = f2bf(x0); oAb[(long)r * kD + tid + 256] = f2bf(x1); }
  } else {
    float x0 = opval<OPB>(Ab, Bb, r, b, tid) * fac;
    float x1 = opval<OPB>(Ab, Bb, r, b, tid + 256) * fac;
    outB[(long)r * kD + tid] = x0;
    outB[(long)r * kD + tid + 256] = x1;
    if (oBb) { oBb[(long)r * kD + tid] = f2bf(x0); oBb[(long)r * kD + tid + 256] = f2bf(x1); }
  }
}

// tail phase 1 (one pass): part[v*kR+r] for v in {a_r^2, a_i^2, b_r^2, b_i^2, a_r b_r, a_i b_i}
// where a = t1*mk, b = t1 + c3.
__global__ __launch_bounds__(256) void k_ss6(const float* __restrict__ t1r,
                                             const float* __restrict__ t1i,
                                             const float* __restrict__ mkr,
                                             const float* __restrict__ mki,
                                             const float* __restrict__ c3,
                                             float* __restrict__ part) {
  __shared__ float red[4][6];
  int r = blockIdx.x;
  int tid = threadIdx.x;
  long base = (long)r * kD;
  float mr_ = mkr[r], mi_ = mki[r];
  float s[6] = {0.f, 0.f, 0.f, 0.f, 0.f, 0.f};
#pragma unroll
  for (int j = 0; j < 2; ++j) {
    int d = tid + j * 256;
    float tr = t1r[base + d], ti = t1i[base + d];
    float cr = c3[base + d], ci = c3[kHBD + base + d];
    float ar = tr * mr_, ai = ti * mi_;
    float br = tr + cr, bi = ti + ci;
    s[0] += ar * ar; s[1] += ai * ai;
    s[2] += br * br; s[3] += bi * bi;
    s[4] += ar * br; s[5] += ai * bi;
  }
  int w = tid >> 6, lane = tid & 63;
#pragma unroll
  for (int v = 0; v < 6; ++v) {
    float t = wsum(s[v]);
    if (lane == 0) red[w][v] = t;
  }
  __syncthreads();
  if (tid < 6) part[(long)tid * kR + r] = red[0][tid] + red[1][tid] + red[2][tid] + red[3][tid];
}

// tail phase 3: coefficients ca = f2*fac, cb = f4*fac  (coef[0:16]=ca, coef[16:32]=cb)
__global__ void k_ssfin(const float* __restrict__ ss, float* __restrict__ coef) {
  int i = threadIdx.x;
  if (i >= 16) return;
  int v = i >> 3, b = i & 7;
  float SSa = ss[v * kB + b], SSb = ss[(2 + v) * kB + b], SSab = ss[(4 + v) * kB + b];
  float f2 = kScaleN * sqrtf(kCnt / (SSa + 1e-5f));
  float f4 = kScaleN * sqrtf(kCnt / (SSb + 1e-5f));
  float ssz = f2 * f2 * SSa + f4 * f4 * SSb + 2.f * f2 * f4 * SSab;
  float fac = kScaleN * sqrtf(kCnt / (ssz + 1e-5f));
  coef[v * kB + b] = f2 * fac;
  coef[16 + v * kB + b] = f4 * fac;
}

// tail phase 4: t2b[r][v*512+d] = bf16( a*ca + b*cb )
__global__ __launch_bounds__(256) void k_zfin(const float* __restrict__ t1r,
                                              const float* __restrict__ t1i,
                                              const float* __restrict__ mkr,
                                              const float* __restrict__ mki,
                                              const float* __restrict__ c3,
                                              const float* __restrict__ coef,
                                              u16b* __restrict__ t2b) {
  int r = blockIdx.x, v = blockIdx.y;
  int b = r % kB;
  int tid = threadIdx.x;
  const float* t1 = v ? t1i : t1r;
  float mk = (v ? mki : mkr)[r];
  const float* c = c3 + (long)v * kHBD;
  float ca = coef[v * kB + b], cb = coef[16 + v * kB + b];
  long base = (long)r * kD;
#pragma unroll
  for (int j = 0; j < 2; ++j) {
    int d = tid + j * 256;
    float t = t1[base + d];
    float ov = t * mk * ca + (t + c[base + d]) * cb;
    t2b[(long)r * 1024 + v * 512 + d] = f2bf(ov);
  }
}

__global__ void k_vb(const float* __restrict__ t1i, const float* __restrict__ Wk,
                     const float* __restrict__ bk, float* __restrict__ vb) {
  __shared__ float part[4][128];
  __shared__ float red[2];
  int b = blockIdx.x;
  int j = threadIdx.x;
  int dz = threadIdx.y;
  const float* row = t1i + (long)b * kD;
  float acc = 0.f;
  int d0 = dz * 128;
  for (int d = d0; d < d0 + 128; ++d) acc += row[d] * Wk[(long)d * kKD + j];
  part[dz][j] = acc;
  __syncthreads();
  if (dz == 0) {
    float a = part[0][j] + part[1][j] + part[2][j] + part[3][j] + bk[j];
    float s = a * a;
    s = wsum(s);
    if ((j & 63) == 0) red[j >> 6] = s;
    part[0][j] = a;
  }
  __syncthreads();
  if (dz == 0) {
    float inv = 1.f / fmaxf(sqrtf(red[0] + red[1]), 1e-12f);
    vb[(long)b * kKD + j] = part[0][j] * inv;
  }
}

__global__ void k_cRcI(const float* __restrict__ vb, const u16b* __restrict__ Kc,
                       float* __restrict__ cR, float* __restrict__ cI) {
  int idx = blockIdx.x * 4 + (threadIdx.x >> 6);
  if (idx >= kL * kB) return;
  int k = idx / kB, b = idx % kB;
  int lane = threadIdx.x & 63;
  const float* v = vb + (long)b * kKD;
  const u16b* pr = Kc + ((long)k * kB + b) * kKD;
  const u16b* pi = pr + (long)kL * kB * kKD;
  float sR = 0.f, sI = 0.f;
  for (int c = lane; c < kKD; c += 64) {
    sR += v[c] * bf2f(pr[c]);
    sI += v[c] * bf2f(pi[c]);
  }
  sR = wsum(sR);
  sI = wsum(sI);
  if (lane == 0) {
    cR[(long)b * kL + k] = sR;
    cI[(long)b * kL + k] = sI;
  }
}

template <int BM, int BN, bool AF32, bool ACC>
void gemm(hipStream_t s, const void* A, const u16b* B, float* C, int M, int N, int K, int lda,
          int ldb, int ldc, long sAb, long sBb, long sCb, int batch) {
  dim3 grd(CDIV(N, BN), CDIV(M, BM), batch), blk(256);
  k_gemm<BM, BN, AF32, ACC><<<grd, blk, 0, s>>>(A, B, C, M, N, K, lda, ldb, ldc, sAb, sBb, sCb);
}

}  // namespace

extern "C" void kernel_launch(void* const* d_in, const int* in_sizes, int n_in, void* d_out,
                              int out_size, void* d_ws, size_t ws_size, hipStream_t stream) {
  (void)in_sizes; (void)n_in; (void)out_size;
  const float* tf  = (const float*)d_in[0];
  const float* sf  = (const float*)d_in[1];
  const float* tl  = (const float*)d_in[2];
  const float* WkE = (const float*)d_in[3];
  const float* bkE = (const float*)d_in[4];
  const float* WkS = (const float*)d_in[5];
  const float* bkS = (const float*)d_in[6];
  const float* WkC = (const float*)d_in[7];
  const float* bkC = (const float*)d_in[8];
  const float* Wc  = (const float*)d_in[9];
  float* out = (float*)d_out;
  float* ws = (float*)d_ws;

  const long LBD = (long)kL * kB * kD;
  const long LBK = (long)kL * kB * kKD;
  const long HBD = kHBD;

  long off = 0;
  auto alloc = [&](long n) { long o = off; off += (n + 255) & ~255L; return o; };
  auto allocU = [&](long nu) { return alloc((nu + 1) / 2); };

  long o_seqT = alloc(LBD);
  long o_seqS = alloc(LBD);
  long o_Kr   = alloc(LBK);
  long o_Ki   = alloc(LBK);
  long o_Kcb  = allocU(2 * LBK);
  long o_VrT  = allocU((long)kB * kD * kLp);
  long o_tfb  = allocU((long)kNI * kB * kD * kHWp);
  long o_sfb  = allocU((long)kNI * kB * kD * kHWp);
  long o_WkTE = allocU((long)kD * kD);
  long o_WkTS = allocU((long)kKD * kD);
  long o_WkTC = allocU((long)kKD * kD);
  long o_Wcb  = allocU((long)kD * 2 * kD);
  long o_lab = alloc((long)kL * kB);
  long o_uE = alloc(kD);
  long o_uS = alloc(kKD);
  long o_vb = alloc((long)kB * kKD);
  long o_g = alloc((long)kB * kL);
  long o_cR = alloc((long)kB * kL);
  long o_cI = alloc((long)kB * kL);
  long o_row = alloc((long)kB * kD);
  long o_mkr = alloc((long)kHW * kB);
  long o_mki = alloc((long)kHW * kB);
  long o_ss = alloc(128);
  long o_part = alloc(4L * kL * kB);
  long o_scr = off;

  // encoder overlay
  long o_Pe  = o_scr;
  long o_Peb = o_Pe + LBD;
  long o_Ae  = o_Peb + LBD / 2;
  long o_Aeb = o_Ae + (long)kB * kL * kL;
  long enc_end = o_Aeb + (8L * kL * kLp + 1) / 2;
  long o_ar  = o_Pe;
  long o_mib = o_Peb;
  long o_mr  = o_Ae;
  long o_mi  = o_Ae + LBD;
  long o_mrb = o_Ae + 2 * LBD;

  // decoder overlay
  long p = o_scr;
  auto nxt = [&](long n) { long o = p; p += (n + 255) & ~255L; return o; };
  long o_Sf   = nxt((long)kR * 2 * kL);
  long o_Psb  = nxt(((long)kR * kKD + 1) / 2);
  long o_Pcb  = nxt(((long)kR * kKD + 1) / 2);
  long o_Asb  = nxt(((long)kR * kHWp + 1) / 2);
  long o_Ph   = nxt((2L * kR * kLp + 1) / 2);
  long o_t1r  = nxt(HBD);
  long o_t1rb = nxt((HBD + 1) / 2);
  long o_t1i  = nxt(HBD);
  long o_c3   = nxt(2 * HBD);
  long o_t2b  = nxt(((long)kR * 1024 + 1) / 2);
  long img_end = p;

  long total = (enc_end > img_end ? enc_end : img_end);
  if ((size_t)total * sizeof(float) > ws_size) return;

  float* seqT = ws + o_seqT;
  float* seqS = ws + o_seqS;
  float* Kr = ws + o_Kr;
  float* Ki = ws + o_Ki;
  u16b* Kcb = (u16b*)(ws + o_Kcb);
  u16b* VrT = (u16b*)(ws + o_VrT);
  u16b* tfb = (u16b*)(ws + o_tfb);
  u16b* sfb = (u16b*)(ws + o_sfb);
  u16b* WkTE = (u16b*)(ws + o_WkTE);
  u16b* WkTS = (u16b*)(ws + o_WkTS);
  u16b* WkTC = (u16b*)(ws + o_WkTC);
  u16b* Wcb = (u16b*)(ws + o_Wcb);
  float* lab = ws + o_lab;
  float* uE = ws + o_uE;
  float* uS = ws + o_uS;
  float* vb = ws + o_vb;
  float* g_ = ws + o_g;
  float* cR = ws + o_cR;
  float* cI = ws + o_cI;
  float* row = ws + o_row;
  float* mkr = ws + o_mkr;
  float* mki = ws + o_mki;
  float* ssp = ws + o_ss;
  float* coef = ssp + 64;
  float* part = ws + o_part;
  float* Pe = ws + o_Pe;
  u16b* Peb = (u16b*)(ws + o_Peb);
  float* Ae = ws + o_Ae;
  u16b* Aeb = (u16b*)(ws + o_Aeb);
  float* ar = ws + o_ar;
  float* mr = ws + o_mr;
  float* mi = ws + o_mi;
  u16b* mrb = (u16b*)(ws + o_mrb);
  u16b* mib = (u16b*)(ws + o_mib);
  float* Sf = ws + o_Sf;
  float* Ps = ws + o_Sf;
  float* As_ = ws + o_Sf;
  float* Pc = ws + o_Sf;
  u16b* Psb = (u16b*)(ws + o_Psb);
  u16b* Pcb = (u16b*)(ws + o_Pcb);
  u16b* Asb = (u16b*)(ws + o_Asb);
  u16b* Ph = (u16b*)(ws + o_Ph);
  float* t1r = ws + o_t1r;
  u16b* t1rb = (u16b*)(ws + o_t1rb);
  float* t1i = ws + o_t1i;
  float* c3 = ws + o_c3;
  u16b* t2b = (u16b*)(ws + o_t2b);

  // ---- stage 0 ----
  {
    dim3 grd(CDIV(kHW, 32), CDIV(kD, 32), kNI * kB), blk(32, 8);
    k_toseq<<<grd, blk, 0, stream>>>(tf, seqT);
    k_toseq<<<grd, blk, 0, stream>>>(sf, seqS);
  }
  k_cvt2d<<<kNI * kB * kD, 256, 0, stream>>>(tf, tfb, kHW, kHWp);
  k_cvt2d<<<kNI * kB * kD, 256, 0, stream>>>(sf, sfb, kHW, kHWp);
  k_cvt2d<<<kD, 256, 0, stream>>>(Wc, Wcb, 2 * kD, 2 * kD);
  k_tcvt<<<dim3(kD / 32, kD / 32), dim3(32, 8), 0, stream>>>(WkE, WkTE, kD, kD);
  k_tcvt<<<dim3(kKD / 32, kD / 32), dim3(32, 8), 0, stream>>>(WkS, WkTS, kD, kKD);
  k_tcvt<<<dim3(kKD / 32, kD / 32), dim3(32, 8), 0, stream>>>(WkC, WkTC, kD, kKD);
  k_lab<<<CDIV(kNI * kB * kHW, 256), 256, 0, stream>>>(tl, lab);
  k_l2n_vec<<<1, 128, 0, stream>>>(bkE, uE, kD);
  k_l2n_vec<<<1, 128, 0, stream>>>(bkS, uS, kKD);

  // ---- encoder ----
  gemm<64, 128, true, false>(stream, seqT, WkTE, Pe, kL * kB, kD, kD, kD, kD, kD, 0, 0, 0, 1);
  k_bias_l2n<<<kL * kB, 128, 0, stream>>>(Pe, bkE, kD, Peb, uE, g_, kL);
  k_softmax<<<kB, 256, 0, stream>>>(g_, 1, kL, nullptr, 0);
  gemm<128, 128, false, false>(stream, Peb, Peb, Ae, kL, kL, kD, kB * kD, kB * kD, kL, kD, kD,
                               (long)kL * kL, 8);
  k_softmax<<<kB * kL, 256, 0, stream>>>(Ae, kL, kL, Aeb, kLp);
  gemm<64, 128, false, false>(stream, Aeb, tfb, ar, kL, kD, kHW, kLp, kHWp, kB * kD,
                              (long)kL * kLp, (long)kD * kHWp, kD, 8);
  gemm<64, 128, false, true>(stream, Aeb + kHW, tfb + (long)kB * kD * kHWp, ar, kL, kD, kHW,
                             kLp, kHWp, kB * kD, (long)kL * kLp, (long)kD * kHWp, kD, 8);
  gemm<64, 128, false, true>(stream, Aeb + 2 * kHW, tfb + 2L * kB * kD * kHWp, ar, kL, kD, kHW,
                             kLp, kHWp, kB * kD, (long)kL * kLp, (long)kD * kHWp, kD, 8);
  hipMemsetAsync(row, 0, kB * kD * sizeof(float), stream);
  k_wrowsum<<<dim3(kD / 128, kB, CDIV(kL, 64)), 128, 0, stream>>>(g_, seqT, row, kL, 64);
  k_ss2<0, 1><<<dim3(kL * kB, 2), 256, 0, stream>>>(seqT, ar, row, nullptr, part, kL * kB);
  k_ssred<<<dim3(kNI * kB, 2), 512, 0, stream>>>(part, ssp, kL * kB, kNI * kB);
  k_scale2<0, 1><<<dim3(kL * kB, 2), 256, 0, stream>>>(seqT, ar, mr, row, nullptr, mi, ssp,
                                                       kNI * kB, mrb, mib);
  k_vrt<<<dim3(CDIV(kL, 32), kD / 32, kB), dim3(32, 8), 0, stream>>>(mr, lab, VrT);
  gemm<64, 64, false, false>(stream, mrb, WkTC, Kr, kL * kB, kKD, kD, kD, kD, kKD, 0, 0, 0, 1);
  k_bias_l2n<<<kL * kB, 128, 0, stream>>>(Kr, bkC, kKD, Kcb, nullptr, nullptr, 0);
  gemm<64, 64, false, false>(stream, mib, WkTC, Ki, kL * kB, kKD, kD, kD, kD, kKD, 0, 0, 0, 1);
  k_bias_l2n<<<kL * kB, 128, 0, stream>>>(Ki, bkC, kKD, Kcb + LBK, nullptr, nullptr, 0);

  // ---- decoder ----
  for (int img = 0; img < 6; ++img) {
    const float* t = (img < 3) ? (seqT + (long)img * HBD) : (seqS + (long)(img - 3) * HBD);
    const u16b* tb = (img < 3) ? (tfb + (long)img * kB * kD * kHWp)
                               : (sfb + (long)(img - 3) * kB * kD * kHWp);
    float* osl = out + (long)img * kB * kD * kHW;

    // self-attention
    gemm<64, 64, true, false>(stream, t, WkTS, Ps, kHW * kB, kKD, kD, kD, kD, kKD, 0, 0, 0, 1);
    k_bias_l2n<<<kHW * kB, 128, 0, stream>>>(Ps, bkS, kKD, Psb, uS, g_, kHW);
    k_softmax<<<kB, 256, 0, stream>>>(g_, 1, kHW, nullptr, 0);
    gemm<64, 64, false, false>(stream, Psb, Psb, As_, kHW, kHW, kKD, kB * kKD, kB * kKD, kHW,
                               kKD, kKD, (long)kHW * kHW, 8);
    k_softmax<<<kB * kHW, 256, 0, stream>>>(As_, kHW, kHW, Asb, kHWp);
    gemm<64, 64, false, false>(stream, Asb, tb, c3, kHW, kD, kHW, kHWp, kHWp, kB * kD,
                               (long)kHW * kHWp, (long)kD * kHWp, kD, 8);  // s2r in c3[0:HBD]
    hipMemsetAsync(row, 0, kB * kD * sizeof(float), stream);
    k_wrowsum<<<dim3(kD / 128, kB, CDIV(kHW, 64)), 128, 0, stream>>>(g_, t, row, kHW, 64);
    // t1r = inorm(t + s2r); t1i = inorm(bcast s2i)
    k_ss2<0, 1><<<dim3(kR, 2), 256, 0, stream>>>(t, c3, row, nullptr, part, kR);
    k_ssred<<<dim3(kB, 2), 512, 0, stream>>>(part, ssp, kR, kB);
    k_scale2<0, 1><<<dim3(kR, 2), 256, 0, stream>>>(t, c3, t1r, row, nullptr, t1i, ssp, kB,
                                                    t1rb, nullptr);
    // cross-attention (fused S1/S2 and c3r/c3i)
    k_vb<<<kB, dim3(128, 4), 0, stream>>>(t1i, WkC, bkC, vb);
    gemm<64, 64, false, false>(stream, t1rb, WkTC, Pc, kHW * kB, kKD, kD, kD, kD, kKD, 0, 0, 0,
                               1);
    k_bias_l2n<<<kHW * kB, 128, 0, stream>>>(Pc, bkC, kKD, Pcb, nullptr, nullptr, 0);
    k_cRcI<<<CDIV(kL * kB, 4), 256, 0, stream>>>(vb, Kcb, cR, cI);
    gemm<64, 128, false, false>(stream, Pcb, Kcb, Sf, kHW, 2 * kL, kKD, kB * kKD, kB * kKD,
                                2 * kL, kKD, kKD, (long)kHW * 2 * kL, 8);
    k_softmax2<<<dim3(kB * kHW, 2), 256, 0, stream>>>(Sf, cR, cI, lab, Ph, mkr, mki);
    gemm<64, 128, false, false>(stream, Ph, VrT, c3, 2 * kHW, kD, kL, kLp, kLp, kB * kD,
                                2L * kHW * kLp, (long)kD * kLp, kD, 8);
    // fused tail: one-pass partials -> group reduce -> coefficients -> direct bf16 write
    k_ss6<<<kR, 256, 0, stream>>>(t1r, t1i, mkr, mki, c3, part);
    k_ssred<<<dim3(kB, 6), 512, 0, stream>>>(part, ssp, kR, kB);
    k_ssfin<<<1, 64, 0, stream>>>(ssp, coef);
    k_zfin<<<dim3(kR, 2), 256, 0, stream>>>(t1r, t1i, mkr, mki, c3, coef, t2b);
    // 1x1 conv: single GEMM, K = 1024
    gemm<64, 64, false, false>(stream, Wcb, t2b, osl, kD, kHW, 2 * kD, 2 * kD, kB * 2 * kD,
                               kHW, 0, 2 * kD, (long)kD * kHW, 8);
  }
}

// Round 9
// 1607.120 us; speedup vs baseline: 7.1805x; 1.0706x over previous
//
#include <hip/hip_runtime.h>

// ComTransformer on MI355X — round 9: rank-1 imaginary-branch collapse.
// New algebra: mem_i rank-1 => Ki const over k => S1 bias cancels; S2's Pc.Ki^T
// const over k => Ai = softmax(30 cR) q-INDEPENDENT => mki 8 scalars, c3i rank-1,
// outi rank-1 => Wc conv imag half is a rank-1 epilogue add. Encoder imag branch dead.
// Kept: pipelined BK=64 bf16 NT GEMM + XCD swizzle, fused score bias (gone now),
// label-dot mk, atomic-free 3-phase inorm, group-sum tail identity.

namespace {

constexpr int kNI = 3;
constexpr int kB  = 8;
constexpr int kD  = 512;
constexpr int kKD = 128;
constexpr int kHW = 484;
constexpr int kL  = kNI * kHW;  // 1452
constexpr int kLp = 1456;
constexpr int kHWp = 488;
constexpr float kTemp = 30.0f;
constexpr float kCnt  = 247808.0f;
constexpr float kScaleN = 0.011048543456039806f;
constexpr long kHBD = (long)kHW * kB * kD;
constexpr int kR = kHW * kB;  // 3872

#define CDIV(a, b) (((a) + (b) - 1) / (b))

typedef float f32x4 __attribute__((ext_vector_type(4)));
typedef unsigned int u32x4 __attribute__((ext_vector_type(4)));
typedef unsigned short u16b;

__device__ __forceinline__ float wsum(float v) {
#pragma unroll
  for (int o = 32; o; o >>= 1) v += __shfl_down(v, o);
  return v;
}
__device__ __forceinline__ float wmax(float v) {
#pragma unroll
  for (int o = 32; o; o >>= 1) v = fmaxf(v, __shfl_down(v, o));
  return v;
}

__device__ __forceinline__ unsigned pk2bf(float lo, float hi) {
  union { float f; unsigned u; } a, b;
  a.f = lo; b.f = hi;
  unsigned ra = (a.u + 0x7FFFu + ((a.u >> 16) & 1u)) >> 16;
  unsigned rb = (b.u + 0x7FFFu + ((b.u >> 16) & 1u)) >> 16;
  return (ra & 0xFFFFu) | (rb << 16);
}
__device__ __forceinline__ u16b f2bf(float x) {
  union { float f; unsigned u; } a;
  a.f = x;
  return (u16b)((a.u + 0x7FFFu + ((a.u >> 16) & 1u)) >> 16);
}
__device__ __forceinline__ float bf2f(u16b x) {
  union { unsigned u; float f; } a;
  a.u = (unsigned)x << 16;
  return a.f;
}

__device__ __forceinline__ void mfma_bf16(f32x4& d, const u32x4& a, const u32x4& b) {
  asm("v_mfma_f32_16x16x32_bf16 %0, %1, %2, %0" : "+v"(d) : "v"(a), "v"(b));
}

// ---------------- layout transform: [n,b,d,hw] -> seq [(n*hw),b,d] fp32 -----------
__global__ void k_toseq(const float* __restrict__ in, float* __restrict__ out) {
  __shared__ float tile[32][33];
  int nb = blockIdx.z;
  int n = nb / kB, b = nb % kB;
  int p0 = blockIdx.x * 32, d0 = blockIdx.y * 32;
  int tx = threadIdx.x, ty = threadIdx.y;
#pragma unroll
  for (int j = 0; j < 4; ++j) {
    int d = d0 + ty + j * 8, p = p0 + tx;
    if (d < kD && p < kHW) tile[ty + j * 8][tx] = in[(long)nb * kD * kHW + (long)d * kHW + p];
  }
  __syncthreads();
#pragma unroll
  for (int j = 0; j < 4; ++j) {
    int p = p0 + ty + j * 8, d = d0 + tx;
    if (p < kHW && d < kD)
      out[((long)(n * kHW + p) * kB + b) * kD + d] = tile[tx][ty + j * 8];
  }
}

__global__ void k_cvt2d(const float* __restrict__ in, u16b* __restrict__ out, int C, int Cp) {
  long r = blockIdx.x;
  for (int c = threadIdx.x; c < C; c += 256)
    out[r * Cp + c] = f2bf(in[r * (long)C + c]);
}

__global__ void k_tcvt(const float* __restrict__ in, u16b* __restrict__ out, int R, int C) {
  __shared__ float tile[32][33];
  int c0 = blockIdx.x * 32, r0 = blockIdx.y * 32;
  int tx = threadIdx.x, ty = threadIdx.y;
#pragma unroll
  for (int j = 0; j < 4; ++j) {
    int r = r0 + ty + j * 8, c = c0 + tx;
    if (r < R && c < C) tile[ty + j * 8][tx] = in[(long)r * C + c];
  }
  __syncthreads();
#pragma unroll
  for (int j = 0; j < 4; ++j) {
    int c = c0 + ty + j * 8, r = r0 + tx;
    if (r < R && c < C) out[(long)c * R + r] = f2bf(tile[tx][ty + j * 8]);
  }
}

// VrT[b][d][l] = bf16( mr[(l,b),d] * lab[l,b] ), stride kLp
__global__ void k_vrt(const float* __restrict__ mr, const float* __restrict__ lab,
                      u16b* __restrict__ vt) {
  __shared__ float tile[32][33];
  int l0 = blockIdx.x * 32, d0 = blockIdx.y * 32, b = blockIdx.z;
  int tx = threadIdx.x, ty = threadIdx.y;
#pragma unroll
  for (int j = 0; j < 4; ++j) {
    int l = l0 + ty + j * 8;
    if (l < kL)
      tile[ty + j * 8][tx] = mr[((long)l * kB + b) * kD + d0 + tx] * lab[(long)l * kB + b];
  }
  __syncthreads();
#pragma unroll
  for (int j = 0; j < 4; ++j) {
    int d = d0 + ty + j * 8, l = l0 + tx;
    if (l < kL) vt[((long)b * kD + d) * kLp + l] = f2bf(tile[tx][ty + j * 8]);
  }
}

__global__ void k_lab(const float* __restrict__ tl, float* __restrict__ lab) {
  long i = (long)blockIdx.x * 256 + threadIdx.x;
  const long tot = (long)kNI * kB * kHW;
  if (i >= tot) return;
  int p = (int)(i % kHW);
  long t = i / kHW;
  int b = (int)(t % kB);
  int n = (int)(t / kB);
  lab[(long)(n * kHW + p) * kB + b] = tl[i];
}

__global__ void k_l2n_vec(const float* __restrict__ src, float* __restrict__ u, int C) {
  __shared__ float red[2];
  int tid = threadIdx.x;  // 128
  float s = 0.f;
  for (int c = tid; c < C; c += 128) { float x = src[c]; s += x * x; }
  s = wsum(s);
  if ((tid & 63) == 0) red[tid >> 6] = s;
  __syncthreads();
  float inv = 1.f / fmaxf(sqrtf(red[0] + red[1]), 1e-12f);
  for (int c = tid; c < C; c += 128) u[c] = src[c] * inv;
}

// ---------------- pipelined NT bf16 MFMA GEMM (XCD-swizzled, optional add) --------
template <int BM, int BN, bool AF32, bool ACC>
__global__ __launch_bounds__(256) void k_gemm(const void* Ap, const u16b* __restrict__ B,
                                              float* __restrict__ C, int M, int N, int K,
                                              int lda, int ldb, int ldc, long sAb, long sBb,
                                              long sCb, const float* __restrict__ addv) {
  const int gx = gridDim.x, gy = gridDim.y;
  const int nwg = gx * gy * gridDim.z;
  const int orig = (blockIdx.z * gy + blockIdx.y) * gx + blockIdx.x;
  const int q = nwg >> 3, rr = nwg & 7, xcd = orig & 7, idx = orig >> 3;
  const int swz = (xcd < rr ? xcd * (q + 1) : rr * (q + 1) + (xcd - rr) * q) + idx;
  const int bx = swz % gx;
  const int tmp = swz / gx;
  const int by = tmp % gy, bz = tmp / gy;

  const char* Ab = (const char*)Ap + (long)bz * sAb * (AF32 ? 4 : 2);
  const u16b* Bb = B + (long)bz * sBb;
  C += (long)bz * sCb;
  constexpr int FM = BM / 32, FN = BN / 32;
  constexpr int NSA = BM * 8 / 256;
  constexpr int NSB = BN * 8 / 256;
  const int m0 = by * BM, n0 = bx * BN;
  const int tid = threadIdx.x;
  const int wid = tid >> 6, lane = tid & 63;
  const int wr = wid >> 1, wc = wid & 1;
  const int fr = lane & 15, fk = lane >> 4;

  __shared__ unsigned AsU[BM * 36];
  __shared__ unsigned BsU[BN * 36];
  f32x4 acc[FM][FN] = {};

  u32x4 pa[NSA];
  float4 paf[AF32 ? 2 * NSA : 1];
  u32x4 pb[NSB];

  auto loadA = [&](int k0) {
#pragma unroll
    for (int i = 0; i < NSA; ++i) {
      int si = tid + i * 256;
      int row = si >> 3, c = si & 7;
      int gr = m0 + row, gk = k0 + c * 8;
      if constexpr (AF32) {
        const float* A = (const float*)Ab;
        if (gr < M && gk + 8 <= K) {
          const float* ap = A + (long)gr * lda + gk;
          paf[2 * i] = *(const float4*)ap;
          paf[2 * i + 1] = *(const float4*)(ap + 4);
        } else {
          float v[8];
#pragma unroll
          for (int j = 0; j < 8; ++j)
            v[j] = (gr < M && gk + j < K) ? A[(long)gr * lda + gk + j] : 0.f;
          paf[2 * i] = make_float4(v[0], v[1], v[2], v[3]);
          paf[2 * i + 1] = make_float4(v[4], v[5], v[6], v[7]);
        }
      } else {
        const u16b* A = (const u16b*)Ab;
        if (gr < M && gk + 8 <= K) {
          pa[i] = *(const u32x4*)(A + (long)gr * lda + gk);
        } else {
          unsigned v[8];
#pragma unroll
          for (int j = 0; j < 8; ++j)
            v[j] = (gr < M && gk + j < K) ? A[(long)gr * lda + gk + j] : 0u;
          pa[i].x = v[0] | (v[1] << 16); pa[i].y = v[2] | (v[3] << 16);
          pa[i].z = v[4] | (v[5] << 16); pa[i].w = v[6] | (v[7] << 16);
        }
      }
    }
  };
  auto loadB = [&](int k0) {
#pragma unroll
    for (int i = 0; i < NSB; ++i) {
      int si = tid + i * 256;
      int row = si >> 3, c = si & 7;
      int gr = n0 + row, gk = k0 + c * 8;
      if (gr < N && gk + 8 <= K) {
        pb[i] = *(const u32x4*)(Bb + (long)gr * ldb + gk);
      } else {
        unsigned v[8];
#pragma unroll
        for (int j = 0; j < 8; ++j)
          v[j] = (gr < N && gk + j < K) ? Bb[(long)gr * ldb + gk + j] : 0u;
        pb[i].x = v[0] | (v[1] << 16); pb[i].y = v[2] | (v[3] << 16);
        pb[i].z = v[4] | (v[5] << 16); pb[i].w = v[6] | (v[7] << 16);
      }
    }
  };
  auto storeAB = [&]() {
#pragma unroll
    for (int i = 0; i < NSA; ++i) {
      int si = tid + i * 256;
      int row = si >> 3, c = si & 7;
      u32x4 w;
      if constexpr (AF32) {
        float4 u0 = paf[2 * i], u1 = paf[2 * i + 1];
        w.x = pk2bf(u0.x, u0.y); w.y = pk2bf(u0.z, u0.w);
        w.z = pk2bf(u1.x, u1.y); w.w = pk2bf(u1.z, u1.w);
      } else {
        w = pa[i];
      }
      *(u32x4*)&AsU[row * 36 + c * 4] = w;
    }
#pragma unroll
    for (int i = 0; i < NSB; ++i) {
      int si = tid + i * 256;
      int row = si >> 3, c = si & 7;
      *(u32x4*)&BsU[row * 36 + c * 4] = pb[i];
    }
  };

  loadA(0);
  loadB(0);
  storeAB();
  __syncthreads();
  const int nk = CDIV(K, 64);
  for (int t = 0; t < nk; ++t) {
    const bool more = (t + 1 < nk);
    if (more) { loadA((t + 1) * 64); loadB((t + 1) * 64); }
#pragma unroll
    for (int kk = 0; kk < 2; ++kk) {
      u32x4 af[FM], bf[FN];
#pragma unroll
      for (int mi = 0; mi < FM; ++mi)
        af[mi] = *(const u32x4*)&AsU[(wr * (BM / 2) + mi * 16 + fr) * 36 + kk * 16 + fk * 4];
#pragma unroll
      for (int ni = 0; ni < FN; ++ni)
        bf[ni] = *(const u32x4*)&BsU[(wc * (BN / 2) + ni * 16 + fr) * 36 + kk * 16 + fk * 4];
#pragma unroll
      for (int mi = 0; mi < FM; ++mi)
#pragma unroll
        for (int ni = 0; ni < FN; ++ni) mfma_bf16(acc[mi][ni], af[mi], bf[ni]);
    }
    if (more) {
      __syncthreads();
      storeAB();
      __syncthreads();
    }
  }
  asm volatile("s_nop 7\n\ts_nop 7" ::: );
#pragma unroll
  for (int mi = 0; mi < FM; ++mi) {
#pragma unroll
    for (int r = 0; r < 4; ++r) {
      int gm = m0 + wr * (BM / 2) + mi * 16 + fk * 4 + r;
      if (gm >= M) continue;
      float av = addv ? addv[(long)gm * 8 + bz] : 0.f;
#pragma unroll
      for (int ni = 0; ni < FN; ++ni) {
        int gn = n0 + wc * (BN / 2) + ni * 16 + fr;
        if (gn >= N) continue;
        long idx2 = (long)gm * ldc + gn;
        float v = acc[mi][ni][r] + av;
        C[idx2] = ACC ? (C[idx2] + v) : v;
      }
    }
  }
}

// row += bias; l2-normalize; fp32 in place + bf16 mirror; optional g[b*L+k] = u.row
__global__ void k_bias_l2n(float* __restrict__ P, const float* __restrict__ bias, int C,
                           u16b* __restrict__ outb, const float* __restrict__ u,
                           float* __restrict__ g, int L) {
  __shared__ float red[2];
  long row = blockIdx.x;
  float* p = P + row * C;
  int tid = threadIdx.x;  // 128
  int nv = C >> 7;
  float v[4];
  float s = 0.f;
#pragma unroll
  for (int i = 0; i < 4; ++i)
    if (i < nv) {
      float x = p[tid + (i << 7)] + bias[tid + (i << 7)];
      v[i] = x;
      s += x * x;
    }
  s = wsum(s);
  if ((tid & 63) == 0) red[tid >> 6] = s;
  __syncthreads();
  float inv = 1.f / fmaxf(sqrtf(red[0] + red[1]), 1e-12f);
  float dot = 0.f;
#pragma unroll
  for (int i = 0; i < 4; ++i)
    if (i < nv) {
      float x = v[i] * inv;
      p[tid + (i << 7)] = x;
      outb[row * C + tid + (i << 7)] = f2bf(x);
      if (u) dot += x * u[tid + (i << 7)];
    }
  if (u) {
    __syncthreads();
    dot = wsum(dot);
    if ((tid & 63) == 0) red[tid >> 6] = dot;
    __syncthreads();
    if (tid == 0) {
      int k = (int)(row / kB), b = (int)(row % kB);
      g[(long)b * L + k] = red[0] + red[1];
    }
  }
}

// generic softmax; optional bf16 out at row*ldo
__global__ __launch_bounds__(256) void k_softmax(float* __restrict__ S, int Lq, int Lk,
                                                 u16b* __restrict__ outb, int ldo) {
  __shared__ float sm[1456];
  __shared__ float red[4];
  int row = blockIdx.x;
  float* Sr = S + (long)row * Lk;
  int tid = threadIdx.x;
  float mx = -3.0e38f;
  for (int k = tid; k < Lk; k += 256) {
    float v = Sr[k] * kTemp;
    sm[k] = v;
    mx = fmaxf(mx, v);
  }
  mx = wmax(mx);
  if ((tid & 63) == 0) red[tid >> 6] = mx;
  __syncthreads();
  mx = fmaxf(fmaxf(red[0], red[1]), fmaxf(red[2], red[3]));
  __syncthreads();
  float s = 0.f;
  for (int k = tid; k < Lk; k += 256) {
    float e = expf(sm[k] - mx);
    sm[k] = e;
    s += e;
  }
  s = wsum(s);
  if ((tid & 63) == 0) red[tid >> 6] = s;
  __syncthreads();
  float inv = 1.0f / (red[0] + red[1] + red[2] + red[3]);
  for (int k = tid; k < Lk; k += 256) {
    float p = sm[k] * inv;
    if (outb) outb[(long)row * ldo + k] = f2bf(p); else Sr[k] = p;
  }
}

// S1 softmax -> Ph bf16 (padded) + mkr (lab dot); no bias (cI cancels exactly)
__global__ __launch_bounds__(256) void k_softmaxm(const float* __restrict__ Sf,
                                                  const float* __restrict__ lab,
                                                  u16b* __restrict__ Ph,
                                                  float* __restrict__ mkr) {
  __shared__ float sm[1456];
  __shared__ float red[4];
  int row = blockIdx.x;  // b*kHW + q
  int b = row / kHW, q = row - b * kHW;
  const float* Sr = Sf + (long)row * kL;
  int tid = threadIdx.x;
  float mx = -3.0e38f;
  for (int k = tid; k < kL; k += 256) {
    float v = Sr[k] * kTemp;
    sm[k] = v;
    mx = fmaxf(mx, v);
  }
  mx = wmax(mx);
  if ((tid & 63) == 0) red[tid >> 6] = mx;
  __syncthreads();
  mx = fmaxf(fmaxf(red[0], red[1]), fmaxf(red[2], red[3]));
  __syncthreads();
  float s = 0.f;
  for (int k = tid; k < kL; k += 256) {
    float e = expf(sm[k] - mx);
    sm[k] = e;
    s += e;
  }
  s = wsum(s);
  if ((tid & 63) == 0) red[tid >> 6] = s;
  __syncthreads();
  float inv = 1.0f / (red[0] + red[1] + red[2] + red[3]);
  __syncthreads();
  u16b* outp = Ph + (long)row * kLp;
  float dot = 0.f;
  for (int k = tid; k < kL; k += 256) {
    float p = sm[k] * inv;
    outp[k] = f2bf(p);
    dot += p * lab[(long)k * kB + b];
  }
  for (int k = kL + tid; k < kLp; k += 256) outp[k] = 0;
  dot = wsum(dot);
  if ((tid & 63) == 0) red[tid >> 6] = dot;
  __syncthreads();
  if (tid == 0) mkr[(long)q * kB + b] = red[0] + red[1] + red[2] + red[3];
}

// wI[b,:] = softmax(30*cR[b,:]); mki8[b] = wI . lab[:,b]
__global__ __launch_bounds__(256) void k_wi(const float* __restrict__ cR,
                                            const float* __restrict__ lab,
                                            float* __restrict__ wI,
                                            float* __restrict__ mki8) {
  __shared__ float sm[1456];
  __shared__ float red[4];
  int b = blockIdx.x;
  const float* Sr = cR + (long)b * kL;
  int tid = threadIdx.x;
  float mx = -3.0e38f;
  for (int k = tid; k < kL; k += 256) {
    float v = Sr[k] * kTemp;
    sm[k] = v;
    mx = fmaxf(mx, v);
  }
  mx = wmax(mx);
  if ((tid & 63) == 0) red[tid >> 6] = mx;
  __syncthreads();
  mx = fmaxf(fmaxf(red[0], red[1]), fmaxf(red[2], red[3]));
  __syncthreads();
  float s = 0.f;
  for (int k = tid; k < kL; k += 256) {
    float e = expf(sm[k] - mx);
    sm[k] = e;
    s += e;
  }
  s = wsum(s);
  if ((tid & 63) == 0) red[tid >> 6] = s;
  __syncthreads();
  float inv = 1.0f / (red[0] + red[1] + red[2] + red[3]);
  __syncthreads();
  float dot = 0.f;
  for (int k = tid; k < kL; k += 256) {
    float p = sm[k] * inv;
    wI[(long)b * kL + k] = p;
    dot += p * lab[(long)k * kB + b];
  }
  dot = wsum(dot);
  if ((tid & 63) == 0) red[tid >> 6] = dot;
  __syncthreads();
  if (tid == 0) mki8[b] = red[0] + red[1] + red[2] + red[3];
}

__global__ void k_wrowsum(const float* __restrict__ w, const float* __restrict__ S,
                          float* __restrict__ rowout, int L, int kchunk) {
  int b = blockIdx.y;
  int d = blockIdx.x * 128 + threadIdx.x;
  int k0 = blockIdx.z * kchunk;
  int k1 = min(L, k0 + kchunk);
  float s = 0.f;
  for (int k = k0; k < k1; ++k) s += w[(long)b * L + k] * S[((long)k * kB + b) * kD + d];
  atomicAdd(&rowout[(long)b * kD + d], s);
}

// single-variant inorm phase 1/3 (OP0: A+B2)
__global__ __launch_bounds__(256) void k_ss1(const float* __restrict__ A,
                                             const float* __restrict__ B2,
                                             float* __restrict__ part) {
  __shared__ float red[4];
  long r = blockIdx.x;
  int tid = threadIdx.x;
  long base = r * kD;
  float z0 = A[base + tid] + B2[base + tid];
  float z1 = A[base + tid + 256] + B2[base + tid + 256];
  float s = z0 * z0 + z1 * z1;
  s = wsum(s);
  if ((tid & 63) == 0) red[tid >> 6] = s;
  __syncthreads();
  if (tid == 0) part[r] = red[0] + red[1] + red[2] + red[3];
}

__global__ void k_ssred(const float* __restrict__ part, float* __restrict__ ss, int R, int NG) {
  __shared__ float red[8];
  int g = blockIdx.x, v = blockIdx.y;
  int n = g / kB, b = g % kB;
  int tid = threadIdx.x;  // 512
  float s = 0.f;
  for (int p = tid; p < kHW; p += 512) s += part[(long)v * R + ((long)(n * kHW + p) * kB + b)];
  s = wsum(s);
  if ((tid & 63) == 0) red[tid >> 6] = s;
  __syncthreads();
  if (tid == 0) {
    float t = 0.f;
#pragma unroll
    for (int i = 0; i < 8; ++i) t += red[i];
    ss[(long)v * NG + g] = t;
  }
}

__global__ __launch_bounds__(256) void k_scale1(const float* __restrict__ A,
                                                const float* __restrict__ B2,
                                                float* __restrict__ outp,
                                                const float* __restrict__ ss, int NG,
                                                u16b* __restrict__ ob) {
  long r = blockIdx.x;
  int l = (int)(r / kB), b = (int)(r % kB);
  int g = (l / kHW) * kB + b;
  int tid = threadIdx.x;
  float fac = kScaleN * sqrtf(kCnt / (ss[g] + 1e-5f));
  long base = r * kD;
  float x0 = (A[base + tid] + B2[base + tid]) * fac;
  float x1 = (A[base + tid + 256] + B2[base + tid + 256]) * fac;
  outp[base + tid] = x0;
  outp[base + tid + 256] = x1;
  if (ob) { ob[base + tid] = f2bf(x0); ob[base + tid + 256] = f2bf(x1); }
}

// ti8[b,d] = row[b,d] * scaleN*sqrt(cnt/(kHW*sum_d row^2 + eps))
__global__ void k_ti8(const float* __restrict__ row, float* __restrict__ ti8) {
  __shared__ float red[4];
  int b = blockIdx.x;
  int tid = threadIdx.x;  // 256
  float r0 = row[(long)b * kD + tid], r1 = row[(long)b * kD + tid + 256];
  float s = r0 * r0 + r1 * r1;
  s = wsum(s);
  if ((tid & 63) == 0) red[tid >> 6] = s;
  __syncthreads();
  float ssv = (float)kHW * (red[0] + red[1] + red[2] + red[3]);
  float fac = kScaleN * sqrtf(kCnt / (ssv + 1e-5f));
  ti8[(long)b * kD + tid] = r0 * fac;
  ti8[(long)b * kD + tid + 256] = r1 * fac;
}

// vb[b,:] = l2n(ti8_b @ WkC + bkC)
__global__ void k_vb(const float* __restrict__ ti8, const float* __restrict__ Wk,
                     const float* __restrict__ bk, float* __restrict__ vb) {
  __shared__ float part[4][128];
  __shared__ float red[2];
  int b = blockIdx.x;
  int j = threadIdx.x;
  int dz = threadIdx.y;
  const float* row = ti8 + (long)b * kD;
  float acc = 0.f;
  int d0 = dz * 128;
  for (int d = d0; d < d0 + 128; ++d) acc += row[d] * Wk[(long)d * kKD + j];
  part[dz][j] = acc;
  __syncthreads();
  if (dz == 0) {
    float a = part[0][j] + part[1][j] + part[2][j] + part[3][j] + bk[j];
    float s = a * a;
    s = wsum(s);
    if ((j & 63) == 0) red[j >> 6] = s;
    part[0][j] = a;
  }
  __syncthreads();
  if (dz == 0) {
    float inv = 1.f / fmaxf(sqrtf(red[0] + red[1]), 1e-12f);
    vb[(long)b * kKD + j] = part[0][j] * inv;
  }
}

// cR[b*kL + k] = vb_b . Krb[k,b,:]  (bf16 keys)
__global__ void k_cR(const float* __restrict__ vb, const u16b* __restrict__ Krb,
                     float* __restrict__ cR) {
  int idx = blockIdx.x * 4 + (threadIdx.x >> 6);
  if (idx >= kL * kB) return;
  int k = idx / kB, b = idx % kB;
  int lane = threadIdx.x & 63;
  const float* v = vb + (long)b * kKD;
  const u16b* pr = Krb + ((long)k * kB + b) * kKD;
  float sR = 0.f;
  for (int c = lane; c < kKD; c += 64) sR += v[c] * bf2f(pr[c]);
  sR = wsum(sR);
  if (lane == 0) cR[(long)b * kL + k] = sR;
}

// ci8[b,d] = sum_l wI[b,l] * VrT[b,d,l]
__global__ void k_ci8(const float* __restrict__ wI, const u16b* __restrict__ VrT,
                      float* __restrict__ ci8) {
  int idx = blockIdx.x * 4 + (threadIdx.x >> 6);  // 0..4095
  int b = idx >> 9, d = idx & 511;
  int lane = threadIdx.x & 63;
  const float* w = wI + (long)b * kL;
  const u16b* vt = VrT + ((long)b * kD + d) * kLp;
  float s = 0.f;
  for (int l = lane; l < kL; l += 64) s += w[l] * bf2f(vt[l]);
  s = wsum(s);
  if (lane == 0) ci8[(long)b * kD + d] = s;
}

// tail real partials: part[v*kR+r], v in {a^2, b^2, ab}, a=t1r*mkr[r], b=t1r+c3r
__global__ __launch_bounds__(256) void k_ss3(const float* __restrict__ t1r,
                                             const float* __restrict__ mkr,
                                             const float* __restrict__ c3,
                                             float* __restrict__ part) {
  __shared__ float red[4][3];
  int r = blockIdx.x;
  int tid = threadIdx.x;
  long base = (long)r * kD;
  float mk = mkr[r];
  float s0 = 0.f, s1 = 0.f, s2 = 0.f;
#pragma unroll
  for (int j = 0; j < 2; ++j) {
    int d = tid + j * 256;
    float t = t1r[base + d];
    float a = t * mk;
    float bb = t + c3[base + d];
    s0 += a * a; s1 += bb * bb; s2 += a * bb;
  }
  int w = tid >> 6, lane = tid & 63;
  float t0 = wsum(s0), t1 = wsum(s1), t2 = wsum(s2);
  if (lane == 0) { red[w][0] = t0; red[w][1] = t1; red[w][2] = t2; }
  __syncthreads();
  if (tid < 3) part[(long)tid * kR + r] = red[0][tid] + red[1][tid] + red[2][tid] + red[3][tid];
}

// coefficients + oi8. ssp real: [0..7]=SSa,[8..15]=SSb,[16..23]=SSab.
// imag from ti8/ci8/mki8 analytically (all rows identical -> ss = kHW * per-row sum).
// coef out: [0..7]=ca_r, [8..15]=cb_r. oi8[b,d] = ti*mki*ca_i + (ti+ci)*cb_i.
__global__ __launch_bounds__(512) void k_coef(const float* __restrict__ ssp,
                                              const float* __restrict__ ti8,
                                              const float* __restrict__ ci8,
                                              const float* __restrict__ mki8,
                                              float* __restrict__ coef,
                                              float* __restrict__ oi8) {
  __shared__ float cai[8], cbi[8];
  int tid = threadIdx.x;
  int b = tid >> 6, lane = tid & 63;
  float sT = 0.f, sU = 0.f, sV = 0.f;
  for (int d = lane; d < kD; d += 64) {
    float ti = ti8[(long)b * kD + d], ci = ci8[(long)b * kD + d];
    float u = ti + ci;
    sT += ti * ti; sU += u * u; sV += ti * u;
  }
  sT = wsum(sT); sU = wsum(sU); sV = wsum(sV);
  if (lane == 0) {
    // real
    float SSa = ssp[b], SSb = ssp[8 + b], SSab = ssp[16 + b];
    float f2 = kScaleN * sqrtf(kCnt / (SSa + 1e-5f));
    float f4 = kScaleN * sqrtf(kCnt / (SSb + 1e-5f));
    float ssz = f2 * f2 * SSa + f4 * f4 * SSb + 2.f * f2 * f4 * SSab;
    float fac = kScaleN * sqrtf(kCnt / (ssz + 1e-5f));
    coef[b] = f2 * fac;
    coef[8 + b] = f4 * fac;
    // imag
    float mk = mki8[b];
    float SSai = (float)kHW * mk * mk * sT;
    float SSbi = (float)kHW * sU;
    float SSabi = (float)kHW * mk * sV;
    float f2i = kScaleN * sqrtf(kCnt / (SSai + 1e-5f));
    float f4i = kScaleN * sqrtf(kCnt / (SSbi + 1e-5f));
    float sszi = f2i * f2i * SSai + f4i * f4i * SSbi + 2.f * f2i * f4i * SSabi;
    float faci = kScaleN * sqrtf(kCnt / (sszi + 1e-5f));
    cai[b] = f2i * faci;
    cbi[b] = f4i * faci;
  }
  __syncthreads();
  // oi8: 4096 elems / 512 threads = 8 each
#pragma unroll
  for (int j = 0; j < 8; ++j) {
    int i = tid * 8 + j;
    int bb = i >> 9, d = i & 511;
    float ti = ti8[(long)bb * kD + d], ci = ci8[(long)bb * kD + d];
    oi8[i] = ti * mki8[bb] * cai[bb] + (ti + ci) * cbi[bb];
  }
}

// oadd[o*8+b] = sum_d Wc[o*1024 + 512 + d] * oi8[b*512+d]   (fp32 Wc imag half)
__global__ void k_oadd(const float* __restrict__ Wc, const float* __restrict__ oi8,
                       float* __restrict__ oadd) {
  int idx = blockIdx.x * 4 + (threadIdx.x >> 6);  // 0..4095
  int o = idx >> 3, b = idx & 7;
  int lane = threadIdx.x & 63;
  const float* wrow = Wc + (long)o * 1024 + 512;
  const float* oi = oi8 + (long)b * kD;
  float s = 0.f;
  for (int d = lane; d < kD; d += 64) s += wrow[d] * oi[d];
  s = wsum(s);
  if (lane == 0) oadd[(long)o * 8 + b] = s;
}

// t2b[r][d] = bf16( t1r*mkr*ca_r + (t1r+c3r)*cb_r )
__global__ __launch_bounds__(256) void k_zfin(const float* __restrict__ t1r,
                                              const float* __restrict__ mkr,
                                              const float* __restrict__ c3,
                                              const float* __restrict__ coef,
                                              u16b* __restrict__ t2b) {
  int r = blockIdx.x;
  int b = r % kB;
  int tid = threadIdx.x;
  float mk = mkr[r];
  float ca = coef[b], cb = coef[8 + b];
  long base = (long)r * kD;
#pragma unroll
  for (int j = 0; j < 2; ++j) {
    int d = tid + j * 256;
    float t = t1r[base + d];
    float ov = t * mk * ca + (t + c3[base + d]) * cb;
    t2b[(long)r * 512 + d] = f2bf(ov);
  }
}

template <int BM, int BN, bool AF32, bool ACC>
void gemm(hipStream_t s, const void* A, const u16b* B, float* C, int M, int N, int K, int lda,
          int ldb, int ldc, long sAb, long sBb, long sCb, int batch,
          const float* addv = nullptr) {
  dim3 grd(CDIV(N, BN), CDIV(M, BM), batch), blk(256);
  k_gemm<BM, BN, AF32, ACC><<<grd, blk, 0, s>>>(A, B, C, M, N, K, lda, ldb, ldc, sAb, sBb, sCb,
                                                addv);
}

}  // namespace

extern "C" void kernel_launch(void* const* d_in, const int* in_sizes, int n_in, void* d_out,
                              int out_size, void* d_ws, size_t ws_size, hipStream_t stream) {
  (void)in_sizes; (void)n_in; (void)out_size;
  const float* tf  = (const float*)d_in[0];
  const float* sf  = (const float*)d_in[1];
  const float* tl  = (const float*)d_in[2];
  const float* WkE = (const float*)d_in[3];
  const float* bkE = (const float*)d_in[4];
  const float* WkS = (const float*)d_in[5];
  const float* bkS = (const float*)d_in[6];
  const float* WkC = (const float*)d_in[7];
  const float* bkC = (const float*)d_in[8];
  const float* Wc  = (const float*)d_in[9];
  float* out = (float*)d_out;
  float* ws = (float*)d_ws;

  const long LBD = (long)kL * kB * kD;
  const long LBK = (long)kL * kB * kKD;
  const long HBD = kHBD;

  long off = 0;
  auto alloc = [&](long n) { long o = off; off += (n + 255) & ~255L; return o; };
  auto allocU = [&](long nu) { return alloc((nu + 1) / 2); };

  long o_seqT = alloc(LBD);
  long o_seqS = alloc(LBD);
  long o_Kr   = alloc(LBK);
  long o_Krb  = allocU(LBK);
  long o_VrT  = allocU((long)kB * kD * kLp);
  long o_tfb  = allocU((long)kNI * kB * kD * kHWp);
  long o_sfb  = allocU((long)kNI * kB * kD * kHWp);
  long o_WkTE = allocU((long)kD * kD);
  long o_WkTS = allocU((long)kKD * kD);
  long o_WkTC = allocU((long)kKD * kD);
  long o_Wcb  = allocU((long)kD * 2 * kD);
  long o_lab  = alloc((long)kL * kB);
  long o_uS   = alloc(kKD);
  long o_vb   = alloc((long)kB * kKD);
  long o_g    = alloc((long)kB * kL);
  long o_cRw  = alloc((long)kB * kL);
  long o_wI   = alloc((long)kB * kL);
  long o_row  = alloc((long)kB * kD);
  long o_mkr  = alloc((long)kHW * kB);
  long o_mki8 = alloc(8);
  long o_ti8  = alloc((long)kB * kD);
  long o_ci8  = alloc((long)kB * kD);
  long o_oi8  = alloc((long)kB * kD);
  long o_oadd = alloc((long)kD * 8);
  long o_ss   = alloc(128);
  long o_part = alloc(3L * kL * kB);
  long o_scr  = off;

  // encoder overlay
  long o_Pe  = o_scr;
  long o_Peb = o_Pe + LBD;
  long o_Ae  = o_Peb + LBD / 2;
  long o_Aeb = o_Ae + (long)kB * kL * kL;
  long enc_end = o_Aeb + (8L * kL * kLp + 1) / 2;
  long o_ar  = o_Pe;                 // after Pe dead
  long o_mr  = o_Ae;                 // after Ae dead

  // decoder overlay
  long p = o_scr;
  auto nxt = [&](long n) { long o = p; p += (n + 255) & ~255L; return o; };
  long o_Sf   = nxt((long)kR * kL);  // also Ps/As/Pc fp32 staging (disjoint lifetimes)
  long o_Psb  = nxt(((long)kR * kKD + 1) / 2);
  long o_Pcb  = nxt(((long)kR * kKD + 1) / 2);
  long o_Asb  = nxt(((long)kR * kHWp + 1) / 2);
  long o_Ph   = nxt(((long)kR * kLp + 1) / 2);
  long o_t1r  = nxt(HBD);
  long o_t1rb = nxt((HBD + 1) / 2);
  long o_c3   = nxt(HBD);
  long o_t2b  = nxt(((long)kR * 512 + 1) / 2);
  long img_end = p;

  long total = (enc_end > img_end ? enc_end : img_end);
  if ((size_t)total * sizeof(float) > ws_size) return;

  float* seqT = ws + o_seqT;
  float* seqS = ws + o_seqS;
  float* Kr = ws + o_Kr;
  u16b* Krb = (u16b*)(ws + o_Krb);
  u16b* VrT = (u16b*)(ws + o_VrT);
  u16b* tfb = (u16b*)(ws + o_tfb);
  u16b* sfb = (u16b*)(ws + o_sfb);
  u16b* WkTE = (u16b*)(ws + o_WkTE);
  u16b* WkTS = (u16b*)(ws + o_WkTS);
  u16b* WkTC = (u16b*)(ws + o_WkTC);
  u16b* Wcb = (u16b*)(ws + o_Wcb);
  float* lab = ws + o_lab;
  float* uS = ws + o_uS;
  float* vb = ws + o_vb;
  float* g_ = ws + o_g;
  float* cRw = ws + o_cRw;
  float* wI = ws + o_wI;
  float* row = ws + o_row;
  float* mkr = ws + o_mkr;
  float* mki8 = ws + o_mki8;
  float* ti8 = ws + o_ti8;
  float* ci8 = ws + o_ci8;
  float* oi8 = ws + o_oi8;
  float* oadd = ws + o_oadd;
  float* ssp = ws + o_ss;
  float* coef = ssp + 64;
  float* part = ws + o_part;
  float* Pe = ws + o_Pe;
  u16b* Peb = (u16b*)(ws + o_Peb);
  float* Ae = ws + o_Ae;
  u16b* Aeb = (u16b*)(ws + o_Aeb);
  float* ar = ws + o_ar;
  float* mr = ws + o_mr;
  u16b* mrb = (u16b*)(ws + o_mr + LBD);  // after mr in the dead-Ae region
  float* Sf = ws + o_Sf;
  float* Ps = ws + o_Sf;
  float* As_ = ws + o_Sf;
  float* Pc = ws + o_Sf;
  u16b* Psb = (u16b*)(ws + o_Psb);
  u16b* Pcb = (u16b*)(ws + o_Pcb);
  u16b* Asb = (u16b*)(ws + o_Asb);
  u16b* Ph = (u16b*)(ws + o_Ph);
  float* t1r = ws + o_t1r;
  u16b* t1rb = (u16b*)(ws + o_t1rb);
  float* c3 = ws + o_c3;
  u16b* t2b = (u16b*)(ws + o_t2b);

  // ---- stage 0 ----
  {
    dim3 grd(CDIV(kHW, 32), CDIV(kD, 32), kNI * kB), blk(32, 8);
    k_toseq<<<grd, blk, 0, stream>>>(tf, seqT);
    k_toseq<<<grd, blk, 0, stream>>>(sf, seqS);
  }
  k_cvt2d<<<kNI * kB * kD, 256, 0, stream>>>(tf, tfb, kHW, kHWp);
  k_cvt2d<<<kNI * kB * kD, 256, 0, stream>>>(sf, sfb, kHW, kHWp);
  k_cvt2d<<<kD, 256, 0, stream>>>(Wc, Wcb, 2 * kD, 2 * kD);
  k_tcvt<<<dim3(kD / 32, kD / 32), dim3(32, 8), 0, stream>>>(WkE, WkTE, kD, kD);
  k_tcvt<<<dim3(kKD / 32, kD / 32), dim3(32, 8), 0, stream>>>(WkS, WkTS, kD, kKD);
  k_tcvt<<<dim3(kKD / 32, kD / 32), dim3(32, 8), 0, stream>>>(WkC, WkTC, kD, kKD);
  k_lab<<<CDIV(kNI * kB * kHW, 256), 256, 0, stream>>>(tl, lab);
  k_l2n_vec<<<1, 128, 0, stream>>>(bkS, uS, kKD);

  // ---- encoder (imag branch fully dead: mem_i/Ki never affect the output) ----
  gemm<64, 128, true, false>(stream, seqT, WkTE, Pe, kL * kB, kD, kD, kD, kD, kD, 0, 0, 0, 1);
  k_bias_l2n<<<kL * kB, 128, 0, stream>>>(Pe, bkE, kD, Peb, nullptr, nullptr, 0);
  gemm<128, 128, false, false>(stream, Peb, Peb, Ae, kL, kL, kD, kB * kD, kB * kD, kL, kD, kD,
                               (long)kL * kL, 8);
  k_softmax<<<kB * kL, 256, 0, stream>>>(Ae, kL, kL, Aeb, kLp);
  gemm<64, 128, false, false>(stream, Aeb, tfb, ar, kL, kD, kHW, kLp, kHWp, kB * kD,
                              (long)kL * kLp, (long)kD * kHWp, kD, 8);
  gemm<64, 128, false, true>(stream, Aeb + kHW, tfb + (long)kB * kD * kHWp, ar, kL, kD, kHW,
                             kLp, kHWp, kB * kD, (long)kL * kLp, (long)kD * kHWp, kD, 8);
  gemm<64, 128, false, true>(stream, Aeb + 2 * kHW, tfb + 2L * kB * kD * kHWp, ar, kL, kD, kHW,
                             kLp, kHWp, kB * kD, (long)kL * kLp, (long)kD * kHWp, kD, 8);
  // mem_r = inorm(seqT + ar)
  k_ss1<<<kL * kB, 256, 0, stream>>>(seqT, ar, part);
  k_ssred<<<dim3(kNI * kB, 1), 512, 0, stream>>>(part, ssp, kL * kB, kNI * kB);
  k_scale1<<<kL * kB, 256, 0, stream>>>(seqT, ar, mr, ssp, kNI * kB, mrb);
  k_vrt<<<dim3(CDIV(kL, 32), kD / 32, kB), dim3(32, 8), 0, stream>>>(mr, lab, VrT);
  gemm<64, 64, false, false>(stream, mrb, WkTC, Kr, kL * kB, kKD, kD, kD, kD, kKD, 0, 0, 0, 1);
  k_bias_l2n<<<kL * kB, 128, 0, stream>>>(Kr, bkC, kKD, Krb, nullptr, nullptr, 0);

  // ---- decoder ----
  for (int img = 0; img < 6; ++img) {
    const float* t = (img < 3) ? (seqT + (long)img * HBD) : (seqS + (long)(img - 3) * HBD);
    const u16b* tb = (img < 3) ? (tfb + (long)img * kB * kD * kHWp)
                               : (sfb + (long)(img - 3) * kB * kD * kHWp);
    float* osl = out + (long)img * kB * kD * kHW;

    // self-attention (real full; imag row rank-1)
    gemm<64, 64, true, false>(stream, t, WkTS, Ps, kHW * kB, kKD, kD, kD, kD, kKD, 0, 0, 0, 1);
    k_bias_l2n<<<kHW * kB, 128, 0, stream>>>(Ps, bkS, kKD, Psb, uS, g_, kHW);
    k_softmax<<<kB, 256, 0, stream>>>(g_, 1, kHW, nullptr, 0);
    gemm<64, 64, false, false>(stream, Psb, Psb, As_, kHW, kHW, kKD, kB * kKD, kB * kKD, kHW,
                               kKD, kKD, (long)kHW * kHW, 8);
    k_softmax<<<kB * kHW, 256, 0, stream>>>(As_, kHW, kHW, Asb, kHWp);
    gemm<64, 64, false, false>(stream, Asb, tb, c3, kHW, kD, kHW, kHWp, kHWp, kB * kD,
                               (long)kHW * kHWp, (long)kD * kHWp, kD, 8);  // s2r -> c3
    hipMemsetAsync(row, 0, kB * kD * sizeof(float), stream);
    k_wrowsum<<<dim3(kD / 128, kB, CDIV(kHW, 64)), 128, 0, stream>>>(g_, t, row, kHW, 64);
    // t1r = inorm(t + s2r); ti8 = rank-1 inorm of s2i row
    k_ss1<<<kR, 256, 0, stream>>>(t, c3, part);
    k_ssred<<<dim3(kB, 1), 512, 0, stream>>>(part, ssp, kR, kB);
    k_scale1<<<kR, 256, 0, stream>>>(t, c3, t1r, ssp, kB, t1rb);
    k_ti8<<<kB, 256, 0, stream>>>(row, ti8);
    // cross-attention: real S1 softmax (cI bias cancels); imag = q-independent wI
    k_vb<<<kB, dim3(128, 4), 0, stream>>>(ti8, WkC, bkC, vb);
    gemm<64, 64, false, false>(stream, t1rb, WkTC, Pc, kHW * kB, kKD, kD, kD, kD, kKD, 0, 0, 0,
                               1);
    k_bias_l2n<<<kHW * kB, 128, 0, stream>>>(Pc, bkC, kKD, Pcb, nullptr, nullptr, 0);
    k_cR<<<CDIV(kL * kB, 4), 256, 0, stream>>>(vb, Krb, cRw);
    k_wi<<<kB, 256, 0, stream>>>(cRw, lab, wI, mki8);
    k_ci8<<<1024, 256, 0, stream>>>(wI, VrT, ci8);
    gemm<64, 128, false, false>(stream, Pcb, Krb, Sf, kHW, kL, kKD, kB * kKD, kB * kKD, kL,
                                kKD, kKD, (long)kHW * kL, 8);
    k_softmaxm<<<kB * kHW, 256, 0, stream>>>(Sf, lab, Ph, mkr);
    gemm<64, 64, false, false>(stream, Ph, VrT, c3, kHW, kD, kL, kLp, kLp, kB * kD,
                               (long)kHW * kLp, (long)kD * kLp, kD, 8);  // c3r
    // fused tail (imag analytic)
    k_ss3<<<kR, 256, 0, stream>>>(t1r, mkr, c3, part);
    k_ssred<<<dim3(kB, 3), 512, 0, stream>>>(part, ssp, kR, kB);
    k_coef<<<1, 512, 0, stream>>>(ssp, ti8, ci8, mki8, coef, oi8);
    k_oadd<<<1024, 256, 0, stream>>>(Wc, oi8, oadd);
    k_zfin<<<kR, 256, 0, stream>>>(t1r, mkr, c3, coef, t2b);
    // 1x1 conv: real GEMM K=512 + rank-1 imag epilogue add
    gemm<64, 64, false, false>(stream, Wcb, t2b, osl, kD, kHW, kD, 2 * kD, kB * 512, kHW, 0,
                               512, (long)kD * kHW, 8, oadd);
  }
}

// Round 12
// 842.664 us; speedup vs baseline: 13.6947x; 1.9072x over previous
//
#include <hip/hip_runtime.h>

// ComTransformer on MI355X — round 12: round 11 + determinism fixes.
//  - k_flash: s_nop hazard guards on VALU->MFMA(SrcC) and MFMA->VALU edges
//    (inline-asm MFMA is opaque to the compiler hazard recognizer; the
//    rescale->PV edge had a zero-instruction window -> timing-dependent race).
//  - k_wrow48 atomicAdd -> two-phase deterministic reduction.
// Prior: flash attention (self+cross), fully batched decoder, rank-1 imag
// collapse, pipelined BK=64 bf16 NT GEMM + XCD swizzle, group-sum tail identity.

namespace {

constexpr int kNI = 3;
constexpr int kB  = 8;
constexpr int kD  = 512;
constexpr int kKD = 128;
constexpr int kHW = 484;
constexpr int kL  = kNI * kHW;  // 1452
constexpr int kLp = 1456;
constexpr int kHWp = 488;
constexpr float kTemp = 30.0f;
constexpr float kCnt  = 247808.0f;
constexpr float kScaleN = 0.011048543456039806f;
constexpr int kR = kHW * kB;   // 3872 rows per image
constexpr int kR6 = 6 * kR;    // 23232

#define CDIV(a, b) (((a) + (b) - 1) / (b))

typedef float f32x4 __attribute__((ext_vector_type(4)));
typedef unsigned int u32x4 __attribute__((ext_vector_type(4)));
typedef unsigned short u16b;

__device__ __forceinline__ float wsum(float v) {
#pragma unroll
  for (int o = 32; o; o >>= 1) v += __shfl_down(v, o);
  return v;
}
__device__ __forceinline__ float wmax(float v) {
#pragma unroll
  for (int o = 32; o; o >>= 1) v = fmaxf(v, __shfl_down(v, o));
  return v;
}

__device__ __forceinline__ unsigned pk2bf(float lo, float hi) {
  union { float f; unsigned u; } a, b;
  a.f = lo; b.f = hi;
  unsigned ra = (a.u + 0x7FFFu + ((a.u >> 16) & 1u)) >> 16;
  unsigned rb = (b.u + 0x7FFFu + ((b.u >> 16) & 1u)) >> 16;
  return (ra & 0xFFFFu) | (rb << 16);
}
__device__ __forceinline__ u16b f2bf(float x) {
  union { float f; unsigned u; } a;
  a.f = x;
  return (u16b)((a.u + 0x7FFFu + ((a.u >> 16) & 1u)) >> 16);
}
__device__ __forceinline__ float bf2f(u16b x) {
  union { unsigned u; float f; } a;
  a.u = (unsigned)x << 16;
  return a.f;
}

__device__ __forceinline__ void mfma_bf16(f32x4& d, const u32x4& a, const u32x4& b) {
  asm("v_mfma_f32_16x16x32_bf16 %0, %1, %2, %0" : "+v"(d) : "v"(a), "v"(b));
}

// ---------------- layout transform: [n,b,d,hw] -> seq [(n*hw),b,d] fp32 -----------
__global__ void k_toseq(const float* __restrict__ in, float* __restrict__ out) {
  __shared__ float tile[32][33];
  int nb = blockIdx.z;
  int n = nb / kB, b = nb % kB;
  int p0 = blockIdx.x * 32, d0 = blockIdx.y * 32;
  int tx = threadIdx.x, ty = threadIdx.y;
#pragma unroll
  for (int j = 0; j < 4; ++j) {
    int d = d0 + ty + j * 8, p = p0 + tx;
    if (d < kD && p < kHW) tile[ty + j * 8][tx] = in[(long)nb * kD * kHW + (long)d * kHW + p];
  }
  __syncthreads();
#pragma unroll
  for (int j = 0; j < 4; ++j) {
    int p = p0 + ty + j * 8, d = d0 + tx;
    if (p < kHW && d < kD)
      out[((long)(n * kHW + p) * kB + b) * kD + d] = tile[tx][ty + j * 8];
  }
}

__global__ void k_cvt2d(const float* __restrict__ in, u16b* __restrict__ out, int C, int Cp) {
  long r = blockIdx.x;
  for (int c = threadIdx.x; c < C; c += 256)
    out[r * Cp + c] = f2bf(in[r * (long)C + c]);
}

__global__ void k_tcvt(const float* __restrict__ in, u16b* __restrict__ out, int R, int C) {
  __shared__ float tile[32][33];
  int c0 = blockIdx.x * 32, r0 = blockIdx.y * 32;
  int tx = threadIdx.x, ty = threadIdx.y;
#pragma unroll
  for (int j = 0; j < 4; ++j) {
    int r = r0 + ty + j * 8, c = c0 + tx;
    if (r < R && c < C) tile[ty + j * 8][tx] = in[(long)r * C + c];
  }
  __syncthreads();
#pragma unroll
  for (int j = 0; j < 4; ++j) {
    int c = c0 + ty + j * 8, r = r0 + tx;
    if (r < R && c < C) out[(long)c * R + r] = f2bf(tile[tx][ty + j * 8]);
  }
}

// VrT[b][d][l] = bf16( mr[(l,b),d] * lab[l,b] ), stride kLp
__global__ void k_vrt(const float* __restrict__ mr, const float* __restrict__ lab,
                      u16b* __restrict__ vt) {
  __shared__ float tile[32][33];
  int l0 = blockIdx.x * 32, d0 = blockIdx.y * 32, b = blockIdx.z;
  int tx = threadIdx.x, ty = threadIdx.y;
#pragma unroll
  for (int j = 0; j < 4; ++j) {
    int l = l0 + ty + j * 8;
    if (l < kL)
      tile[ty + j * 8][tx] = mr[((long)l * kB + b) * kD + d0 + tx] * lab[(long)l * kB + b];
  }
  __syncthreads();
#pragma unroll
  for (int j = 0; j < 4; ++j) {
    int d = d0 + ty + j * 8, l = l0 + tx;
    if (l < kL) vt[((long)b * kD + d) * kLp + l] = f2bf(tile[tx][ty + j * 8]);
  }
}

__global__ void k_lab(const float* __restrict__ tl, float* __restrict__ lab) {
  long i = (long)blockIdx.x * 256 + threadIdx.x;
  const long tot = (long)kNI * kB * kHW;
  if (i >= tot) return;
  int p = (int)(i % kHW);
  long t = i / kHW;
  int b = (int)(t % kB);
  int n = (int)(t / kB);
  lab[(long)(n * kHW + p) * kB + b] = tl[i];
}

__global__ void k_l2n_vec(const float* __restrict__ src, float* __restrict__ u, int C) {
  __shared__ float red[2];
  int tid = threadIdx.x;  // 128
  float s = 0.f;
  for (int c = tid; c < C; c += 128) { float x = src[c]; s += x * x; }
  s = wsum(s);
  if ((tid & 63) == 0) red[tid >> 6] = s;
  __syncthreads();
  float inv = 1.f / fmaxf(sqrtf(red[0] + red[1]), 1e-12f);
  for (int c = tid; c < C; c += 128) u[c] = src[c] * inv;
}

// ---------------- pipelined NT bf16 MFMA GEMM (XCD swizzle, 2-stride batch) -------
template <int BM, int BN, bool AF32, bool ACC>
__global__ __launch_bounds__(256) void k_gemm(const void* Ap, const u16b* __restrict__ B,
                                              float* __restrict__ C, int M, int N, int K,
                                              int lda, int ldb, int ldc,
                                              long sA1, long sA2, long sB1, long sB2,
                                              long sC1, long sC2,
                                              const float* __restrict__ addv) {
  const int gx = gridDim.x, gy = gridDim.y;
  const int nwg = gx * gy * gridDim.z;
  const int orig = (blockIdx.z * gy + blockIdx.y) * gx + blockIdx.x;
  const int q = nwg >> 3, rr = nwg & 7, xcd = orig & 7, idx = orig >> 3;
  const int swz = (xcd < rr ? xcd * (q + 1) : rr * (q + 1) + (xcd - rr) * q) + idx;
  const int bx = swz % gx;
  const int tmp = swz / gx;
  const int by = tmp % gy, bz = tmp / gy;
  const int za = bz >> 3, zb = bz & 7;

  const char* Ab = (const char*)Ap + (za * sA1 + zb * sA2) * (AF32 ? 4 : 2);
  const u16b* Bb = B + za * sB1 + zb * sB2;
  C += za * sC1 + zb * sC2;
  constexpr int FM = BM / 32, FN = BN / 32;
  constexpr int NSA = BM * 8 / 256;
  constexpr int NSB = BN * 8 / 256;
  const int m0 = by * BM, n0 = bx * BN;
  const int tid = threadIdx.x;
  const int wid = tid >> 6, lane = tid & 63;
  const int wr = wid >> 1, wc = wid & 1;
  const int fr = lane & 15, fk = lane >> 4;

  __shared__ unsigned AsU[BM * 36];
  __shared__ unsigned BsU[BN * 36];
  f32x4 acc[FM][FN] = {};

  u32x4 pa[NSA];
  float4 paf[AF32 ? 2 * NSA : 1];
  u32x4 pb[NSB];

  auto loadA = [&](int k0) {
#pragma unroll
    for (int i = 0; i < NSA; ++i) {
      int si = tid + i * 256;
      int row = si >> 3, c = si & 7;
      int gr = m0 + row, gk = k0 + c * 8;
      if constexpr (AF32) {
        const float* A = (const float*)Ab;
        if (gr < M && gk + 8 <= K) {
          const float* ap = A + (long)gr * lda + gk;
          paf[2 * i] = *(const float4*)ap;
          paf[2 * i + 1] = *(const float4*)(ap + 4);
        } else {
          float v[8];
#pragma unroll
          for (int j = 0; j < 8; ++j)
            v[j] = (gr < M && gk + j < K) ? A[(long)gr * lda + gk + j] : 0.f;
          paf[2 * i] = make_float4(v[0], v[1], v[2], v[3]);
          paf[2 * i + 1] = make_float4(v[4], v[5], v[6], v[7]);
        }
      } else {
        const u16b* A = (const u16b*)Ab;
        if (gr < M && gk + 8 <= K) {
          pa[i] = *(const u32x4*)(A + (long)gr * lda + gk);
        } else {
          unsigned v[8];
#pragma unroll
          for (int j = 0; j < 8; ++j)
            v[j] = (gr < M && gk + j < K) ? A[(long)gr * lda + gk + j] : 0u;
          pa[i].x = v[0] | (v[1] << 16); pa[i].y = v[2] | (v[3] << 16);
          pa[i].z = v[4] | (v[5] << 16); pa[i].w = v[6] | (v[7] << 16);
        }
      }
    }
  };
  auto loadB = [&](int k0) {
#pragma unroll
    for (int i = 0; i < NSB; ++i) {
      int si = tid + i * 256;
      int row = si >> 3, c = si & 7;
      int gr = n0 + row, gk = k0 + c * 8;
      if (gr < N && gk + 8 <= K) {
        pb[i] = *(const u32x4*)(Bb + (long)gr * ldb + gk);
      } else {
        unsigned v[8];
#pragma unroll
        for (int j = 0; j < 8; ++j)
          v[j] = (gr < N && gk + j < K) ? Bb[(long)gr * ldb + gk + j] : 0u;
        pb[i].x = v[0] | (v[1] << 16); pb[i].y = v[2] | (v[3] << 16);
        pb[i].z = v[4] | (v[5] << 16); pb[i].w = v[6] | (v[7] << 16);
      }
    }
  };
  auto storeAB = [&]() {
#pragma unroll
    for (int i = 0; i < NSA; ++i) {
      int si = tid + i * 256;
      int row = si >> 3, c = si & 7;
      u32x4 w;
      if constexpr (AF32) {
        float4 u0 = paf[2 * i], u1 = paf[2 * i + 1];
        w.x = pk2bf(u0.x, u0.y); w.y = pk2bf(u0.z, u0.w);
        w.z = pk2bf(u1.x, u1.y); w.w = pk2bf(u1.z, u1.w);
      } else {
        w = pa[i];
      }
      *(u32x4*)&AsU[row * 36 + c * 4] = w;
    }
#pragma unroll
    for (int i = 0; i < NSB; ++i) {
      int si = tid + i * 256;
      int row = si >> 3, c = si & 7;
      *(u32x4*)&BsU[row * 36 + c * 4] = pb[i];
    }
  };

  loadA(0);
  loadB(0);
  storeAB();
  __syncthreads();
  const int nk = CDIV(K, 64);
  for (int t = 0; t < nk; ++t) {
    const bool more = (t + 1 < nk);
    if (more) { loadA((t + 1) * 64); loadB((t + 1) * 64); }
#pragma unroll
    for (int kk = 0; kk < 2; ++kk) {
      u32x4 af[FM], bf[FN];
#pragma unroll
      for (int mi = 0; mi < FM; ++mi)
        af[mi] = *(const u32x4*)&AsU[(wr * (BM / 2) + mi * 16 + fr) * 36 + kk * 16 + fk * 4];
#pragma unroll
      for (int ni = 0; ni < FN; ++ni)
        bf[ni] = *(const u32x4*)&BsU[(wc * (BN / 2) + ni * 16 + fr) * 36 + kk * 16 + fk * 4];
#pragma unroll
      for (int mi = 0; mi < FM; ++mi)
#pragma unroll
        for (int ni = 0; ni < FN; ++ni) mfma_bf16(acc[mi][ni], af[mi], bf[ni]);
    }
    if (more) {
      __syncthreads();
      storeAB();
      __syncthreads();
    }
  }
  asm volatile("s_nop 7\n\ts_nop 7" ::: );
#pragma unroll
  for (int mi = 0; mi < FM; ++mi) {
#pragma unroll
    for (int r = 0; r < 4; ++r) {
      int gm = m0 + wr * (BM / 2) + mi * 16 + fk * 4 + r;
      if (gm >= M) continue;
      float av = addv ? addv[(long)za * (kD * 8) + (long)gm * 8 + zb] : 0.f;
#pragma unroll
      for (int ni = 0; ni < FN; ++ni) {
        int gn = n0 + wc * (BN / 2) + ni * 16 + fr;
        if (gn >= N) continue;
        long idx2 = (long)gm * ldc + gn;
        float v = acc[mi][ni][r] + av;
        C[idx2] = ACC ? (C[idx2] + v) : v;
      }
    }
  }
}

// ---------------- flash attention: O = softmax(30 Q K^T) V, optional lab-dot ------
template <bool LAB, bool KIMG, bool VZ>
__global__ __launch_bounds__(256) void k_flash(const u16b* __restrict__ Q,
                                               const u16b* __restrict__ K,
                                               const u16b* __restrict__ V,
                                               const float* __restrict__ labv,
                                               u16b* __restrict__ O,
                                               float* __restrict__ mkout,
                                               int S, int ldv) {
  int qt0 = blockIdx.x * 32;
  int z = blockIdx.y, img = z >> 3, b = z & 7;
  int tid = threadIdx.x, wid = tid >> 6, lane = tid & 63;
  int fr = lane & 15, fk = lane >> 4;

  __shared__ float Ssm[32 * 65];
  __shared__ unsigned Plds[32 * 36];
  __shared__ float mrun[32], lrun[32], scal[32], mka[32];

  const long qbase = ((long)img * kR + b) * kKD;
  const long kbase = KIMG ? ((long)img * kR + b) * kKD : (long)b * kKD;
  const long vbase = (long)(VZ ? z : b) * kD * ldv;

  u32x4 afq[2][4];
#pragma unroll
  for (int mi = 0; mi < 2; ++mi) {
    int qq = qt0 + mi * 16 + fr;
    if (qq >= kHW) qq = kHW - 1;
#pragma unroll
    for (int kk = 0; kk < 4; ++kk)
      afq[mi][kk] = *(const u32x4*)(Q + qbase + (long)qq * (kB * kKD) + kk * 32 + fk * 8);
  }

  f32x4 oacc[2][8] = {};
  if (tid < 32) { mrun[tid] = -3.0e38f; lrun[tid] = 0.f; mka[tid] = 0.f; }
  __syncthreads();

  int r8 = lane >> 3, i8 = lane & 7;
  int srow = wid * 8 + r8;

  for (int kt = 0; kt < S; kt += 64) {
    // QK^T strip
    {
      f32x4 sacc[2] = {};
      int krow = kt + wid * 16 + fr;
      int kc = krow < S ? krow : S - 1;
      const u16b* kp = K + kbase + (long)kc * (kB * kKD);
#pragma unroll
      for (int kk = 0; kk < 4; ++kk) {
        u32x4 bf = *(const u32x4*)(kp + kk * 32 + fk * 8);
        mfma_bf16(sacc[0], afq[0][kk], bf);
        mfma_bf16(sacc[1], afq[1][kk], bf);
      }
      asm volatile("s_nop 7\n\ts_nop 7" ::: );  // MFMA -> VALU hazard
      if (krow >= S) {
#pragma unroll
        for (int mi = 0; mi < 2; ++mi)
#pragma unroll
          for (int r = 0; r < 4; ++r) sacc[mi][r] = -1.0e30f;
      }
#pragma unroll
      for (int mi = 0; mi < 2; ++mi)
#pragma unroll
        for (int r = 0; r < 4; ++r)
          Ssm[(mi * 16 + fk * 4 + r) * 65 + wid * 16 + fr] = sacc[mi][r];
    }
    __syncthreads();
    // online softmax
    {
      float v[8];
      float mx = -3.0e38f;
#pragma unroll
      for (int j = 0; j < 8; ++j) {
        v[j] = Ssm[srow * 65 + i8 * 8 + j] * kTemp;
        mx = fmaxf(mx, v[j]);
      }
#pragma unroll
      for (int o = 1; o < 8; o <<= 1) mx = fmaxf(mx, __shfl_xor(mx, o));
      float mold = mrun[srow];
      float mnew = fmaxf(mold, mx);
      float p[8], ts = 0.f, lacc = 0.f;
#pragma unroll
      for (int j = 0; j < 8; ++j) {
        p[j] = __expf(v[j] - mnew);
        ts += p[j];
        if (LAB) {
          int kidx = kt + i8 * 8 + j;
          lacc += p[j] * labv[(long)(kidx < S ? kidx : S - 1) * kB + b];
        }
      }
#pragma unroll
      for (int o = 1; o < 8; o <<= 1) ts += __shfl_xor(ts, o);
      if (LAB) {
#pragma unroll
        for (int o = 1; o < 8; o <<= 1) lacc += __shfl_xor(lacc, o);
      }
      u32x4 w0;
      w0.x = pk2bf(p[0], p[1]); w0.y = pk2bf(p[2], p[3]);
      w0.z = pk2bf(p[4], p[5]); w0.w = pk2bf(p[6], p[7]);
      *(u32x4*)&Plds[srow * 36 + i8 * 4] = w0;
      if (i8 == 0) {
        float sc = __expf(mold - mnew);
        mrun[srow] = mnew;
        lrun[srow] = lrun[srow] * sc + ts;
        scal[srow] = sc;
        if (LAB) mka[srow] = mka[srow] * sc + lacc;
      }
    }
    __syncthreads();
    // rescale O (VALU), then PV (MFMA reads oacc as SrcC)
#pragma unroll
    for (int mi = 0; mi < 2; ++mi)
#pragma unroll
      for (int r = 0; r < 4; ++r) {
        float sc = scal[mi * 16 + fk * 4 + r];
#pragma unroll
        for (int n = 0; n < 8; ++n) oacc[mi][n][r] *= sc;
      }
    asm volatile("s_nop 7" ::: );  // VALU write -> MFMA SrcC read hazard
#pragma unroll
    for (int kk = 0; kk < 2; ++kk) {
      u32x4 ap0 = *(const u32x4*)&Plds[fr * 36 + kk * 16 + fk * 4];
      u32x4 ap1 = *(const u32x4*)&Plds[(16 + fr) * 36 + kk * 16 + fk * 4];
#pragma unroll
      for (int n = 0; n < 8; ++n) {
        int d = wid * 128 + n * 16 + fr;
        int kidx = kt + kk * 32 + fk * 8;
        if (kidx > ldv - 8) kidx = ldv - 8;
        u32x4 bv = *(const u32x4*)(V + vbase + (long)d * ldv + kidx);
        mfma_bf16(oacc[0][n], ap0, bv);
        mfma_bf16(oacc[1][n], ap1, bv);
      }
    }
    asm volatile("s_nop 7\n\ts_nop 7" ::: );  // MFMA -> VALU (next rescale/epilogue)
    __syncthreads();
  }
  asm volatile("s_nop 7\n\ts_nop 7" ::: );
#pragma unroll
  for (int mi = 0; mi < 2; ++mi)
#pragma unroll
    for (int r = 0; r < 4; ++r) {
      int qq = mi * 16 + fk * 4 + r;
      int gq = qt0 + qq;
      if (gq >= kHW) continue;
      float invl = 1.0f / lrun[qq];
      long orow = ((long)img * kR + (long)gq * kB + b) * kD;
#pragma unroll
      for (int n = 0; n < 8; ++n)
        O[orow + wid * 128 + n * 16 + fr] = f2bf(oacc[mi][n][r] * invl);
    }
  if (LAB && tid < 32) {
    int gq = qt0 + tid;
    if (gq < kHW) mkout[(long)img * kR + (long)gq * kB + b] = mka[tid] / lrun[tid];
  }
}

// row += bias; l2-normalize; fp32 in place + bf16 mirror; optional g = u.row
__global__ void k_bias_l2n(float* __restrict__ P, const float* __restrict__ bias, int C,
                           u16b* __restrict__ outb, const float* __restrict__ u,
                           float* __restrict__ g, int L) {
  __shared__ float red[2];
  long row = blockIdx.x;
  float* p = P + row * C;
  int tid = threadIdx.x;  // 128
  int nv = C >> 7;
  float v[4];
  float s = 0.f;
#pragma unroll
  for (int i = 0; i < 4; ++i)
    if (i < nv) {
      float x = p[tid + (i << 7)] + bias[tid + (i << 7)];
      v[i] = x;
      s += x * x;
    }
  s = wsum(s);
  if ((tid & 63) == 0) red[tid >> 6] = s;
  __syncthreads();
  float inv = 1.f / fmaxf(sqrtf(red[0] + red[1]), 1e-12f);
  float dot = 0.f;
#pragma unroll
  for (int i = 0; i < 4; ++i)
    if (i < nv) {
      float x = v[i] * inv;
      p[tid + (i << 7)] = x;
      outb[row * C + tid + (i << 7)] = f2bf(x);
      if (u) dot += x * u[tid + (i << 7)];
    }
  if (u) {
    __syncthreads();
    dot = wsum(dot);
    if ((tid & 63) == 0) red[tid >> 6] = dot;
    __syncthreads();
    if (tid == 0) {
      int img = (int)(row / kR);
      int within = (int)(row % kR);
      int qq = within >> 3, b = within & 7;
      g[((long)(img * 8 + b)) * L + qq] = red[0] + red[1];
    }
  }
}

// generic softmax; optional bf16 out at row*ldo
__global__ __launch_bounds__(256) void k_softmax(float* __restrict__ S, int Lq, int Lk,
                                                 u16b* __restrict__ outb, int ldo) {
  __shared__ float sm[1456];
  __shared__ float red[4];
  int row = blockIdx.x;
  float* Sr = S + (long)row * Lk;
  int tid = threadIdx.x;
  float mx = -3.0e38f;
  for (int k = tid; k < Lk; k += 256) {
    float v = Sr[k] * kTemp;
    sm[k] = v;
    mx = fmaxf(mx, v);
  }
  mx = wmax(mx);
  if ((tid & 63) == 0) red[tid >> 6] = mx;
  __syncthreads();
  mx = fmaxf(fmaxf(red[0], red[1]), fmaxf(red[2], red[3]));
  __syncthreads();
  float s = 0.f;
  for (int k = tid; k < Lk; k += 256) {
    float e = __expf(sm[k] - mx);
    sm[k] = e;
    s += e;
  }
  s = wsum(s);
  if ((tid & 63) == 0) red[tid >> 6] = s;
  __syncthreads();
  float inv = 1.0f / (red[0] + red[1] + red[2] + red[3]);
  for (int k = tid; k < Lk; k += 256) {
    float p = sm[k] * inv;
    if (outb) outb[(long)row * ldo + k] = f2bf(p); else Sr[k] = p;
  }
}

// fused cR + softmax + lab-dot: block z in [0,48)
__global__ __launch_bounds__(256) void k_cwi(const float* __restrict__ vb,
                                             const u16b* __restrict__ Krb,
                                             const float* __restrict__ labv,
                                             float* __restrict__ wI,
                                             float* __restrict__ mki8) {
  __shared__ float sm[kL];
  __shared__ float vbl[kKD];
  __shared__ float red[4];
  int z = blockIdx.x, b = z & 7;
  int tid = threadIdx.x;
  if (tid < kKD) vbl[tid] = vb[(long)z * kKD + tid];
  __syncthreads();
  float mx = -3.0e38f;
  for (int k = tid; k < kL; k += 256) {
    const u16b* kp = Krb + ((long)k * kB + b) * kKD;
    float s = 0.f;
    for (int c = 0; c < kKD; c += 8) {
      u32x4 w = *(const u32x4*)(kp + c);
      s += vbl[c] * bf2f((u16b)(w.x & 0xFFFF)) + vbl[c + 1] * bf2f((u16b)(w.x >> 16));
      s += vbl[c + 2] * bf2f((u16b)(w.y & 0xFFFF)) + vbl[c + 3] * bf2f((u16b)(w.y >> 16));
      s += vbl[c + 4] * bf2f((u16b)(w.z & 0xFFFF)) + vbl[c + 5] * bf2f((u16b)(w.z >> 16));
      s += vbl[c + 6] * bf2f((u16b)(w.w & 0xFFFF)) + vbl[c + 7] * bf2f((u16b)(w.w >> 16));
    }
    sm[k] = s * kTemp;
    mx = fmaxf(mx, sm[k]);
  }
  mx = wmax(mx);
  if ((tid & 63) == 0) red[tid >> 6] = mx;
  __syncthreads();
  mx = fmaxf(fmaxf(red[0], red[1]), fmaxf(red[2], red[3]));
  __syncthreads();
  float s = 0.f;
  for (int k = tid; k < kL; k += 256) {
    float e = __expf(sm[k] - mx);
    sm[k] = e;
    s += e;
  }
  s = wsum(s);
  if ((tid & 63) == 0) red[tid >> 6] = s;
  __syncthreads();
  float inv = 1.0f / (red[0] + red[1] + red[2] + red[3]);
  __syncthreads();
  float dot = 0.f;
  for (int k = tid; k < kL; k += 256) {
    float p = sm[k] * inv;
    wI[(long)z * kL + k] = p;
    dot += p * labv[(long)k * kB + b];
  }
  dot = wsum(dot);
  if ((tid & 63) == 0) red[tid >> 6] = dot;
  __syncthreads();
  if (tid == 0) mki8[z] = red[0] + red[1] + red[2] + red[3];
}

// deterministic rank-1 AV, phase A: row2[(z*8+c)*kD+d] = sum_{k in chunk c} g*seq
__global__ void k_wrowA(const float* __restrict__ g, const float* __restrict__ seq,
                        float* __restrict__ row2) {
  int z = blockIdx.y, img = z >> 3, b = z & 7;
  int c = blockIdx.z;
  int d = blockIdx.x * 128 + threadIdx.x;
  int k0 = c * 61;
  int k1 = min(kHW, k0 + 61);
  float s = 0.f;
  for (int k = k0; k < k1; ++k)
    s += g[(long)z * kHW + k] * seq[((long)img * kR + (long)k * kB + b) * kD + d];
  row2[((long)z * 8 + c) * kD + d] = s;
}

// phase B: row[z*kD+d] = sum_c row2 (fixed order)
__global__ void k_wrowB(const float* __restrict__ row2, float* __restrict__ row) {
  int idx = blockIdx.x * 256 + threadIdx.x;  // 0..48*512
  int z = idx >> 9, d = idx & 511;
  float s = 0.f;
#pragma unroll
  for (int c = 0; c < 8; ++c) s += row2[((long)z * 8 + c) * kD + d];
  row[(long)z * kD + d] = s;
}

// fp32 inorm phase 1 (encoder)
__global__ __launch_bounds__(256) void k_ss1f(const float* __restrict__ A,
                                              const float* __restrict__ B2,
                                              float* __restrict__ part) {
  __shared__ float red[4];
  long r = blockIdx.x;
  int tid = threadIdx.x;
  long base = r * kD;
  float z0 = A[base + tid] + B2[base + tid];
  float z1 = A[base + tid + 256] + B2[base + tid + 256];
  float s = z0 * z0 + z1 * z1;
  s = wsum(s);
  if ((tid & 63) == 0) red[tid >> 6] = s;
  __syncthreads();
  if (tid == 0) part[r] = red[0] + red[1] + red[2] + red[3];
}

// fp32 inorm phase 3 (encoder): fp32 out + bf16 mirror
__global__ __launch_bounds__(256) void k_scale1f(const float* __restrict__ A,
                                                 const float* __restrict__ B2,
                                                 float* __restrict__ outp,
                                                 const float* __restrict__ ss,
                                                 u16b* __restrict__ ob) {
  long r = blockIdx.x;
  int l = (int)(r / kB), b = (int)(r % kB);
  int g = (l / kHW) * kB + b;
  int tid = threadIdx.x;
  float fac = kScaleN * sqrtf(kCnt / (ss[g] + 1e-5f));
  long base = r * kD;
  float x0 = (A[base + tid] + B2[base + tid]) * fac;
  float x1 = (A[base + tid + 256] + B2[base + tid + 256]) * fac;
  outp[base + tid] = x0;
  outp[base + tid + 256] = x1;
  ob[base + tid] = f2bf(x0);
  ob[base + tid + 256] = f2bf(x1);
}

// t1 inorm, phase 1 (B2 bf16)
__global__ __launch_bounds__(256) void k_ss1b(const float* __restrict__ A,
                                              const u16b* __restrict__ B2,
                                              float* __restrict__ part) {
  __shared__ float red[4];
  long r = blockIdx.x;
  int tid = threadIdx.x;
  long base = r * kD;
  float z0 = A[base + tid] + bf2f(B2[base + tid]);
  float z1 = A[base + tid + 256] + bf2f(B2[base + tid + 256]);
  float s = z0 * z0 + z1 * z1;
  s = wsum(s);
  if ((tid & 63) == 0) red[tid >> 6] = s;
  __syncthreads();
  if (tid == 0) part[r] = red[0] + red[1] + red[2] + red[3];
}

__global__ void k_ssred(const float* __restrict__ part, float* __restrict__ ss, int R, int NG) {
  __shared__ float red[8];
  int g = blockIdx.x, v = blockIdx.y;
  int n = g / kB, b = g % kB;
  int tid = threadIdx.x;  // 512
  float s = 0.f;
  for (int p = tid; p < kHW; p += 512) s += part[(long)v * R + ((long)(n * kHW + p) * kB + b)];
  s = wsum(s);
  if ((tid & 63) == 0) red[tid >> 6] = s;
  __syncthreads();
  if (tid == 0) {
    float t = 0.f;
#pragma unroll
    for (int i = 0; i < 8; ++i) t += red[i];
    ss[(long)v * NG + g] = t;
  }
}

// t1 inorm, phase 3 -> bf16 only
__global__ __launch_bounds__(256) void k_scale1b(const float* __restrict__ A,
                                                 const u16b* __restrict__ B2,
                                                 const float* __restrict__ ss,
                                                 u16b* __restrict__ ob) {
  long r = blockIdx.x;
  int img = (int)(r / kR), b = (int)(r & 7);
  int g = img * 8 + b;
  int tid = threadIdx.x;
  float fac = kScaleN * sqrtf(kCnt / (ss[g] + 1e-5f));
  long base = r * kD;
  ob[base + tid] = f2bf((A[base + tid] + bf2f(B2[base + tid])) * fac);
  ob[base + tid + 256] = f2bf((A[base + tid + 256] + bf2f(B2[base + tid + 256])) * fac);
}

// ti8[z,d] = row[z,d] * scale(kHW * ||row||^2)
__global__ void k_ti8(const float* __restrict__ row, float* __restrict__ ti8) {
  __shared__ float red[4];
  int z = blockIdx.x;
  int tid = threadIdx.x;  // 256
  float r0 = row[(long)z * kD + tid], r1 = row[(long)z * kD + tid + 256];
  float s = r0 * r0 + r1 * r1;
  s = wsum(s);
  if ((tid & 63) == 0) red[tid >> 6] = s;
  __syncthreads();
  float ssv = (float)kHW * (red[0] + red[1] + red[2] + red[3]);
  float fac = kScaleN * sqrtf(kCnt / (ssv + 1e-5f));
  ti8[(long)z * kD + tid] = r0 * fac;
  ti8[(long)z * kD + tid + 256] = r1 * fac;
}

// vb[z,:] = l2n(ti8_z @ WkC + bkC)
__global__ void k_vb(const float* __restrict__ ti8, const float* __restrict__ Wk,
                     const float* __restrict__ bk, float* __restrict__ vb) {
  __shared__ float part[4][128];
  __shared__ float red[2];
  int z = blockIdx.x;
  int j = threadIdx.x;
  int dz = threadIdx.y;
  const float* row = ti8 + (long)z * kD;
  float acc = 0.f;
  int d0 = dz * 128;
  for (int d = d0; d < d0 + 128; ++d) acc += row[d] * Wk[(long)d * kKD + j];
  part[dz][j] = acc;
  __syncthreads();
  if (dz == 0) {
    float a = part[0][j] + part[1][j] + part[2][j] + part[3][j] + bk[j];
    float s = a * a;
    s = wsum(s);
    if ((j & 63) == 0) red[j >> 6] = s;
    part[0][j] = a;
  }
  __syncthreads();
  if (dz == 0) {
    float inv = 1.f / fmaxf(sqrtf(red[0] + red[1]), 1e-12f);
    vb[(long)z * kKD + j] = part[0][j] * inv;
  }
}

// ci8[z,d] = sum_l wI[z,l] * VrT[b][d][l]
__global__ void k_ci8(const float* __restrict__ wI, const u16b* __restrict__ VrT,
                      float* __restrict__ ci8) {
  int idx = blockIdx.x * 4 + (threadIdx.x >> 6);
  int z = idx >> 9, d = idx & 511;
  int b = z & 7;
  int lane = threadIdx.x & 63;
  const float* w = wI + (long)z * kL;
  const u16b* vt = VrT + ((long)b * kD + d) * kLp;
  float s = 0.f;
  for (int l = lane; l < kL; l += 64) s += w[l] * bf2f(vt[l]);
  s = wsum(s);
  if (lane == 0) ci8[(long)z * kD + d] = s;
}

// tail partials: v in {a^2, b^2, ab}, a = t1*mk, b = t1 + c3 (bf16 inputs)
__global__ __launch_bounds__(256) void k_ss3b(const u16b* __restrict__ t1b,
                                              const float* __restrict__ mkr,
                                              const u16b* __restrict__ c3b,
                                              float* __restrict__ part) {
  __shared__ float red[4][3];
  long r = blockIdx.x;
  int tid = threadIdx.x;
  long base = r * kD;
  float mk = mkr[r];
  float s0 = 0.f, s1 = 0.f, s2 = 0.f;
#pragma unroll
  for (int j = 0; j < 2; ++j) {
    int d = tid + j * 256;
    float t = bf2f(t1b[base + d]);
    float a = t * mk;
    float bb = t + bf2f(c3b[base + d]);
    s0 += a * a; s1 += bb * bb; s2 += a * bb;
  }
  int w = tid >> 6, lane = tid & 63;
  float t0 = wsum(s0), t1 = wsum(s1), t2 = wsum(s2);
  if (lane == 0) { red[w][0] = t0; red[w][1] = t1; red[w][2] = t2; }
  __syncthreads();
  if (tid < 3)
    part[(long)tid * kR6 + r] = red[0][tid] + red[1][tid] + red[2][tid] + red[3][tid];
}

// per-image coefficients + oi8 (imag analytic)
__global__ __launch_bounds__(512) void k_coef(const float* __restrict__ ssp,
                                              const float* __restrict__ ti8,
                                              const float* __restrict__ ci8,
                                              const float* __restrict__ mki8,
                                              float* __restrict__ coef,
                                              float* __restrict__ oi8) {
  __shared__ float cai[8], cbi[8];
  int img = blockIdx.x;
  int tid = threadIdx.x;
  int b = tid >> 6, lane = tid & 63;
  int z = img * 8 + b;
  float sT = 0.f, sU = 0.f, sV = 0.f;
  for (int d = lane; d < kD; d += 64) {
    float ti = ti8[(long)z * kD + d], ci = ci8[(long)z * kD + d];
    float u = ti + ci;
    sT += ti * ti; sU += u * u; sV += ti * u;
  }
  sT = wsum(sT); sU = wsum(sU); sV = wsum(sV);
  if (lane == 0) {
    float SSa = ssp[z], SSb = ssp[48 + z], SSab = ssp[96 + z];
    float f2 = kScaleN * sqrtf(kCnt / (SSa + 1e-5f));
    float f4 = kScaleN * sqrtf(kCnt / (SSb + 1e-5f));
    float ssz = f2 * f2 * SSa + f4 * f4 * SSb + 2.f * f2 * f4 * SSab;
    float fac = kScaleN * sqrtf(kCnt / (ssz + 1e-5f));
    coef[img * 16 + b] = f2 * fac;
    coef[img * 16 + 8 + b] = f4 * fac;
    float mk = mki8[z];
    float SSai = (float)kHW * mk * mk * sT;
    float SSbi = (float)kHW * sU;
    float SSabi = (float)kHW * mk * sV;
    float f2i = kScaleN * sqrtf(kCnt / (SSai + 1e-5f));
    float f4i = kScaleN * sqrtf(kCnt / (SSbi + 1e-5f));
    float sszi = f2i * f2i * SSai + f4i * f4i * SSbi + 2.f * f2i * f4i * SSabi;
    float faci = kScaleN * sqrtf(kCnt / (sszi + 1e-5f));
    cai[b] = f2i * faci;
    cbi[b] = f4i * faci;
  }
  __syncthreads();
#pragma unroll
  for (int j = 0; j < 8; ++j) {
    int i = tid * 8 + j;
    int bb = i >> 9, d = i & 511;
    int zz = img * 8 + bb;
    float ti = ti8[(long)zz * kD + d], ci = ci8[(long)zz * kD + d];
    oi8[(long)img * 4096 + i] = ti * mki8[zz] * cai[bb] + (ti + ci) * cbi[bb];
  }
}

// oadd[img][o*8+b] = Wc_imag_row(o) . oi8[img*8+b]
__global__ void k_oadd(const float* __restrict__ Wc, const float* __restrict__ oi8,
                       float* __restrict__ oadd) {
  int idx = blockIdx.x * 4 + (threadIdx.x >> 6);
  int img = idx >> 12, rem = idx & 4095;
  int o = rem >> 3, b = rem & 7;
  int lane = threadIdx.x & 63;
  const float* wrow = Wc + (long)o * 1024 + 512;
  const float* oi = oi8 + (long)img * 4096 + (long)b * kD;
  float s = 0.f;
  for (int d = lane; d < kD; d += 64) s += wrow[d] * oi[d];
  s = wsum(s);
  if (lane == 0) oadd[(long)img * 4096 + o * 8 + b] = s;
}

// t2b[r][d] = bf16( t1*mk*ca + (t1+c3)*cb )
__global__ __launch_bounds__(256) void k_zfinb(const u16b* __restrict__ t1b,
                                               const float* __restrict__ mkr,
                                               const u16b* __restrict__ c3b,
                                               const float* __restrict__ coef,
                                               u16b* __restrict__ t2b) {
  long r = blockIdx.x;
  int img = (int)(r / kR), b = (int)(r & 7);
  int tid = threadIdx.x;
  float mk = mkr[r];
  float ca = coef[img * 16 + b], cb = coef[img * 16 + 8 + b];
  long base = r * kD;
#pragma unroll
  for (int j = 0; j < 2; ++j) {
    int d = tid + j * 256;
    float t = bf2f(t1b[base + d]);
    float ov = t * mk * ca + (t + bf2f(c3b[base + d])) * cb;
    t2b[base + d] = f2bf(ov);
  }
}

template <int BM, int BN, bool AF32, bool ACC>
void gemm(hipStream_t s, const void* A, const u16b* B, float* C, int M, int N, int K, int lda,
          int ldb, int ldc, long sA1, long sA2, long sB1, long sB2, long sC1, long sC2,
          int batch, const float* addv = nullptr) {
  dim3 grd(CDIV(N, BN), CDIV(M, BM), batch), blk(256);
  k_gemm<BM, BN, AF32, ACC><<<grd, blk, 0, s>>>(A, B, C, M, N, K, lda, ldb, ldc, sA1, sA2,
                                                sB1, sB2, sC1, sC2, addv);
}

}  // namespace

extern "C" void kernel_launch(void* const* d_in, const int* in_sizes, int n_in, void* d_out,
                              int out_size, void* d_ws, size_t ws_size, hipStream_t stream) {
  (void)in_sizes; (void)n_in; (void)out_size;
  const float* tf  = (const float*)d_in[0];
  const float* sf  = (const float*)d_in[1];
  const float* tl  = (const float*)d_in[2];
  const float* WkE = (const float*)d_in[3];
  const float* bkE = (const float*)d_in[4];
  const float* WkS = (const float*)d_in[5];
  const float* bkS = (const float*)d_in[6];
  const float* WkC = (const float*)d_in[7];
  const float* bkC = (const float*)d_in[8];
  const float* Wc  = (const float*)d_in[9];
  float* out = (float*)d_out;
  float* ws = (float*)d_ws;

  const long LBD = (long)kL * kB * kD;
  const long LBK = (long)kL * kB * kKD;

  long off = 0;
  auto alloc = [&](long n) { long o = off; off += (n + 255) & ~255L; return o; };
  auto allocU = [&](long nu) { return alloc((nu + 1) / 2); };

  long o_seqT = alloc(LBD);
  long o_seqS = alloc(LBD);
  long o_Kr   = alloc(LBK);
  long o_Krb  = allocU(LBK);
  long o_VrT  = allocU((long)kB * kD * kLp);
  long o_tfb  = allocU((long)kNI * kB * kD * kHWp);
  long o_sfb  = allocU((long)kNI * kB * kD * kHWp);
  long o_WkTE = allocU((long)kD * kD);
  long o_WkTS = allocU((long)kKD * kD);
  long o_WkTC = allocU((long)kKD * kD);
  long o_Wcb  = allocU((long)kD * 2 * kD);
  long o_lab  = alloc((long)kL * kB);
  long o_uS   = alloc(kKD);
  long o_vb   = alloc(48L * kKD);
  long o_g    = alloc(48L * kHW);
  long o_wI   = alloc(48L * kL);
  long o_row  = alloc(48L * kD);
  long o_row2 = alloc(48L * 8 * kD);
  long o_mkr  = alloc((long)kR6);
  long o_mki8 = alloc(48);
  long o_ti8  = alloc(48L * kD);
  long o_ci8  = alloc(48L * kD);
  long o_oi8  = alloc(48L * kD);
  long o_oadd = alloc(6L * kD * 8);
  long o_ss   = alloc(512);
  long o_part = alloc(3L * kR6);
  long o_scr  = off;

  // encoder overlay
  long o_Pe  = o_scr;
  long o_Peb = o_Pe + LBD;
  long o_Ae  = o_Peb + LBD / 2;
  long o_Aeb = o_Ae + (long)kB * kL * kL;
  long enc_end = o_Aeb + (8L * kL * kLp + 1) / 2;
  long o_ar  = o_Pe;   // after Pe dead
  long o_mr  = o_Ae;   // after Ae dead

  // decoder overlay (batched over 6 images)
  long p = o_scr;
  auto nxt = [&](long n) { long o = p; p += (n + 255) & ~255L; return o; };
  long o_Ps   = nxt((long)kR6 * kKD);
  long o_Psb  = nxt(((long)kR6 * kKD + 1) / 2);
  long o_Pcb  = nxt(((long)kR6 * kKD + 1) / 2);
  long o_s2rb = nxt(((long)kR6 * kD + 1) / 2);
  long o_t1rb = nxt(((long)kR6 * kD + 1) / 2);
  long o_c3rb = nxt(((long)kR6 * kD + 1) / 2);
  long o_t2b  = nxt(((long)kR6 * kD + 1) / 2);
  long img_end = p;

  long total = (enc_end > img_end ? enc_end : img_end);
  if ((size_t)total * sizeof(float) > ws_size) return;

  float* seqT = ws + o_seqT;
  float* Kr = ws + o_Kr;
  u16b* Krb = (u16b*)(ws + o_Krb);
  u16b* VrT = (u16b*)(ws + o_VrT);
  u16b* tfb = (u16b*)(ws + o_tfb);
  float* lab = ws + o_lab;
  float* uS = ws + o_uS;
  float* vb = ws + o_vb;
  float* g_ = ws + o_g;
  float* wI = ws + o_wI;
  float* row = ws + o_row;
  float* row2 = ws + o_row2;
  float* mkr = ws + o_mkr;
  float* mki8 = ws + o_mki8;
  float* ti8 = ws + o_ti8;
  float* ci8 = ws + o_ci8;
  float* oi8 = ws + o_oi8;
  float* oadd = ws + o_oadd;
  float* ssp = ws + o_ss;
  float* coef = ssp + 160;
  float* part = ws + o_part;
  float* Pe = ws + o_Pe;
  u16b* Peb = (u16b*)(ws + o_Peb);
  float* Ae = ws + o_Ae;
  u16b* Aeb = (u16b*)(ws + o_Aeb);
  float* ar = ws + o_ar;
  float* mr = ws + o_mr;
  u16b* mrb = (u16b*)(ws + o_mr + LBD);
  float* Ps = ws + o_Ps;
  u16b* Psb = (u16b*)(ws + o_Psb);
  u16b* Pcb = (u16b*)(ws + o_Pcb);
  u16b* s2rb = (u16b*)(ws + o_s2rb);
  u16b* t1rb = (u16b*)(ws + o_t1rb);
  u16b* c3rb = (u16b*)(ws + o_c3rb);
  u16b* t2b = (u16b*)(ws + o_t2b);
  u16b* WkTE = (u16b*)(ws + o_WkTE);
  u16b* WkTS = (u16b*)(ws + o_WkTS);
  u16b* WkTC = (u16b*)(ws + o_WkTC);
  u16b* Wcb = (u16b*)(ws + o_Wcb);

  // ---- stage 0 ----
  {
    dim3 grd(CDIV(kHW, 32), CDIV(kD, 32), kNI * kB), blk(32, 8);
    k_toseq<<<grd, blk, 0, stream>>>(tf, seqT);
    k_toseq<<<grd, blk, 0, stream>>>(sf, ws + o_seqS);
  }
  k_cvt2d<<<kNI * kB * kD, 256, 0, stream>>>(tf, tfb, kHW, kHWp);
  k_cvt2d<<<kNI * kB * kD, 256, 0, stream>>>(sf, (u16b*)(ws + o_sfb), kHW, kHWp);
  k_cvt2d<<<kD, 256, 0, stream>>>(Wc, Wcb, 2 * kD, 2 * kD);
  k_tcvt<<<dim3(kD / 32, kD / 32), dim3(32, 8), 0, stream>>>(WkE, WkTE, kD, kD);
  k_tcvt<<<dim3(kKD / 32, kD / 32), dim3(32, 8), 0, stream>>>(WkS, WkTS, kD, kKD);
  k_tcvt<<<dim3(kKD / 32, kD / 32), dim3(32, 8), 0, stream>>>(WkC, WkTC, kD, kKD);
  k_lab<<<CDIV(kNI * kB * kHW, 256), 256, 0, stream>>>(tl, lab);
  k_l2n_vec<<<1, 128, 0, stream>>>(bkS, uS, kKD);

  // ---- encoder (imag branch dead) ----
  gemm<64, 128, true, false>(stream, seqT, WkTE, Pe, kL * kB, kD, kD, kD, kD, kD,
                             0, 0, 0, 0, 0, 0, 1);
  k_bias_l2n<<<kL * kB, 128, 0, stream>>>(Pe, bkE, kD, Peb, nullptr, nullptr, 0);
  gemm<128, 128, false, false>(stream, Peb, Peb, Ae, kL, kL, kD, kB * kD, kB * kD, kL,
                               0, kD, 0, kD, 0, (long)kL * kL, 8);
  k_softmax<<<kB * kL, 256, 0, stream>>>(Ae, kL, kL, Aeb, kLp);
  gemm<64, 128, false, false>(stream, Aeb, tfb, ar, kL, kD, kHW, kLp, kHWp, kB * kD,
                              0, (long)kL * kLp, 0, (long)kD * kHWp, 0, kD, 8);
  gemm<64, 128, false, true>(stream, Aeb + kHW, tfb + (long)kB * kD * kHWp, ar, kL, kD, kHW,
                             kLp, kHWp, kB * kD, 0, (long)kL * kLp, 0, (long)kD * kHWp, 0, kD,
                             8);
  gemm<64, 128, false, true>(stream, Aeb + 2 * kHW, tfb + 2L * kB * kD * kHWp, ar, kL, kD,
                             kHW, kLp, kHWp, kB * kD, 0, (long)kL * kLp, 0, (long)kD * kHWp,
                             0, kD, 8);
  // mem_r = inorm(seqT + ar)
  k_ss1f<<<kL * kB, 256, 0, stream>>>(seqT, ar, part);
  k_ssred<<<dim3(kNI * kB, 1), 512, 0, stream>>>(part, ssp, kL * kB, kNI * kB);
  k_scale1f<<<kL * kB, 256, 0, stream>>>(seqT, ar, mr, ssp, mrb);
  k_vrt<<<dim3(CDIV(kL, 32), kD / 32, kB), dim3(32, 8), 0, stream>>>(mr, lab, VrT);
  gemm<64, 64, false, false>(stream, mrb, WkTC, Kr, kL * kB, kKD, kD, kD, kD, kKD,
                             0, 0, 0, 0, 0, 0, 1);
  k_bias_l2n<<<kL * kB, 128, 0, stream>>>(Kr, bkC, kKD, Krb, nullptr, nullptr, 0);

  // ---- decoder (fully batched over 48 = 6 img x 8 b) ----
  gemm<64, 128, true, false>(stream, seqT, WkTS, Ps, kR6, kKD, kD, kD, kD, kKD,
                             0, 0, 0, 0, 0, 0, 1);
  k_bias_l2n<<<kR6, 128, 0, stream>>>(Ps, bkS, kKD, Psb, uS, g_, kHW);
  k_softmax<<<48, 256, 0, stream>>>(g_, 1, kHW, nullptr, 0);  // wi rows
  k_wrowA<<<dim3(kD / 128, 48, 8), 128, 0, stream>>>(g_, seqT, row2);
  k_wrowB<<<48 * kD / 256, 256, 0, stream>>>(row2, row);
  k_ti8<<<48, 256, 0, stream>>>(row, ti8);
  k_vb<<<48, dim3(128, 4), 0, stream>>>(ti8, WkC, bkC, vb);
  // self-attention flash: s2r
  k_flash<false, true, true><<<dim3(16, 48), 256, 0, stream>>>(Psb, Psb, tfb, nullptr, s2rb,
                                                               nullptr, kHW, kHWp);
  // t1r = inorm(t + s2r) -> bf16
  k_ss1b<<<kR6, 256, 0, stream>>>(seqT, s2rb, part);
  k_ssred<<<dim3(48, 1), 512, 0, stream>>>(part, ssp, kR6, 48);
  k_scale1b<<<kR6, 256, 0, stream>>>(seqT, s2rb, ssp, t1rb);
  // cross projection
  gemm<64, 128, false, false>(stream, t1rb, WkTC, Ps, kR6, kKD, kD, kD, kD, kKD,
                              0, 0, 0, 0, 0, 0, 1);
  k_bias_l2n<<<kR6, 128, 0, stream>>>(Ps, bkC, kKD, Pcb, nullptr, nullptr, 0);
  // imag branch (q-independent)
  k_cwi<<<48, 256, 0, stream>>>(vb, Krb, lab, wI, mki8);
  k_ci8<<<48 * 512 / 4, 256, 0, stream>>>(wI, VrT, ci8);
  // cross flash: c3r + mkr
  k_flash<true, false, false><<<dim3(16, 48), 256, 0, stream>>>(Pcb, Krb, VrT, lab, c3rb,
                                                                mkr, kL, kLp);
  // fused tail
  k_ss3b<<<kR6, 256, 0, stream>>>(t1rb, mkr, c3rb, part);
  k_ssred<<<dim3(48, 3), 512, 0, stream>>>(part, ssp, kR6, 48);
  k_coef<<<6, 512, 0, stream>>>(ssp, ti8, ci8, mki8, coef, oi8);
  k_oadd<<<6 * 4096 / 4, 256, 0, stream>>>(Wc, oi8, oadd);
  k_zfinb<<<kR6, 256, 0, stream>>>(t1rb, mkr, c3rb, coef, t2b);
  // 1x1 conv: batch 48, K=512 real + rank-1 imag epilogue
  gemm<64, 64, false, false>(stream, Wcb, t2b, out, kD, kHW, kD, 2 * kD, kB * kD, kHW,
                             0, 0, (long)kR * kD, kD, 8L * kD * kHW, (long)kD * kHW, 48, oadd);
}

// Round 14
// 835.807 us; speedup vs baseline: 13.8070x; 1.0082x over previous
//
#include <hip/hip_runtime.h>

// ComTransformer on MI355X — round 14: round 12 (proven) + XCD-local flash grid.
//  - k_flash: 1-D grid, b = blockIdx.x & 7 -> all same-b blocks co-locate on one
//    XCD; per-b K/V fits the 4MB XCD L2. Block mapping is a bijection of round
//    12's (qt0, z) decode; per-block work identical (pure scheduling change).
//  - round 13's fixed-max softmax rewrite produced NaN -> reverted to the proven
//    online-softmax flash body from round 12.
// Prior: flash attention (self+cross), fully batched decoder, rank-1 imag
// collapse, pipelined BK=64 bf16 NT GEMM + XCD swizzle, group-sum tail identity.

namespace {

constexpr int kNI = 3;
constexpr int kB  = 8;
constexpr int kD  = 512;
constexpr int kKD = 128;
constexpr int kHW = 484;
constexpr int kL  = kNI * kHW;  // 1452
constexpr int kLp = 1456;
constexpr int kHWp = 488;
constexpr float kTemp = 30.0f;
constexpr float kCnt  = 247808.0f;
constexpr float kScaleN = 0.011048543456039806f;
constexpr int kR = kHW * kB;   // 3872 rows per image
constexpr int kR6 = 6 * kR;    // 23232

#define CDIV(a, b) (((a) + (b) - 1) / (b))

typedef float f32x4 __attribute__((ext_vector_type(4)));
typedef unsigned int u32x4 __attribute__((ext_vector_type(4)));
typedef unsigned short u16b;

__device__ __forceinline__ float wsum(float v) {
#pragma unroll
  for (int o = 32; o; o >>= 1) v += __shfl_down(v, o);
  return v;
}
__device__ __forceinline__ float wmax(float v) {
#pragma unroll
  for (int o = 32; o; o >>= 1) v = fmaxf(v, __shfl_down(v, o));
  return v;
}

__device__ __forceinline__ unsigned pk2bf(float lo, float hi) {
  union { float f; unsigned u; } a, b;
  a.f = lo; b.f = hi;
  unsigned ra = (a.u + 0x7FFFu + ((a.u >> 16) & 1u)) >> 16;
  unsigned rb = (b.u + 0x7FFFu + ((b.u >> 16) & 1u)) >> 16;
  return (ra & 0xFFFFu) | (rb << 16);
}
__device__ __forceinline__ u16b f2bf(float x) {
  union { float f; unsigned u; } a;
  a.f = x;
  return (u16b)((a.u + 0x7FFFu + ((a.u >> 16) & 1u)) >> 16);
}
__device__ __forceinline__ float bf2f(u16b x) {
  union { unsigned u; float f; } a;
  a.u = (unsigned)x << 16;
  return a.f;
}

__device__ __forceinline__ void mfma_bf16(f32x4& d, const u32x4& a, const u32x4& b) {
  asm("v_mfma_f32_16x16x32_bf16 %0, %1, %2, %0" : "+v"(d) : "v"(a), "v"(b));
}

// ---------------- layout transform: [n,b,d,hw] -> seq [(n*hw),b,d] fp32 -----------
__global__ void k_toseq(const float* __restrict__ in, float* __restrict__ out) {
  __shared__ float tile[32][33];
  int nb = blockIdx.z;
  int n = nb / kB, b = nb % kB;
  int p0 = blockIdx.x * 32, d0 = blockIdx.y * 32;
  int tx = threadIdx.x, ty = threadIdx.y;
#pragma unroll
  for (int j = 0; j < 4; ++j) {
    int d = d0 + ty + j * 8, p = p0 + tx;
    if (d < kD && p < kHW) tile[ty + j * 8][tx] = in[(long)nb * kD * kHW + (long)d * kHW + p];
  }
  __syncthreads();
#pragma unroll
  for (int j = 0; j < 4; ++j) {
    int p = p0 + ty + j * 8, d = d0 + tx;
    if (p < kHW && d < kD)
      out[((long)(n * kHW + p) * kB + b) * kD + d] = tile[tx][ty + j * 8];
  }
}

__global__ void k_cvt2d(const float* __restrict__ in, u16b* __restrict__ out, int C, int Cp) {
  long r = blockIdx.x;
  for (int c = threadIdx.x; c < C; c += 256)
    out[r * Cp + c] = f2bf(in[r * (long)C + c]);
}

__global__ void k_tcvt(const float* __restrict__ in, u16b* __restrict__ out, int R, int C) {
  __shared__ float tile[32][33];
  int c0 = blockIdx.x * 32, r0 = blockIdx.y * 32;
  int tx = threadIdx.x, ty = threadIdx.y;
#pragma unroll
  for (int j = 0; j < 4; ++j) {
    int r = r0 + ty + j * 8, c = c0 + tx;
    if (r < R && c < C) tile[ty + j * 8][tx] = in[(long)r * C + c];
  }
  __syncthreads();
#pragma unroll
  for (int j = 0; j < 4; ++j) {
    int c = c0 + ty + j * 8, r = r0 + tx;
    if (r < R && c < C) out[(long)c * R + r] = f2bf(tile[tx][ty + j * 8]);
  }
}

// VrT[b][d][l] = bf16( mr[(l,b),d] * lab[l,b] ), stride kLp
__global__ void k_vrt(const float* __restrict__ mr, const float* __restrict__ lab,
                      u16b* __restrict__ vt) {
  __shared__ float tile[32][33];
  int l0 = blockIdx.x * 32, d0 = blockIdx.y * 32, b = blockIdx.z;
  int tx = threadIdx.x, ty = threadIdx.y;
#pragma unroll
  for (int j = 0; j < 4; ++j) {
    int l = l0 + ty + j * 8;
    if (l < kL)
      tile[ty + j * 8][tx] = mr[((long)l * kB + b) * kD + d0 + tx] * lab[(long)l * kB + b];
  }
  __syncthreads();
#pragma unroll
  for (int j = 0; j < 4; ++j) {
    int d = d0 + ty + j * 8, l = l0 + tx;
    if (l < kL) vt[((long)b * kD + d) * kLp + l] = f2bf(tile[tx][ty + j * 8]);
  }
}

__global__ void k_lab(const float* __restrict__ tl, float* __restrict__ lab) {
  long i = (long)blockIdx.x * 256 + threadIdx.x;
  const long tot = (long)kNI * kB * kHW;
  if (i >= tot) return;
  int p = (int)(i % kHW);
  long t = i / kHW;
  int b = (int)(t % kB);
  int n = (int)(t / kB);
  lab[(long)(n * kHW + p) * kB + b] = tl[i];
}

__global__ void k_l2n_vec(const float* __restrict__ src, float* __restrict__ u, int C) {
  __shared__ float red[2];
  int tid = threadIdx.x;  // 128
  float s = 0.f;
  for (int c = tid; c < C; c += 128) { float x = src[c]; s += x * x; }
  s = wsum(s);
  if ((tid & 63) == 0) red[tid >> 6] = s;
  __syncthreads();
  float inv = 1.f / fmaxf(sqrtf(red[0] + red[1]), 1e-12f);
  for (int c = tid; c < C; c += 128) u[c] = src[c] * inv;
}

// ---------------- pipelined NT bf16 MFMA GEMM (XCD swizzle, 2-stride batch) -------
template <int BM, int BN, bool AF32, bool ACC>
__global__ __launch_bounds__(256) void k_gemm(const void* Ap, const u16b* __restrict__ B,
                                              float* __restrict__ C, int M, int N, int K,
                                              int lda, int ldb, int ldc,
                                              long sA1, long sA2, long sB1, long sB2,
                                              long sC1, long sC2,
                                              const float* __restrict__ addv) {
  const int gx = gridDim.x, gy = gridDim.y;
  const int nwg = gx * gy * gridDim.z;
  const int orig = (blockIdx.z * gy + blockIdx.y) * gx + blockIdx.x;
  const int q = nwg >> 3, rr = nwg & 7, xcd = orig & 7, idx = orig >> 3;
  const int swz = (xcd < rr ? xcd * (q + 1) : rr * (q + 1) + (xcd - rr) * q) + idx;
  const int bx = swz % gx;
  const int tmp = swz / gx;
  const int by = tmp % gy, bz = tmp / gy;
  const int za = bz >> 3, zb = bz & 7;

  const char* Ab = (const char*)Ap + (za * sA1 + zb * sA2) * (AF32 ? 4 : 2);
  const u16b* Bb = B + za * sB1 + zb * sB2;
  C += za * sC1 + zb * sC2;
  constexpr int FM = BM / 32, FN = BN / 32;
  constexpr int NSA = BM * 8 / 256;
  constexpr int NSB = BN * 8 / 256;
  const int m0 = by * BM, n0 = bx * BN;
  const int tid = threadIdx.x;
  const int wid = tid >> 6, lane = tid & 63;
  const int wr = wid >> 1, wc = wid & 1;
  const int fr = lane & 15, fk = lane >> 4;

  __shared__ unsigned AsU[BM * 36];
  __shared__ unsigned BsU[BN * 36];
  f32x4 acc[FM][FN] = {};

  u32x4 pa[NSA];
  float4 paf[AF32 ? 2 * NSA : 1];
  u32x4 pb[NSB];

  auto loadA = [&](int k0) {
#pragma unroll
    for (int i = 0; i < NSA; ++i) {
      int si = tid + i * 256;
      int row = si >> 3, c = si & 7;
      int gr = m0 + row, gk = k0 + c * 8;
      if constexpr (AF32) {
        const float* A = (const float*)Ab;
        if (gr < M && gk + 8 <= K) {
          const float* ap = A + (long)gr * lda + gk;
          paf[2 * i] = *(const float4*)ap;
          paf[2 * i + 1] = *(const float4*)(ap + 4);
        } else {
          float v[8];
#pragma unroll
          for (int j = 0; j < 8; ++j)
            v[j] = (gr < M && gk + j < K) ? A[(long)gr * lda + gk + j] : 0.f;
          paf[2 * i] = make_float4(v[0], v[1], v[2], v[3]);
          paf[2 * i + 1] = make_float4(v[4], v[5], v[6], v[7]);
        }
      } else {
        const u16b* A = (const u16b*)Ab;
        if (gr < M && gk + 8 <= K) {
          pa[i] = *(const u32x4*)(A + (long)gr * lda + gk);
        } else {
          unsigned v[8];
#pragma unroll
          for (int j = 0; j < 8; ++j)
            v[j] = (gr < M && gk + j < K) ? A[(long)gr * lda + gk + j] : 0u;
          pa[i].x = v[0] | (v[1] << 16); pa[i].y = v[2] | (v[3] << 16);
          pa[i].z = v[4] | (v[5] << 16); pa[i].w = v[6] | (v[7] << 16);
        }
      }
    }
  };
  auto loadB = [&](int k0) {
#pragma unroll
    for (int i = 0; i < NSB; ++i) {
      int si = tid + i * 256;
      int row = si >> 3, c = si & 7;
      int gr = n0 + row, gk = k0 + c * 8;
      if (gr < N && gk + 8 <= K) {
        pb[i] = *(const u32x4*)(Bb + (long)gr * ldb + gk);
      } else {
        unsigned v[8];
#pragma unroll
        for (int j = 0; j < 8; ++j)
          v[j] = (gr < N && gk + j < K) ? Bb[(long)gr * ldb + gk + j] : 0u;
        pb[i].x = v[0] | (v[1] << 16); pb[i].y = v[2] | (v[3] << 16);
        pb[i].z = v[4] | (v[5] << 16); pb[i].w = v[6] | (v[7] << 16);
      }
    }
  };
  auto storeAB = [&]() {
#pragma unroll
    for (int i = 0; i < NSA; ++i) {
      int si = tid + i * 256;
      int row = si >> 3, c = si & 7;
      u32x4 w;
      if constexpr (AF32) {
        float4 u0 = paf[2 * i], u1 = paf[2 * i + 1];
        w.x = pk2bf(u0.x, u0.y); w.y = pk2bf(u0.z, u0.w);
        w.z = pk2bf(u1.x, u1.y); w.w = pk2bf(u1.z, u1.w);
      } else {
        w = pa[i];
      }
      *(u32x4*)&AsU[row * 36 + c * 4] = w;
    }
#pragma unroll
    for (int i = 0; i < NSB; ++i) {
      int si = tid + i * 256;
      int row = si >> 3, c = si & 7;
      *(u32x4*)&BsU[row * 36 + c * 4] = pb[i];
    }
  };

  loadA(0);
  loadB(0);
  storeAB();
  __syncthreads();
  const int nk = CDIV(K, 64);
  for (int t = 0; t < nk; ++t) {
    const bool more = (t + 1 < nk);
    if (more) { loadA((t + 1) * 64); loadB((t + 1) * 64); }
#pragma unroll
    for (int kk = 0; kk < 2; ++kk) {
      u32x4 af[FM], bf[FN];
#pragma unroll
      for (int mi = 0; mi < FM; ++mi)
        af[mi] = *(const u32x4*)&AsU[(wr * (BM / 2) + mi * 16 + fr) * 36 + kk * 16 + fk * 4];
#pragma unroll
      for (int ni = 0; ni < FN; ++ni)
        bf[ni] = *(const u32x4*)&BsU[(wc * (BN / 2) + ni * 16 + fr) * 36 + kk * 16 + fk * 4];
#pragma unroll
      for (int mi = 0; mi < FM; ++mi)
#pragma unroll
        for (int ni = 0; ni < FN; ++ni) mfma_bf16(acc[mi][ni], af[mi], bf[ni]);
    }
    if (more) {
      __syncthreads();
      storeAB();
      __syncthreads();
    }
  }
  asm volatile("s_nop 7\n\ts_nop 7" ::: );
#pragma unroll
  for (int mi = 0; mi < FM; ++mi) {
#pragma unroll
    for (int r = 0; r < 4; ++r) {
      int gm = m0 + wr * (BM / 2) + mi * 16 + fk * 4 + r;
      if (gm >= M) continue;
      float av = addv ? addv[(long)za * (kD * 8) + (long)gm * 8 + zb] : 0.f;
#pragma unroll
      for (int ni = 0; ni < FN; ++ni) {
        int gn = n0 + wc * (BN / 2) + ni * 16 + fr;
        if (gn >= N) continue;
        long idx2 = (long)gm * ldc + gn;
        float v = acc[mi][ni][r] + av;
        C[idx2] = ACC ? (C[idx2] + v) : v;
      }
    }
  }
}

// ---------------- flash attention: O = softmax(30 Q K^T) V, optional lab-dot ------
// 1-D grid, b = blockIdx.x & 7 -> same-b blocks co-locate on one XCD (K/V L2 reuse).
template <bool LAB, bool KIMG, bool VZ>
__global__ __launch_bounds__(256) void k_flash(const u16b* __restrict__ Q,
                                               const u16b* __restrict__ K,
                                               const u16b* __restrict__ V,
                                               const float* __restrict__ labv,
                                               u16b* __restrict__ O,
                                               float* __restrict__ mkout,
                                               int S, int ldv) {
  int orig = blockIdx.x;
  int b = orig & 7;
  int t = orig >> 3;
  int qt0 = (t & 15) * 32;
  int img = t >> 4;
  int z = img * 8 + b;
  int tid = threadIdx.x, wid = tid >> 6, lane = tid & 63;
  int fr = lane & 15, fk = lane >> 4;

  __shared__ float Ssm[32 * 65];
  __shared__ unsigned Plds[32 * 36];
  __shared__ float mrun[32], lrun[32], scal[32], mka[32];

  const long qbase = ((long)img * kR + b) * kKD;
  const long kbase = KIMG ? ((long)img * kR + b) * kKD : (long)b * kKD;
  const long vbase = (long)(VZ ? z : b) * kD * ldv;

  u32x4 afq[2][4];
#pragma unroll
  for (int mi = 0; mi < 2; ++mi) {
    int qq = qt0 + mi * 16 + fr;
    if (qq >= kHW) qq = kHW - 1;
#pragma unroll
    for (int kk = 0; kk < 4; ++kk)
      afq[mi][kk] = *(const u32x4*)(Q + qbase + (long)qq * (kB * kKD) + kk * 32 + fk * 8);
  }

  f32x4 oacc[2][8] = {};
  if (tid < 32) { mrun[tid] = -3.0e38f; lrun[tid] = 0.f; mka[tid] = 0.f; }
  __syncthreads();

  int r8 = lane >> 3, i8 = lane & 7;
  int srow = wid * 8 + r8;

  for (int kt = 0; kt < S; kt += 64) {
    // QK^T strip
    {
      f32x4 sacc[2] = {};
      int krow = kt + wid * 16 + fr;
      int kc = krow < S ? krow : S - 1;
      const u16b* kp = K + kbase + (long)kc * (kB * kKD);
#pragma unroll
      for (int kk = 0; kk < 4; ++kk) {
        u32x4 bf = *(const u32x4*)(kp + kk * 32 + fk * 8);
        mfma_bf16(sacc[0], afq[0][kk], bf);
        mfma_bf16(sacc[1], afq[1][kk], bf);
      }
      asm volatile("s_nop 7\n\ts_nop 7" ::: );  // MFMA -> VALU hazard
      if (krow >= S) {
#pragma unroll
        for (int mi = 0; mi < 2; ++mi)
#pragma unroll
          for (int r = 0; r < 4; ++r) sacc[mi][r] = -1.0e30f;
      }
#pragma unroll
      for (int mi = 0; mi < 2; ++mi)
#pragma unroll
        for (int r = 0; r < 4; ++r)
          Ssm[(mi * 16 + fk * 4 + r) * 65 + wid * 16 + fr] = sacc[mi][r];
    }
    __syncthreads();
    // online softmax
    {
      float v[8];
      float mx = -3.0e38f;
#pragma unroll
      for (int j = 0; j < 8; ++j) {
        v[j] = Ssm[srow * 65 + i8 * 8 + j] * kTemp;
        mx = fmaxf(mx, v[j]);
      }
#pragma unroll
      for (int o = 1; o < 8; o <<= 1) mx = fmaxf(mx, __shfl_xor(mx, o));
      float mold = mrun[srow];
      float mnew = fmaxf(mold, mx);
      float p[8], ts = 0.f, lacc = 0.f;
#pragma unroll
      for (int j = 0; j < 8; ++j) {
        p[j] = __expf(v[j] - mnew);
        ts += p[j];
        if (LAB) {
          int kidx = kt + i8 * 8 + j;
          lacc += p[j] * labv[(long)(kidx < S ? kidx : S - 1) * kB + b];
        }
      }
#pragma unroll
      for (int o = 1; o < 8; o <<= 1) ts += __shfl_xor(ts, o);
      if (LAB) {
#pragma unroll
        for (int o = 1; o < 8; o <<= 1) lacc += __shfl_xor(lacc, o);
      }
      u32x4 w0;
      w0.x = pk2bf(p[0], p[1]); w0.y = pk2bf(p[2], p[3]);
      w0.z = pk2bf(p[4], p[5]); w0.w = pk2bf(p[6], p[7]);
      *(u32x4*)&Plds[srow * 36 + i8 * 4] = w0;
      if (i8 == 0) {
        float sc = __expf(mold - mnew);
        mrun[srow] = mnew;
        lrun[srow] = lrun[srow] * sc + ts;
        scal[srow] = sc;
        if (LAB) mka[srow] = mka[srow] * sc + lacc;
      }
    }
    __syncthreads();
    // rescale O (VALU), then PV (MFMA reads oacc as SrcC)
#pragma unroll
    for (int mi = 0; mi < 2; ++mi)
#pragma unroll
      for (int r = 0; r < 4; ++r) {
        float sc = scal[mi * 16 + fk * 4 + r];
#pragma unroll
        for (int n = 0; n < 8; ++n) oacc[mi][n][r] *= sc;
      }
    asm volatile("s_nop 7" ::: );  // VALU write -> MFMA SrcC read hazard
#pragma unroll
    for (int kk = 0; kk < 2; ++kk) {
      u32x4 ap0 = *(const u32x4*)&Plds[fr * 36 + kk * 16 + fk * 4];
      u32x4 ap1 = *(const u32x4*)&Plds[(16 + fr) * 36 + kk * 16 + fk * 4];
#pragma unroll
      for (int n = 0; n < 8; ++n) {
        int d = wid * 128 + n * 16 + fr;
        int kidx = kt + kk * 32 + fk * 8;
        if (kidx > ldv - 8) kidx = ldv - 8;
        u32x4 bv = *(const u32x4*)(V + vbase + (long)d * ldv + kidx);
        mfma_bf16(oacc[0][n], ap0, bv);
        mfma_bf16(oacc[1][n], ap1, bv);
      }
    }
    asm volatile("s_nop 7\n\ts_nop 7" ::: );  // MFMA -> VALU (next rescale/epilogue)
    __syncthreads();
  }
  asm volatile("s_nop 7\n\ts_nop 7" ::: );
#pragma unroll
  for (int mi = 0; mi < 2; ++mi)
#pragma unroll
    for (int r = 0; r < 4; ++r) {
      int qq = mi * 16 + fk * 4 + r;
      int gq = qt0 + qq;
      if (gq >= kHW) continue;
      float invl = 1.0f / lrun[qq];
      long orow = ((long)img * kR + (long)gq * kB + b) * kD;
#pragma unroll
      for (int n = 0; n < 8; ++n)
        O[orow + wid * 128 + n * 16 + fr] = f2bf(oacc[mi][n][r] * invl);
    }
  if (LAB && tid < 32) {
    int gq = qt0 + tid;
    if (gq < kHW) mkout[(long)img * kR + (long)gq * kB + b] = mka[tid] / lrun[tid];
  }
}

// row += bias; l2-normalize; fp32 in place + bf16 mirror; optional g = u.row
__global__ void k_bias_l2n(float* __restrict__ P, const float* __restrict__ bias, int C,
                           u16b* __restrict__ outb, const float* __restrict__ u,
                           float* __restrict__ g, int L) {
  __shared__ float red[2];
  long row = blockIdx.x;
  float* p = P + row * C;
  int tid = threadIdx.x;  // 128
  int nv = C >> 7;
  float v[4];
  float s = 0.f;
#pragma unroll
  for (int i = 0; i < 4; ++i)
    if (i < nv) {
      float x = p[tid + (i << 7)] + bias[tid + (i << 7)];
      v[i] = x;
      s += x * x;
    }
  s = wsum(s);
  if ((tid & 63) == 0) red[tid >> 6] = s;
  __syncthreads();
  float inv = 1.f / fmaxf(sqrtf(red[0] + red[1]), 1e-12f);
  float dot = 0.f;
#pragma unroll
  for (int i = 0; i < 4; ++i)
    if (i < nv) {
      float x = v[i] * inv;
      p[tid + (i << 7)] = x;
      outb[row * C + tid + (i << 7)] = f2bf(x);
      if (u) dot += x * u[tid + (i << 7)];
    }
  if (u) {
    __syncthreads();
    dot = wsum(dot);
    if ((tid & 63) == 0) red[tid >> 6] = dot;
    __syncthreads();
    if (tid == 0) {
      int img = (int)(row / kR);
      int within = (int)(row % kR);
      int qq = within >> 3, b = within & 7;
      g[((long)(img * 8 + b)) * L + qq] = red[0] + red[1];
    }
  }
}

// generic softmax; optional bf16 out at row*ldo
__global__ __launch_bounds__(256) void k_softmax(float* __restrict__ S, int Lq, int Lk,
                                                 u16b* __restrict__ outb, int ldo) {
  __shared__ float sm[1456];
  __shared__ float red[4];
  int row = blockIdx.x;
  float* Sr = S + (long)row * Lk;
  int tid = threadIdx.x;
  float mx = -3.0e38f;
  for (int k = tid; k < Lk; k += 256) {
    float v = Sr[k] * kTemp;
    sm[k] = v;
    mx = fmaxf(mx, v);
  }
  mx = wmax(mx);
  if ((tid & 63) == 0) red[tid >> 6] = mx;
  __syncthreads();
  mx = fmaxf(fmaxf(red[0], red[1]), fmaxf(red[2], red[3]));
  __syncthreads();
  float s = 0.f;
  for (int k = tid; k < Lk; k += 256) {
    float e = __expf(sm[k] - mx);
    sm[k] = e;
    s += e;
  }
  s = wsum(s);
  if ((tid & 63) == 0) red[tid >> 6] = s;
  __syncthreads();
  float inv = 1.0f / (red[0] + red[1] + red[2] + red[3]);
  for (int k = tid; k < Lk; k += 256) {
    float p = sm[k] * inv;
    if (outb) outb[(long)row * ldo + k] = f2bf(p); else Sr[k] = p;
  }
}

// fused cR + softmax + lab-dot: block z in [0,48)
__global__ __launch_bounds__(256) void k_cwi(const float* __restrict__ vb,
                                             const u16b* __restrict__ Krb,
                                             const float* __restrict__ labv,
                                             float* __restrict__ wI,
                                             float* __restrict__ mki8) {
  __shared__ float sm[kL];
  __shared__ float vbl[kKD];
  __shared__ float red[4];
  int z = blockIdx.x, b = z & 7;
  int tid = threadIdx.x;
  if (tid < kKD) vbl[tid] = vb[(long)z * kKD + tid];
  __syncthreads();
  float mx = -3.0e38f;
  for (int k = tid; k < kL; k += 256) {
    const u16b* kp = Krb + ((long)k * kB + b) * kKD;
    float s = 0.f;
    for (int c = 0; c < kKD; c += 8) {
      u32x4 w = *(const u32x4*)(kp + c);
      s += vbl[c] * bf2f((u16b)(w.x & 0xFFFF)) + vbl[c + 1] * bf2f((u16b)(w.x >> 16));
      s += vbl[c + 2] * bf2f((u16b)(w.y & 0xFFFF)) + vbl[c + 3] * bf2f((u16b)(w.y >> 16));
      s += vbl[c + 4] * bf2f((u16b)(w.z & 0xFFFF)) + vbl[c + 5] * bf2f((u16b)(w.z >> 16));
      s += vbl[c + 6] * bf2f((u16b)(w.w & 0xFFFF)) + vbl[c + 7] * bf2f((u16b)(w.w >> 16));
    }
    sm[k] = s * kTemp;
    mx = fmaxf(mx, sm[k]);
  }
  mx = wmax(mx);
  if ((tid & 63) == 0) red[tid >> 6] = mx;
  __syncthreads();
  mx = fmaxf(fmaxf(red[0], red[1]), fmaxf(red[2], red[3]));
  __syncthreads();
  float s = 0.f;
  for (int k = tid; k < kL; k += 256) {
    float e = __expf(sm[k] - mx);
    sm[k] = e;
    s += e;
  }
  s = wsum(s);
  if ((tid & 63) == 0) red[tid >> 6] = s;
  __syncthreads();
  float inv = 1.0f / (red[0] + red[1] + red[2] + red[3]);
  __syncthreads();
  float dot = 0.f;
  for (int k = tid; k < kL; k += 256) {
    float p = sm[k] * inv;
    wI[(long)z * kL + k] = p;
    dot += p * labv[(long)k * kB + b];
  }
  dot = wsum(dot);
  if ((tid & 63) == 0) red[tid >> 6] = dot;
  __syncthreads();
  if (tid == 0) mki8[z] = red[0] + red[1] + red[2] + red[3];
}

// deterministic rank-1 AV, phase A: row2[(z*8+c)*kD+d] = sum_{k in chunk c} g*seq
__global__ void k_wrowA(const float* __restrict__ g, const float* __restrict__ seq,
                        float* __restrict__ row2) {
  int z = blockIdx.y, img = z >> 3, b = z & 7;
  int c = blockIdx.z;
  int d = blockIdx.x * 128 + threadIdx.x;
  int k0 = c * 61;
  int k1 = min(kHW, k0 + 61);
  float s = 0.f;
  for (int k = k0; k < k1; ++k)
    s += g[(long)z * kHW + k] * seq[((long)img * kR + (long)k * kB + b) * kD + d];
  row2[((long)z * 8 + c) * kD + d] = s;
}

// phase B: row[z*kD+d] = sum_c row2 (fixed order)
__global__ void k_wrowB(const float* __restrict__ row2, float* __restrict__ row) {
  int idx = blockIdx.x * 256 + threadIdx.x;  // 0..48*512
  int z = idx >> 9, d = idx & 511;
  float s = 0.f;
#pragma unroll
  for (int c = 0; c < 8; ++c) s += row2[((long)z * 8 + c) * kD + d];
  row[(long)z * kD + d] = s;
}

// fp32 inorm phase 1 (encoder)
__global__ __launch_bounds__(256) void k_ss1f(const float* __restrict__ A,
                                              const float* __restrict__ B2,
                                              float* __restrict__ part) {
  __shared__ float red[4];
  long r = blockIdx.x;
  int tid = threadIdx.x;
  long base = r * kD;
  float z0 = A[base + tid] + B2[base + tid];
  float z1 = A[base + tid + 256] + B2[base + tid + 256];
  float s = z0 * z0 + z1 * z1;
  s = wsum(s);
  if ((tid & 63) == 0) red[tid >> 6] = s;
  __syncthreads();
  if (tid == 0) part[r] = red[0] + red[1] + red[2] + red[3];
}

// fp32 inorm phase 3 (encoder): fp32 out + bf16 mirror
__global__ __launch_bounds__(256) void k_scale1f(const float* __restrict__ A,
                                                 const float* __restrict__ B2,
                                                 float* __restrict__ outp,
                                                 const float* __restrict__ ss,
                                                 u16b* __restrict__ ob) {
  long r = blockIdx.x;
  int l = (int)(r / kB), b = (int)(r % kB);
  int g = (l / kHW) * kB + b;
  int tid = threadIdx.x;
  float fac = kScaleN * sqrtf(kCnt / (ss[g] + 1e-5f));
  long base = r * kD;
  float x0 = (A[base + tid] + B2[base + tid]) * fac;
  float x1 = (A[base + tid + 256] + B2[base + tid + 256]) * fac;
  outp[base + tid] = x0;
  outp[base + tid + 256] = x1;
  ob[base + tid] = f2bf(x0);
  ob[base + tid + 256] = f2bf(x1);
}

// t1 inorm, phase 1 (B2 bf16)
__global__ __launch_bounds__(256) void k_ss1b(const float* __restrict__ A,
                                              const u16b* __restrict__ B2,
                                              float* __restrict__ part) {
  __shared__ float red[4];
  long r = blockIdx.x;
  int tid = threadIdx.x;
  long base = r * kD;
  float z0 = A[base + tid] + bf2f(B2[base + tid]);
  float z1 = A[base + tid + 256] + bf2f(B2[base + tid + 256]);
  float s = z0 * z0 + z1 * z1;
  s = wsum(s);
  if ((tid & 63) == 0) red[tid >> 6] = s;
  __syncthreads();
  if (tid == 0) part[r] = red[0] + red[1] + red[2] + red[3];
}

__global__ void k_ssred(const float* __restrict__ part, float* __restrict__ ss, int R, int NG) {
  __shared__ float red[8];
  int g = blockIdx.x, v = blockIdx.y;
  int n = g / kB, b = g % kB;
  int tid = threadIdx.x;  // 512
  float s = 0.f;
  for (int p = tid; p < kHW; p += 512) s += part[(long)v * R + ((long)(n * kHW + p) * kB + b)];
  s = wsum(s);
  if ((tid & 63) == 0) red[tid >> 6] = s;
  __syncthreads();
  if (tid == 0) {
    float t = 0.f;
#pragma unroll
    for (int i = 0; i < 8; ++i) t += red[i];
    ss[(long)v * NG + g] = t;
  }
}

// t1 inorm, phase 3 -> bf16 only
__global__ __launch_bounds__(256) void k_scale1b(const float* __restrict__ A,
                                                 const u16b* __restrict__ B2,
                                                 const float* __restrict__ ss,
                                                 u16b* __restrict__ ob) {
  long r = blockIdx.x;
  int img = (int)(r / kR), b = (int)(r & 7);
  int g = img * 8 + b;
  int tid = threadIdx.x;
  float fac = kScaleN * sqrtf(kCnt / (ss[g] + 1e-5f));
  long base = r * kD;
  ob[base + tid] = f2bf((A[base + tid] + bf2f(B2[base + tid])) * fac);
  ob[base + tid + 256] = f2bf((A[base + tid + 256] + bf2f(B2[base + tid + 256])) * fac);
}

// ti8[z,d] = row[z,d] * scale(kHW * ||row||^2)
__global__ void k_ti8(const float* __restrict__ row, float* __restrict__ ti8) {
  __shared__ float red[4];
  int z = blockIdx.x;
  int tid = threadIdx.x;  // 256
  float r0 = row[(long)z * kD + tid], r1 = row[(long)z * kD + tid + 256];
  float s = r0 * r0 + r1 * r1;
  s = wsum(s);
  if ((tid & 63) == 0) red[tid >> 6] = s;
  __syncthreads();
  float ssv = (float)kHW * (red[0] + red[1] + red[2] + red[3]);
  float fac = kScaleN * sqrtf(kCnt / (ssv + 1e-5f));
  ti8[(long)z * kD + tid] = r0 * fac;
  ti8[(long)z * kD + tid + 256] = r1 * fac;
}

// vb[z,:] = l2n(ti8_z @ WkC + bkC)
__global__ void k_vb(const float* __restrict__ ti8, const float* __restrict__ Wk,
                     const float* __restrict__ bk, float* __restrict__ vb) {
  __shared__ float part[4][128];
  __shared__ float red[2];
  int z = blockIdx.x;
  int j = threadIdx.x;
  int dz = threadIdx.y;
  const float* row = ti8 + (long)z * kD;
  float acc = 0.f;
  int d0 = dz * 128;
  for (int d = d0; d < d0 + 128; ++d) acc += row[d] * Wk[(long)d * kKD + j];
  part[dz][j] = acc;
  __syncthreads();
  if (dz == 0) {
    float a = part[0][j] + part[1][j] + part[2][j] + part[3][j] + bk[j];
    float s = a * a;
    s = wsum(s);
    if ((j & 63) == 0) red[j >> 6] = s;
    part[0][j] = a;
  }
  __syncthreads();
  if (dz == 0) {
    float inv = 1.f / fmaxf(sqrtf(red[0] + red[1]), 1e-12f);
    vb[(long)z * kKD + j] = part[0][j] * inv;
  }
}

// ci8[z,d] = sum_l wI[z,l] * VrT[b][d][l]
__global__ void k_ci8(const float* __restrict__ wI, const u16b* __restrict__ VrT,
                      float* __restrict__ ci8) {
  int idx = blockIdx.x * 4 + (threadIdx.x >> 6);
  int z = idx >> 9, d = idx & 511;
  int b = z & 7;
  int lane = threadIdx.x & 63;
  const float* w = wI + (long)z * kL;
  const u16b* vt = VrT + ((long)b * kD + d) * kLp;
  float s = 0.f;
  for (int l = lane; l < kL; l += 64) s += w[l] * bf2f(vt[l]);
  s = wsum(s);
  if (lane == 0) ci8[(long)z * kD + d] = s;
}

// tail partials: v in {a^2, b^2, ab}, a = t1*mk, b = t1 + c3 (bf16 inputs)
__global__ __launch_bounds__(256) void k_ss3b(const u16b* __restrict__ t1b,
                                              const float* __restrict__ mkr,
                                              const u16b* __restrict__ c3b,
                                              float* __restrict__ part) {
  __shared__ float red[4][3];
  long r = blockIdx.x;
  int tid = threadIdx.x;
  long base = r * kD;
  float mk = mkr[r];
  float s0 = 0.f, s1 = 0.f, s2 = 0.f;
#pragma unroll
  for (int j = 0; j < 2; ++j) {
    int d = tid + j * 256;
    float t = bf2f(t1b[base + d]);
    float a = t * mk;
    float bb = t + bf2f(c3b[base + d]);
    s0 += a * a; s1 += bb * bb; s2 += a * bb;
  }
  int w = tid >> 6, lane = tid & 63;
  float t0 = wsum(s0), t1 = wsum(s1), t2 = wsum(s2);
  if (lane == 0) { red[w][0] = t0; red[w][1] = t1; red[w][2] = t2; }
  __syncthreads();
  if (tid < 3)
    part[(long)tid * kR6 + r] = red[0][tid] + red[1][tid] + red[2][tid] + red[3][tid];
}

// per-image coefficients + oi8 (imag analytic)
__global__ __launch_bounds__(512) void k_coef(const float* __restrict__ ssp,
                                              const float* __restrict__ ti8,
                                              const float* __restrict__ ci8,
                                              const float* __restrict__ mki8,
                                              float* __restrict__ coef,
                                              float* __restrict__ oi8) {
  __shared__ float cai[8], cbi[8];
  int img = blockIdx.x;
  int tid = threadIdx.x;
  int b = tid >> 6, lane = tid & 63;
  int z = img * 8 + b;
  float sT = 0.f, sU = 0.f, sV = 0.f;
  for (int d = lane; d < kD; d += 64) {
    float ti = ti8[(long)z * kD + d], ci = ci8[(long)z * kD + d];
    float u = ti + ci;
    sT += ti * ti; sU += u * u; sV += ti * u;
  }
  sT = wsum(sT); sU = wsum(sU); sV = wsum(sV);
  if (lane == 0) {
    float SSa = ssp[z], SSb = ssp[48 + z], SSab = ssp[96 + z];
    float f2 = kScaleN * sqrtf(kCnt / (SSa + 1e-5f));
    float f4 = kScaleN * sqrtf(kCnt / (SSb + 1e-5f));
    float ssz = f2 * f2 * SSa + f4 * f4 * SSb + 2.f * f2 * f4 * SSab;
    float fac = kScaleN * sqrtf(kCnt / (ssz + 1e-5f));
    coef[img * 16 + b] = f2 * fac;
    coef[img * 16 + 8 + b] = f4 * fac;
    float mk = mki8[z];
    float SSai = (float)kHW * mk * mk * sT;
    float SSbi = (float)kHW * sU;
    float SSabi = (float)kHW * mk * sV;
    float f2i = kScaleN * sqrtf(kCnt / (SSai + 1e-5f));
    float f4i = kScaleN * sqrtf(kCnt / (SSbi + 1e-5f));
    float sszi = f2i * f2i * SSai + f4i * f4i * SSbi + 2.f * f2i * f4i * SSabi;
    float faci = kScaleN * sqrtf(kCnt / (sszi + 1e-5f));
    cai[b] = f2i * faci;
    cbi[b] = f4i * faci;
  }
  __syncthreads();
#pragma unroll
  for (int j = 0; j < 8; ++j) {
    int i = tid * 8 + j;
    int bb = i >> 9, d = i & 511;
    int zz = img * 8 + bb;
    float ti = ti8[(long)zz * kD + d], ci = ci8[(long)zz * kD + d];
    oi8[(long)img * 4096 + i] = ti * mki8[zz] * cai[bb] + (ti + ci) * cbi[bb];
  }
}

// oadd[img][o*8+b] = Wc_imag_row(o) . oi8[img*8+b]
__global__ void k_oadd(const float* __restrict__ Wc, const float* __restrict__ oi8,
                       float* __restrict__ oadd) {
  int idx = blockIdx.x * 4 + (threadIdx.x >> 6);
  int img = idx >> 12, rem = idx & 4095;
  int o = rem >> 3, b = rem & 7;
  int lane = threadIdx.x & 63;
  const float* wrow = Wc + (long)o * 1024 + 512;
  const float* oi = oi8 + (long)img * 4096 + (long)b * kD;
  float s = 0.f;
  for (int d = lane; d < kD; d += 64) s += wrow[d] * oi[d];
  s = wsum(s);
  if (lane == 0) oadd[(long)img * 4096 + o * 8 + b] = s;
}

// t2b[r][d] = bf16( t1*mk*ca + (t1+c3)*cb )
__global__ __launch_bounds__(256) void k_zfinb(const u16b* __restrict__ t1b,
                                               const float* __restrict__ mkr,
                                               const u16b* __restrict__ c3b,
                                               const float* __restrict__ coef,
                                               u16b* __restrict__ t2b) {
  long r = blockIdx.x;
  int img = (int)(r / kR), b = (int)(r & 7);
  int tid = threadIdx.x;
  float mk = mkr[r];
  float ca = coef[img * 16 + b], cb = coef[img * 16 + 8 + b];
  long base = r * kD;
#pragma unroll
  for (int j = 0; j < 2; ++j) {
    int d = tid + j * 256;
    float t = bf2f(t1b[base + d]);
    float ov = t * mk * ca + (t + bf2f(c3b[base + d])) * cb;
    t2b[base + d] = f2bf(ov);
  }
}

template <int BM, int BN, bool AF32, bool ACC>
void gemm(hipStream_t s, const void* A, const u16b* B, float* C, int M, int N, int K, int lda,
          int ldb, int ldc, long sA1, long sA2, long sB1, long sB2, long sC1, long sC2,
          int batch, const float* addv = nullptr) {
  dim3 grd(CDIV(N, BN), CDIV(M, BM), batch), blk(256);
  k_gemm<BM, BN, AF32, ACC><<<grd, blk, 0, s>>>(A, B, C, M, N, K, lda, ldb, ldc, sA1, sA2,
                                                sB1, sB2, sC1, sC2, addv);
}

}  // namespace

extern "C" void kernel_launch(void* const* d_in, const int* in_sizes, int n_in, void* d_out,
                              int out_size, void* d_ws, size_t ws_size, hipStream_t stream) {
  (void)in_sizes; (void)n_in; (void)out_size;
  const float* tf  = (const float*)d_in[0];
  const float* sf  = (const float*)d_in[1];
  const float* tl  = (const float*)d_in[2];
  const float* WkE = (const float*)d_in[3];
  const float* bkE = (const float*)d_in[4];
  const float* WkS = (const float*)d_in[5];
  const float* bkS = (const float*)d_in[6];
  const float* WkC = (const float*)d_in[7];
  const float* bkC = (const float*)d_in[8];
  const float* Wc  = (const float*)d_in[9];
  float* out = (float*)d_out;
  float* ws = (float*)d_ws;

  const long LBD = (long)kL * kB * kD;
  const long LBK = (long)kL * kB * kKD;

  long off = 0;
  auto alloc = [&](long n) { long o = off; off += (n + 255) & ~255L; return o; };
  auto allocU = [&](long nu) { return alloc((nu + 1) / 2); };

  long o_seqT = alloc(LBD);
  long o_seqS = alloc(LBD);
  long o_Kr   = alloc(LBK);
  long o_Krb  = allocU(LBK);
  long o_VrT  = allocU((long)kB * kD * kLp);
  long o_tfb  = allocU((long)kNI * kB * kD * kHWp);
  long o_sfb  = allocU((long)kNI * kB * kD * kHWp);
  long o_WkTE = allocU((long)kD * kD);
  long o_WkTS = allocU((long)kKD * kD);
  long o_WkTC = allocU((long)kKD * kD);
  long o_Wcb  = allocU((long)kD * 2 * kD);
  long o_lab  = alloc((long)kL * kB);
  long o_uS   = alloc(kKD);
  long o_vb   = alloc(48L * kKD);
  long o_g    = alloc(48L * kHW);
  long o_wI   = alloc(48L * kL);
  long o_row  = alloc(48L * kD);
  long o_row2 = alloc(48L * 8 * kD);
  long o_mkr  = alloc((long)kR6);
  long o_mki8 = alloc(48);
  long o_ti8  = alloc(48L * kD);
  long o_ci8  = alloc(48L * kD);
  long o_oi8  = alloc(48L * kD);
  long o_oadd = alloc(6L * kD * 8);
  long o_ss   = alloc(512);
  long o_part = alloc(3L * kR6);
  long o_scr  = off;

  // encoder overlay
  long o_Pe  = o_scr;
  long o_Peb = o_Pe + LBD;
  long o_Ae  = o_Peb + LBD / 2;
  long o_Aeb = o_Ae + (long)kB * kL * kL;
  long enc_end = o_Aeb + (8L * kL * kLp + 1) / 2;
  long o_ar  = o_Pe;   // after Pe dead
  long o_mr  = o_Ae;   // after Ae dead

  // decoder overlay (batched over 6 images)
  long p = o_scr;
  auto nxt = [&](long n) { long o = p; p += (n + 255) & ~255L; return o; };
  long o_Ps   = nxt((long)kR6 * kKD);
  long o_Psb  = nxt(((long)kR6 * kKD + 1) / 2);
  long o_Pcb  = nxt(((long)kR6 * kKD + 1) / 2);
  long o_s2rb = nxt(((long)kR6 * kD + 1) / 2);
  long o_t1rb = nxt(((long)kR6 * kD + 1) / 2);
  long o_c3rb = nxt(((long)kR6 * kD + 1) / 2);
  long o_t2b  = nxt(((long)kR6 * kD + 1) / 2);
  long img_end = p;

  long total = (enc_end > img_end ? enc_end : img_end);
  if ((size_t)total * sizeof(float) > ws_size) return;

  float* seqT = ws + o_seqT;
  float* Kr = ws + o_Kr;
  u16b* Krb = (u16b*)(ws + o_Krb);
  u16b* VrT = (u16b*)(ws + o_VrT);
  u16b* tfb = (u16b*)(ws + o_tfb);
  float* lab = ws + o_lab;
  float* uS = ws + o_uS;
  float* vb = ws + o_vb;
  float* g_ = ws + o_g;
  float* wI = ws + o_wI;
  float* row = ws + o_row;
  float* row2 = ws + o_row2;
  float* mkr = ws + o_mkr;
  float* mki8 = ws + o_mki8;
  float* ti8 = ws + o_ti8;
  float* ci8 = ws + o_ci8;
  float* oi8 = ws + o_oi8;
  float* oadd = ws + o_oadd;
  float* ssp = ws + o_ss;
  float* coef = ssp + 160;
  float* part = ws + o_part;
  float* Pe = ws + o_Pe;
  u16b* Peb = (u16b*)(ws + o_Peb);
  float* Ae = ws + o_Ae;
  u16b* Aeb = (u16b*)(ws + o_Aeb);
  float* ar = ws + o_ar;
  float* mr = ws + o_mr;
  u16b* mrb = (u16b*)(ws + o_mr + LBD);
  float* Ps = ws + o_Ps;
  u16b* Psb = (u16b*)(ws + o_Psb);
  u16b* Pcb = (u16b*)(ws + o_Pcb);
  u16b* s2rb = (u16b*)(ws + o_s2rb);
  u16b* t1rb = (u16b*)(ws + o_t1rb);
  u16b* c3rb = (u16b*)(ws + o_c3rb);
  u16b* t2b = (u16b*)(ws + o_t2b);
  u16b* WkTE = (u16b*)(ws + o_WkTE);
  u16b* WkTS = (u16b*)(ws + o_WkTS);
  u16b* WkTC = (u16b*)(ws + o_WkTC);
  u16b* Wcb = (u16b*)(ws + o_Wcb);

  // ---- stage 0 ----
  {
    dim3 grd(CDIV(kHW, 32), CDIV(kD, 32), kNI * kB), blk(32, 8);
    k_toseq<<<grd, blk, 0, stream>>>(tf, seqT);
    k_toseq<<<grd, blk, 0, stream>>>(sf, ws + o_seqS);
  }
  k_cvt2d<<<kNI * kB * kD, 256, 0, stream>>>(tf, tfb, kHW, kHWp);
  k_cvt2d<<<kNI * kB * kD, 256, 0, stream>>>(sf, (u16b*)(ws + o_sfb), kHW, kHWp);
  k_cvt2d<<<kD, 256, 0, stream>>>(Wc, Wcb, 2 * kD, 2 * kD);
  k_tcvt<<<dim3(kD / 32, kD / 32), dim3(32, 8), 0, stream>>>(WkE, WkTE, kD, kD);
  k_tcvt<<<dim3(kKD / 32, kD / 32), dim3(32, 8), 0, stream>>>(WkS, WkTS, kD, kKD);
  k_tcvt<<<dim3(kKD / 32, kD / 32), dim3(32, 8), 0, stream>>>(WkC, WkTC, kD, kKD);
  k_lab<<<CDIV(kNI * kB * kHW, 256), 256, 0, stream>>>(tl, lab);
  k_l2n_vec<<<1, 128, 0, stream>>>(bkS, uS, kKD);

  // ---- encoder (imag branch dead) ----
  gemm<64, 128, true, false>(stream, seqT, WkTE, Pe, kL * kB, kD, kD, kD, kD, kD,
                             0, 0, 0, 0, 0, 0, 1);
  k_bias_l2n<<<kL * kB, 128, 0, stream>>>(Pe, bkE, kD, Peb, nullptr, nullptr, 0);
  gemm<128, 128, false, false>(stream, Peb, Peb, Ae, kL, kL, kD, kB * kD, kB * kD, kL,
                               0, kD, 0, kD, 0, (long)kL * kL, 8);
  k_softmax<<<kB * kL, 256, 0, stream>>>(Ae, kL, kL, Aeb, kLp);
  gemm<64, 128, false, false>(stream, Aeb, tfb, ar, kL, kD, kHW, kLp, kHWp, kB * kD,
                              0, (long)kL * kLp, 0, (long)kD * kHWp, 0, kD, 8);
  gemm<64, 128, false, true>(stream, Aeb + kHW, tfb + (long)kB * kD * kHWp, ar, kL, kD, kHW,
                             kLp, kHWp, kB * kD, 0, (long)kL * kLp, 0, (long)kD * kHWp, 0, kD,
                             8);
  gemm<64, 128, false, true>(stream, Aeb + 2 * kHW, tfb + 2L * kB * kD * kHWp, ar, kL, kD,
                             kHW, kLp, kHWp, kB * kD, 0, (long)kL * kLp, 0, (long)kD * kHWp,
                             0, kD, 8);
  // mem_r = inorm(seqT + ar)
  k_ss1f<<<kL * kB, 256, 0, stream>>>(seqT, ar, part);
  k_ssred<<<dim3(kNI * kB, 1), 512, 0, stream>>>(part, ssp, kL * kB, kNI * kB);
  k_scale1f<<<kL * kB, 256, 0, stream>>>(seqT, ar, mr, ssp, mrb);
  k_vrt<<<dim3(CDIV(kL, 32), kD / 32, kB), dim3(32, 8), 0, stream>>>(mr, lab, VrT);
  gemm<64, 64, false, false>(stream, mrb, WkTC, Kr, kL * kB, kKD, kD, kD, kD, kKD,
                             0, 0, 0, 0, 0, 0, 1);
  k_bias_l2n<<<kL * kB, 128, 0, stream>>>(Kr, bkC, kKD, Krb, nullptr, nullptr, 0);

  // ---- decoder (fully batched over 48 = 6 img x 8 b) ----
  gemm<64, 128, true, false>(stream, seqT, WkTS, Ps, kR6, kKD, kD, kD, kD, kKD,
                             0, 0, 0, 0, 0, 0, 1);
  k_bias_l2n<<<kR6, 128, 0, stream>>>(Ps, bkS, kKD, Psb, uS, g_, kHW);
  k_softmax<<<48, 256, 0, stream>>>(g_, 1, kHW, nullptr, 0);  // wi rows
  k_wrowA<<<dim3(kD / 128, 48, 8), 128, 0, stream>>>(g_, seqT, row2);
  k_wrowB<<<48 * kD / 256, 256, 0, stream>>>(row2, row);
  k_ti8<<<48, 256, 0, stream>>>(row, ti8);
  k_vb<<<48, dim3(128, 4), 0, stream>>>(ti8, WkC, bkC, vb);
  // self-attention flash: s2r
  k_flash<false, true, true><<<768, 256, 0, stream>>>(Psb, Psb, tfb, nullptr, s2rb,
                                                      nullptr, kHW, kHWp);
  // t1r = inorm(t + s2r) -> bf16
  k_ss1b<<<kR6, 256, 0, stream>>>(seqT, s2rb, part);
  k_ssred<<<dim3(48, 1), 512, 0, stream>>>(part, ssp, kR6, 48);
  k_scale1b<<<kR6, 256, 0, stream>>>(seqT, s2rb, ssp, t1rb);
  // cross projection
  gemm<64, 128, false, false>(stream, t1rb, WkTC, Ps, kR6, kKD, kD, kD, kD, kKD,
                              0, 0, 0, 0, 0, 0, 1);
  k_bias_l2n<<<kR6, 128, 0, stream>>>(Ps, bkC, kKD, Pcb, nullptr, nullptr, 0);
  // imag branch (q-independent)
  k_cwi<<<48, 256, 0, stream>>>(vb, Krb, lab, wI, mki8);
  k_ci8<<<48 * 512 / 4, 256, 0, stream>>>(wI, VrT, ci8);
  // cross flash: c3r + mkr
  k_flash<true, false, false><<<768, 256, 0, stream>>>(Pcb, Krb, VrT, lab, c3rb,
                                                       mkr, kL, kLp);
  // fused tail
  k_ss3b<<<kR6, 256, 0, stream>>>(t1rb, mkr, c3rb, part);
  k_ssred<<<dim3(48, 3), 512, 0, stream>>>(part, ssp, kR6, 48);
  k_coef<<<6, 512, 0, stream>>>(ssp, ti8, ci8, mki8, coef, oi8);
  k_oadd<<<6 * 4096 / 4, 256, 0, stream>>>(Wc, oi8, oadd);
  k_zfinb<<<kR6, 256, 0, stream>>>(t1rb, mkr, c3rb, coef, t2b);
  // 1x1 conv: batch 48, K=512 real + rank-1 imag epilogue
  gemm<64, 64, false, false>(stream, Wcb, t2b, out, kD, kHW, kD, 2 * kD, kB * kD, kHW,
                             0, 0, (long)kR * kD, kD, 8L * kD * kHW, (long)kD * kHW, 48, oadd);
}

// Round 15
// 808.717 us; speedup vs baseline: 14.2695x; 1.0335x over previous
//
#include <hip/hip_runtime.h>

// ComTransformer on MI355X — round 15: software-pipelined flash (T14).
//  - k_flash: V-tile prefetched into REGISTERS right after QK^T issue (latency
//    hidden under mask+softmax+2 barriers); K double-buffered across tiles.
//    Same addresses/order as round 14 -> numerics identical.
//  - keeps XCD-local 1-D flash grid (b = blockIdx.x & 7).
// Prior: flash attention (self+cross), fully batched decoder, rank-1 imag
// collapse, pipelined BK=64 bf16 NT GEMM + XCD swizzle, group-sum tail identity.

namespace {

constexpr int kNI = 3;
constexpr int kB  = 8;
constexpr int kD  = 512;
constexpr int kKD = 128;
constexpr int kHW = 484;
constexpr int kL  = kNI * kHW;  // 1452
constexpr int kLp = 1456;
constexpr int kHWp = 488;
constexpr float kTemp = 30.0f;
constexpr float kCnt  = 247808.0f;
constexpr float kScaleN = 0.011048543456039806f;
constexpr int kR = kHW * kB;   // 3872 rows per image
constexpr int kR6 = 6 * kR;    // 23232

#define CDIV(a, b) (((a) + (b) - 1) / (b))

typedef float f32x4 __attribute__((ext_vector_type(4)));
typedef unsigned int u32x4 __attribute__((ext_vector_type(4)));
typedef unsigned short u16b;

__device__ __forceinline__ float wsum(float v) {
#pragma unroll
  for (int o = 32; o; o >>= 1) v += __shfl_down(v, o);
  return v;
}
__device__ __forceinline__ float wmax(float v) {
#pragma unroll
  for (int o = 32; o; o >>= 1) v = fmaxf(v, __shfl_down(v, o));
  return v;
}

__device__ __forceinline__ unsigned pk2bf(float lo, float hi) {
  union { float f; unsigned u; } a, b;
  a.f = lo; b.f = hi;
  unsigned ra = (a.u + 0x7FFFu + ((a.u >> 16) & 1u)) >> 16;
  unsigned rb = (b.u + 0x7FFFu + ((b.u >> 16) & 1u)) >> 16;
  return (ra & 0xFFFFu) | (rb << 16);
}
__device__ __forceinline__ u16b f2bf(float x) {
  union { float f; unsigned u; } a;
  a.f = x;
  return (u16b)((a.u + 0x7FFFu + ((a.u >> 16) & 1u)) >> 16);
}
__device__ __forceinline__ float bf2f(u16b x) {
  union { unsigned u; float f; } a;
  a.u = (unsigned)x << 16;
  return a.f;
}

__device__ __forceinline__ void mfma_bf16(f32x4& d, const u32x4& a, const u32x4& b) {
  asm("v_mfma_f32_16x16x32_bf16 %0, %1, %2, %0" : "+v"(d) : "v"(a), "v"(b));
}

// ---------------- layout transform: [n,b,d,hw] -> seq [(n*hw),b,d] fp32 -----------
__global__ void k_toseq(const float* __restrict__ in, float* __restrict__ out) {
  __shared__ float tile[32][33];
  int nb = blockIdx.z;
  int n = nb / kB, b = nb % kB;
  int p0 = blockIdx.x * 32, d0 = blockIdx.y * 32;
  int tx = threadIdx.x, ty = threadIdx.y;
#pragma unroll
  for (int j = 0; j < 4; ++j) {
    int d = d0 + ty + j * 8, p = p0 + tx;
    if (d < kD && p < kHW) tile[ty + j * 8][tx] = in[(long)nb * kD * kHW + (long)d * kHW + p];
  }
  __syncthreads();
#pragma unroll
  for (int j = 0; j < 4; ++j) {
    int p = p0 + ty + j * 8, d = d0 + tx;
    if (p < kHW && d < kD)
      out[((long)(n * kHW + p) * kB + b) * kD + d] = tile[tx][ty + j * 8];
  }
}

__global__ void k_cvt2d(const float* __restrict__ in, u16b* __restrict__ out, int C, int Cp) {
  long r = blockIdx.x;
  for (int c = threadIdx.x; c < C; c += 256)
    out[r * Cp + c] = f2bf(in[r * (long)C + c]);
}

__global__ void k_tcvt(const float* __restrict__ in, u16b* __restrict__ out, int R, int C) {
  __shared__ float tile[32][33];
  int c0 = blockIdx.x * 32, r0 = blockIdx.y * 32;
  int tx = threadIdx.x, ty = threadIdx.y;
#pragma unroll
  for (int j = 0; j < 4; ++j) {
    int r = r0 + ty + j * 8, c = c0 + tx;
    if (r < R && c < C) tile[ty + j * 8][tx] = in[(long)r * C + c];
  }
  __syncthreads();
#pragma unroll
  for (int j = 0; j < 4; ++j) {
    int c = c0 + ty + j * 8, r = r0 + tx;
    if (r < R && c < C) out[(long)c * R + r] = f2bf(tile[tx][ty + j * 8]);
  }
}

// VrT[b][d][l] = bf16( mr[(l,b),d] * lab[l,b] ), stride kLp
__global__ void k_vrt(const float* __restrict__ mr, const float* __restrict__ lab,
                      u16b* __restrict__ vt) {
  __shared__ float tile[32][33];
  int l0 = blockIdx.x * 32, d0 = blockIdx.y * 32, b = blockIdx.z;
  int tx = threadIdx.x, ty = threadIdx.y;
#pragma unroll
  for (int j = 0; j < 4; ++j) {
    int l = l0 + ty + j * 8;
    if (l < kL)
      tile[ty + j * 8][tx] = mr[((long)l * kB + b) * kD + d0 + tx] * lab[(long)l * kB + b];
  }
  __syncthreads();
#pragma unroll
  for (int j = 0; j < 4; ++j) {
    int d = d0 + ty + j * 8, l = l0 + tx;
    if (l < kL) vt[((long)b * kD + d) * kLp + l] = f2bf(tile[tx][ty + j * 8]);
  }
}

__global__ void k_lab(const float* __restrict__ tl, float* __restrict__ lab) {
  long i = (long)blockIdx.x * 256 + threadIdx.x;
  const long tot = (long)kNI * kB * kHW;
  if (i >= tot) return;
  int p = (int)(i % kHW);
  long t = i / kHW;
  int b = (int)(t % kB);
  int n = (int)(t / kB);
  lab[(long)(n * kHW + p) * kB + b] = tl[i];
}

__global__ void k_l2n_vec(const float* __restrict__ src, float* __restrict__ u, int C) {
  __shared__ float red[2];
  int tid = threadIdx.x;  // 128
  float s = 0.f;
  for (int c = tid; c < C; c += 128) { float x = src[c]; s += x * x; }
  s = wsum(s);
  if ((tid & 63) == 0) red[tid >> 6] = s;
  __syncthreads();
  float inv = 1.f / fmaxf(sqrtf(red[0] + red[1]), 1e-12f);
  for (int c = tid; c < C; c += 128) u[c] = src[c] * inv;
}

// ---------------- pipelined NT bf16 MFMA GEMM (XCD swizzle, 2-stride batch) -------
template <int BM, int BN, bool AF32, bool ACC>
__global__ __launch_bounds__(256) void k_gemm(const void* Ap, const u16b* __restrict__ B,
                                              float* __restrict__ C, int M, int N, int K,
                                              int lda, int ldb, int ldc,
                                              long sA1, long sA2, long sB1, long sB2,
                                              long sC1, long sC2,
                                              const float* __restrict__ addv) {
  const int gx = gridDim.x, gy = gridDim.y;
  const int nwg = gx * gy * gridDim.z;
  const int orig = (blockIdx.z * gy + blockIdx.y) * gx + blockIdx.x;
  const int q = nwg >> 3, rr = nwg & 7, xcd = orig & 7, idx = orig >> 3;
  const int swz = (xcd < rr ? xcd * (q + 1) : rr * (q + 1) + (xcd - rr) * q) + idx;
  const int bx = swz % gx;
  const int tmp = swz / gx;
  const int by = tmp % gy, bz = tmp / gy;
  const int za = bz >> 3, zb = bz & 7;

  const char* Ab = (const char*)Ap + (za * sA1 + zb * sA2) * (AF32 ? 4 : 2);
  const u16b* Bb = B + za * sB1 + zb * sB2;
  C += za * sC1 + zb * sC2;
  constexpr int FM = BM / 32, FN = BN / 32;
  constexpr int NSA = BM * 8 / 256;
  constexpr int NSB = BN * 8 / 256;
  const int m0 = by * BM, n0 = bx * BN;
  const int tid = threadIdx.x;
  const int wid = tid >> 6, lane = tid & 63;
  const int wr = wid >> 1, wc = wid & 1;
  const int fr = lane & 15, fk = lane >> 4;

  __shared__ unsigned AsU[BM * 36];
  __shared__ unsigned BsU[BN * 36];
  f32x4 acc[FM][FN] = {};

  u32x4 pa[NSA];
  float4 paf[AF32 ? 2 * NSA : 1];
  u32x4 pb[NSB];

  auto loadA = [&](int k0) {
#pragma unroll
    for (int i = 0; i < NSA; ++i) {
      int si = tid + i * 256;
      int row = si >> 3, c = si & 7;
      int gr = m0 + row, gk = k0 + c * 8;
      if constexpr (AF32) {
        const float* A = (const float*)Ab;
        if (gr < M && gk + 8 <= K) {
          const float* ap = A + (long)gr * lda + gk;
          paf[2 * i] = *(const float4*)ap;
          paf[2 * i + 1] = *(const float4*)(ap + 4);
        } else {
          float v[8];
#pragma unroll
          for (int j = 0; j < 8; ++j)
            v[j] = (gr < M && gk + j < K) ? A[(long)gr * lda + gk + j] : 0.f;
          paf[2 * i] = make_float4(v[0], v[1], v[2], v[3]);
          paf[2 * i + 1] = make_float4(v[4], v[5], v[6], v[7]);
        }
      } else {
        const u16b* A = (const u16b*)Ab;
        if (gr < M && gk + 8 <= K) {
          pa[i] = *(const u32x4*)(A + (long)gr * lda + gk);
        } else {
          unsigned v[8];
#pragma unroll
          for (int j = 0; j < 8; ++j)
            v[j] = (gr < M && gk + j < K) ? A[(long)gr * lda + gk + j] : 0u;
          pa[i].x = v[0] | (v[1] << 16); pa[i].y = v[2] | (v[3] << 16);
          pa[i].z = v[4] | (v[5] << 16); pa[i].w = v[6] | (v[7] << 16);
        }
      }
    }
  };
  auto loadB = [&](int k0) {
#pragma unroll
    for (int i = 0; i < NSB; ++i) {
      int si = tid + i * 256;
      int row = si >> 3, c = si & 7;
      int gr = n0 + row, gk = k0 + c * 8;
      if (gr < N && gk + 8 <= K) {
        pb[i] = *(const u32x4*)(Bb + (long)gr * ldb + gk);
      } else {
        unsigned v[8];
#pragma unroll
        for (int j = 0; j < 8; ++j)
          v[j] = (gr < N && gk + j < K) ? Bb[(long)gr * ldb + gk + j] : 0u;
        pb[i].x = v[0] | (v[1] << 16); pb[i].y = v[2] | (v[3] << 16);
        pb[i].z = v[4] | (v[5] << 16); pb[i].w = v[6] | (v[7] << 16);
      }
    }
  };
  auto storeAB = [&]() {
#pragma unroll
    for (int i = 0; i < NSA; ++i) {
      int si = tid + i * 256;
      int row = si >> 3, c = si & 7;
      u32x4 w;
      if constexpr (AF32) {
        float4 u0 = paf[2 * i], u1 = paf[2 * i + 1];
        w.x = pk2bf(u0.x, u0.y); w.y = pk2bf(u0.z, u0.w);
        w.z = pk2bf(u1.x, u1.y); w.w = pk2bf(u1.z, u1.w);
      } else {
        w = pa[i];
      }
      *(u32x4*)&AsU[row * 36 + c * 4] = w;
    }
#pragma unroll
    for (int i = 0; i < NSB; ++i) {
      int si = tid + i * 256;
      int row = si >> 3, c = si & 7;
      *(u32x4*)&BsU[row * 36 + c * 4] = pb[i];
    }
  };

  loadA(0);
  loadB(0);
  storeAB();
  __syncthreads();
  const int nk = CDIV(K, 64);
  for (int t = 0; t < nk; ++t) {
    const bool more = (t + 1 < nk);
    if (more) { loadA((t + 1) * 64); loadB((t + 1) * 64); }
#pragma unroll
    for (int kk = 0; kk < 2; ++kk) {
      u32x4 af[FM], bf[FN];
#pragma unroll
      for (int mi = 0; mi < FM; ++mi)
        af[mi] = *(const u32x4*)&AsU[(wr * (BM / 2) + mi * 16 + fr) * 36 + kk * 16 + fk * 4];
#pragma unroll
      for (int ni = 0; ni < FN; ++ni)
        bf[ni] = *(const u32x4*)&BsU[(wc * (BN / 2) + ni * 16 + fr) * 36 + kk * 16 + fk * 4];
#pragma unroll
      for (int mi = 0; mi < FM; ++mi)
#pragma unroll
        for (int ni = 0; ni < FN; ++ni) mfma_bf16(acc[mi][ni], af[mi], bf[ni]);
    }
    if (more) {
      __syncthreads();
      storeAB();
      __syncthreads();
    }
  }
  asm volatile("s_nop 7\n\ts_nop 7" ::: );
#pragma unroll
  for (int mi = 0; mi < FM; ++mi) {
#pragma unroll
    for (int r = 0; r < 4; ++r) {
      int gm = m0 + wr * (BM / 2) + mi * 16 + fk * 4 + r;
      if (gm >= M) continue;
      float av = addv ? addv[(long)za * (kD * 8) + (long)gm * 8 + zb] : 0.f;
#pragma unroll
      for (int ni = 0; ni < FN; ++ni) {
        int gn = n0 + wc * (BN / 2) + ni * 16 + fr;
        if (gn >= N) continue;
        long idx2 = (long)gm * ldc + gn;
        float v = acc[mi][ni][r] + av;
        C[idx2] = ACC ? (C[idx2] + v) : v;
      }
    }
  }
}

// ---------------- flash attention: O = softmax(30 Q K^T) V, optional lab-dot ------
// 1-D grid, b = blockIdx.x & 7 (XCD-local K/V). Software-pipelined: V prefetched
// into registers after QK^T issue; K double-buffered across tiles.
template <bool LAB, bool KIMG, bool VZ>
__global__ __launch_bounds__(256) void k_flash(const u16b* __restrict__ Q,
                                               const u16b* __restrict__ K,
                                               const u16b* __restrict__ V,
                                               const float* __restrict__ labv,
                                               u16b* __restrict__ O,
                                               float* __restrict__ mkout,
                                               int S, int ldv) {
  int orig = blockIdx.x;
  int b = orig & 7;
  int t = orig >> 3;
  int qt0 = (t & 15) * 32;
  int img = t >> 4;
  int z = img * 8 + b;
  int tid = threadIdx.x, wid = tid >> 6, lane = tid & 63;
  int fr = lane & 15, fk = lane >> 4;

  __shared__ float Ssm[32 * 65];
  __shared__ unsigned Plds[32 * 36];
  __shared__ float mrun[32], lrun[32], scal[32], mka[32];

  const long qbase = ((long)img * kR + b) * kKD;
  const long kbase = KIMG ? ((long)img * kR + b) * kKD : (long)b * kKD;
  const long vbase = (long)(VZ ? z : b) * kD * ldv;

  u32x4 afq[2][4];
#pragma unroll
  for (int mi = 0; mi < 2; ++mi) {
    int qq = qt0 + mi * 16 + fr;
    if (qq >= kHW) qq = kHW - 1;
#pragma unroll
    for (int kk = 0; kk < 4; ++kk)
      afq[mi][kk] = *(const u32x4*)(Q + qbase + (long)qq * (kB * kKD) + kk * 32 + fk * 8);
  }

  f32x4 oacc[2][8] = {};
  if (tid < 32) { mrun[tid] = -3.0e38f; lrun[tid] = 0.f; mka[tid] = 0.f; }
  __syncthreads();

  int r8 = lane >> 3, i8 = lane & 7;
  int srow = wid * 8 + r8;

  // K double-buffer: load tile 0
  u32x4 kcur[4], knxt[4];
  {
    int krow = wid * 16 + fr;
    int kc = krow < S ? krow : S - 1;
    const u16b* kp = K + kbase + (long)kc * (kB * kKD);
#pragma unroll
    for (int kk = 0; kk < 4; ++kk) kcur[kk] = *(const u32x4*)(kp + kk * 32 + fk * 8);
  }

  for (int kt = 0; kt < S; kt += 64) {
    // QK^T strip (uses kcur)
    f32x4 sacc[2] = {};
#pragma unroll
    for (int kk = 0; kk < 4; ++kk) {
      mfma_bf16(sacc[0], afq[0][kk], kcur[kk]);
      mfma_bf16(sacc[1], afq[1][kk], kcur[kk]);
    }
    // prefetch THIS tile's V into registers (consumed after 2 barriers -> latency hidden)
    u32x4 vreg[2][8];
#pragma unroll
    for (int kk = 0; kk < 2; ++kk) {
      int kidx = kt + kk * 32 + fk * 8;
      if (kidx > ldv - 8) kidx = ldv - 8;
#pragma unroll
      for (int n = 0; n < 8; ++n) {
        int d = wid * 128 + n * 16 + fr;
        vreg[kk][n] = *(const u32x4*)(V + vbase + (long)d * ldv + kidx);
      }
    }
    // prefetch NEXT tile's K
    const bool more = (kt + 64 < S);
    if (more) {
      int krow2 = kt + 64 + wid * 16 + fr;
      int kc2 = krow2 < S ? krow2 : S - 1;
      const u16b* kp2 = K + kbase + (long)kc2 * (kB * kKD);
#pragma unroll
      for (int kk = 0; kk < 4; ++kk) knxt[kk] = *(const u32x4*)(kp2 + kk * 32 + fk * 8);
    }
    asm volatile("s_nop 7\n\ts_nop 7" ::: );  // MFMA -> VALU hazard
    {
      int krow = kt + wid * 16 + fr;
      if (krow >= S) {
#pragma unroll
        for (int mi = 0; mi < 2; ++mi)
#pragma unroll
          for (int r = 0; r < 4; ++r) sacc[mi][r] = -1.0e30f;
      }
#pragma unroll
      for (int mi = 0; mi < 2; ++mi)
#pragma unroll
        for (int r = 0; r < 4; ++r)
          Ssm[(mi * 16 + fk * 4 + r) * 65 + wid * 16 + fr] = sacc[mi][r];
    }
    __syncthreads();
    // online softmax
    {
      float v[8];
      float mx = -3.0e38f;
#pragma unroll
      for (int j = 0; j < 8; ++j) {
        v[j] = Ssm[srow * 65 + i8 * 8 + j] * kTemp;
        mx = fmaxf(mx, v[j]);
      }
#pragma unroll
      for (int o = 1; o < 8; o <<= 1) mx = fmaxf(mx, __shfl_xor(mx, o));
      float mold = mrun[srow];
      float mnew = fmaxf(mold, mx);
      float p[8], ts = 0.f, lacc = 0.f;
#pragma unroll
      for (int j = 0; j < 8; ++j) {
        p[j] = __expf(v[j] - mnew);
        ts += p[j];
        if (LAB) {
          int kidx = kt + i8 * 8 + j;
          lacc += p[j] * labv[(long)(kidx < S ? kidx : S - 1) * kB + b];
        }
      }
#pragma unroll
      for (int o = 1; o < 8; o <<= 1) ts += __shfl_xor(ts, o);
      if (LAB) {
#pragma unroll
        for (int o = 1; o < 8; o <<= 1) lacc += __shfl_xor(lacc, o);
      }
      u32x4 w0;
      w0.x = pk2bf(p[0], p[1]); w0.y = pk2bf(p[2], p[3]);
      w0.z = pk2bf(p[4], p[5]); w0.w = pk2bf(p[6], p[7]);
      *(u32x4*)&Plds[srow * 36 + i8 * 4] = w0;
      if (i8 == 0) {
        float sc = __expf(mold - mnew);
        mrun[srow] = mnew;
        lrun[srow] = lrun[srow] * sc + ts;
        scal[srow] = sc;
        if (LAB) mka[srow] = mka[srow] * sc + lacc;
      }
    }
    __syncthreads();
    // rescale O (VALU), then PV (MFMA reads oacc as SrcC) using prefetched vreg
#pragma unroll
    for (int mi = 0; mi < 2; ++mi)
#pragma unroll
      for (int r = 0; r < 4; ++r) {
        float sc = scal[mi * 16 + fk * 4 + r];
#pragma unroll
        for (int n = 0; n < 8; ++n) oacc[mi][n][r] *= sc;
      }
    asm volatile("s_nop 7" ::: );  // VALU write -> MFMA SrcC read hazard
#pragma unroll
    for (int kk = 0; kk < 2; ++kk) {
      u32x4 ap0 = *(const u32x4*)&Plds[fr * 36 + kk * 16 + fk * 4];
      u32x4 ap1 = *(const u32x4*)&Plds[(16 + fr) * 36 + kk * 16 + fk * 4];
#pragma unroll
      for (int n = 0; n < 8; ++n) {
        mfma_bf16(oacc[0][n], ap0, vreg[kk][n]);
        mfma_bf16(oacc[1][n], ap1, vreg[kk][n]);
      }
    }
    asm volatile("s_nop 7\n\ts_nop 7" ::: );  // MFMA -> VALU (next rescale/epilogue)
    __syncthreads();
    if (more) {
#pragma unroll
      for (int kk = 0; kk < 4; ++kk) kcur[kk] = knxt[kk];
    }
  }
  asm volatile("s_nop 7\n\ts_nop 7" ::: );
#pragma unroll
  for (int mi = 0; mi < 2; ++mi)
#pragma unroll
    for (int r = 0; r < 4; ++r) {
      int qq = mi * 16 + fk * 4 + r;
      int gq = qt0 + qq;
      if (gq >= kHW) continue;
      float invl = 1.0f / lrun[qq];
      long orow = ((long)img * kR + (long)gq * kB + b) * kD;
#pragma unroll
      for (int n = 0; n < 8; ++n)
        O[orow + wid * 128 + n * 16 + fr] = f2bf(oacc[mi][n][r] * invl);
    }
  if (LAB && tid < 32) {
    int gq = qt0 + tid;
    if (gq < kHW) mkout[(long)img * kR + (long)gq * kB + b] = mka[tid] / lrun[tid];
  }
}

// row += bias; l2-normalize; fp32 in place + bf16 mirror; optional g = u.row
__global__ void k_bias_l2n(float* __restrict__ P, const float* __restrict__ bias, int C,
                           u16b* __restrict__ outb, const float* __restrict__ u,
                           float* __restrict__ g, int L) {
  __shared__ float red[2];
  long row = blockIdx.x;
  float* p = P + row * C;
  int tid = threadIdx.x;  // 128
  int nv = C >> 7;
  float v[4];
  float s = 0.f;
#pragma unroll
  for (int i = 0; i < 4; ++i)
    if (i < nv) {
      float x = p[tid + (i << 7)] + bias[tid + (i << 7)];
      v[i] = x;
      s += x * x;
    }
  s = wsum(s);
  if ((tid & 63) == 0) red[tid >> 6] = s;
  __syncthreads();
  float inv = 1.f / fmaxf(sqrtf(red[0] + red[1]), 1e-12f);
  float dot = 0.f;
#pragma unroll
  for (int i = 0; i < 4; ++i)
    if (i < nv) {
      float x = v[i] * inv;
      p[tid + (i << 7)] = x;
      outb[row * C + tid + (i << 7)] = f2bf(x);
      if (u) dot += x * u[tid + (i << 7)];
    }
  if (u) {
    __syncthreads();
    dot = wsum(dot);
    if ((tid & 63) == 0) red[tid >> 6] = dot;
    __syncthreads();
    if (tid == 0) {
      int img = (int)(row / kR);
      int within = (int)(row % kR);
      int qq = within >> 3, b = within & 7;
      g[((long)(img * 8 + b)) * L + qq] = red[0] + red[1];
    }
  }
}

// generic softmax; optional bf16 out at row*ldo
__global__ __launch_bounds__(256) void k_softmax(float* __restrict__ S, int Lq, int Lk,
                                                 u16b* __restrict__ outb, int ldo) {
  __shared__ float sm[1456];
  __shared__ float red[4];
  int row = blockIdx.x;
  float* Sr = S + (long)row * Lk;
  int tid = threadIdx.x;
  float mx = -3.0e38f;
  for (int k = tid; k < Lk; k += 256) {
    float v = Sr[k] * kTemp;
    sm[k] = v;
    mx = fmaxf(mx, v);
  }
  mx = wmax(mx);
  if ((tid & 63) == 0) red[tid >> 6] = mx;
  __syncthreads();
  mx = fmaxf(fmaxf(red[0], red[1]), fmaxf(red[2], red[3]));
  __syncthreads();
  float s = 0.f;
  for (int k = tid; k < Lk; k += 256) {
    float e = __expf(sm[k] - mx);
    sm[k] = e;
    s += e;
  }
  s = wsum(s);
  if ((tid & 63) == 0) red[tid >> 6] = s;
  __syncthreads();
  float inv = 1.0f / (red[0] + red[1] + red[2] + red[3]);
  for (int k = tid; k < Lk; k += 256) {
    float p = sm[k] * inv;
    if (outb) outb[(long)row * ldo + k] = f2bf(p); else Sr[k] = p;
  }
}

// fused cR + softmax + lab-dot: block z in [0,48)
__global__ __launch_bounds__(256) void k_cwi(const float* __restrict__ vb,
                                             const u16b* __restrict__ Krb,
                                             const float* __restrict__ labv,
                                             float* __restrict__ wI,
                                             float* __restrict__ mki8) {
  __shared__ float sm[kL];
  __shared__ float vbl[kKD];
  __shared__ float red[4];
  int z = blockIdx.x, b = z & 7;
  int tid = threadIdx.x;
  if (tid < kKD) vbl[tid] = vb[(long)z * kKD + tid];
  __syncthreads();
  float mx = -3.0e38f;
  for (int k = tid; k < kL; k += 256) {
    const u16b* kp = Krb + ((long)k * kB + b) * kKD;
    float s = 0.f;
    for (int c = 0; c < kKD; c += 8) {
      u32x4 w = *(const u32x4*)(kp + c);
      s += vbl[c] * bf2f((u16b)(w.x & 0xFFFF)) + vbl[c + 1] * bf2f((u16b)(w.x >> 16));
      s += vbl[c + 2] * bf2f((u16b)(w.y & 0xFFFF)) + vbl[c + 3] * bf2f((u16b)(w.y >> 16));
      s += vbl[c + 4] * bf2f((u16b)(w.z & 0xFFFF)) + vbl[c + 5] * bf2f((u16b)(w.z >> 16));
      s += vbl[c + 6] * bf2f((u16b)(w.w & 0xFFFF)) + vbl[c + 7] * bf2f((u16b)(w.w >> 16));
    }
    sm[k] = s * kTemp;
    mx = fmaxf(mx, sm[k]);
  }
  mx = wmax(mx);
  if ((tid & 63) == 0) red[tid >> 6] = mx;
  __syncthreads();
  mx = fmaxf(fmaxf(red[0], red[1]), fmaxf(red[2], red[3]));
  __syncthreads();
  float s = 0.f;
  for (int k = tid; k < kL; k += 256) {
    float e = __expf(sm[k] - mx);
    sm[k] = e;
    s += e;
  }
  s = wsum(s);
  if ((tid & 63) == 0) red[tid >> 6] = s;
  __syncthreads();
  float inv = 1.0f / (red[0] + red[1] + red[2] + red[3]);
  __syncthreads();
  float dot = 0.f;
  for (int k = tid; k < kL; k += 256) {
    float p = sm[k] * inv;
    wI[(long)z * kL + k] = p;
    dot += p * labv[(long)k * kB + b];
  }
  dot = wsum(dot);
  if ((tid & 63) == 0) red[tid >> 6] = dot;
  __syncthreads();
  if (tid == 0) mki8[z] = red[0] + red[1] + red[2] + red[3];
}

// deterministic rank-1 AV, phase A: row2[(z*8+c)*kD+d] = sum_{k in chunk c} g*seq
__global__ void k_wrowA(const float* __restrict__ g, const float* __restrict__ seq,
                        float* __restrict__ row2) {
  int z = blockIdx.y, img = z >> 3, b = z & 7;
  int c = blockIdx.z;
  int d = blockIdx.x * 128 + threadIdx.x;
  int k0 = c * 61;
  int k1 = min(kHW, k0 + 61);
  float s = 0.f;
  for (int k = k0; k < k1; ++k)
    s += g[(long)z * kHW + k] * seq[((long)img * kR + (long)k * kB + b) * kD + d];
  row2[((long)z * 8 + c) * kD + d] = s;
}

// phase B: row[z*kD+d] = sum_c row2 (fixed order)
__global__ void k_wrowB(const float* __restrict__ row2, float* __restrict__ row) {
  int idx = blockIdx.x * 256 + threadIdx.x;  // 0..48*512
  int z = idx >> 9, d = idx & 511;
  float s = 0.f;
#pragma unroll
  for (int c = 0; c < 8; ++c) s += row2[((long)z * 8 + c) * kD + d];
  row[(long)z * kD + d] = s;
}

// fp32 inorm phase 1 (encoder)
__global__ __launch_bounds__(256) void k_ss1f(const float* __restrict__ A,
                                              const float* __restrict__ B2,
                                              float* __restrict__ part) {
  __shared__ float red[4];
  long r = blockIdx.x;
  int tid = threadIdx.x;
  long base = r * kD;
  float z0 = A[base + tid] + B2[base + tid];
  float z1 = A[base + tid + 256] + B2[base + tid + 256];
  float s = z0 * z0 + z1 * z1;
  s = wsum(s);
  if ((tid & 63) == 0) red[tid >> 6] = s;
  __syncthreads();
  if (tid == 0) part[r] = red[0] + red[1] + red[2] + red[3];
}

// fp32 inorm phase 3 (encoder): fp32 out + bf16 mirror
__global__ __launch_bounds__(256) void k_scale1f(const float* __restrict__ A,
                                                 const float* __restrict__ B2,
                                                 float* __restrict__ outp,
                                                 const float* __restrict__ ss,
                                                 u16b* __restrict__ ob) {
  long r = blockIdx.x;
  int l = (int)(r / kB), b = (int)(r % kB);
  int g = (l / kHW) * kB + b;
  int tid = threadIdx.x;
  float fac = kScaleN * sqrtf(kCnt / (ss[g] + 1e-5f));
  long base = r * kD;
  float x0 = (A[base + tid] + B2[base + tid]) * fac;
  float x1 = (A[base + tid + 256] + B2[base + tid + 256]) * fac;
  outp[base + tid] = x0;
  outp[base + tid + 256] = x1;
  ob[base + tid] = f2bf(x0);
  ob[base + tid + 256] = f2bf(x1);
}

// t1 inorm, phase 1 (B2 bf16)
__global__ __launch_bounds__(256) void k_ss1b(const float* __restrict__ A,
                                              const u16b* __restrict__ B2,
                                              float* __restrict__ part) {
  __shared__ float red[4];
  long r = blockIdx.x;
  int tid = threadIdx.x;
  long base = r * kD;
  float z0 = A[base + tid] + bf2f(B2[base + tid]);
  float z1 = A[base + tid + 256] + bf2f(B2[base + tid + 256]);
  float s = z0 * z0 + z1 * z1;
  s = wsum(s);
  if ((tid & 63) == 0) red[tid >> 6] = s;
  __syncthreads();
  if (tid == 0) part[r] = red[0] + red[1] + red[2] + red[3];
}

__global__ void k_ssred(const float* __restrict__ part, float* __restrict__ ss, int R, int NG) {
  __shared__ float red[8];
  int g = blockIdx.x, v = blockIdx.y;
  int n = g / kB, b = g % kB;
  int tid = threadIdx.x;  // 512
  float s = 0.f;
  for (int p = tid; p < kHW; p += 512) s += part[(long)v * R + ((long)(n * kHW + p) * kB + b)];
  s = wsum(s);
  if ((tid & 63) == 0) red[tid >> 6] = s;
  __syncthreads();
  if (tid == 0) {
    float t = 0.f;
#pragma unroll
    for (int i = 0; i < 8; ++i) t += red[i];
    ss[(long)v * NG + g] = t;
  }
}

// t1 inorm, phase 3 -> bf16 only
__global__ __launch_bounds__(256) void k_scale1b(const float* __restrict__ A,
                                                 const u16b* __restrict__ B2,
                                                 const float* __restrict__ ss,
                                                 u16b* __restrict__ ob) {
  long r = blockIdx.x;
  int img = (int)(r / kR), b = (int)(r & 7);
  int g = img * 8 + b;
  int tid = threadIdx.x;
  float fac = kScaleN * sqrtf(kCnt / (ss[g] + 1e-5f));
  long base = r * kD;
  ob[base + tid] = f2bf((A[base + tid] + bf2f(B2[base + tid])) * fac);
  ob[base + tid + 256] = f2bf((A[base + tid + 256] + bf2f(B2[base + tid + 256])) * fac);
}

// ti8[z,d] = row[z,d] * scale(kHW * ||row||^2)
__global__ void k_ti8(const float* __restrict__ row, float* __restrict__ ti8) {
  __shared__ float red[4];
  int z = blockIdx.x;
  int tid = threadIdx.x;  // 256
  float r0 = row[(long)z * kD + tid], r1 = row[(long)z * kD + tid + 256];
  float s = r0 * r0 + r1 * r1;
  s = wsum(s);
  if ((tid & 63) == 0) red[tid >> 6] = s;
  __syncthreads();
  float ssv = (float)kHW * (red[0] + red[1] + red[2] + red[3]);
  float fac = kScaleN * sqrtf(kCnt / (ssv + 1e-5f));
  ti8[(long)z * kD + tid] = r0 * fac;
  ti8[(long)z * kD + tid + 256] = r1 * fac;
}

// vb[z,:] = l2n(ti8_z @ WkC + bkC)
__global__ void k_vb(const float* __restrict__ ti8, const float* __restrict__ Wk,
                     const float* __restrict__ bk, float* __restrict__ vb) {
  __shared__ float part[4][128];
  __shared__ float red[2];
  int z = blockIdx.x;
  int j = threadIdx.x;
  int dz = threadIdx.y;
  const float* row = ti8 + (long)z * kD;
  float acc = 0.f;
  int d0 = dz * 128;
  for (int d = d0; d < d0 + 128; ++d) acc += row[d] * Wk[(long)d * kKD + j];
  part[dz][j] = acc;
  __syncthreads();
  if (dz == 0) {
    float a = part[0][j] + part[1][j] + part[2][j] + part[3][j] + bk[j];
    float s = a * a;
    s = wsum(s);
    if ((j & 63) == 0) red[j >> 6] = s;
    part[0][j] = a;
  }
  __syncthreads();
  if (dz == 0) {
    float inv = 1.f / fmaxf(sqrtf(red[0] + red[1]), 1e-12f);
    vb[(long)z * kKD + j] = part[0][j] * inv;
  }
}

// ci8[z,d] = sum_l wI[z,l] * VrT[b][d][l]
__global__ void k_ci8(const float* __restrict__ wI, const u16b* __restrict__ VrT,
                      float* __restrict__ ci8) {
  int idx = blockIdx.x * 4 + (threadIdx.x >> 6);
  int z = idx >> 9, d = idx & 511;
  int b = z & 7;
  int lane = threadIdx.x & 63;
  const float* w = wI + (long)z * kL;
  const u16b* vt = VrT + ((long)b * kD + d) * kLp;
  float s = 0.f;
  for (int l = lane; l < kL; l += 64) s += w[l] * bf2f(vt[l]);
  s = wsum(s);
  if (lane == 0) ci8[(long)z * kD + d] = s;
}

// tail partials: v in {a^2, b^2, ab}, a = t1*mk, b = t1 + c3 (bf16 inputs)
__global__ __launch_bounds__(256) void k_ss3b(const u16b* __restrict__ t1b,
                                              const float* __restrict__ mkr,
                                              const u16b* __restrict__ c3b,
                                              float* __restrict__ part) {
  __shared__ float red[4][3];
  long r = blockIdx.x;
  int tid = threadIdx.x;
  long base = r * kD;
  float mk = mkr[r];
  float s0 = 0.f, s1 = 0.f, s2 = 0.f;
#pragma unroll
  for (int j = 0; j < 2; ++j) {
    int d = tid + j * 256;
    float t = bf2f(t1b[base + d]);
    float a = t * mk;
    float bb = t + bf2f(c3b[base + d]);
    s0 += a * a; s1 += bb * bb; s2 += a * bb;
  }
  int w = tid >> 6, lane = tid & 63;
  float t0 = wsum(s0), t1 = wsum(s1), t2 = wsum(s2);
  if (lane == 0) { red[w][0] = t0; red[w][1] = t1; red[w][2] = t2; }
  __syncthreads();
  if (tid < 3)
    part[(long)tid * kR6 + r] = red[0][tid] + red[1][tid] + red[2][tid] + red[3][tid];
}

// per-image coefficients + oi8 (imag analytic)
__global__ __launch_bounds__(512) void k_coef(const float* __restrict__ ssp,
                                              const float* __restrict__ ti8,
                                              const float* __restrict__ ci8,
                                              const float* __restrict__ mki8,
                                              float* __restrict__ coef,
                                              float* __restrict__ oi8) {
  __shared__ float cai[8], cbi[8];
  int img = blockIdx.x;
  int tid = threadIdx.x;
  int b = tid >> 6, lane = tid & 63;
  int z = img * 8 + b;
  float sT = 0.f, sU = 0.f, sV = 0.f;
  for (int d = lane; d < kD; d += 64) {
    float ti = ti8[(long)z * kD + d], ci = ci8[(long)z * kD + d];
    float u = ti + ci;
    sT += ti * ti; sU += u * u; sV += ti * u;
  }
  sT = wsum(sT); sU = wsum(sU); sV = wsum(sV);
  if (lane == 0) {
    float SSa = ssp[z], SSb = ssp[48 + z], SSab = ssp[96 + z];
    float f2 = kScaleN * sqrtf(kCnt / (SSa + 1e-5f));
    float f4 = kScaleN * sqrtf(kCnt / (SSb + 1e-5f));
    float ssz = f2 * f2 * SSa + f4 * f4 * SSb + 2.f * f2 * f4 * SSab;
    float fac = kScaleN * sqrtf(kCnt / (ssz + 1e-5f));
    coef[img * 16 + b] = f2 * fac;
    coef[img * 16 + 8 + b] = f4 * fac;
    float mk = mki8[z];
    float SSai = (float)kHW * mk * mk * sT;
    float SSbi = (float)kHW * sU;
    float SSabi = (float)kHW * mk * sV;
    float f2i = kScaleN * sqrtf(kCnt / (SSai + 1e-5f));
    float f4i = kScaleN * sqrtf(kCnt / (SSbi + 1e-5f));
    float sszi = f2i * f2i * SSai + f4i * f4i * SSbi + 2.f * f2i * f4i * SSabi;
    float faci = kScaleN * sqrtf(kCnt / (sszi + 1e-5f));
    cai[b] = f2i * faci;
    cbi[b] = f4i * faci;
  }
  __syncthreads();
#pragma unroll
  for (int j = 0; j < 8; ++j) {
    int i = tid * 8 + j;
    int bb = i >> 9, d = i & 511;
    int zz = img * 8 + bb;
    float ti = ti8[(long)zz * kD + d], ci = ci8[(long)zz * kD + d];
    oi8[(long)img * 4096 + i] = ti * mki8[zz] * cai[bb] + (ti + ci) * cbi[bb];
  }
}

// oadd[img][o*8+b] = Wc_imag_row(o) . oi8[img*8+b]
__global__ void k_oadd(const float* __restrict__ Wc, const float* __restrict__ oi8,
                       float* __restrict__ oadd) {
  int idx = blockIdx.x * 4 + (threadIdx.x >> 6);
  int img = idx >> 12, rem = idx & 4095;
  int o = rem >> 3, b = rem & 7;
  int lane = threadIdx.x & 63;
  const float* wrow = Wc + (long)o * 1024 + 512;
  const float* oi = oi8 + (long)img * 4096 + (long)b * kD;
  float s = 0.f;
  for (int d = lane; d < kD; d += 64) s += wrow[d] * oi[d];
  s = wsum(s);
  if (lane == 0) oadd[(long)img * 4096 + o * 8 + b] = s;
}

// t2b[r][d] = bf16( t1*mk*ca + (t1+c3)*cb )
__global__ __launch_bounds__(256) void k_zfinb(const u16b* __restrict__ t1b,
                                               const float* __restrict__ mkr,
                                               const u16b* __restrict__ c3b,
                                               const float* __restrict__ coef,
                                               u16b* __restrict__ t2b) {
  long r = blockIdx.x;
  int img = (int)(r / kR), b = (int)(r & 7);
  int tid = threadIdx.x;
  float mk = mkr[r];
  float ca = coef[img * 16 + b], cb = coef[img * 16 + 8 + b];
  long base = r * kD;
#pragma unroll
  for (int j = 0; j < 2; ++j) {
    int d = tid + j * 256;
    float t = bf2f(t1b[base + d]);
    float ov = t * mk * ca + (t + bf2f(c3b[base + d])) * cb;
    t2b[base + d] = f2bf(ov);
  }
}

template <int BM, int BN, bool AF32, bool ACC>
void gemm(hipStream_t s, const void* A, const u16b* B, float* C, int M, int N, int K, int lda,
          int ldb, int ldc, long sA1, long sA2, long sB1, long sB2, long sC1, long sC2,
          int batch, const float* addv = nullptr) {
  dim3 grd(CDIV(N, BN), CDIV(M, BM), batch), blk(256);
  k_gemm<BM, BN, AF32, ACC><<<grd, blk, 0, s>>>(A, B, C, M, N, K, lda, ldb, ldc, sA1, sA2,
                                                sB1, sB2, sC1, sC2, addv);
}

}  // namespace

extern "C" void kernel_launch(void* const* d_in, const int* in_sizes, int n_in, void* d_out,
                              int out_size, void* d_ws, size_t ws_size, hipStream_t stream) {
  (void)in_sizes; (void)n_in; (void)out_size;
  const float* tf  = (const float*)d_in[0];
  const float* sf  = (const float*)d_in[1];
  const float* tl  = (const float*)d_in[2];
  const float* WkE = (const float*)d_in[3];
  const float* bkE = (const float*)d_in[4];
  const float* WkS = (const float*)d_in[5];
  const float* bkS = (const float*)d_in[6];
  const float* WkC = (const float*)d_in[7];
  const float* bkC = (const float*)d_in[8];
  const float* Wc  = (const float*)d_in[9];
  float* out = (float*)d_out;
  float* ws = (float*)d_ws;

  const long LBD = (long)kL * kB * kD;
  const long LBK = (long)kL * kB * kKD;

  long off = 0;
  auto alloc = [&](long n) { long o = off; off += (n + 255) & ~255L; return o; };
  auto allocU = [&](long nu) { return alloc((nu + 1) / 2); };

  long o_seqT = alloc(LBD);
  long o_seqS = alloc(LBD);
  long o_Kr   = alloc(LBK);
  long o_Krb  = allocU(LBK);
  long o_VrT  = allocU((long)kB * kD * kLp);
  long o_tfb  = allocU((long)kNI * kB * kD * kHWp);
  long o_sfb  = allocU((long)kNI * kB * kD * kHWp);
  long o_WkTE = allocU((long)kD * kD);
  long o_WkTS = allocU((long)kKD * kD);
  long o_WkTC = allocU((long)kKD * kD);
  long o_Wcb  = allocU((long)kD * 2 * kD);
  long o_lab  = alloc((long)kL * kB);
  long o_uS   = alloc(kKD);
  long o_vb   = alloc(48L * kKD);
  long o_g    = alloc(48L * kHW);
  long o_wI   = alloc(48L * kL);
  long o_row  = alloc(48L * kD);
  long o_row2 = alloc(48L * 8 * kD);
  long o_mkr  = alloc((long)kR6);
  long o_mki8 = alloc(48);
  long o_ti8  = alloc(48L * kD);
  long o_ci8  = alloc(48L * kD);
  long o_oi8  = alloc(48L * kD);
  long o_oadd = alloc(6L * kD * 8);
  long o_ss   = alloc(512);
  long o_part = alloc(3L * kR6);
  long o_scr  = off;

  // encoder overlay
  long o_Pe  = o_scr;
  long o_Peb = o_Pe + LBD;
  long o_Ae  = o_Peb + LBD / 2;
  long o_Aeb = o_Ae + (long)kB * kL * kL;
  long enc_end = o_Aeb + (8L * kL * kLp + 1) / 2;
  long o_ar  = o_Pe;   // after Pe dead
  long o_mr  = o_Ae;   // after Ae dead

  // decoder overlay (batched over 6 images)
  long p = o_scr;
  auto nxt = [&](long n) { long o = p; p += (n + 255) & ~255L; return o; };
  long o_Ps   = nxt((long)kR6 * kKD);
  long o_Psb  = nxt(((long)kR6 * kKD + 1) / 2);
  long o_Pcb  = nxt(((long)kR6 * kKD + 1) / 2);
  long o_s2rb = nxt(((long)kR6 * kD + 1) / 2);
  long o_t1rb = nxt(((long)kR6 * kD + 1) / 2);
  long o_c3rb = nxt(((long)kR6 * kD + 1) / 2);
  long o_t2b  = nxt(((long)kR6 * kD + 1) / 2);
  long img_end = p;

  long total = (enc_end > img_end ? enc_end : img_end);
  if ((size_t)total * sizeof(float) > ws_size) return;

  float* seqT = ws + o_seqT;
  float* Kr = ws + o_Kr;
  u16b* Krb = (u16b*)(ws + o_Krb);
  u16b* VrT = (u16b*)(ws + o_VrT);
  u16b* tfb = (u16b*)(ws + o_tfb);
  float* lab = ws + o_lab;
  float* uS = ws + o_uS;
  float* vb = ws + o_vb;
  float* g_ = ws + o_g;
  float* wI = ws + o_wI;
  float* row = ws + o_row;
  float* row2 = ws + o_row2;
  float* mkr = ws + o_mkr;
  float* mki8 = ws + o_mki8;
  float* ti8 = ws + o_ti8;
  float* ci8 = ws + o_ci8;
  float* oi8 = ws + o_oi8;
  float* oadd = ws + o_oadd;
  float* ssp = ws + o_ss;
  float* coef = ssp + 160;
  float* part = ws + o_part;
  float* Pe = ws + o_Pe;
  u16b* Peb = (u16b*)(ws + o_Peb);
  float* Ae = ws + o_Ae;
  u16b* Aeb = (u16b*)(ws + o_Aeb);
  float* ar = ws + o_ar;
  float* mr = ws + o_mr;
  u16b* mrb = (u16b*)(ws + o_mr + LBD);
  float* Ps = ws + o_Ps;
  u16b* Psb = (u16b*)(ws + o_Psb);
  u16b* Pcb = (u16b*)(ws + o_Pcb);
  u16b* s2rb = (u16b*)(ws + o_s2rb);
  u16b* t1rb = (u16b*)(ws + o_t1rb);
  u16b* c3rb = (u16b*)(ws + o_c3rb);
  u16b* t2b = (u16b*)(ws + o_t2b);
  u16b* WkTE = (u16b*)(ws + o_WkTE);
  u16b* WkTS = (u16b*)(ws + o_WkTS);
  u16b* WkTC = (u16b*)(ws + o_WkTC);
  u16b* Wcb = (u16b*)(ws + o_Wcb);

  // ---- stage 0 ----
  {
    dim3 grd(CDIV(kHW, 32), CDIV(kD, 32), kNI * kB), blk(32, 8);
    k_toseq<<<grd, blk, 0, stream>>>(tf, seqT);
    k_toseq<<<grd, blk, 0, stream>>>(sf, ws + o_seqS);
  }
  k_cvt2d<<<kNI * kB * kD, 256, 0, stream>>>(tf, tfb, kHW, kHWp);
  k_cvt2d<<<kNI * kB * kD, 256, 0, stream>>>(sf, (u16b*)(ws + o_sfb), kHW, kHWp);
  k_cvt2d<<<kD, 256, 0, stream>>>(Wc, Wcb, 2 * kD, 2 * kD);
  k_tcvt<<<dim3(kD / 32, kD / 32), dim3(32, 8), 0, stream>>>(WkE, WkTE, kD, kD);
  k_tcvt<<<dim3(kKD / 32, kD / 32), dim3(32, 8), 0, stream>>>(WkS, WkTS, kD, kKD);
  k_tcvt<<<dim3(kKD / 32, kD / 32), dim3(32, 8), 0, stream>>>(WkC, WkTC, kD, kKD);
  k_lab<<<CDIV(kNI * kB * kHW, 256), 256, 0, stream>>>(tl, lab);
  k_l2n_vec<<<1, 128, 0, stream>>>(bkS, uS, kKD);

  // ---- encoder (imag branch dead) ----
  gemm<64, 128, true, false>(stream, seqT, WkTE, Pe, kL * kB, kD, kD, kD, kD, kD,
                             0, 0, 0, 0, 0, 0, 1);
  k_bias_l2n<<<kL * kB, 128, 0, stream>>>(Pe, bkE, kD, Peb, nullptr, nullptr, 0);
  gemm<128, 128, false, false>(stream, Peb, Peb, Ae, kL, kL, kD, kB * kD, kB * kD, kL,
                               0, kD, 0, kD, 0, (long)kL * kL, 8);
  k_softmax<<<kB * kL, 256, 0, stream>>>(Ae, kL, kL, Aeb, kLp);
  gemm<64, 128, false, false>(stream, Aeb, tfb, ar, kL, kD, kHW, kLp, kHWp, kB * kD,
                              0, (long)kL * kLp, 0, (long)kD * kHWp, 0, kD, 8);
  gemm<64, 128, false, true>(stream, Aeb + kHW, tfb + (long)kB * kD * kHWp, ar, kL, kD, kHW,
                             kLp, kHWp, kB * kD, 0, (long)kL * kLp, 0, (long)kD * kHWp, 0, kD,
                             8);
  gemm<64, 128, false, true>(stream, Aeb + 2 * kHW, tfb + 2L * kB * kD * kHWp, ar, kL, kD,
                             kHW, kLp, kHWp, kB * kD, 0, (long)kL * kLp, 0, (long)kD * kHWp,
                             0, kD, 8);
  // mem_r = inorm(seqT + ar)
  k_ss1f<<<kL * kB, 256, 0, stream>>>(seqT, ar, part);
  k_ssred<<<dim3(kNI * kB, 1), 512, 0, stream>>>(part, ssp, kL * kB, kNI * kB);
  k_scale1f<<<kL * kB, 256, 0, stream>>>(seqT, ar, mr, ssp, mrb);
  k_vrt<<<dim3(CDIV(kL, 32), kD / 32, kB), dim3(32, 8), 0, stream>>>(mr, lab, VrT);
  gemm<64, 64, false, false>(stream, mrb, WkTC, Kr, kL * kB, kKD, kD, kD, kD, kKD,
                             0, 0, 0, 0, 0, 0, 1);
  k_bias_l2n<<<kL * kB, 128, 0, stream>>>(Kr, bkC, kKD, Krb, nullptr, nullptr, 0);

  // ---- decoder (fully batched over 48 = 6 img x 8 b) ----
  gemm<64, 128, true, false>(stream, seqT, WkTS, Ps, kR6, kKD, kD, kD, kD, kKD,
                             0, 0, 0, 0, 0, 0, 1);
  k_bias_l2n<<<kR6, 128, 0, stream>>>(Ps, bkS, kKD, Psb, uS, g_, kHW);
  k_softmax<<<48, 256, 0, stream>>>(g_, 1, kHW, nullptr, 0);  // wi rows
  k_wrowA<<<dim3(kD / 128, 48, 8), 128, 0, stream>>>(g_, seqT, row2);
  k_wrowB<<<48 * kD / 256, 256, 0, stream>>>(row2, row);
  k_ti8<<<48, 256, 0, stream>>>(row, ti8);
  k_vb<<<48, dim3(128, 4), 0, stream>>>(ti8, WkC, bkC, vb);
  // self-attention flash: s2r
  k_flash<false, true, true><<<768, 256, 0, stream>>>(Psb, Psb, tfb, nullptr, s2rb,
                                                      nullptr, kHW, kHWp);
  // t1r = inorm(t + s2r) -> bf16
  k_ss1b<<<kR6, 256, 0, stream>>>(seqT, s2rb, part);
  k_ssred<<<dim3(48, 1), 512, 0, stream>>>(part, ssp, kR6, 48);
  k_scale1b<<<kR6, 256, 0, stream>>>(seqT, s2rb, ssp, t1rb);
  // cross projection
  gemm<64, 128, false, false>(stream, t1rb, WkTC, Ps, kR6, kKD, kD, kD, kD, kKD,
                              0, 0, 0, 0, 0, 0, 1);
  k_bias_l2n<<<kR6, 128, 0, stream>>>(Ps, bkC, kKD, Pcb, nullptr, nullptr, 0);
  // imag branch (q-independent)
  k_cwi<<<48, 256, 0, stream>>>(vb, Krb, lab, wI, mki8);
  k_ci8<<<48 * 512 / 4, 256, 0, stream>>>(wI, VrT, ci8);
  // cross flash: c3r + mkr
  k_flash<true, false, false><<<768, 256, 0, stream>>>(Pcb, Krb, VrT, lab, c3rb,
                                                       mkr, kL, kLp);
  // fused tail
  k_ss3b<<<kR6, 256, 0, stream>>>(t1rb, mkr, c3rb, part);
  k_ssred<<<dim3(48, 3), 512, 0, stream>>>(part, ssp, kR6, 48);
  k_coef<<<6, 512, 0, stream>>>(ssp, ti8, ci8, mki8, coef, oi8);
  k_oadd<<<6 * 4096 / 4, 256, 0, stream>>>(Wc, oi8, oadd);
  k_zfinb<<<kR6, 256, 0, stream>>>(t1rb, mkr, c3rb, coef, t2b);
  // 1x1 conv: batch 48, K=512 real + rank-1 imag epilogue
  gemm<64, 64, false, false>(stream, Wcb, t2b, out, kD, kHW, kD, 2 * kD, kB * kD, kHW,
                             0, 0, (long)kR * kD, kD, 8L * kD * kHW, (long)kD * kHW, 48, oadd);
}